// Round 1
// baseline (7174.803 us; speedup 1.0000x reference)
//
#include <hip/hip_runtime.h>
#include <hip/hip_bf16.h>
#include <math.h>

#define TPB 256

// ---------------------------------------------------------------- conv 3x3
// generic direct conv: in (B,Ci,H,W) -> out (B,Co,Ho,Wo), pad=1, stride s
__global__ void conv3x3_kernel(const float* __restrict__ in,
                               const float* __restrict__ w,
                               const float* __restrict__ bias,
                               float* __restrict__ out,
                               int B, int Ci, int H, int W,
                               int Co, int Ho, int Wo, int stride)
{
    int idx = blockIdx.x * TPB + threadIdx.x;
    int total = B * Co * Ho * Wo;
    if (idx >= total) return;
    int wo = idx % Wo;
    int t  = idx / Wo;
    int ho = t % Ho;  t /= Ho;
    int co = t % Co;
    int bb = t / Co;

    float acc = bias ? bias[co] : 0.0f;
    int iy0 = ho * stride - 1;
    int ix0 = wo * stride - 1;
    for (int c = 0; c < Ci; ++c) {
        const float* xp = in + ((size_t)(bb * Ci + c)) * H * W;
        const float* wp = w + ((size_t)(co * Ci + c)) * 9;
#pragma unroll
        for (int ky = 0; ky < 3; ++ky) {
            int iy = iy0 + ky;
            if (iy < 0 || iy >= H) continue;
#pragma unroll
            for (int kx = 0; kx < 3; ++kx) {
                int ix = ix0 + kx;
                if (ix < 0 || ix >= W) continue;
                acc += wp[ky * 3 + kx] * xp[iy * W + ix];
            }
        }
    }
    out[idx] = acc;
}

// ---------------------------------------------------------------- deform conv
// torchvision DeformConv2d, 3x3, dilation 1, pad 1.
// Block = 256 threads. G = 256/O groups; each group computes O channels for
// PW pixels (PW accumulators per thread). P = G*PW pixels per block.
template <int C, int O, int PW>
__global__ void deform_kernel(const float* __restrict__ x,
                              const float* __restrict__ off,
                              const float* __restrict__ w,
                              const float* __restrict__ bias,
                              float* __restrict__ out,
                              int B, int H, int W, int Ho, int Wo, int stride)
{
    constexpr int G = TPB / O;
    constexpr int P = G * PW;
    __shared__ float samp[P][C * 9];
    __shared__ int   sidx[P * 9][4];
    __shared__ float swt[P * 9][4];

    const int tid = threadIdx.x;
    const int HW = Ho * Wo;
    const int total = B * HW;
    const int pix0 = blockIdx.x * P;

    // phase 1: bilinear corner indices + weights per (pixel, tap)
    for (int item = tid; item < P * 9; item += TPB) {
        int p = item / 9, k = item % 9;
        int pix = pix0 + p;
        if (pix < total) {
            int bb = pix / HW, r = pix % HW, ho = r / Wo, wo = r % Wo;
            float dy = off[((size_t)(bb * 18 + 2 * k) * Ho + ho) * Wo + wo];
            float dx = off[((size_t)(bb * 18 + 2 * k + 1) * Ho + ho) * Wo + wo];
            float ys = (float)(ho * stride - 1 + k / 3) + dy;
            float xs = (float)(wo * stride - 1 + k % 3) + dx;
            float y0f = floorf(ys), x0f = floorf(xs);
            float fy = ys - y0f, fx = xs - x0f;
            int y0 = (int)y0f, x0 = (int)x0f;
            float wts[4] = { (1.f - fy) * (1.f - fx), (1.f - fy) * fx,
                             fy * (1.f - fx),          fy * fx };
#pragma unroll
            for (int j = 0; j < 4; ++j) {
                int iy = y0 + (j >> 1);
                int ix = x0 + (j & 1);
                bool v = (iy >= 0) && (iy < H) && (ix >= 0) && (ix < W);
                sidx[item][j] = v ? (iy * W + ix) : -1;
                swt[item][j]  = wts[j];
            }
        } else {
#pragma unroll
            for (int j = 0; j < 4; ++j) { sidx[item][j] = -1; swt[item][j] = 0.f; }
        }
    }
    __syncthreads();

    // phase 2: gather bilinear samples for every (pixel, channel, tap)
    for (int item = tid; item < P * C * 9; item += TPB) {
        int p = item / (C * 9);
        int ck = item % (C * 9);
        int c = ck / 9, k = ck % 9;
        int pix = pix0 + p;
        float v = 0.f;
        if (pix < total) {
            int bb = pix / HW;
            const float* xp = x + ((size_t)(bb * C + c)) * H * W;
            int e = p * 9 + k;
#pragma unroll
            for (int j = 0; j < 4; ++j) {
                int id = sidx[e][j];
                if (id >= 0) v += swt[e][j] * xp[id];
            }
        }
        samp[p][ck] = v;
    }
    __syncthreads();

    // phase 3: MAC. thread -> output channel o, group g handles PW pixels
    int g = tid / O;
    int o = tid % O;
    float acc[PW];
#pragma unroll
    for (int pi = 0; pi < PW; ++pi) acc[pi] = bias[o];
    for (int c = 0; c < C; ++c) {
#pragma unroll
        for (int k = 0; k < 9; ++k) {
            float wv = w[((size_t)(o * C + c)) * 9 + k];
#pragma unroll
            for (int pi = 0; pi < PW; ++pi)
                acc[pi] += wv * samp[g * PW + pi][c * 9 + k];
        }
    }
#pragma unroll
    for (int pi = 0; pi < PW; ++pi) {
        int pix = pix0 + g * PW + pi;
        if (pix < total) {
            int bb = pix / HW, r = pix % HW;
            out[((size_t)(bb * O + o)) * HW + r] = acc[pi];
        }
    }
}

// ---------------------------------------------------------------- avgpool 4x4
__global__ void avgpool4_kernel(const float* __restrict__ in,
                                float* __restrict__ out,
                                int BC, int Ho, int Wo, int H, int W)
{
    int idx = blockIdx.x * TPB + threadIdx.x;
    int total = BC * Ho * Wo;
    if (idx >= total) return;
    int wo = idx % Wo;
    int t = idx / Wo;
    int ho = t % Ho;
    int bc = t / Ho;
    const float* xp = in + (size_t)bc * H * W + (ho * 4) * W + wo * 4;
    float s = 0.f;
#pragma unroll
    for (int i = 0; i < 4; ++i)
#pragma unroll
        for (int j = 0; j < 4; ++j)
            s += xp[i * W + j];
    out[idx] = s * (1.0f / 16.0f);
}

// ------------------------------------------------- skip: d1 += 1x1conv(pool)
__global__ void skip_add_kernel(float* __restrict__ d1,
                                const float* __restrict__ pool,
                                const float* __restrict__ wsk,
                                const float* __restrict__ bsk,
                                int B, int HW)
{
    int idx = blockIdx.x * TPB + threadIdx.x;
    int total = B * 64 * HW;
    if (idx >= total) return;
    int r = idx % HW;
    int t = idx / HW;
    int o = t % 64;
    int bb = t / 64;
    const float* pp = pool + (size_t)bb * 3 * HW + r;
    float v = d1[idx] + bsk[o];
    v += wsk[o * 3 + 0] * pp[0];
    v += wsk[o * 3 + 1] * pp[HW];
    v += wsk[o * 3 + 2] * pp[2 * HW];
    d1[idx] = v;
}

// ---------------------------------------------------------------- batchnorm
__global__ void zero_stats_kernel(float* __restrict__ stats)
{
    if (threadIdx.x < 128) stats[threadIdx.x] = 0.f;
}

__global__ void bn_stats_kernel(const float* __restrict__ in,
                                float* __restrict__ stats,
                                int C, int HW)
{
    int bc = blockIdx.x;           // over B*C planes
    int c = bc % C;
    const float* p = in + (size_t)bc * HW;
    float s = 0.f, s2 = 0.f;
    for (int i = threadIdx.x; i < HW; i += TPB) {
        float v = p[i];
        s += v;
        s2 += v * v;
    }
    __shared__ float ss[TPB], sq[TPB];
    ss[threadIdx.x] = s;
    sq[threadIdx.x] = s2;
    __syncthreads();
    for (int st = TPB / 2; st > 0; st >>= 1) {
        if (threadIdx.x < st) {
            ss[threadIdx.x] += ss[threadIdx.x + st];
            sq[threadIdx.x] += sq[threadIdx.x + st];
        }
        __syncthreads();
    }
    if (threadIdx.x == 0) {
        atomicAdd(&stats[c * 2], ss[0]);
        atomicAdd(&stats[c * 2 + 1], sq[0]);
    }
}

__global__ void bn_apply_kernel(const float* __restrict__ in,
                                const float* __restrict__ stats,
                                float* __restrict__ out,
                                int C, int HW, int total, float invN)
{
    int idx = blockIdx.x * TPB + threadIdx.x;
    if (idx >= total) return;
    int c = (idx / HW) % C;
    float mean = stats[c * 2] * invN;
    float var = stats[c * 2 + 1] * invN - mean * mean;
    float r = rsqrtf(var + 1e-5f);
    float v = (in[idx] - mean) * r;
    out[idx] = v > 0.f ? v : 0.f;
}

// ---------------------------------------------------------------- launch
extern "C" void kernel_launch(void* const* d_in, const int* in_sizes, int n_in,
                              void* d_out, int out_size, void* d_ws, size_t ws_size,
                              hipStream_t stream)
{
    const float* x      = (const float*)d_in[0];
    const float* w_off1 = (const float*)d_in[1];
    const float* b_off1 = (const float*)d_in[2];
    const float* w_d1   = (const float*)d_in[3];
    const float* b_d1   = (const float*)d_in[4];
    const float* w_skip = (const float*)d_in[5];
    const float* b_skip = (const float*)d_in[6];
    const float* w_bl1  = (const float*)d_in[7];
    const float* w_bl2  = (const float*)d_in[8];
    const float* w_off2 = (const float*)d_in[9];
    const float* b_off2 = (const float*)d_in[10];
    const float* w_d2   = (const float*)d_in[11];
    const float* b_d2   = (const float*)d_in[12];
    const float* w_off3 = (const float*)d_in[13];
    const float* b_off3 = (const float*)d_in[14];
    const float* w_d3   = (const float*)d_in[15];
    const float* b_d3   = (const float*)d_in[16];

    const int B = 8;
    // workspace layout (floats):
    //   A    : 3,686,400  (offset1; reused for pool / offset2 / offset3)
    //   bufB : 13,107,200
    //   bufC : 13,107,200
    //   stats: 128
    float* A     = (float*)d_ws;
    float* bufB  = A + 3686400;
    float* bufC  = bufB + 13107200;
    float* stats = bufC + 13107200;

    float* out0 = (float*)d_out;                 // feat_1_4  (8,64,160,160)
    float* out1 = out0 + 13107200;               // feat_1_8  (8,64,80,80)
    float* out2 = out1 + 3276800;                // feat_1_16 (8,256,40,40)

    // 1) offset1 = conv3x3(x, w_off1, b_off1, s=4): (8,18,160,160)
    {
        int total = B * 18 * 160 * 160;
        conv3x3_kernel<<<(total + TPB - 1) / TPB, TPB, 0, stream>>>(
            x, w_off1, b_off1, A, B, 3, 640, 640, 18, 160, 160, 4);
    }
    // 2) d1 = deform_conv(x, offset1, w_d1, b_d1, s=4): (8,64,160,160) -> bufB
    {
        int pixels = B * 160 * 160;              // 204800, P=16
        deform_kernel<3, 64, 4><<<pixels / 16, TPB, 0, stream>>>(
            x, A, w_d1, b_d1, bufB, B, 640, 640, 160, 160, 4);
    }
    // 3) pool = avgpool4(x): (8,3,160,160) -> A (offset1 is consumed)
    {
        int total = B * 3 * 160 * 160;
        avgpool4_kernel<<<(total + TPB - 1) / TPB, TPB, 0, stream>>>(
            x, A, B * 3, 160, 160, 640, 640);
    }
    // 4) bufB += conv1x1(pool, w_skip) + b_skip
    {
        int total = B * 64 * 25600;
        skip_add_kernel<<<(total + TPB - 1) / TPB, TPB, 0, stream>>>(
            bufB, A, w_skip, b_skip, B, 25600);
    }
    // 5) bufC = conv3x3(bufB, w_bl1); bn+relu in place -> f
    {
        int total = B * 64 * 160 * 160;
        conv3x3_kernel<<<(total + TPB - 1) / TPB, TPB, 0, stream>>>(
            bufB, w_bl1, nullptr, bufC, B, 64, 160, 160, 64, 160, 160, 1);
        zero_stats_kernel<<<1, 128, 0, stream>>>(stats);
        bn_stats_kernel<<<B * 64, TPB, 0, stream>>>(bufC, stats, 64, 25600);
        bn_apply_kernel<<<(total + TPB - 1) / TPB, TPB, 0, stream>>>(
            bufC, stats, bufC, 64, 25600, total, 1.0f / (B * 25600));
    }
    // 6) bufB = conv3x3(f, w_bl2); bn+relu -> out0 (feat_1_4)
    {
        int total = B * 64 * 160 * 160;
        conv3x3_kernel<<<(total + TPB - 1) / TPB, TPB, 0, stream>>>(
            bufC, w_bl2, nullptr, bufB, B, 64, 160, 160, 64, 160, 160, 1);
        zero_stats_kernel<<<1, 128, 0, stream>>>(stats);
        bn_stats_kernel<<<B * 64, TPB, 0, stream>>>(bufB, stats, 64, 25600);
        bn_apply_kernel<<<(total + TPB - 1) / TPB, TPB, 0, stream>>>(
            bufB, stats, out0, 64, 25600, total, 1.0f / (B * 25600));
    }
    // 7) offset2 = conv3x3(feat_1_4, w_off2, b_off2, s=2): (8,18,80,80) -> A
    {
        int total = B * 18 * 80 * 80;
        conv3x3_kernel<<<(total + TPB - 1) / TPB, TPB, 0, stream>>>(
            out0, w_off2, b_off2, A, B, 64, 160, 160, 18, 80, 80, 2);
    }
    // 8) feat_1_8 = deform_conv(feat_1_4, offset2, w_d2, b_d2, s=2) -> out1
    {
        int pixels = B * 80 * 80;                // 51200, P=16
        deform_kernel<64, 64, 4><<<pixels / 16, TPB, 0, stream>>>(
            out0, A, w_d2, b_d2, out1, B, 160, 160, 80, 80, 2);
    }
    // 9) offset3 = conv3x3(feat_1_8, w_off3, b_off3, s=2): (8,18,40,40) -> A
    {
        int total = B * 18 * 40 * 40;
        conv3x3_kernel<<<(total + TPB - 1) / TPB, TPB, 0, stream>>>(
            out1, w_off3, b_off3, A, B, 64, 80, 80, 18, 40, 40, 2);
    }
    // 10) feat_1_16 = deform_conv(feat_1_8, offset3, w_d3, b_d3, s=2) -> out2
    {
        int pixels = B * 40 * 40;                // 12800, P=4
        deform_kernel<64, 256, 4><<<pixels / 4, TPB, 0, stream>>>(
            out1, A, w_d3, b_d3, out2, B, 80, 80, 40, 40, 2);
    }
}

// Round 2
// 1965.741 us; speedup vs baseline: 3.6499x; 3.6499x over previous
//
#include <hip/hip_runtime.h>
#include <hip/hip_bf16.h>
#include <math.h>

#define TPB 256

typedef __attribute__((ext_vector_type(8))) short bf16x8_t;
typedef __attribute__((ext_vector_type(4))) float f32x4_t;

// ---------------------------------------------------------------- conv 3x3
// generic direct conv: in (B,Ci,H,W) -> out (B,Co,Ho,Wo), pad=1, stride s
__global__ void conv3x3_kernel(const float* __restrict__ in,
                               const float* __restrict__ w,
                               const float* __restrict__ bias,
                               float* __restrict__ out,
                               int B, int Ci, int H, int W,
                               int Co, int Ho, int Wo, int stride)
{
    int idx = blockIdx.x * TPB + threadIdx.x;
    int total = B * Co * Ho * Wo;
    if (idx >= total) return;
    int wo = idx % Wo;
    int t  = idx / Wo;
    int ho = t % Ho;  t /= Ho;
    int co = t % Co;
    int bb = t / Co;

    float acc = bias ? bias[co] : 0.0f;
    int iy0 = ho * stride - 1;
    int ix0 = wo * stride - 1;
    for (int c = 0; c < Ci; ++c) {
        const float* xp = in + ((size_t)(bb * Ci + c)) * H * W;
        const float* wp = w + ((size_t)(co * Ci + c)) * 9;
#pragma unroll
        for (int ky = 0; ky < 3; ++ky) {
            int iy = iy0 + ky;
            if (iy < 0 || iy >= H) continue;
#pragma unroll
            for (int kx = 0; kx < 3; ++kx) {
                int ix = ix0 + kx;
                if (ix < 0 || ix >= W) continue;
                acc += wp[ky * 3 + kx] * xp[iy * W + ix];
            }
        }
    }
    out[idx] = acc;
}

// ------------------------------------------------- weight repack for MFMA
// w (O=64, Ci=64, 3, 3) fp32  ->  wt bf16 [oc][tap*64+ic]  (row-major [64][576])
__global__ void repack_w_kernel(const float* __restrict__ w,
                                short* __restrict__ wt)
{
    int idx = blockIdx.x * TPB + threadIdx.x;
    if (idx >= 64 * 64 * 9) return;
    int ic  = idx % 64;
    int t   = idx / 64;
    int tap = t % 9;
    int oc  = t / 9;
    float v = w[((size_t)(oc * 64 + ic)) * 9 + tap];
    ((__hip_bfloat16*)wt)[(size_t)oc * 576 + tap * 64 + ic] = __float2bfloat16(v);
}

// ------------------------------------------------- MFMA conv 3x3 (64->64, s1)
// in (B,64,160,160) fp32, wt bf16 [64][576], out (B,64,160,160) fp32, no bias.
// Block: 256 thr = 4 waves; tile 16x16 pixels x 64 oc.
// LDS: input halo tile [row 0..17][col 0..17][ic 0..63] bf16, ic-chunk (16B)
// XOR-swizzled by (col&7) to kill ds_read_b128 bank conflicts.
__global__ __launch_bounds__(256, 1) void conv3x3_mfma_kernel(
    const float* __restrict__ in,
    const short* __restrict__ wt,
    float* __restrict__ out,
    int B)
{
    __shared__ short tile[18 * 18 * 64];   // 41472 B
    const int H = 160, W = 160;
    int blk = blockIdx.x;
    int b  = blk / 100;
    int r  = blk % 100;
    int y0 = (r / 10) * 16;
    int x0 = (r % 10) * 16;
    const int tid = threadIdx.x;

    // ---- stage halo tile, fp32 -> bf16, swizzled
    const float* inb = in + (size_t)b * 64 * H * W;
    for (int it = tid; it < 18 * 18 * 64; it += TPB) {
        int col = it % 18;
        int t2  = it / 18;
        int row = t2 % 18;
        int ic  = t2 / 18;
        int y = y0 + row - 1;
        int x = x0 + col - 1;
        float v = 0.f;
        if (y >= 0 && y < H && x >= 0 && x < W)
            v = inb[(size_t)ic * H * W + y * W + x];
        int sw = ((((ic >> 3) ^ (col & 7)) << 3) | (ic & 7));
        ((__hip_bfloat16*)tile)[(row * 18 + col) * 64 + sw] = __float2bfloat16(v);
    }
    __syncthreads();

    const int wv  = tid >> 6;   // wave 0..3 -> tile rows wv*4 .. wv*4+3
    const int l   = tid & 63;
    const int l15 = l & 15;
    const int lg  = l >> 4;     // 0..3

    f32x4_t acc[4][4];
#pragma unroll
    for (int i = 0; i < 4; ++i)
#pragma unroll
        for (int j = 0; j < 4; ++j)
            acc[i][j] = (f32x4_t){0.f, 0.f, 0.f, 0.f};

    // K = 576 = 9 taps x 64 ic ; k-chunk = 32 (half the ics of one tap)
#pragma unroll 2
    for (int kc = 0; kc < 18; ++kc) {
        int tap = kc >> 1;
        int dy  = tap / 3;
        int dx  = tap % 3;

        // B fragments: lane holds wt[oc = nf*16 + l15][k = kc*32 + lg*8 .. +7]
        bf16x8_t bf[4];
#pragma unroll
        for (int nf = 0; nf < 4; ++nf) {
            int oc = nf * 16 + l15;
            bf[nf] = *(const bf16x8_t*)(wt + (size_t)oc * 576 + kc * 32 + lg * 8);
        }

        // A fragments: lane holds tile[row][col = l15+dx][ic = (kc&1)*32 + lg*8 .. +7]
        int colr  = l15 + dx;
        int chunk = (((kc & 1) << 2) + lg) ^ (colr & 7);
        bf16x8_t af[4];
#pragma unroll
        for (int mf = 0; mf < 4; ++mf) {
            int row = wv * 4 + mf + dy;
            af[mf] = *(const bf16x8_t*)&tile[(row * 18 + colr) * 64 + chunk * 8];
        }

#pragma unroll
        for (int mf = 0; mf < 4; ++mf)
#pragma unroll
            for (int nf = 0; nf < 4; ++nf)
                acc[mf][nf] = __builtin_amdgcn_mfma_f32_16x16x32_bf16(
                    af[mf], bf[nf], acc[mf][nf], 0, 0, 0);
    }

    // ---- store: D row=(lg*4+reg) -> x, col=l15 -> oc
    float* outb = out + (size_t)b * 64 * H * W;
#pragma unroll
    for (int mf = 0; mf < 4; ++mf) {
        int y = y0 + wv * 4 + mf;
#pragma unroll
        for (int nf = 0; nf < 4; ++nf) {
            int oc = nf * 16 + l15;
            *(f32x4_t*)&outb[(size_t)oc * H * W + y * W + x0 + lg * 4] = acc[mf][nf];
        }
    }
}

// ---------------------------------------------------------------- deform conv
template <int C, int O, int PW>
__global__ void deform_kernel(const float* __restrict__ x,
                              const float* __restrict__ off,
                              const float* __restrict__ w,
                              const float* __restrict__ bias,
                              float* __restrict__ out,
                              int B, int H, int W, int Ho, int Wo, int stride)
{
    constexpr int G = TPB / O;
    constexpr int P = G * PW;
    __shared__ float samp[P][C * 9];
    __shared__ int   sidx[P * 9][4];
    __shared__ float swt[P * 9][4];

    const int tid = threadIdx.x;
    const int HW = Ho * Wo;
    const int total = B * HW;
    const int pix0 = blockIdx.x * P;

    for (int item = tid; item < P * 9; item += TPB) {
        int p = item / 9, k = item % 9;
        int pix = pix0 + p;
        if (pix < total) {
            int bb = pix / HW, r = pix % HW, ho = r / Wo, wo = r % Wo;
            float dy = off[((size_t)(bb * 18 + 2 * k) * Ho + ho) * Wo + wo];
            float dx = off[((size_t)(bb * 18 + 2 * k + 1) * Ho + ho) * Wo + wo];
            float ys = (float)(ho * stride - 1 + k / 3) + dy;
            float xs = (float)(wo * stride - 1 + k % 3) + dx;
            float y0f = floorf(ys), x0f = floorf(xs);
            float fy = ys - y0f, fx = xs - x0f;
            int y0 = (int)y0f, x0 = (int)x0f;
            float wts[4] = { (1.f - fy) * (1.f - fx), (1.f - fy) * fx,
                             fy * (1.f - fx),          fy * fx };
#pragma unroll
            for (int j = 0; j < 4; ++j) {
                int iy = y0 + (j >> 1);
                int ix = x0 + (j & 1);
                bool v = (iy >= 0) && (iy < H) && (ix >= 0) && (ix < W);
                sidx[item][j] = v ? (iy * W + ix) : -1;
                swt[item][j]  = wts[j];
            }
        } else {
#pragma unroll
            for (int j = 0; j < 4; ++j) { sidx[item][j] = -1; swt[item][j] = 0.f; }
        }
    }
    __syncthreads();

    for (int item = tid; item < P * C * 9; item += TPB) {
        int p = item / (C * 9);
        int ck = item % (C * 9);
        int c = ck / 9, k = ck % 9;
        int pix = pix0 + p;
        float v = 0.f;
        if (pix < total) {
            int bb = pix / HW;
            const float* xp = x + ((size_t)(bb * C + c)) * H * W;
            int e = p * 9 + k;
#pragma unroll
            for (int j = 0; j < 4; ++j) {
                int id = sidx[e][j];
                if (id >= 0) v += swt[e][j] * xp[id];
            }
        }
        samp[p][ck] = v;
    }
    __syncthreads();

    int g = tid / O;
    int o = tid % O;
    float acc[PW];
#pragma unroll
    for (int pi = 0; pi < PW; ++pi) acc[pi] = bias[o];
    for (int c = 0; c < C; ++c) {
#pragma unroll
        for (int k = 0; k < 9; ++k) {
            float wv = w[((size_t)(o * C + c)) * 9 + k];
#pragma unroll
            for (int pi = 0; pi < PW; ++pi)
                acc[pi] += wv * samp[g * PW + pi][c * 9 + k];
        }
    }
#pragma unroll
    for (int pi = 0; pi < PW; ++pi) {
        int pix = pix0 + g * PW + pi;
        if (pix < total) {
            int bb = pix / HW, r = pix % HW;
            out[((size_t)(bb * O + o)) * HW + r] = acc[pi];
        }
    }
}

// ---------------------------------------------------------------- avgpool 4x4
__global__ void avgpool4_kernel(const float* __restrict__ in,
                                float* __restrict__ out,
                                int BC, int Ho, int Wo, int H, int W)
{
    int idx = blockIdx.x * TPB + threadIdx.x;
    int total = BC * Ho * Wo;
    if (idx >= total) return;
    int wo = idx % Wo;
    int t = idx / Wo;
    int ho = t % Ho;
    int bc = t / Ho;
    const float* xp = in + (size_t)bc * H * W + (ho * 4) * W + wo * 4;
    float s = 0.f;
#pragma unroll
    for (int i = 0; i < 4; ++i)
#pragma unroll
        for (int j = 0; j < 4; ++j)
            s += xp[i * W + j];
    out[idx] = s * (1.0f / 16.0f);
}

// ------------------------------------------------- skip: d1 += 1x1conv(pool)
__global__ void skip_add_kernel(float* __restrict__ d1,
                                const float* __restrict__ pool,
                                const float* __restrict__ wsk,
                                const float* __restrict__ bsk,
                                int B, int HW)
{
    int idx = blockIdx.x * TPB + threadIdx.x;
    int total = B * 64 * HW;
    if (idx >= total) return;
    int r = idx % HW;
    int t = idx / HW;
    int o = t % 64;
    int bb = t / 64;
    const float* pp = pool + (size_t)bb * 3 * HW + r;
    float v = d1[idx] + bsk[o];
    v += wsk[o * 3 + 0] * pp[0];
    v += wsk[o * 3 + 1] * pp[HW];
    v += wsk[o * 3 + 2] * pp[2 * HW];
    d1[idx] = v;
}

// ---------------------------------------------------------------- batchnorm
__global__ void zero_stats_kernel(float* __restrict__ stats)
{
    if (threadIdx.x < 128) stats[threadIdx.x] = 0.f;
}

__global__ void bn_stats_kernel(const float* __restrict__ in,
                                float* __restrict__ stats,
                                int C, int HW)
{
    int bc = blockIdx.x;
    int c = bc % C;
    const float* p = in + (size_t)bc * HW;
    float s = 0.f, s2 = 0.f;
    for (int i = threadIdx.x; i < HW; i += TPB) {
        float v = p[i];
        s += v;
        s2 += v * v;
    }
    __shared__ float ss[TPB], sq[TPB];
    ss[threadIdx.x] = s;
    sq[threadIdx.x] = s2;
    __syncthreads();
    for (int st = TPB / 2; st > 0; st >>= 1) {
        if (threadIdx.x < st) {
            ss[threadIdx.x] += ss[threadIdx.x + st];
            sq[threadIdx.x] += sq[threadIdx.x + st];
        }
        __syncthreads();
    }
    if (threadIdx.x == 0) {
        atomicAdd(&stats[c * 2], ss[0]);
        atomicAdd(&stats[c * 2 + 1], sq[0]);
    }
}

__global__ void bn_apply_kernel(const float* __restrict__ in,
                                const float* __restrict__ stats,
                                float* __restrict__ out,
                                int C, int HW, int total, float invN)
{
    int idx = blockIdx.x * TPB + threadIdx.x;
    if (idx >= total) return;
    int c = (idx / HW) % C;
    float mean = stats[c * 2] * invN;
    float var = stats[c * 2 + 1] * invN - mean * mean;
    float r = rsqrtf(var + 1e-5f);
    float v = (in[idx] - mean) * r;
    out[idx] = v > 0.f ? v : 0.f;
}

// ---------------------------------------------------------------- launch
extern "C" void kernel_launch(void* const* d_in, const int* in_sizes, int n_in,
                              void* d_out, int out_size, void* d_ws, size_t ws_size,
                              hipStream_t stream)
{
    const float* x      = (const float*)d_in[0];
    const float* w_off1 = (const float*)d_in[1];
    const float* b_off1 = (const float*)d_in[2];
    const float* w_d1   = (const float*)d_in[3];
    const float* b_d1   = (const float*)d_in[4];
    const float* w_skip = (const float*)d_in[5];
    const float* b_skip = (const float*)d_in[6];
    const float* w_bl1  = (const float*)d_in[7];
    const float* w_bl2  = (const float*)d_in[8];
    const float* w_off2 = (const float*)d_in[9];
    const float* b_off2 = (const float*)d_in[10];
    const float* w_d2   = (const float*)d_in[11];
    const float* b_d2   = (const float*)d_in[12];
    const float* w_off3 = (const float*)d_in[13];
    const float* b_off3 = (const float*)d_in[14];
    const float* w_d3   = (const float*)d_in[15];
    const float* b_d3   = (const float*)d_in[16];

    const int B = 8;
    float* A     = (float*)d_ws;          // 3,686,400 floats (multi-use)
    float* bufB  = A + 3686400;           // 13,107,200
    float* bufC  = bufB + 13107200;       // 13,107,200
    float* stats = bufC + 13107200;       // 128

    float* out0 = (float*)d_out;          // feat_1_4  (8,64,160,160)
    float* out1 = out0 + 13107200;        // feat_1_8  (8,64,80,80)
    float* out2 = out1 + 3276800;         // feat_1_16 (8,256,40,40)

    // 1) offset1 = conv3x3(x, w_off1, b_off1, s=4): (8,18,160,160) -> A
    {
        int total = B * 18 * 160 * 160;
        conv3x3_kernel<<<(total + TPB - 1) / TPB, TPB, 0, stream>>>(
            x, w_off1, b_off1, A, B, 3, 640, 640, 18, 160, 160, 4);
    }
    // 2) d1 = deform_conv(x, offset1, w_d1, b_d1, s=4) -> bufB
    {
        int pixels = B * 160 * 160;
        deform_kernel<3, 64, 4><<<pixels / 16, TPB, 0, stream>>>(
            x, A, w_d1, b_d1, bufB, B, 640, 640, 160, 160, 4);
    }
    // 3) pool = avgpool4(x) -> A
    {
        int total = B * 3 * 160 * 160;
        avgpool4_kernel<<<(total + TPB - 1) / TPB, TPB, 0, stream>>>(
            x, A, B * 3, 160, 160, 640, 640);
    }
    // 4) bufB += conv1x1(pool, w_skip) + b_skip
    {
        int total = B * 64 * 25600;
        skip_add_kernel<<<(total + TPB - 1) / TPB, TPB, 0, stream>>>(
            bufB, A, w_skip, b_skip, B, 25600);
    }
    // 4.5) repack weights for the two MFMA convs into A (free until step 7)
    short* wt1 = (short*)A;
    short* wt2 = wt1 + 64 * 576;
    {
        int total = 64 * 64 * 9;
        repack_w_kernel<<<(total + TPB - 1) / TPB, TPB, 0, stream>>>(w_bl1, wt1);
        repack_w_kernel<<<(total + TPB - 1) / TPB, TPB, 0, stream>>>(w_bl2, wt2);
    }
    // 5) bufC = conv_mfma(bufB, wt1); bn+relu in place -> f
    {
        int total = B * 64 * 160 * 160;
        conv3x3_mfma_kernel<<<800, TPB, 0, stream>>>(bufB, wt1, bufC, B);
        zero_stats_kernel<<<1, 128, 0, stream>>>(stats);
        bn_stats_kernel<<<B * 64, TPB, 0, stream>>>(bufC, stats, 64, 25600);
        bn_apply_kernel<<<(total + TPB - 1) / TPB, TPB, 0, stream>>>(
            bufC, stats, bufC, 64, 25600, total, 1.0f / (B * 25600));
    }
    // 6) bufB = conv_mfma(f, wt2); bn+relu -> out0 (feat_1_4)
    {
        int total = B * 64 * 160 * 160;
        conv3x3_mfma_kernel<<<800, TPB, 0, stream>>>(bufC, wt2, bufB, B);
        zero_stats_kernel<<<1, 128, 0, stream>>>(stats);
        bn_stats_kernel<<<B * 64, TPB, 0, stream>>>(bufB, stats, 64, 25600);
        bn_apply_kernel<<<(total + TPB - 1) / TPB, TPB, 0, stream>>>(
            bufB, stats, out0, 64, 25600, total, 1.0f / (B * 25600));
    }
    // 7) offset2 = conv3x3(feat_1_4, s=2): (8,18,80,80) -> A (wt consumed)
    {
        int total = B * 18 * 80 * 80;
        conv3x3_kernel<<<(total + TPB - 1) / TPB, TPB, 0, stream>>>(
            out0, w_off2, b_off2, A, B, 64, 160, 160, 18, 80, 80, 2);
    }
    // 8) feat_1_8 = deform_conv(feat_1_4, offset2, s=2) -> out1
    {
        int pixels = B * 80 * 80;
        deform_kernel<64, 64, 4><<<pixels / 16, TPB, 0, stream>>>(
            out0, A, w_d2, b_d2, out1, B, 160, 160, 80, 80, 2);
    }
    // 9) offset3 = conv3x3(feat_1_8, s=2): (8,18,40,40) -> A
    {
        int total = B * 18 * 40 * 40;
        conv3x3_kernel<<<(total + TPB - 1) / TPB, TPB, 0, stream>>>(
            out1, w_off3, b_off3, A, B, 64, 80, 80, 18, 40, 40, 2);
    }
    // 10) feat_1_16 = deform_conv(feat_1_8, offset3, s=2) -> out2
    {
        int pixels = B * 40 * 40;
        deform_kernel<64, 256, 4><<<pixels / 4, TPB, 0, stream>>>(
            out1, A, w_d3, b_d3, out2, B, 80, 80, 40, 40, 2);
    }
}

// Round 6
// 1212.281 us; speedup vs baseline: 5.9184x; 1.6215x over previous
//
#include <hip/hip_runtime.h>
#include <hip/hip_bf16.h>
#include <math.h>

#define TPB 256

typedef __attribute__((ext_vector_type(8))) short bf16x8_t;
typedef __attribute__((ext_vector_type(4))) float f32x4_t;

static __device__ __forceinline__ float bf16_to_f(short s) {
    union { unsigned u; float f; } cv;
    cv.u = ((unsigned)(unsigned short)s) << 16;
    return cv.f;
}
static __device__ __forceinline__ short f_to_bf16(float v) {
    __hip_bfloat16 h = __float2bfloat16(v);
    return *(short*)&h;
}

// ---------------------------------------------------------------- conv 3x3
// generic direct conv (used for the exact-fp32 offset convs)
__global__ void conv3x3_kernel(const float* __restrict__ in,
                               const float* __restrict__ w,
                               const float* __restrict__ bias,
                               float* __restrict__ out,
                               int B, int Ci, int H, int W,
                               int Co, int Ho, int Wo, int stride)
{
    int idx = blockIdx.x * TPB + threadIdx.x;
    int total = B * Co * Ho * Wo;
    if (idx >= total) return;
    int wo = idx % Wo;
    int t  = idx / Wo;
    int ho = t % Ho;  t /= Ho;
    int co = t % Co;
    int bb = t / Co;

    float acc = bias ? bias[co] : 0.0f;
    int iy0 = ho * stride - 1;
    int ix0 = wo * stride - 1;
    for (int c = 0; c < Ci; ++c) {
        const float* xp = in + ((size_t)(bb * Ci + c)) * H * W;
        const float* wp = w + ((size_t)(co * Ci + c)) * 9;
#pragma unroll
        for (int ky = 0; ky < 3; ++ky) {
            int iy = iy0 + ky;
            if (iy < 0 || iy >= H) continue;
#pragma unroll
            for (int kx = 0; kx < 3; ++kx) {
                int ix = ix0 + kx;
                if (ix < 0 || ix >= W) continue;
                acc += wp[ky * 3 + kx] * xp[iy * W + ix];
            }
        }
    }
    out[idx] = acc;
}

// ------------------------------------------------- weight repack for MFMA
// w (O, 64, 3, 3) fp32 -> wt bf16 [oc][tap*64+ic]
__global__ void repack_w_kernel(const float* __restrict__ w,
                                short* __restrict__ wt, int O)
{
    int idx = blockIdx.x * TPB + threadIdx.x;
    if (idx >= O * 64 * 9) return;
    int ic  = idx % 64;
    int t   = idx / 64;
    int tap = t % 9;
    int oc  = t / 9;
    wt[(size_t)oc * 576 + tap * 64 + ic] =
        f_to_bf16(w[((size_t)(oc * 64 + ic)) * 9 + tap]);
}

// ------------------------------------------------- MFMA conv 3x3 (64->64, s1)
__global__ __launch_bounds__(256, 1) void conv3x3_mfma_kernel(
    const float* __restrict__ in,
    const short* __restrict__ wt,
    float* __restrict__ out,
    int B)
{
    __shared__ short tile[18 * 18 * 64];   // 41472 B
    const int H = 160, W = 160;
    int blk = blockIdx.x;
    int b  = blk / 100;
    int r  = blk % 100;
    int y0 = (r / 10) * 16;
    int x0 = (r % 10) * 16;
    const int tid = threadIdx.x;

    const float* inb = in + (size_t)b * 64 * H * W;
    for (int it = tid; it < 18 * 18 * 64; it += TPB) {
        int col = it % 18;
        int t2  = it / 18;
        int row = t2 % 18;
        int ic  = t2 / 18;
        int y = y0 + row - 1;
        int x = x0 + col - 1;
        float v = 0.f;
        if (y >= 0 && y < H && x >= 0 && x < W)
            v = inb[(size_t)ic * H * W + y * W + x];
        int sw = ((((ic >> 3) ^ (col & 7)) << 3) | (ic & 7));
        tile[(row * 18 + col) * 64 + sw] = f_to_bf16(v);
    }
    __syncthreads();

    const int wv  = tid >> 6;
    const int l   = tid & 63;
    const int l15 = l & 15;
    const int lg  = l >> 4;

    f32x4_t acc[4][4];
#pragma unroll
    for (int i = 0; i < 4; ++i)
#pragma unroll
        for (int j = 0; j < 4; ++j)
            acc[i][j] = (f32x4_t){0.f, 0.f, 0.f, 0.f};

#pragma unroll 2
    for (int kc = 0; kc < 18; ++kc) {
        int tap = kc >> 1;
        int dy  = tap / 3;
        int dx  = tap % 3;

        bf16x8_t bf[4];
#pragma unroll
        for (int nf = 0; nf < 4; ++nf) {
            int oc = nf * 16 + l15;
            bf[nf] = *(const bf16x8_t*)(wt + (size_t)oc * 576 + kc * 32 + lg * 8);
        }

        int colr  = l15 + dx;
        int chunk = (((kc & 1) << 2) + lg) ^ (colr & 7);
        bf16x8_t af[4];
#pragma unroll
        for (int mf = 0; mf < 4; ++mf) {
            int row = wv * 4 + mf + dy;
            af[mf] = *(const bf16x8_t*)&tile[(row * 18 + colr) * 64 + chunk * 8];
        }

#pragma unroll
        for (int mf = 0; mf < 4; ++mf)
#pragma unroll
            for (int nf = 0; nf < 4; ++nf)
                acc[mf][nf] = __builtin_amdgcn_mfma_f32_16x16x32_bf16(
                    af[mf], bf[nf], acc[mf][nf], 0, 0, 0);
    }

    float* outb = out + (size_t)b * 64 * H * W;
#pragma unroll
    for (int mf = 0; mf < 4; ++mf) {
        int y = y0 + wv * 4 + mf;
#pragma unroll
        for (int nf = 0; nf < 4; ++nf) {
            int oc = nf * 16 + l15;
            *(f32x4_t*)&outb[(size_t)oc * H * W + y * W + x0 + lg * 4] = acc[mf][nf];
        }
    }
}

// ------------------------------------------------- NCHW fp32 -> NHWC bf16 (C=64)
__global__ void nchw_to_nhwc_bf16_kernel(const float* __restrict__ in,
                                         short* __restrict__ out, int HW)
{
    __shared__ short tile[64][66];
    int nchunks = HW >> 6;
    int b  = blockIdx.x / nchunks;
    int p0 = (blockIdx.x % nchunks) << 6;
    int tid = threadIdx.x;
#pragma unroll
    for (int rep = 0; rep < 16; ++rep) {
        int item = rep * 256 + tid;
        int c = item >> 6, p = item & 63;
        tile[p][c] = f_to_bf16(in[((size_t)b * 64 + c) * HW + p0 + p]);
    }
    __syncthreads();
#pragma unroll
    for (int rep = 0; rep < 16; ++rep) {
        int item = rep * 256 + tid;
        int p = item >> 6, c = item & 63;
        out[((size_t)b * HW + p0 + p) * 64 + c] = tile[p][c];
    }
}

// ------------------------------------------------- x NCHW (C=3) -> NHWC4 fp32
__global__ void x_to_nhwc4_kernel(const float* __restrict__ in,
                                  float* __restrict__ out)
{
    int idx = blockIdx.x * TPB + threadIdx.x;
    const int HW = 640 * 640;
    if (idx >= 8 * HW) return;
    int b = idx / HW, p = idx % HW;
    f32x4_t v;
    v[0] = in[((size_t)b * 3 + 0) * HW + p];
    v[1] = in[((size_t)b * 3 + 1) * HW + p];
    v[2] = in[((size_t)b * 3 + 2) * HW + p];
    v[3] = 0.f;
    *(f32x4_t*)&out[(size_t)idx * 4] = v;
}

// ------------------------------------------------- deform1: C=3 (NHWC4), O=64
__global__ __launch_bounds__(256, 1) void deform1_kernel(
    const float* __restrict__ x4,   // [B][640][640][4] fp32
    const float* __restrict__ off,  // [B][18][160][160]
    const float* __restrict__ w,    // (64,3,3,3) fp32
    const float* __restrict__ bias,
    float* __restrict__ out)        // [B][64][160][160]
{
    const int H = 640, W = 640, Ho = 160, Wo = 160, HW = 25600;
    __shared__ float samp[16][27];
    __shared__ int   sidx[144][4];
    __shared__ float swt[144][4];
    const int tid = threadIdx.x;
    const int pix0 = blockIdx.x * 16;
    const int b = pix0 / HW;
    const int r0 = pix0 - b * HW;

    if (tid < 144) {
        int p = tid / 9, tap = tid % 9;
        int r = r0 + p, ho = r / Wo, wo = r % Wo;
        float dy = off[((size_t)(b * 18 + 2 * tap) * Ho + ho) * Wo + wo];
        float dx = off[((size_t)(b * 18 + 2 * tap + 1) * Ho + ho) * Wo + wo];
        float ys = (float)(ho * 4 - 1 + tap / 3) + dy;
        float xs = (float)(wo * 4 - 1 + tap % 3) + dx;
        float y0f = floorf(ys), x0f = floorf(xs);
        float fy = ys - y0f, fx = xs - x0f;
        int y0 = (int)y0f, x0 = (int)x0f;
        float wts[4] = {(1.f - fy) * (1.f - fx), (1.f - fy) * fx,
                        fy * (1.f - fx),          fy * fx};
#pragma unroll
        for (int j = 0; j < 4; ++j) {
            int iy = y0 + (j >> 1), ix = x0 + (j & 1);
            bool v = (iy >= 0) && (iy < H) && (ix >= 0) && (ix < W);
            sidx[tid][j] = v ? (iy * W + ix) : -1;
            swt[tid][j]  = wts[j];
        }
    }
    __syncthreads();

    if (tid < 144) {
        int p = tid / 9, tap = tid % 9;
        const float* xb = x4 + (size_t)b * H * W * 4;
        float s0 = 0.f, s1 = 0.f, s2 = 0.f;
#pragma unroll
        for (int j = 0; j < 4; ++j) {
            int id = sidx[tid][j];
            if (id >= 0) {
                f32x4_t v = *(const f32x4_t*)&xb[(size_t)id * 4];
                float wj = swt[tid][j];
                s0 += wj * v[0];
                s1 += wj * v[1];
                s2 += wj * v[2];
            }
        }
        // layout MUST match MAC phase read: samp[p][c*9 + tap]
        samp[p][0 * 9 + tap] = s0;
        samp[p][1 * 9 + tap] = s1;
        samp[p][2 * 9 + tap] = s2;
    }
    __syncthreads();

    int g = tid >> 6;      // wave -> 4-pixel group
    int o = tid & 63;
    float acc[4];
#pragma unroll
    for (int pi = 0; pi < 4; ++pi) acc[pi] = bias[o];
#pragma unroll
    for (int c = 0; c < 3; ++c)
#pragma unroll
        for (int k = 0; k < 9; ++k) {
            float wv = w[((size_t)(o * 3 + c)) * 9 + k];
#pragma unroll
            for (int pi = 0; pi < 4; ++pi)
                acc[pi] += wv * samp[g * 4 + pi][c * 9 + k];
        }
#pragma unroll
    for (int pi = 0; pi < 4; ++pi)
        out[((size_t)(b * 64 + o)) * HW + r0 + g * 4 + pi] = acc[pi];
}

// ------------------------------------------------- deform MFMA: C=64 -> O
// xh NHWC bf16 [B][H][W][64]; samp LDS [16 pixels][K=576] bf16, XOR-swizzled.
template <int O>
__global__ __launch_bounds__(256, 1) void deform_mfma_kernel(
    const short* __restrict__ xh,
    const float* __restrict__ off,  // [B][18][Ho][Wo]
    const short* __restrict__ wt,   // bf16 [O][576]
    const float* __restrict__ bias,
    float* __restrict__ out,        // [B][O][Ho][Wo]
    int H, int W, int Ho, int Wo, int stride)
{
    constexpr int NF = O / 64;      // N-frags per wave
    __shared__ alignas(16) short samp[16 * 576];
    __shared__ int   sidx[144][4];
    __shared__ float swt[144][4];

    const int tid = threadIdx.x;
    const int HW = Ho * Wo;
    const int pix0 = blockIdx.x * 16;
    const int b = pix0 / HW;
    const int r0 = pix0 - b * HW;

    // phase 1: bilinear corners for 16 pixels x 9 taps
    if (tid < 144) {
        int p = tid / 9, tap = tid % 9;
        int r = r0 + p, ho = r / Wo, wo = r % Wo;
        float dy = off[((size_t)(b * 18 + 2 * tap) * Ho + ho) * Wo + wo];
        float dx = off[((size_t)(b * 18 + 2 * tap + 1) * Ho + ho) * Wo + wo];
        float ys = (float)(ho * stride - 1 + tap / 3) + dy;
        float xs = (float)(wo * stride - 1 + tap % 3) + dx;
        float y0f = floorf(ys), x0f = floorf(xs);
        float fy = ys - y0f, fx = xs - x0f;
        int y0 = (int)y0f, x0 = (int)x0f;
        float wts[4] = {(1.f - fy) * (1.f - fx), (1.f - fy) * fx,
                        fy * (1.f - fx),          fy * fx};
#pragma unroll
        for (int j = 0; j < 4; ++j) {
            int iy = y0 + (j >> 1), ix = x0 + (j & 1);
            bool v = (iy >= 0) && (iy < H) && (ix >= 0) && (ix < W);
            sidx[tid][j] = v ? (iy * W + ix) : -1;
            swt[tid][j]  = wts[j];
        }
    }
    __syncthreads();

    const int wv = tid >> 6;
    const int l  = tid & 63;

    // phase 2: coalesced channel-gather (lane = channel)
    const short* xb = xh + (size_t)b * H * W * 64;
#pragma unroll 2
    for (int i = 0; i < 36; ++i) {
        int e = wv * 36 + i;
        int p = e / 9, tap = e % 9;
        float v = 0.f;
#pragma unroll
        for (int j = 0; j < 4; ++j) {
            int id = sidx[e][j];
            if (id >= 0)
                v += swt[e][j] * bf16_to_f(xb[(size_t)id * 64 + l]);
        }
        int sw = (tap * 8 + ((l >> 3) ^ (p & 7))) * 8 + (l & 7);
        samp[p * 576 + sw] = f_to_bf16(v);
    }
    __syncthreads();

    // phase 3: MFMA  (M=16 pixels, N=O, K=576)
    const int l15 = l & 15, lg = l >> 4;
    f32x4_t acc[NF];
#pragma unroll
    for (int nf = 0; nf < NF; ++nf)
        acc[nf] = (f32x4_t){0.f, 0.f, 0.f, 0.f};

#pragma unroll 2
    for (int kc = 0; kc < 18; ++kc) {
        int tap = kc >> 1;
        int low = (((kc & 1) << 2) | lg) ^ (l15 & 7);
        bf16x8_t af = *(const bf16x8_t*)&samp[l15 * 576 + (tap * 8 + low) * 8];
#pragma unroll
        for (int nf = 0; nf < NF; ++nf) {
            int oc = (wv * NF + nf) * 16 + l15;
            bf16x8_t bf = *(const bf16x8_t*)(wt + (size_t)oc * 576 + kc * 32 + lg * 8);
            acc[nf] = __builtin_amdgcn_mfma_f32_16x16x32_bf16(af, bf, acc[nf], 0, 0, 0);
        }
    }

#pragma unroll
    for (int nf = 0; nf < NF; ++nf) {
        int oc = (wv * NF + nf) * 16 + l15;
        float bv = bias[oc];
        f32x4_t v = acc[nf];
        v[0] += bv; v[1] += bv; v[2] += bv; v[3] += bv;
        *(f32x4_t*)&out[((size_t)(b * O + oc)) * HW + r0 + lg * 4] = v;
    }
}

// ---------------------------------------------------------------- avgpool 4x4
__global__ void avgpool4_kernel(const float* __restrict__ in,
                                float* __restrict__ out,
                                int BC, int Ho, int Wo, int H, int W)
{
    int idx = blockIdx.x * TPB + threadIdx.x;
    int total = BC * Ho * Wo;
    if (idx >= total) return;
    int wo = idx % Wo;
    int t = idx / Wo;
    int ho = t % Ho;
    int bc = t / Ho;
    const float* xp = in + (size_t)bc * H * W + (ho * 4) * W + wo * 4;
    float s = 0.f;
#pragma unroll
    for (int i = 0; i < 4; ++i)
#pragma unroll
        for (int j = 0; j < 4; ++j)
            s += xp[i * W + j];
    out[idx] = s * (1.0f / 16.0f);
}

// ------------------------------------------------- skip: d1 += 1x1conv(pool)
__global__ void skip_add_kernel(float* __restrict__ d1,
                                const float* __restrict__ pool,
                                const float* __restrict__ wsk,
                                const float* __restrict__ bsk,
                                int B, int HW)
{
    int idx = blockIdx.x * TPB + threadIdx.x;
    int total = B * 64 * HW;
    if (idx >= total) return;
    int r = idx % HW;
    int t = idx / HW;
    int o = t % 64;
    int bb = t / 64;
    const float* pp = pool + (size_t)bb * 3 * HW + r;
    float v = d1[idx] + bsk[o];
    v += wsk[o * 3 + 0] * pp[0];
    v += wsk[o * 3 + 1] * pp[HW];
    v += wsk[o * 3 + 2] * pp[2 * HW];
    d1[idx] = v;
}

// ---------------------------------------------------------------- batchnorm
__global__ void zero_stats_kernel(float* __restrict__ stats)
{
    if (threadIdx.x < 128) stats[threadIdx.x] = 0.f;
}

__global__ void bn_stats_kernel(const float* __restrict__ in,
                                float* __restrict__ stats,
                                int C, int HW)
{
    int bc = blockIdx.x;
    int c = bc % C;
    const float* p = in + (size_t)bc * HW;
    float s = 0.f, s2 = 0.f;
    for (int i = threadIdx.x; i < HW; i += TPB) {
        float v = p[i];
        s += v;
        s2 += v * v;
    }
    __shared__ float ss[TPB], sq[TPB];
    ss[threadIdx.x] = s;
    sq[threadIdx.x] = s2;
    __syncthreads();
    for (int st = TPB / 2; st > 0; st >>= 1) {
        if (threadIdx.x < st) {
            ss[threadIdx.x] += ss[threadIdx.x + st];
            sq[threadIdx.x] += sq[threadIdx.x + st];
        }
        __syncthreads();
    }
    if (threadIdx.x == 0) {
        atomicAdd(&stats[c * 2], ss[0]);
        atomicAdd(&stats[c * 2 + 1], sq[0]);
    }
}

__global__ void bn_apply_kernel(const float* __restrict__ in,
                                const float* __restrict__ stats,
                                float* __restrict__ out,
                                int C, int HW, int total, float invN)
{
    int idx = blockIdx.x * TPB + threadIdx.x;
    if (idx >= total) return;
    int c = (idx / HW) % C;
    float mean = stats[c * 2] * invN;
    float var = stats[c * 2 + 1] * invN - mean * mean;
    float r = rsqrtf(var + 1e-5f);
    float v = (in[idx] - mean) * r;
    out[idx] = v > 0.f ? v : 0.f;
}

// ---------------------------------------------------------------- launch
extern "C" void kernel_launch(void* const* d_in, const int* in_sizes, int n_in,
                              void* d_out, int out_size, void* d_ws, size_t ws_size,
                              hipStream_t stream)
{
    const float* x      = (const float*)d_in[0];
    const float* w_off1 = (const float*)d_in[1];
    const float* b_off1 = (const float*)d_in[2];
    const float* w_d1   = (const float*)d_in[3];
    const float* b_d1   = (const float*)d_in[4];
    const float* w_skip = (const float*)d_in[5];
    const float* b_skip = (const float*)d_in[6];
    const float* w_bl1  = (const float*)d_in[7];
    const float* w_bl2  = (const float*)d_in[8];
    const float* w_off2 = (const float*)d_in[9];
    const float* b_off2 = (const float*)d_in[10];
    const float* w_d2   = (const float*)d_in[11];
    const float* b_d2   = (const float*)d_in[12];
    const float* w_off3 = (const float*)d_in[13];
    const float* b_off3 = (const float*)d_in[14];
    const float* w_d3   = (const float*)d_in[15];
    const float* b_d3   = (const float*)d_in[16];

    const int B = 8;
    float* A     = (float*)d_ws;          // 3,686,400 floats (multi-use)
    float* bufB  = A + 3686400;           // 13,107,200 floats
    float* bufC  = bufB + 13107200;       // 13,107,200 floats
    float* stats = bufC + 13107200;       // 128

    // weight repack areas inside A. Lifetime analysis: repacked AFTER
    // offset1 (which covers all of A) is consumed; later writes into A are
    // pool (614,400 fl), offset2 (921,600 fl), offset3 (230,400 fl) — all
    // below A+1,000,000, so these regions survive until their uses.
    short* wt1  = (short*)(A + 1000000);        //  36,864 shorts
    short* wt2  = wt1 + 64 * 576;
    short* wtd2 = (short*)(A + 1500000);        //  36,864 shorts
    short* wtd3 = (short*)(A + 1550000);        // 147,456 shorts

    float* out0 = (float*)d_out;          // feat_1_4  (8,64,160,160)
    float* out1 = out0 + 13107200;        // feat_1_8  (8,64,80,80)
    float* out2 = out1 + 3276800;         // feat_1_16 (8,256,40,40)

    // 0) x -> NHWC4 fp32 into bufC (free until step 5)
    x_to_nhwc4_kernel<<<(8 * 409600 + TPB - 1) / TPB, TPB, 0, stream>>>(x, bufC);

    // 1) offset1 = conv3x3(x, s=4): (8,18,160,160) -> A  (covers ALL of A)
    {
        int total = B * 18 * 160 * 160;
        conv3x3_kernel<<<(total + TPB - 1) / TPB, TPB, 0, stream>>>(
            x, w_off1, b_off1, A, B, 3, 640, 640, 18, 160, 160, 4);
    }
    // 2) d1 = deform1(x NHWC4, offset1) -> bufB   (offset1 dead after this)
    deform1_kernel<<<8 * 25600 / 16, TPB, 0, stream>>>(bufC, A, w_d1, b_d1, bufB);

    // 2.5) repack all MFMA weights (A is now safe above +1,000,000)
    repack_w_kernel<<<(64 * 576 + TPB - 1) / TPB, TPB, 0, stream>>>(w_bl1, wt1, 64);
    repack_w_kernel<<<(64 * 576 + TPB - 1) / TPB, TPB, 0, stream>>>(w_bl2, wt2, 64);
    repack_w_kernel<<<(64 * 576 + TPB - 1) / TPB, TPB, 0, stream>>>(w_d2, wtd2, 64);
    repack_w_kernel<<<(256 * 576 + TPB - 1) / TPB, TPB, 0, stream>>>(w_d3, wtd3, 256);

    // 3) pool = avgpool4(x) -> A[0 .. 614,399]
    {
        int total = B * 3 * 160 * 160;
        avgpool4_kernel<<<(total + TPB - 1) / TPB, TPB, 0, stream>>>(
            x, A, B * 3, 160, 160, 640, 640);
    }
    // 4) bufB += conv1x1(pool) + b_skip
    {
        int total = B * 64 * 25600;
        skip_add_kernel<<<(total + TPB - 1) / TPB, TPB, 0, stream>>>(
            bufB, A, w_skip, b_skip, B, 25600);
    }
    // 5) bufC = conv_mfma(bufB, wt1); bn+relu in place  (x NHWC4 dead)
    {
        int total = B * 64 * 160 * 160;
        conv3x3_mfma_kernel<<<800, TPB, 0, stream>>>(bufB, wt1, bufC, B);
        zero_stats_kernel<<<1, 128, 0, stream>>>(stats);
        bn_stats_kernel<<<B * 64, TPB, 0, stream>>>(bufC, stats, 64, 25600);
        bn_apply_kernel<<<(total + TPB - 1) / TPB, TPB, 0, stream>>>(
            bufC, stats, bufC, 64, 25600, total, 1.0f / (B * 25600));
    }
    // 6) bufB = conv_mfma(bufC, wt2); bn+relu -> out0 (feat_1_4)
    {
        int total = B * 64 * 160 * 160;
        conv3x3_mfma_kernel<<<800, TPB, 0, stream>>>(bufC, wt2, bufB, B);
        zero_stats_kernel<<<1, 128, 0, stream>>>(stats);
        bn_stats_kernel<<<B * 64, TPB, 0, stream>>>(bufB, stats, 64, 25600);
        bn_apply_kernel<<<(total + TPB - 1) / TPB, TPB, 0, stream>>>(
            bufB, stats, out0, 64, 25600, total, 1.0f / (B * 25600));
    }
    // 6.5) feat_1_4 -> NHWC bf16 into bufC
    nchw_to_nhwc_bf16_kernel<<<8 * (25600 / 64), TPB, 0, stream>>>(
        out0, (short*)bufC, 25600);

    // 7) offset2 = conv3x3(feat_1_4, s=2) exact fp32 -> A[0 .. 921,599]
    {
        int total = B * 18 * 80 * 80;
        conv3x3_kernel<<<(total + TPB - 1) / TPB, TPB, 0, stream>>>(
            out0, w_off2, b_off2, A, B, 64, 160, 160, 18, 80, 80, 2);
    }
    // 8) feat_1_8 = deform_mfma<64>(nhwc(feat_1_4), offset2) -> out1
    deform_mfma_kernel<64><<<8 * 6400 / 16, TPB, 0, stream>>>(
        (const short*)bufC, A, wtd2, b_d2, out1, 160, 160, 80, 80, 2);

    // 8.5) feat_1_8 -> NHWC bf16 into bufB
    nchw_to_nhwc_bf16_kernel<<<8 * (6400 / 64), TPB, 0, stream>>>(
        out1, (short*)bufB, 6400);

    // 9) offset3 = conv3x3(feat_1_8, s=2) exact fp32 -> A[0 .. 230,399]
    {
        int total = B * 18 * 40 * 40;
        conv3x3_kernel<<<(total + TPB - 1) / TPB, TPB, 0, stream>>>(
            out1, w_off3, b_off3, A, B, 64, 80, 80, 18, 40, 40, 2);
    }
    // 10) feat_1_16 = deform_mfma<256>(nhwc(feat_1_8), offset3) -> out2
    deform_mfma_kernel<256><<<8 * 1600 / 16, TPB, 0, stream>>>(
        (const short*)bufB, A, wtd3, b_d3, out2, 80, 80, 40, 40, 2);
}

// Round 7
// 694.485 us; speedup vs baseline: 10.3311x; 1.7456x over previous
//
#include <hip/hip_runtime.h>
#include <hip/hip_bf16.h>
#include <math.h>

#define TPB 256

typedef __attribute__((ext_vector_type(8))) short bf16x8_t;
typedef __attribute__((ext_vector_type(4))) float f32x4_t;

static __device__ __forceinline__ float bf16_to_f(short s) {
    union { unsigned u; float f; } cv;
    cv.u = ((unsigned)(unsigned short)s) << 16;
    return cv.f;
}
static __device__ __forceinline__ short f_to_bf16(float v) {
    __hip_bfloat16 h = __float2bfloat16(v);
    return *(short*)&h;
}

// ------------------------------------------------- weight repack for MFMA
// w (O, 64, 3, 3) fp32 -> wt bf16 [oc][tap*64+ic]
__global__ void repack_w_kernel(const float* __restrict__ w,
                                short* __restrict__ wt, int O)
{
    int idx = blockIdx.x * TPB + threadIdx.x;
    if (idx >= O * 64 * 9) return;
    int ic  = idx % 64;
    int t   = idx / 64;
    int tap = t % 9;
    int oc  = t / 9;
    wt[(size_t)oc * 576 + tap * 64 + ic] =
        f_to_bf16(w[((size_t)(oc * 64 + ic)) * 9 + tap]);
}

// ------------------------------------------------- MFMA conv 3x3 (64->64, s1)
__global__ __launch_bounds__(256, 1) void conv3x3_mfma_kernel(
    const float* __restrict__ in,
    const short* __restrict__ wt,
    float* __restrict__ out,
    int B)
{
    __shared__ short tile[18 * 18 * 64];   // 41472 B
    const int H = 160, W = 160;
    int blk = blockIdx.x;
    int b  = blk / 100;
    int r  = blk % 100;
    int y0 = (r / 10) * 16;
    int x0 = (r % 10) * 16;
    const int tid = threadIdx.x;

    const float* inb = in + (size_t)b * 64 * H * W;
    for (int it = tid; it < 18 * 18 * 64; it += TPB) {
        int col = it % 18;
        int t2  = it / 18;
        int row = t2 % 18;
        int ic  = t2 / 18;
        int y = y0 + row - 1;
        int x = x0 + col - 1;
        float v = 0.f;
        if (y >= 0 && y < H && x >= 0 && x < W)
            v = inb[(size_t)ic * H * W + y * W + x];
        int sw = ((((ic >> 3) ^ (col & 7)) << 3) | (ic & 7));
        tile[(row * 18 + col) * 64 + sw] = f_to_bf16(v);
    }
    __syncthreads();

    const int wv  = tid >> 6;
    const int l   = tid & 63;
    const int l15 = l & 15;
    const int lg  = l >> 4;

    f32x4_t acc[4][4];
#pragma unroll
    for (int i = 0; i < 4; ++i)
#pragma unroll
        for (int j = 0; j < 4; ++j)
            acc[i][j] = (f32x4_t){0.f, 0.f, 0.f, 0.f};

#pragma unroll 2
    for (int kc = 0; kc < 18; ++kc) {
        int tap = kc >> 1;
        int dy  = tap / 3;
        int dx  = tap % 3;

        bf16x8_t bf[4];
#pragma unroll
        for (int nf = 0; nf < 4; ++nf) {
            int oc = nf * 16 + l15;
            bf[nf] = *(const bf16x8_t*)(wt + (size_t)oc * 576 + kc * 32 + lg * 8);
        }

        int colr  = l15 + dx;
        int chunk = (((kc & 1) << 2) + lg) ^ (colr & 7);
        bf16x8_t af[4];
#pragma unroll
        for (int mf = 0; mf < 4; ++mf) {
            int row = wv * 4 + mf + dy;
            af[mf] = *(const bf16x8_t*)&tile[(row * 18 + colr) * 64 + chunk * 8];
        }

#pragma unroll
        for (int mf = 0; mf < 4; ++mf)
#pragma unroll
            for (int nf = 0; nf < 4; ++nf)
                acc[mf][nf] = __builtin_amdgcn_mfma_f32_16x16x32_bf16(
                    af[mf], bf[nf], acc[mf][nf], 0, 0, 0);
    }

    float* outb = out + (size_t)b * 64 * H * W;
#pragma unroll
    for (int mf = 0; mf < 4; ++mf) {
        int y = y0 + wv * 4 + mf;
#pragma unroll
        for (int nf = 0; nf < 4; ++nf) {
            int oc = nf * 16 + l15;
            *(f32x4_t*)&outb[(size_t)oc * H * W + y * W + x0 + lg * 4] = acc[mf][nf];
        }
    }
}

// ------------------------------------------------- NCHW fp32 -> NHWC bf16 (C=64)
__global__ void nchw_to_nhwc_bf16_kernel(const float* __restrict__ in,
                                         short* __restrict__ out, int HW)
{
    __shared__ short tile[64][66];
    int nchunks = HW >> 6;
    int b  = blockIdx.x / nchunks;
    int p0 = (blockIdx.x % nchunks) << 6;
    int tid = threadIdx.x;
#pragma unroll
    for (int rep = 0; rep < 16; ++rep) {
        int item = rep * 256 + tid;
        int c = item >> 6, p = item & 63;
        tile[p][c] = f_to_bf16(in[((size_t)b * 64 + c) * HW + p0 + p]);
    }
    __syncthreads();
#pragma unroll
    for (int rep = 0; rep < 16; ++rep) {
        int item = rep * 256 + tid;
        int p = item >> 6, c = item & 63;
        out[((size_t)b * HW + p0 + p) * 64 + c] = tile[p][c];
    }
}

// ------------------------------------------------- x NCHW (C=3) -> NHWC4 fp32
__global__ void x_to_nhwc4_kernel(const float* __restrict__ in,
                                  float* __restrict__ out)
{
    int idx = blockIdx.x * TPB + threadIdx.x;
    const int HW = 640 * 640;
    if (idx >= 8 * HW) return;
    int b = idx / HW, p = idx % HW;
    f32x4_t v;
    v[0] = in[((size_t)b * 3 + 0) * HW + p];
    v[1] = in[((size_t)b * 3 + 1) * HW + p];
    v[2] = in[((size_t)b * 3 + 2) * HW + p];
    v[3] = 0.f;
    *(f32x4_t*)&out[(size_t)idx * 4] = v;
}

// ------------------------------------------------- offset1: exact fp32, NHWC4
// x4 [8][640][640][4] fp32 -> out (8,18,160,160), 3x3 s=4 pad=1
__global__ void offset1_kernel(const float* __restrict__ x4,
                               const float* __restrict__ w,   // (18,3,3,3)
                               const float* __restrict__ bias,
                               float* __restrict__ out)
{
    const int H = 640, W = 640, HW = 25600;
    int idx = blockIdx.x * TPB + threadIdx.x;
    if (idx >= 8 * HW) return;
    int b = idx / HW, r = idx % HW;
    int ho = r / 160, wo = r % 160;

    float acc[18];
#pragma unroll
    for (int o = 0; o < 18; ++o) acc[o] = bias[o];

    const float* xb = x4 + (size_t)b * H * W * 4;
#pragma unroll
    for (int tap = 0; tap < 9; ++tap) {
        int iy = ho * 4 - 1 + tap / 3;
        int ix = wo * 4 - 1 + tap % 3;
        if (iy < 0 || iy >= H || ix < 0 || ix >= W) continue;
        f32x4_t s = *(const f32x4_t*)&xb[((size_t)iy * W + ix) * 4];
#pragma unroll
        for (int c = 0; c < 3; ++c)
#pragma unroll
            for (int o = 0; o < 18; ++o)
                acc[o] += s[c] * w[(o * 3 + c) * 9 + tap];
    }
#pragma unroll
    for (int o = 0; o < 18; ++o)
        out[((size_t)(b * 18 + o)) * HW + r] = acc[o];
}

// ------------------------------------------------- offset2/3: MFMA conv, N=18
// xh NHWC bf16 [B][H][W][64]; 3x3, stride 2, pad 1; out (B,18,Ho,Wo) fp32.
// Block = 4 waves x 16 pixels = 64 consecutive output pixels (HW % 64 == 0).
__global__ __launch_bounds__(256, 1) void offconv_mfma_kernel(
    const short* __restrict__ xh,
    const short* __restrict__ wt,    // bf16 [18][576]
    const float* __restrict__ bias,  // (18,)
    float* __restrict__ out,
    int H, int W, int Ho, int Wo)
{
    const int HW = Ho * Wo;
    const int tid = threadIdx.x;
    const int wv = tid >> 6, l = tid & 63;
    const int l15 = l & 15, lg = l >> 4;
    const int pix0 = blockIdx.x * 64 + wv * 16;    // wave's 16 pixels
    const int b = pix0 / HW;
    const int r0 = pix0 - b * HW;

    // this lane's A-row pixel
    int rp = r0 + l15;
    int ho = rp / Wo, wo = rp % Wo;
    const short* xb = xh + (size_t)b * H * W * 64;

    f32x4_t acc[2];
    acc[0] = (f32x4_t){0.f, 0.f, 0.f, 0.f};
    acc[1] = (f32x4_t){0.f, 0.f, 0.f, 0.f};

#pragma unroll 2
    for (int kc = 0; kc < 18; ++kc) {
        int tap = kc >> 1;
        int iy = ho * 2 - 1 + tap / 3;
        int ix = wo * 2 - 1 + tap % 3;
        bf16x8_t af = {};
        if (iy >= 0 && iy < H && ix >= 0 && ix < W)
            af = *(const bf16x8_t*)&xb[((size_t)iy * W + ix) * 64
                                       + (kc & 1) * 32 + lg * 8];
#pragma unroll
        for (int nf = 0; nf < 2; ++nf) {
            int oc = nf * 16 + l15;
            bf16x8_t bf = {};
            if (oc < 18)
                bf = *(const bf16x8_t*)(wt + (size_t)oc * 576 + kc * 32 + lg * 8);
            acc[nf] = __builtin_amdgcn_mfma_f32_16x16x32_bf16(af, bf, acc[nf], 0, 0, 0);
        }
    }

#pragma unroll
    for (int nf = 0; nf < 2; ++nf) {
        int oc = nf * 16 + l15;
        if (oc < 18) {
            float bv = bias[oc];
            f32x4_t v = acc[nf];
            v[0] += bv; v[1] += bv; v[2] += bv; v[3] += bv;
            *(f32x4_t*)&out[((size_t)(b * 18 + oc)) * HW + r0 + lg * 4] = v;
        }
    }
}

// ------------------------------------------------- deform1: C=3 (NHWC4), O=64
__global__ __launch_bounds__(256, 1) void deform1_kernel(
    const float* __restrict__ x4,   // [B][640][640][4] fp32
    const float* __restrict__ off,  // [B][18][160][160]
    const float* __restrict__ w,    // (64,3,3,3) fp32
    const float* __restrict__ bias,
    float* __restrict__ out)        // [B][64][160][160]
{
    const int H = 640, W = 640, Ho = 160, Wo = 160, HW = 25600;
    __shared__ float samp[16][27];
    __shared__ int   sidx[144][4];
    __shared__ float swt[144][4];
    const int tid = threadIdx.x;
    const int pix0 = blockIdx.x * 16;
    const int b = pix0 / HW;
    const int r0 = pix0 - b * HW;

    if (tid < 144) {
        int p = tid / 9, tap = tid % 9;
        int r = r0 + p, ho = r / Wo, wo = r % Wo;
        float dy = off[((size_t)(b * 18 + 2 * tap) * Ho + ho) * Wo + wo];
        float dx = off[((size_t)(b * 18 + 2 * tap + 1) * Ho + ho) * Wo + wo];
        float ys = (float)(ho * 4 - 1 + tap / 3) + dy;
        float xs = (float)(wo * 4 - 1 + tap % 3) + dx;
        float y0f = floorf(ys), x0f = floorf(xs);
        float fy = ys - y0f, fx = xs - x0f;
        int y0 = (int)y0f, x0 = (int)x0f;
        float wts[4] = {(1.f - fy) * (1.f - fx), (1.f - fy) * fx,
                        fy * (1.f - fx),          fy * fx};
#pragma unroll
        for (int j = 0; j < 4; ++j) {
            int iy = y0 + (j >> 1), ix = x0 + (j & 1);
            bool v = (iy >= 0) && (iy < H) && (ix >= 0) && (ix < W);
            sidx[tid][j] = v ? (iy * W + ix) : -1;
            swt[tid][j]  = wts[j];
        }
    }
    __syncthreads();

    if (tid < 144) {
        int p = tid / 9, tap = tid % 9;
        const float* xb = x4 + (size_t)b * H * W * 4;
        float s0 = 0.f, s1 = 0.f, s2 = 0.f;
#pragma unroll
        for (int j = 0; j < 4; ++j) {
            int id = sidx[tid][j];
            if (id >= 0) {
                f32x4_t v = *(const f32x4_t*)&xb[(size_t)id * 4];
                float wj = swt[tid][j];
                s0 += wj * v[0];
                s1 += wj * v[1];
                s2 += wj * v[2];
            }
        }
        // layout MUST match MAC phase read: samp[p][c*9 + tap]
        samp[p][0 * 9 + tap] = s0;
        samp[p][1 * 9 + tap] = s1;
        samp[p][2 * 9 + tap] = s2;
    }
    __syncthreads();

    int g = tid >> 6;      // wave -> 4-pixel group
    int o = tid & 63;
    float acc[4];
#pragma unroll
    for (int pi = 0; pi < 4; ++pi) acc[pi] = bias[o];
#pragma unroll
    for (int c = 0; c < 3; ++c)
#pragma unroll
        for (int k = 0; k < 9; ++k) {
            float wv = w[((size_t)(o * 3 + c)) * 9 + k];
#pragma unroll
            for (int pi = 0; pi < 4; ++pi)
                acc[pi] += wv * samp[g * 4 + pi][c * 9 + k];
        }
#pragma unroll
    for (int pi = 0; pi < 4; ++pi)
        out[((size_t)(b * 64 + o)) * HW + r0 + g * 4 + pi] = acc[pi];
}

// ------------------------------------------------- deform MFMA: C=64 -> O
// xh NHWC bf16 [B][H][W][64]; samp LDS [16 pixels][K=576] bf16, XOR-swizzled.
template <int O>
__global__ __launch_bounds__(256, 1) void deform_mfma_kernel(
    const short* __restrict__ xh,
    const float* __restrict__ off,  // [B][18][Ho][Wo]
    const short* __restrict__ wt,   // bf16 [O][576]
    const float* __restrict__ bias,
    float* __restrict__ out,        // [B][O][Ho][Wo]
    int H, int W, int Ho, int Wo, int stride)
{
    constexpr int NF = O / 64;      // N-frags per wave
    __shared__ alignas(16) short samp[16 * 576];
    __shared__ int   sidx[144][4];
    __shared__ float swt[144][4];

    const int tid = threadIdx.x;
    const int HW = Ho * Wo;
    const int pix0 = blockIdx.x * 16;
    const int b = pix0 / HW;
    const int r0 = pix0 - b * HW;

    // phase 1: bilinear corners for 16 pixels x 9 taps
    if (tid < 144) {
        int p = tid / 9, tap = tid % 9;
        int r = r0 + p, ho = r / Wo, wo = r % Wo;
        float dy = off[((size_t)(b * 18 + 2 * tap) * Ho + ho) * Wo + wo];
        float dx = off[((size_t)(b * 18 + 2 * tap + 1) * Ho + ho) * Wo + wo];
        float ys = (float)(ho * stride - 1 + tap / 3) + dy;
        float xs = (float)(wo * stride - 1 + tap % 3) + dx;
        float y0f = floorf(ys), x0f = floorf(xs);
        float fy = ys - y0f, fx = xs - x0f;
        int y0 = (int)y0f, x0 = (int)x0f;
        float wts[4] = {(1.f - fy) * (1.f - fx), (1.f - fy) * fx,
                        fy * (1.f - fx),          fy * fx};
#pragma unroll
        for (int j = 0; j < 4; ++j) {
            int iy = y0 + (j >> 1), ix = x0 + (j & 1);
            bool v = (iy >= 0) && (iy < H) && (ix >= 0) && (ix < W);
            sidx[tid][j] = v ? (iy * W + ix) : -1;
            swt[tid][j]  = wts[j];
        }
    }
    __syncthreads();

    const int wv = tid >> 6;
    const int l  = tid & 63;

    // phase 2: coalesced channel-gather (lane = channel)
    const short* xb = xh + (size_t)b * H * W * 64;
#pragma unroll 2
    for (int i = 0; i < 36; ++i) {
        int e = wv * 36 + i;
        int p = e / 9, tap = e % 9;
        float v = 0.f;
#pragma unroll
        for (int j = 0; j < 4; ++j) {
            int id = sidx[e][j];
            if (id >= 0)
                v += swt[e][j] * bf16_to_f(xb[(size_t)id * 64 + l]);
        }
        int sw = (tap * 8 + ((l >> 3) ^ (p & 7))) * 8 + (l & 7);
        samp[p * 576 + sw] = f_to_bf16(v);
    }
    __syncthreads();

    // phase 3: MFMA  (M=16 pixels, N=O, K=576)
    const int l15 = l & 15, lg = l >> 4;
    f32x4_t acc[NF];
#pragma unroll
    for (int nf = 0; nf < NF; ++nf)
        acc[nf] = (f32x4_t){0.f, 0.f, 0.f, 0.f};

#pragma unroll 2
    for (int kc = 0; kc < 18; ++kc) {
        int tap = kc >> 1;
        int low = (((kc & 1) << 2) | lg) ^ (l15 & 7);
        bf16x8_t af = *(const bf16x8_t*)&samp[l15 * 576 + (tap * 8 + low) * 8];
#pragma unroll
        for (int nf = 0; nf < NF; ++nf) {
            int oc = (wv * NF + nf) * 16 + l15;
            bf16x8_t bf = *(const bf16x8_t*)(wt + (size_t)oc * 576 + kc * 32 + lg * 8);
            acc[nf] = __builtin_amdgcn_mfma_f32_16x16x32_bf16(af, bf, acc[nf], 0, 0, 0);
        }
    }

#pragma unroll
    for (int nf = 0; nf < NF; ++nf) {
        int oc = (wv * NF + nf) * 16 + l15;
        float bv = bias[oc];
        f32x4_t v = acc[nf];
        v[0] += bv; v[1] += bv; v[2] += bv; v[3] += bv;
        *(f32x4_t*)&out[((size_t)(b * O + oc)) * HW + r0 + lg * 4] = v;
    }
}

// ---------------------------------------------------------------- avgpool 4x4
__global__ void avgpool4_kernel(const float* __restrict__ in,
                                float* __restrict__ out,
                                int BC, int Ho, int Wo, int H, int W)
{
    int idx = blockIdx.x * TPB + threadIdx.x;
    int total = BC * Ho * Wo;
    if (idx >= total) return;
    int wo = idx % Wo;
    int t = idx / Wo;
    int ho = t % Ho;
    int bc = t / Ho;
    const float* xp = in + (size_t)bc * H * W + (ho * 4) * W + wo * 4;
    float s = 0.f;
#pragma unroll
    for (int i = 0; i < 4; ++i)
#pragma unroll
        for (int j = 0; j < 4; ++j)
            s += xp[i * W + j];
    out[idx] = s * (1.0f / 16.0f);
}

// ------------------------------------------------- skip: d1 += 1x1conv(pool)
__global__ void skip_add_kernel(float* __restrict__ d1,
                                const float* __restrict__ pool,
                                const float* __restrict__ wsk,
                                const float* __restrict__ bsk,
                                int B, int HW)
{
    int idx = blockIdx.x * TPB + threadIdx.x;
    int total = B * 64 * HW;
    if (idx >= total) return;
    int r = idx % HW;
    int t = idx / HW;
    int o = t % 64;
    int bb = t / 64;
    const float* pp = pool + (size_t)bb * 3 * HW + r;
    float v = d1[idx] + bsk[o];
    v += wsk[o * 3 + 0] * pp[0];
    v += wsk[o * 3 + 1] * pp[HW];
    v += wsk[o * 3 + 2] * pp[2 * HW];
    d1[idx] = v;
}

// ---------------------------------------------------------------- batchnorm
__global__ void zero_stats_kernel(float* __restrict__ stats)
{
    if (threadIdx.x < 128) stats[threadIdx.x] = 0.f;
}

__global__ void bn_stats_kernel(const float* __restrict__ in,
                                float* __restrict__ stats,
                                int C, int HW)
{
    int bc = blockIdx.x;
    int c = bc % C;
    const float* p = in + (size_t)bc * HW;
    float s = 0.f, s2 = 0.f;
    for (int i = threadIdx.x; i < HW; i += TPB) {
        float v = p[i];
        s += v;
        s2 += v * v;
    }
    __shared__ float ss[TPB], sq[TPB];
    ss[threadIdx.x] = s;
    sq[threadIdx.x] = s2;
    __syncthreads();
    for (int st = TPB / 2; st > 0; st >>= 1) {
        if (threadIdx.x < st) {
            ss[threadIdx.x] += ss[threadIdx.x + st];
            sq[threadIdx.x] += sq[threadIdx.x + st];
        }
        __syncthreads();
    }
    if (threadIdx.x == 0) {
        atomicAdd(&stats[c * 2], ss[0]);
        atomicAdd(&stats[c * 2 + 1], sq[0]);
    }
}

__global__ void bn_apply_kernel(const float* __restrict__ in,
                                const float* __restrict__ stats,
                                float* __restrict__ out,
                                int C, int HW, int total, float invN)
{
    int idx = blockIdx.x * TPB + threadIdx.x;
    if (idx >= total) return;
    int c = (idx / HW) % C;
    float mean = stats[c * 2] * invN;
    float var = stats[c * 2 + 1] * invN - mean * mean;
    float r = rsqrtf(var + 1e-5f);
    float v = (in[idx] - mean) * r;
    out[idx] = v > 0.f ? v : 0.f;
}

// ---------------------------------------------------------------- launch
extern "C" void kernel_launch(void* const* d_in, const int* in_sizes, int n_in,
                              void* d_out, int out_size, void* d_ws, size_t ws_size,
                              hipStream_t stream)
{
    const float* x      = (const float*)d_in[0];
    const float* w_off1 = (const float*)d_in[1];
    const float* b_off1 = (const float*)d_in[2];
    const float* w_d1   = (const float*)d_in[3];
    const float* b_d1   = (const float*)d_in[4];
    const float* w_skip = (const float*)d_in[5];
    const float* b_skip = (const float*)d_in[6];
    const float* w_bl1  = (const float*)d_in[7];
    const float* w_bl2  = (const float*)d_in[8];
    const float* w_off2 = (const float*)d_in[9];
    const float* b_off2 = (const float*)d_in[10];
    const float* w_d2   = (const float*)d_in[11];
    const float* b_d2   = (const float*)d_in[12];
    const float* w_off3 = (const float*)d_in[13];
    const float* b_off3 = (const float*)d_in[14];
    const float* w_d3   = (const float*)d_in[15];
    const float* b_d3   = (const float*)d_in[16];

    const int B = 8;
    float* A     = (float*)d_ws;          // 3,686,400 floats (multi-use)
    float* bufB  = A + 3686400;           // 13,107,200 floats
    float* bufC  = bufB + 13107200;       // 13,107,200 floats
    float* stats = bufC + 13107200;       // 128

    // weight repack areas inside A. Lifetime: repacked AFTER offset1
    // (which covers all of A) is consumed; later writes into A are
    // pool (614,400 fl), offset2 (921,600 fl), offset3 (230,400 fl) — all
    // below A+1,000,000, so these regions survive until their uses.
    short* wt1    = (short*)(A + 1000000);      //  36,864 shorts
    short* wt2    = wt1 + 64 * 576;
    short* wtd2   = (short*)(A + 1500000);      //  36,864 shorts
    short* wtd3   = (short*)(A + 1550000);      // 147,456 shorts
    short* wtoff2 = (short*)(A + 1700000);      //  10,368 shorts
    short* wtoff3 = (short*)(A + 1710000);      //  10,368 shorts

    float* out0 = (float*)d_out;          // feat_1_4  (8,64,160,160)
    float* out1 = out0 + 13107200;        // feat_1_8  (8,64,80,80)
    float* out2 = out1 + 3276800;         // feat_1_16 (8,256,40,40)

    // 0) x -> NHWC4 fp32 into bufC (free until step 5)
    x_to_nhwc4_kernel<<<(8 * 409600 + TPB - 1) / TPB, TPB, 0, stream>>>(x, bufC);

    // 1) offset1 = conv3x3(x NHWC4, s=4) exact fp32 -> A (covers ALL of A)
    offset1_kernel<<<(8 * 25600 + TPB - 1) / TPB, TPB, 0, stream>>>(
        bufC, w_off1, b_off1, A);

    // 2) d1 = deform1(x NHWC4, offset1) -> bufB   (offset1 dead after this)
    deform1_kernel<<<8 * 25600 / 16, TPB, 0, stream>>>(bufC, A, w_d1, b_d1, bufB);

    // 2.5) repack all MFMA weights (A is now safe above +1,000,000)
    repack_w_kernel<<<(64 * 576 + TPB - 1) / TPB, TPB, 0, stream>>>(w_bl1, wt1, 64);
    repack_w_kernel<<<(64 * 576 + TPB - 1) / TPB, TPB, 0, stream>>>(w_bl2, wt2, 64);
    repack_w_kernel<<<(64 * 576 + TPB - 1) / TPB, TPB, 0, stream>>>(w_d2, wtd2, 64);
    repack_w_kernel<<<(256 * 576 + TPB - 1) / TPB, TPB, 0, stream>>>(w_d3, wtd3, 256);
    repack_w_kernel<<<(18 * 576 + TPB - 1) / TPB, TPB, 0, stream>>>(w_off2, wtoff2, 18);
    repack_w_kernel<<<(18 * 576 + TPB - 1) / TPB, TPB, 0, stream>>>(w_off3, wtoff3, 18);

    // 3) pool = avgpool4(x) -> A[0 .. 614,399]
    {
        int total = B * 3 * 160 * 160;
        avgpool4_kernel<<<(total + TPB - 1) / TPB, TPB, 0, stream>>>(
            x, A, B * 3, 160, 160, 640, 640);
    }
    // 4) bufB += conv1x1(pool) + b_skip
    {
        int total = B * 64 * 25600;
        skip_add_kernel<<<(total + TPB - 1) / TPB, TPB, 0, stream>>>(
            bufB, A, w_skip, b_skip, B, 25600);
    }
    // 5) bufC = conv_mfma(bufB, wt1); bn+relu in place  (x NHWC4 dead)
    {
        int total = B * 64 * 160 * 160;
        conv3x3_mfma_kernel<<<800, TPB, 0, stream>>>(bufB, wt1, bufC, B);
        zero_stats_kernel<<<1, 128, 0, stream>>>(stats);
        bn_stats_kernel<<<B * 64, TPB, 0, stream>>>(bufC, stats, 64, 25600);
        bn_apply_kernel<<<(total + TPB - 1) / TPB, TPB, 0, stream>>>(
            bufC, stats, bufC, 64, 25600, total, 1.0f / (B * 25600));
    }
    // 6) bufB = conv_mfma(bufC, wt2); bn+relu -> out0 (feat_1_4)
    {
        int total = B * 64 * 160 * 160;
        conv3x3_mfma_kernel<<<800, TPB, 0, stream>>>(bufC, wt2, bufB, B);
        zero_stats_kernel<<<1, 128, 0, stream>>>(stats);
        bn_stats_kernel<<<B * 64, TPB, 0, stream>>>(bufB, stats, 64, 25600);
        bn_apply_kernel<<<(total + TPB - 1) / TPB, TPB, 0, stream>>>(
            bufB, stats, out0, 64, 25600, total, 1.0f / (B * 25600));
    }
    // 6.5) feat_1_4 -> NHWC bf16 into bufC
    nchw_to_nhwc_bf16_kernel<<<8 * (25600 / 64), TPB, 0, stream>>>(
        out0, (short*)bufC, 25600);

    // 7) offset2 = offconv_mfma(nhwc(feat_1_4)) -> A[0 .. 921,599]
    offconv_mfma_kernel<<<8 * 6400 / 64, TPB, 0, stream>>>(
        (const short*)bufC, wtoff2, b_off2, A, 160, 160, 80, 80);

    // 8) feat_1_8 = deform_mfma<64>(nhwc(feat_1_4), offset2) -> out1
    deform_mfma_kernel<64><<<8 * 6400 / 16, TPB, 0, stream>>>(
        (const short*)bufC, A, wtd2, b_d2, out1, 160, 160, 80, 80, 2);

    // 8.5) feat_1_8 -> NHWC bf16 into bufB
    nchw_to_nhwc_bf16_kernel<<<8 * (6400 / 64), TPB, 0, stream>>>(
        out1, (short*)bufB, 6400);

    // 9) offset3 = offconv_mfma(nhwc(feat_1_8)) -> A[0 .. 230,399]
    offconv_mfma_kernel<<<8 * 1600 / 64, TPB, 0, stream>>>(
        (const short*)bufB, wtoff3, b_off3, A, 80, 80, 40, 40);

    // 10) feat_1_16 = deform_mfma<256>(nhwc(feat_1_8), offset3) -> out2
    deform_mfma_kernel<256><<<8 * 1600 / 16, TPB, 0, stream>>>(
        (const short*)bufB, A, wtd3, b_d3, out2, 80, 80, 40, 40, 2);
}

// Round 8
// 638.850 us; speedup vs baseline: 11.2308x; 1.0871x over previous
//
#include <hip/hip_runtime.h>
#include <hip/hip_bf16.h>
#include <math.h>

#define TPB 256

typedef __attribute__((ext_vector_type(8))) short bf16x8_t;
typedef __attribute__((ext_vector_type(4))) float f32x4_t;
typedef __attribute__((ext_vector_type(4))) unsigned short u16x4_t;

static __device__ __forceinline__ float bf16_to_f(unsigned short s) {
    union { unsigned u; float f; } cv;
    cv.u = ((unsigned)s) << 16;
    return cv.f;
}
static __device__ __forceinline__ short f_to_bf16(float v) {
    __hip_bfloat16 h = __float2bfloat16(v);
    return *(short*)&h;
}

// ------------------------------------------------- weight repack for MFMA
// w (O, 64, 3, 3) fp32 -> wt bf16 [oc][tap*64+ic]
__global__ void repack_w_kernel(const float* __restrict__ w,
                                short* __restrict__ wt, int O)
{
    int idx = blockIdx.x * TPB + threadIdx.x;
    if (idx >= O * 64 * 9) return;
    int ic  = idx % 64;
    int t   = idx / 64;
    int tap = t % 9;
    int oc  = t / 9;
    wt[(size_t)oc * 576 + tap * 64 + ic] =
        f_to_bf16(w[((size_t)(oc * 64 + ic)) * 9 + tap]);
}

// ------------------------------------------------- MFMA conv 3x3 (64->64, s1)
__global__ __launch_bounds__(256, 1) void conv3x3_mfma_kernel(
    const float* __restrict__ in,
    const short* __restrict__ wt,
    float* __restrict__ out,
    int B)
{
    __shared__ short tile[18 * 18 * 64];   // 41472 B
    const int H = 160, W = 160;
    int blk = blockIdx.x;
    int b  = blk / 100;
    int r  = blk % 100;
    int y0 = (r / 10) * 16;
    int x0 = (r % 10) * 16;
    const int tid = threadIdx.x;

    const float* inb = in + (size_t)b * 64 * H * W;
    for (int it = tid; it < 18 * 18 * 64; it += TPB) {
        int col = it % 18;
        int t2  = it / 18;
        int row = t2 % 18;
        int ic  = t2 / 18;
        int y = y0 + row - 1;
        int x = x0 + col - 1;
        float v = 0.f;
        if (y >= 0 && y < H && x >= 0 && x < W)
            v = inb[(size_t)ic * H * W + y * W + x];
        int sw = ((((ic >> 3) ^ (col & 7)) << 3) | (ic & 7));
        tile[(row * 18 + col) * 64 + sw] = f_to_bf16(v);
    }
    __syncthreads();

    const int wv  = tid >> 6;
    const int l   = tid & 63;
    const int l15 = l & 15;
    const int lg  = l >> 4;

    f32x4_t acc[4][4];
#pragma unroll
    for (int i = 0; i < 4; ++i)
#pragma unroll
        for (int j = 0; j < 4; ++j)
            acc[i][j] = (f32x4_t){0.f, 0.f, 0.f, 0.f};

#pragma unroll 2
    for (int kc = 0; kc < 18; ++kc) {
        int tap = kc >> 1;
        int dy  = tap / 3;
        int dx  = tap % 3;

        bf16x8_t bf[4];
#pragma unroll
        for (int nf = 0; nf < 4; ++nf) {
            int oc = nf * 16 + l15;
            bf[nf] = *(const bf16x8_t*)(wt + (size_t)oc * 576 + kc * 32 + lg * 8);
        }

        int colr  = l15 + dx;
        int chunk = (((kc & 1) << 2) + lg) ^ (colr & 7);
        bf16x8_t af[4];
#pragma unroll
        for (int mf = 0; mf < 4; ++mf) {
            int row = wv * 4 + mf + dy;
            af[mf] = *(const bf16x8_t*)&tile[(row * 18 + colr) * 64 + chunk * 8];
        }

#pragma unroll
        for (int mf = 0; mf < 4; ++mf)
#pragma unroll
            for (int nf = 0; nf < 4; ++nf)
                acc[mf][nf] = __builtin_amdgcn_mfma_f32_16x16x32_bf16(
                    af[mf], bf[nf], acc[mf][nf], 0, 0, 0);
    }

    float* outb = out + (size_t)b * 64 * H * W;
#pragma unroll
    for (int mf = 0; mf < 4; ++mf) {
        int y = y0 + wv * 4 + mf;
#pragma unroll
        for (int nf = 0; nf < 4; ++nf) {
            int oc = nf * 16 + l15;
            *(f32x4_t*)&outb[(size_t)oc * H * W + y * W + x0 + lg * 4] = acc[mf][nf];
        }
    }
}

// ------------------------------------------------- NCHW fp32 -> NHWC bf16 (C=64)
__global__ void nchw_to_nhwc_bf16_kernel(const float* __restrict__ in,
                                         short* __restrict__ out, int HW)
{
    __shared__ short tile[64][66];
    int nchunks = HW >> 6;
    int b  = blockIdx.x / nchunks;
    int p0 = (blockIdx.x % nchunks) << 6;
    int tid = threadIdx.x;
#pragma unroll
    for (int rep = 0; rep < 16; ++rep) {
        int item = rep * 256 + tid;
        int c = item >> 6, p = item & 63;
        tile[p][c] = f_to_bf16(in[((size_t)b * 64 + c) * HW + p0 + p]);
    }
    __syncthreads();
#pragma unroll
    for (int rep = 0; rep < 16; ++rep) {
        int item = rep * 256 + tid;
        int p = item >> 6, c = item & 63;
        out[((size_t)b * HW + p0 + p) * 64 + c] = tile[p][c];
    }
}

// ------------------------------------------------- x NCHW (C=3) -> NHWC4 fp32
__global__ void x_to_nhwc4_kernel(const float* __restrict__ in,
                                  float* __restrict__ out)
{
    int idx = blockIdx.x * TPB + threadIdx.x;
    const int HW = 640 * 640;
    if (idx >= 8 * HW) return;
    int b = idx / HW, p = idx % HW;
    f32x4_t v;
    v[0] = in[((size_t)b * 3 + 0) * HW + p];
    v[1] = in[((size_t)b * 3 + 1) * HW + p];
    v[2] = in[((size_t)b * 3 + 2) * HW + p];
    v[3] = 0.f;
    *(f32x4_t*)&out[(size_t)idx * 4] = v;
}

// ------------------------------------------------- offset1: exact fp32, NHWC4
__global__ void offset1_kernel(const float* __restrict__ x4,
                               const float* __restrict__ w,   // (18,3,3,3)
                               const float* __restrict__ bias,
                               float* __restrict__ out)
{
    const int H = 640, W = 640, HW = 25600;
    int idx = blockIdx.x * TPB + threadIdx.x;
    if (idx >= 8 * HW) return;
    int b = idx / HW, r = idx % HW;
    int ho = r / 160, wo = r % 160;

    float acc[18];
#pragma unroll
    for (int o = 0; o < 18; ++o) acc[o] = bias[o];

    const float* xb = x4 + (size_t)b * H * W * 4;
#pragma unroll
    for (int tap = 0; tap < 9; ++tap) {
        int iy = ho * 4 - 1 + tap / 3;
        int ix = wo * 4 - 1 + tap % 3;
        if (iy < 0 || iy >= H || ix < 0 || ix >= W) continue;
        f32x4_t s = *(const f32x4_t*)&xb[((size_t)iy * W + ix) * 4];
#pragma unroll
        for (int c = 0; c < 3; ++c)
#pragma unroll
            for (int o = 0; o < 18; ++o)
                acc[o] += s[c] * w[(o * 3 + c) * 9 + tap];
    }
#pragma unroll
    for (int o = 0; o < 18; ++o)
        out[((size_t)(b * 18 + o)) * HW + r] = acc[o];
}

// ------------------------------------------------- offset2/3: MFMA conv, N=18
__global__ __launch_bounds__(256, 1) void offconv_mfma_kernel(
    const short* __restrict__ xh,
    const short* __restrict__ wt,    // bf16 [18][576]
    const float* __restrict__ bias,  // (18,)
    float* __restrict__ out,
    int H, int W, int Ho, int Wo)
{
    const int HW = Ho * Wo;
    const int tid = threadIdx.x;
    const int wv = tid >> 6, l = tid & 63;
    const int l15 = l & 15, lg = l >> 4;
    const int pix0 = blockIdx.x * 64 + wv * 16;
    const int b = pix0 / HW;
    const int r0 = pix0 - b * HW;

    int rp = r0 + l15;
    int ho = rp / Wo, wo = rp % Wo;
    const short* xb = xh + (size_t)b * H * W * 64;

    f32x4_t acc[2];
    acc[0] = (f32x4_t){0.f, 0.f, 0.f, 0.f};
    acc[1] = (f32x4_t){0.f, 0.f, 0.f, 0.f};

#pragma unroll 2
    for (int kc = 0; kc < 18; ++kc) {
        int tap = kc >> 1;
        int iy = ho * 2 - 1 + tap / 3;
        int ix = wo * 2 - 1 + tap % 3;
        bf16x8_t af = {};
        if (iy >= 0 && iy < H && ix >= 0 && ix < W)
            af = *(const bf16x8_t*)&xb[((size_t)iy * W + ix) * 64
                                       + (kc & 1) * 32 + lg * 8];
#pragma unroll
        for (int nf = 0; nf < 2; ++nf) {
            int oc = nf * 16 + l15;
            bf16x8_t bf = {};
            if (oc < 18)
                bf = *(const bf16x8_t*)(wt + (size_t)oc * 576 + kc * 32 + lg * 8);
            acc[nf] = __builtin_amdgcn_mfma_f32_16x16x32_bf16(af, bf, acc[nf], 0, 0, 0);
        }
    }

#pragma unroll
    for (int nf = 0; nf < 2; ++nf) {
        int oc = nf * 16 + l15;
        if (oc < 18) {
            float bv = bias[oc];
            f32x4_t v = acc[nf];
            v[0] += bv; v[1] += bv; v[2] += bv; v[3] += bv;
            *(f32x4_t*)&out[((size_t)(b * 18 + oc)) * HW + r0 + lg * 4] = v;
        }
    }
}

// ------------------------------------------------- deform1: C=3 (NHWC4), O=64
__global__ __launch_bounds__(256, 1) void deform1_kernel(
    const float* __restrict__ x4,   // [B][640][640][4] fp32
    const float* __restrict__ off,  // [B][18][160][160]
    const float* __restrict__ w,    // (64,3,3,3) fp32
    const float* __restrict__ bias,
    float* __restrict__ out)        // [B][64][160][160]
{
    const int H = 640, W = 640, Ho = 160, Wo = 160, HW = 25600;
    __shared__ float samp[16][27];
    __shared__ int   sidx[144][4];
    __shared__ float swt[144][4];
    const int tid = threadIdx.x;
    const int pix0 = blockIdx.x * 16;
    const int b = pix0 / HW;
    const int r0 = pix0 - b * HW;

    if (tid < 144) {
        int p = tid / 9, tap = tid % 9;
        int r = r0 + p, ho = r / Wo, wo = r % Wo;
        float dy = off[((size_t)(b * 18 + 2 * tap) * Ho + ho) * Wo + wo];
        float dx = off[((size_t)(b * 18 + 2 * tap + 1) * Ho + ho) * Wo + wo];
        float ys = (float)(ho * 4 - 1 + tap / 3) + dy;
        float xs = (float)(wo * 4 - 1 + tap % 3) + dx;
        float y0f = floorf(ys), x0f = floorf(xs);
        float fy = ys - y0f, fx = xs - x0f;
        int y0 = (int)y0f, x0 = (int)x0f;
        float wts[4] = {(1.f - fy) * (1.f - fx), (1.f - fy) * fx,
                        fy * (1.f - fx),          fy * fx};
#pragma unroll
        for (int j = 0; j < 4; ++j) {
            int iy = y0 + (j >> 1), ix = x0 + (j & 1);
            bool v = (iy >= 0) && (iy < H) && (ix >= 0) && (ix < W);
            sidx[tid][j] = v ? (iy * W + ix) : -1;
            swt[tid][j]  = wts[j];
        }
    }
    __syncthreads();

    if (tid < 144) {
        int p = tid / 9, tap = tid % 9;
        const float* xb = x4 + (size_t)b * H * W * 4;
        float s0 = 0.f, s1 = 0.f, s2 = 0.f;
#pragma unroll
        for (int j = 0; j < 4; ++j) {
            int id = sidx[tid][j];
            if (id >= 0) {
                f32x4_t v = *(const f32x4_t*)&xb[(size_t)id * 4];
                float wj = swt[tid][j];
                s0 += wj * v[0];
                s1 += wj * v[1];
                s2 += wj * v[2];
            }
        }
        // layout MUST match MAC phase read: samp[p][c*9 + tap]
        samp[p][0 * 9 + tap] = s0;
        samp[p][1 * 9 + tap] = s1;
        samp[p][2 * 9 + tap] = s2;
    }
    __syncthreads();

    int g = tid >> 6;      // wave -> 4-pixel group
    int o = tid & 63;
    float acc[4];
#pragma unroll
    for (int pi = 0; pi < 4; ++pi) acc[pi] = bias[o];
#pragma unroll
    for (int c = 0; c < 3; ++c)
#pragma unroll
        for (int k = 0; k < 9; ++k) {
            float wv = w[((size_t)(o * 3 + c)) * 9 + k];
#pragma unroll
            for (int pi = 0; pi < 4; ++pi)
                acc[pi] += wv * samp[g * 4 + pi][c * 9 + k];
        }
#pragma unroll
    for (int pi = 0; pi < 4; ++pi)
        out[((size_t)(b * 64 + o)) * HW + r0 + g * 4 + pi] = acc[pi];
}

// ------------------------------------------------- deform MFMA: C=64 -> O
// xh NHWC bf16 [B][H][W][64]; P=32 pixels/block; samp LDS [32][576] bf16
// XOR-swizzled; gather vectorized: 16-lane group per (pixel,tap), lane
// loads 4 channels (ushort4, 8B).
template <int O>
__global__ __launch_bounds__(256, 1) void deform_mfma_kernel(
    const short* __restrict__ xh,
    const float* __restrict__ off,  // [B][18][Ho][Wo]
    const short* __restrict__ wt,   // bf16 [O][576]
    const float* __restrict__ bias,
    float* __restrict__ out,        // [B][O][Ho][Wo]
    int H, int W, int Ho, int Wo, int stride)
{
    constexpr int NF = O / 64;      // N-frags per wave
    constexpr int P  = 32;          // pixels per block
    __shared__ alignas(16) short samp[P * 576];   // 36864 B
    __shared__ int   sidx[P * 9][4];
    __shared__ float swt[P * 9][4];

    const int tid = threadIdx.x;
    const int HW = Ho * Wo;
    const int pix0 = blockIdx.x * P;
    const int b = pix0 / HW;
    const int r0 = pix0 - b * HW;

    // phase 1: bilinear corners for 32 pixels x 9 taps (288 entries)
    for (int item = tid; item < P * 9; item += TPB) {
        int p = item / 9, tap = item % 9;
        int r = r0 + p, ho = r / Wo, wo = r % Wo;
        float dy = off[((size_t)(b * 18 + 2 * tap) * Ho + ho) * Wo + wo];
        float dx = off[((size_t)(b * 18 + 2 * tap + 1) * Ho + ho) * Wo + wo];
        float ys = (float)(ho * stride - 1 + tap / 3) + dy;
        float xs = (float)(wo * stride - 1 + tap % 3) + dx;
        float y0f = floorf(ys), x0f = floorf(xs);
        float fy = ys - y0f, fx = xs - x0f;
        int y0 = (int)y0f, x0 = (int)x0f;
        float wts[4] = {(1.f - fy) * (1.f - fx), (1.f - fy) * fx,
                        fy * (1.f - fx),          fy * fx};
#pragma unroll
        for (int j = 0; j < 4; ++j) {
            int iy = y0 + (j >> 1), ix = x0 + (j & 1);
            bool v = (iy >= 0) && (iy < H) && (ix >= 0) && (ix < W);
            sidx[item][j] = v ? (iy * W + ix) : -1;
            swt[item][j]  = wts[j];
        }
    }
    __syncthreads();

    // phase 2: vectorized gather. group = 16 lanes, one entry per group;
    // lane loads channels c4*4 .. c4*4+3 (8 B).
    {
        const int grp = tid >> 4;       // 0..15
        const int c4  = tid & 15;       // channel quad
        const int ic  = c4 * 4;
        const short* xb = xh + (size_t)b * H * W * 64;
#pragma unroll 2
        for (int i = 0; i < 18; ++i) {
            int e = grp * 18 + i;       // entry 0..287
            int p = e / 9, tap = e % 9;
            float v0 = 0.f, v1 = 0.f, v2 = 0.f, v3 = 0.f;
#pragma unroll
            for (int j = 0; j < 4; ++j) {
                int id = sidx[e][j];
                if (id >= 0) {
                    u16x4_t u = *(const u16x4_t*)&xb[(size_t)id * 64 + ic];
                    float wj = swt[e][j];
                    v0 += wj * bf16_to_f(u[0]);
                    v1 += wj * bf16_to_f(u[1]);
                    v2 += wj * bf16_to_f(u[2]);
                    v3 += wj * bf16_to_f(u[3]);
                }
            }
            int sw = (tap * 8 + ((ic >> 3) ^ (p & 7))) * 8 + (ic & 7);
            short* dst = &samp[p * 576 + sw];
            dst[0] = f_to_bf16(v0);
            dst[1] = f_to_bf16(v1);
            dst[2] = f_to_bf16(v2);
            dst[3] = f_to_bf16(v3);
        }
    }
    __syncthreads();

    // phase 3: MFMA  (M=32 pixels, N=O, K=576); 2 M-frags per wave
    const int wv = tid >> 6;
    const int l  = tid & 63;
    const int l15 = l & 15, lg = l >> 4;
    f32x4_t acc[2][NF];
#pragma unroll
    for (int mf = 0; mf < 2; ++mf)
#pragma unroll
        for (int nf = 0; nf < NF; ++nf)
            acc[mf][nf] = (f32x4_t){0.f, 0.f, 0.f, 0.f};

#pragma unroll 2
    for (int kc = 0; kc < 18; ++kc) {
        int tap = kc >> 1;
        int low = (((kc & 1) << 2) | lg) ^ (l15 & 7);   // (row+16)&7 == row&7
        bf16x8_t af0 = *(const bf16x8_t*)&samp[l15 * 576 + (tap * 8 + low) * 8];
        bf16x8_t af1 = *(const bf16x8_t*)&samp[(l15 + 16) * 576 + (tap * 8 + low) * 8];
#pragma unroll
        for (int nf = 0; nf < NF; ++nf) {
            int oc = (wv * NF + nf) * 16 + l15;
            bf16x8_t bf = *(const bf16x8_t*)(wt + (size_t)oc * 576 + kc * 32 + lg * 8);
            acc[0][nf] = __builtin_amdgcn_mfma_f32_16x16x32_bf16(af0, bf, acc[0][nf], 0, 0, 0);
            acc[1][nf] = __builtin_amdgcn_mfma_f32_16x16x32_bf16(af1, bf, acc[1][nf], 0, 0, 0);
        }
    }

#pragma unroll
    for (int mf = 0; mf < 2; ++mf)
#pragma unroll
        for (int nf = 0; nf < NF; ++nf) {
            int oc = (wv * NF + nf) * 16 + l15;
            float bv = bias[oc];
            f32x4_t v = acc[mf][nf];
            v[0] += bv; v[1] += bv; v[2] += bv; v[3] += bv;
            *(f32x4_t*)&out[((size_t)(b * O + oc)) * HW + r0 + mf * 16 + lg * 4] = v;
        }
}

// ---------------------------------------------------------------- avgpool 4x4
__global__ void avgpool4_kernel(const float* __restrict__ in,
                                float* __restrict__ out,
                                int BC, int Ho, int Wo, int H, int W)
{
    int idx = blockIdx.x * TPB + threadIdx.x;
    int total = BC * Ho * Wo;
    if (idx >= total) return;
    int wo = idx % Wo;
    int t = idx / Wo;
    int ho = t % Ho;
    int bc = t / Ho;
    const float* xp = in + (size_t)bc * H * W + (ho * 4) * W + wo * 4;
    float s = 0.f;
#pragma unroll
    for (int i = 0; i < 4; ++i)
#pragma unroll
        for (int j = 0; j < 4; ++j)
            s += xp[i * W + j];
    out[idx] = s * (1.0f / 16.0f);
}

// ------------------------------------------------- skip: d1 += 1x1conv(pool)
__global__ void skip_add_kernel(float* __restrict__ d1,
                                const float* __restrict__ pool,
                                const float* __restrict__ wsk,
                                const float* __restrict__ bsk,
                                int B, int HW)
{
    int idx = blockIdx.x * TPB + threadIdx.x;
    int total = B * 64 * HW;
    if (idx >= total) return;
    int r = idx % HW;
    int t = idx / HW;
    int o = t % 64;
    int bb = t / 64;
    const float* pp = pool + (size_t)bb * 3 * HW + r;
    float v = d1[idx] + bsk[o];
    v += wsk[o * 3 + 0] * pp[0];
    v += wsk[o * 3 + 1] * pp[HW];
    v += wsk[o * 3 + 2] * pp[2 * HW];
    d1[idx] = v;
}

// ---------------------------------------------------------------- batchnorm
__global__ void zero_stats_kernel(float* __restrict__ stats)
{
    if (threadIdx.x < 128) stats[threadIdx.x] = 0.f;
}

__global__ void bn_stats_kernel(const float* __restrict__ in,
                                float* __restrict__ stats,
                                int C, int HW)
{
    int bc = blockIdx.x;
    int c = bc % C;
    const float* p = in + (size_t)bc * HW;
    float s = 0.f, s2 = 0.f;
    for (int i = threadIdx.x; i < HW; i += TPB) {
        float v = p[i];
        s += v;
        s2 += v * v;
    }
    __shared__ float ss[TPB], sq[TPB];
    ss[threadIdx.x] = s;
    sq[threadIdx.x] = s2;
    __syncthreads();
    for (int st = TPB / 2; st > 0; st >>= 1) {
        if (threadIdx.x < st) {
            ss[threadIdx.x] += ss[threadIdx.x + st];
            sq[threadIdx.x] += sq[threadIdx.x + st];
        }
        __syncthreads();
    }
    if (threadIdx.x == 0) {
        atomicAdd(&stats[c * 2], ss[0]);
        atomicAdd(&stats[c * 2 + 1], sq[0]);
    }
}

__global__ void bn_apply_kernel(const float* __restrict__ in,
                                const float* __restrict__ stats,
                                float* __restrict__ out,
                                int C, int HW, int total, float invN)
{
    int idx = blockIdx.x * TPB + threadIdx.x;
    if (idx >= total) return;
    int c = (idx / HW) % C;
    float mean = stats[c * 2] * invN;
    float var = stats[c * 2 + 1] * invN - mean * mean;
    float r = rsqrtf(var + 1e-5f);
    float v = (in[idx] - mean) * r;
    out[idx] = v > 0.f ? v : 0.f;
}

// ---------------------------------------------------------------- launch
extern "C" void kernel_launch(void* const* d_in, const int* in_sizes, int n_in,
                              void* d_out, int out_size, void* d_ws, size_t ws_size,
                              hipStream_t stream)
{
    const float* x      = (const float*)d_in[0];
    const float* w_off1 = (const float*)d_in[1];
    const float* b_off1 = (const float*)d_in[2];
    const float* w_d1   = (const float*)d_in[3];
    const float* b_d1   = (const float*)d_in[4];
    const float* w_skip = (const float*)d_in[5];
    const float* b_skip = (const float*)d_in[6];
    const float* w_bl1  = (const float*)d_in[7];
    const float* w_bl2  = (const float*)d_in[8];
    const float* w_off2 = (const float*)d_in[9];
    const float* b_off2 = (const float*)d_in[10];
    const float* w_d2   = (const float*)d_in[11];
    const float* b_d2   = (const float*)d_in[12];
    const float* w_off3 = (const float*)d_in[13];
    const float* b_off3 = (const float*)d_in[14];
    const float* w_d3   = (const float*)d_in[15];
    const float* b_d3   = (const float*)d_in[16];

    const int B = 8;
    float* A     = (float*)d_ws;          // 3,686,400 floats (multi-use)
    float* bufB  = A + 3686400;           // 13,107,200 floats
    float* bufC  = bufB + 13107200;       // 13,107,200 floats
    float* stats = bufC + 13107200;       // 128

    // weight repack areas inside A. Lifetime: repacked AFTER offset1
    // (which covers all of A) is consumed; later writes into A are
    // pool (614,400 fl), offset2 (921,600 fl), offset3 (230,400 fl) — all
    // below A+1,000,000, so these regions survive until their uses.
    short* wt1    = (short*)(A + 1000000);      //  36,864 shorts
    short* wt2    = wt1 + 64 * 576;
    short* wtd2   = (short*)(A + 1500000);      //  36,864 shorts
    short* wtd3   = (short*)(A + 1550000);      // 147,456 shorts
    short* wtoff2 = (short*)(A + 1700000);      //  10,368 shorts
    short* wtoff3 = (short*)(A + 1710000);      //  10,368 shorts

    float* out0 = (float*)d_out;          // feat_1_4  (8,64,160,160)
    float* out1 = out0 + 13107200;        // feat_1_8  (8,64,80,80)
    float* out2 = out1 + 3276800;         // feat_1_16 (8,256,40,40)

    // 0) x -> NHWC4 fp32 into bufC (free until step 5)
    x_to_nhwc4_kernel<<<(8 * 409600 + TPB - 1) / TPB, TPB, 0, stream>>>(x, bufC);

    // 1) offset1 = conv3x3(x NHWC4, s=4) exact fp32 -> A (covers ALL of A)
    offset1_kernel<<<(8 * 25600 + TPB - 1) / TPB, TPB, 0, stream>>>(
        bufC, w_off1, b_off1, A);

    // 2) d1 = deform1(x NHWC4, offset1) -> bufB   (offset1 dead after this)
    deform1_kernel<<<8 * 25600 / 16, TPB, 0, stream>>>(bufC, A, w_d1, b_d1, bufB);

    // 2.5) repack all MFMA weights (A is now safe above +1,000,000)
    repack_w_kernel<<<(64 * 576 + TPB - 1) / TPB, TPB, 0, stream>>>(w_bl1, wt1, 64);
    repack_w_kernel<<<(64 * 576 + TPB - 1) / TPB, TPB, 0, stream>>>(w_bl2, wt2, 64);
    repack_w_kernel<<<(64 * 576 + TPB - 1) / TPB, TPB, 0, stream>>>(w_d2, wtd2, 64);
    repack_w_kernel<<<(256 * 576 + TPB - 1) / TPB, TPB, 0, stream>>>(w_d3, wtd3, 256);
    repack_w_kernel<<<(18 * 576 + TPB - 1) / TPB, TPB, 0, stream>>>(w_off2, wtoff2, 18);
    repack_w_kernel<<<(18 * 576 + TPB - 1) / TPB, TPB, 0, stream>>>(w_off3, wtoff3, 18);

    // 3) pool = avgpool4(x) -> A[0 .. 614,399]
    {
        int total = B * 3 * 160 * 160;
        avgpool4_kernel<<<(total + TPB - 1) / TPB, TPB, 0, stream>>>(
            x, A, B * 3, 160, 160, 640, 640);
    }
    // 4) bufB += conv1x1(pool) + b_skip
    {
        int total = B * 64 * 25600;
        skip_add_kernel<<<(total + TPB - 1) / TPB, TPB, 0, stream>>>(
            bufB, A, w_skip, b_skip, B, 25600);
    }
    // 5) bufC = conv_mfma(bufB, wt1); bn+relu in place  (x NHWC4 dead)
    {
        int total = B * 64 * 160 * 160;
        conv3x3_mfma_kernel<<<800, TPB, 0, stream>>>(bufB, wt1, bufC, B);
        zero_stats_kernel<<<1, 128, 0, stream>>>(stats);
        bn_stats_kernel<<<B * 64, TPB, 0, stream>>>(bufC, stats, 64, 25600);
        bn_apply_kernel<<<(total + TPB - 1) / TPB, TPB, 0, stream>>>(
            bufC, stats, bufC, 64, 25600, total, 1.0f / (B * 25600));
    }
    // 6) bufB = conv_mfma(bufC, wt2); bn+relu -> out0 (feat_1_4)
    {
        int total = B * 64 * 160 * 160;
        conv3x3_mfma_kernel<<<800, TPB, 0, stream>>>(bufC, wt2, bufB, B);
        zero_stats_kernel<<<1, 128, 0, stream>>>(stats);
        bn_stats_kernel<<<B * 64, TPB, 0, stream>>>(bufB, stats, 64, 25600);
        bn_apply_kernel<<<(total + TPB - 1) / TPB, TPB, 0, stream>>>(
            bufB, stats, out0, 64, 25600, total, 1.0f / (B * 25600));
    }
    // 6.5) feat_1_4 -> NHWC bf16 into bufC
    nchw_to_nhwc_bf16_kernel<<<8 * (25600 / 64), TPB, 0, stream>>>(
        out0, (short*)bufC, 25600);

    // 7) offset2 = offconv_mfma(nhwc(feat_1_4)) -> A[0 .. 921,599]
    offconv_mfma_kernel<<<8 * 6400 / 64, TPB, 0, stream>>>(
        (const short*)bufC, wtoff2, b_off2, A, 160, 160, 80, 80);

    // 8) feat_1_8 = deform_mfma<64>(nhwc(feat_1_4), offset2) -> out1
    deform_mfma_kernel<64><<<8 * 6400 / 32, TPB, 0, stream>>>(
        (const short*)bufC, A, wtd2, b_d2, out1, 160, 160, 80, 80, 2);

    // 8.5) feat_1_8 -> NHWC bf16 into bufB
    nchw_to_nhwc_bf16_kernel<<<8 * (6400 / 64), TPB, 0, stream>>>(
        out1, (short*)bufB, 6400);

    // 9) offset3 = offconv_mfma(nhwc(feat_1_8)) -> A[0 .. 230,399]
    offconv_mfma_kernel<<<8 * 1600 / 64, TPB, 0, stream>>>(
        (const short*)bufB, wtoff3, b_off3, A, 80, 80, 40, 40);

    // 10) feat_1_16 = deform_mfma<256>(nhwc(feat_1_8), offset3) -> out2
    deform_mfma_kernel<256><<<8 * 1600 / 32, TPB, 0, stream>>>(
        (const short*)bufB, A, wtd3, b_d3, out2, 80, 80, 40, 40, 2);
}

// Round 9
// 444.369 us; speedup vs baseline: 16.1461x; 1.4377x over previous
//
#include <hip/hip_runtime.h>
#include <hip/hip_bf16.h>
#include <math.h>

#define TPB 256

typedef __attribute__((ext_vector_type(8))) short bf16x8_t;
typedef __attribute__((ext_vector_type(4))) float f32x4_t;
typedef __attribute__((ext_vector_type(4))) unsigned short u16x4_t;

static __device__ __forceinline__ float bf16_to_f(unsigned short s) {
    union { unsigned u; float f; } cv;
    cv.u = ((unsigned)s) << 16;
    return cv.f;
}
static __device__ __forceinline__ short f_to_bf16(float v) {
    __hip_bfloat16 h = __float2bfloat16(v);
    return *(short*)&h;
}

// ------------------------------------------------- weight repack for MFMA
__global__ void repack_w_kernel(const float* __restrict__ w,
                                short* __restrict__ wt, int O)
{
    int idx = blockIdx.x * TPB + threadIdx.x;
    if (idx >= O * 64 * 9) return;
    int ic  = idx % 64;
    int t   = idx / 64;
    int tap = t % 9;
    int oc  = t / 9;
    wt[(size_t)oc * 576 + tap * 64 + ic] =
        f_to_bf16(w[((size_t)(oc * 64 + ic)) * 9 + tap]);
}

// ------------------------------------------------- MFMA conv 3x3 (64->64, s1)
// in: bf16 NHWC [B][160][160][64]; out: fp32 NCHW; fused BN partial stats.
__global__ __launch_bounds__(256, 1) void conv3x3_mfma_kernel(
    const short* __restrict__ xh,
    const short* __restrict__ wt,
    float* __restrict__ out,
    float* __restrict__ stats)      // [64][2] atomically accumulated
{
    __shared__ short tile[18 * 18 * 64];   // 41472 B
    __shared__ float sstat[128];           // [2][64]
    const int H = 160, W = 160;
    int blk = blockIdx.x;
    int b  = blk / 100;
    int r  = blk % 100;
    int y0 = (r / 10) * 16;
    int x0 = (r % 10) * 16;
    const int tid = threadIdx.x;

    // stage halo tile: pure 16B bf16 copies, swizzled by chunk^col
    const short* inb = xh + (size_t)b * H * W * 64;
    for (int item = tid; item < 18 * 18 * 8; item += TPB) {
        int c8  = item & 7;
        int pix = item >> 3;
        int col = pix % 18, row = pix / 18;
        int y = y0 + row - 1;
        int x = x0 + col - 1;
        bf16x8_t v = {};
        if (y >= 0 && y < H && x >= 0 && x < W)
            v = *(const bf16x8_t*)&inb[((size_t)y * W + x) * 64 + c8 * 8];
        int ch = c8 ^ (col & 7);
        *(bf16x8_t*)&tile[(row * 18 + col) * 64 + ch * 8] = v;
    }
    if (tid < 128) sstat[tid] = 0.f;
    __syncthreads();

    const int wv  = tid >> 6;
    const int l   = tid & 63;
    const int l15 = l & 15;
    const int lg  = l >> 4;

    f32x4_t acc[4][4];
#pragma unroll
    for (int i = 0; i < 4; ++i)
#pragma unroll
        for (int j = 0; j < 4; ++j)
            acc[i][j] = (f32x4_t){0.f, 0.f, 0.f, 0.f};

#pragma unroll 2
    for (int kc = 0; kc < 18; ++kc) {
        int tap = kc >> 1;
        int dy  = tap / 3;
        int dx  = tap % 3;

        bf16x8_t bf[4];
#pragma unroll
        for (int nf = 0; nf < 4; ++nf) {
            int oc = nf * 16 + l15;
            bf[nf] = *(const bf16x8_t*)(wt + (size_t)oc * 576 + kc * 32 + lg * 8);
        }

        int colr  = l15 + dx;
        int chunk = (((kc & 1) << 2) + lg) ^ (colr & 7);
        bf16x8_t af[4];
#pragma unroll
        for (int mf = 0; mf < 4; ++mf) {
            int row = wv * 4 + mf + dy;
            af[mf] = *(const bf16x8_t*)&tile[(row * 18 + colr) * 64 + chunk * 8];
        }

#pragma unroll
        for (int mf = 0; mf < 4; ++mf)
#pragma unroll
            for (int nf = 0; nf < 4; ++nf)
                acc[mf][nf] = __builtin_amdgcn_mfma_f32_16x16x32_bf16(
                    af[mf], bf[nf], acc[mf][nf], 0, 0, 0);
    }

    // store fp32 NCHW
    float* outb = out + (size_t)b * 64 * H * W;
#pragma unroll
    for (int mf = 0; mf < 4; ++mf) {
        int y = y0 + wv * 4 + mf;
#pragma unroll
        for (int nf = 0; nf < 4; ++nf) {
            int oc = nf * 16 + l15;
            *(f32x4_t*)&outb[(size_t)oc * H * W + y * W + x0 + lg * 4] = acc[mf][nf];
        }
    }

    // fused BN partial stats: per-lane sums -> shfl over lg -> LDS -> global
#pragma unroll
    for (int nf = 0; nf < 4; ++nf) {
        float s = 0.f, s2 = 0.f;
#pragma unroll
        for (int mf = 0; mf < 4; ++mf)
#pragma unroll
            for (int k = 0; k < 4; ++k) {
                float v = acc[mf][nf][k];
                s += v; s2 += v * v;
            }
        s  += __shfl_xor(s, 16, 64);  s  += __shfl_xor(s, 32, 64);
        s2 += __shfl_xor(s2, 16, 64); s2 += __shfl_xor(s2, 32, 64);
        if (lg == 0) {
            int oc = nf * 16 + l15;
            atomicAdd(&sstat[oc], s);
            atomicAdd(&sstat[64 + oc], s2);
        }
    }
    __syncthreads();
    if (tid < 64) {
        atomicAdd(&stats[tid * 2],     sstat[tid]);
        atomicAdd(&stats[tid * 2 + 1], sstat[64 + tid]);
    }
}

// ------------------------------------------------- NCHW fp32 -> NHWC bf16 (C=64)
__global__ void nchw_to_nhwc_bf16_kernel(const float* __restrict__ in,
                                         short* __restrict__ out, int HW)
{
    __shared__ short tile[64][66];
    int nchunks = HW >> 6;
    int b  = blockIdx.x / nchunks;
    int p0 = (blockIdx.x % nchunks) << 6;
    int tid = threadIdx.x;
#pragma unroll
    for (int rep = 0; rep < 16; ++rep) {
        int item = rep * 256 + tid;
        int c = item >> 6, p = item & 63;
        tile[p][c] = f_to_bf16(in[((size_t)b * 64 + c) * HW + p0 + p]);
    }
    __syncthreads();
#pragma unroll
    for (int rep = 0; rep < 16; ++rep) {
        int item = rep * 256 + tid;
        int p = item >> 6, c = item & 63;
        out[((size_t)b * HW + p0 + p) * 64 + c] = tile[p][c];
    }
}

// ------------------------------------------------- BN apply -> NHWC bf16 only
__global__ void bn_apply_nhwc_kernel(const float* __restrict__ in, // NCHW fp32
                                     const float* __restrict__ stats,
                                     short* __restrict__ outh,     // NHWC bf16
                                     int HW, float invN)
{
    __shared__ short tile[64][66];
    __shared__ float sm[64], sr[64];
    int nchunks = HW >> 6;
    int b  = blockIdx.x / nchunks;
    int p0 = (blockIdx.x % nchunks) << 6;
    int tid = threadIdx.x;
    if (tid < 64) {
        float mean = stats[tid * 2] * invN;
        float var  = stats[tid * 2 + 1] * invN - mean * mean;
        sm[tid] = mean;
        sr[tid] = rsqrtf(var + 1e-5f);
    }
    __syncthreads();
#pragma unroll
    for (int rep = 0; rep < 16; ++rep) {
        int item = rep * 256 + tid;
        int c = item >> 6, p = item & 63;
        float v = in[((size_t)b * 64 + c) * HW + p0 + p];
        v = (v - sm[c]) * sr[c];
        tile[p][c] = f_to_bf16(v > 0.f ? v : 0.f);
    }
    __syncthreads();
#pragma unroll
    for (int rep = 0; rep < 16; ++rep) {
        int item = rep * 256 + tid;
        int p = item >> 6, c = item & 63;
        outh[((size_t)b * HW + p0 + p) * 64 + c] = tile[p][c];
    }
}

// ------------------------------------------------- BN apply -> NCHW fp32 + NHWC bf16
__global__ void bn_apply_dual_kernel(const float* __restrict__ in, // NCHW fp32
                                     const float* __restrict__ stats,
                                     float* __restrict__ out,      // NCHW fp32
                                     short* __restrict__ outh,     // NHWC bf16
                                     int HW, float invN)
{
    __shared__ short tile[64][66];
    __shared__ float sm[64], sr[64];
    int nchunks = HW >> 6;
    int b  = blockIdx.x / nchunks;
    int p0 = (blockIdx.x % nchunks) << 6;
    int tid = threadIdx.x;
    if (tid < 64) {
        float mean = stats[tid * 2] * invN;
        float var  = stats[tid * 2 + 1] * invN - mean * mean;
        sm[tid] = mean;
        sr[tid] = rsqrtf(var + 1e-5f);
    }
    __syncthreads();
#pragma unroll
    for (int rep = 0; rep < 16; ++rep) {
        int item = rep * 256 + tid;
        int c = item >> 6, p = item & 63;
        size_t idx = ((size_t)b * 64 + c) * HW + p0 + p;
        float v = in[idx];
        v = (v - sm[c]) * sr[c];
        v = v > 0.f ? v : 0.f;
        out[idx] = v;
        tile[p][c] = f_to_bf16(v);
    }
    __syncthreads();
#pragma unroll
    for (int rep = 0; rep < 16; ++rep) {
        int item = rep * 256 + tid;
        int p = item >> 6, c = item & 63;
        outh[((size_t)b * HW + p0 + p) * 64 + c] = tile[p][c];
    }
}

// ------------------------------------------------- x NCHW (C=3) -> NHWC4 fp32
__global__ void x_to_nhwc4_kernel(const float* __restrict__ in,
                                  float* __restrict__ out)
{
    int idx = blockIdx.x * TPB + threadIdx.x;
    const int HW = 640 * 640;
    if (idx >= 8 * HW) return;
    int b = idx / HW, p = idx % HW;
    f32x4_t v;
    v[0] = in[((size_t)b * 3 + 0) * HW + p];
    v[1] = in[((size_t)b * 3 + 1) * HW + p];
    v[2] = in[((size_t)b * 3 + 2) * HW + p];
    v[3] = 0.f;
    *(f32x4_t*)&out[(size_t)idx * 4] = v;
}

// ------------------------------------------------- offset1: exact fp32, NHWC4
__global__ void offset1_kernel(const float* __restrict__ x4,
                               const float* __restrict__ w,   // (18,3,3,3)
                               const float* __restrict__ bias,
                               float* __restrict__ out)
{
    const int H = 640, W = 640, HW = 25600;
    int idx = blockIdx.x * TPB + threadIdx.x;
    if (idx >= 8 * HW) return;
    int b = idx / HW, r = idx % HW;
    int ho = r / 160, wo = r % 160;

    float acc[18];
#pragma unroll
    for (int o = 0; o < 18; ++o) acc[o] = bias[o];

    const float* xb = x4 + (size_t)b * H * W * 4;
#pragma unroll
    for (int tap = 0; tap < 9; ++tap) {
        int iy = ho * 4 - 1 + tap / 3;
        int ix = wo * 4 - 1 + tap % 3;
        if (iy < 0 || iy >= H || ix < 0 || ix >= W) continue;
        f32x4_t s = *(const f32x4_t*)&xb[((size_t)iy * W + ix) * 4];
#pragma unroll
        for (int c = 0; c < 3; ++c)
#pragma unroll
            for (int o = 0; o < 18; ++o)
                acc[o] += s[c] * w[(o * 3 + c) * 9 + tap];
    }
#pragma unroll
    for (int o = 0; o < 18; ++o)
        out[((size_t)(b * 18 + o)) * HW + r] = acc[o];
}

// ------------------------------------------------- offset2/3: MFMA conv, N=18
__global__ __launch_bounds__(256, 1) void offconv_mfma_kernel(
    const short* __restrict__ xh,
    const short* __restrict__ wt,    // bf16 [18][576]
    const float* __restrict__ bias,  // (18,)
    float* __restrict__ out,
    int H, int W, int Ho, int Wo)
{
    const int HW = Ho * Wo;
    const int tid = threadIdx.x;
    const int wv = tid >> 6, l = tid & 63;
    const int l15 = l & 15, lg = l >> 4;
    const int pix0 = blockIdx.x * 64 + wv * 16;
    const int b = pix0 / HW;
    const int r0 = pix0 - b * HW;

    int rp = r0 + l15;
    int ho = rp / Wo, wo = rp % Wo;
    const short* xb = xh + (size_t)b * H * W * 64;

    f32x4_t acc[2];
    acc[0] = (f32x4_t){0.f, 0.f, 0.f, 0.f};
    acc[1] = (f32x4_t){0.f, 0.f, 0.f, 0.f};

#pragma unroll 2
    for (int kc = 0; kc < 18; ++kc) {
        int tap = kc >> 1;
        int iy = ho * 2 - 1 + tap / 3;
        int ix = wo * 2 - 1 + tap % 3;
        bf16x8_t af = {};
        if (iy >= 0 && iy < H && ix >= 0 && ix < W)
            af = *(const bf16x8_t*)&xb[((size_t)iy * W + ix) * 64
                                       + (kc & 1) * 32 + lg * 8];
#pragma unroll
        for (int nf = 0; nf < 2; ++nf) {
            int oc = nf * 16 + l15;
            bf16x8_t bf = {};
            if (oc < 18)
                bf = *(const bf16x8_t*)(wt + (size_t)oc * 576 + kc * 32 + lg * 8);
            acc[nf] = __builtin_amdgcn_mfma_f32_16x16x32_bf16(af, bf, acc[nf], 0, 0, 0);
        }
    }

#pragma unroll
    for (int nf = 0; nf < 2; ++nf) {
        int oc = nf * 16 + l15;
        if (oc < 18) {
            float bv = bias[oc];
            f32x4_t v = acc[nf];
            v[0] += bv; v[1] += bv; v[2] += bv; v[3] += bv;
            *(f32x4_t*)&out[((size_t)(b * 18 + oc)) * HW + r0 + lg * 4] = v;
        }
    }
}

// ------------------------------------------------- deform1: C=3, fused skip,
// writes bf16 NHWC [B][160*160][64]
__global__ __launch_bounds__(256, 1) void deform1_kernel(
    const float* __restrict__ x4,   // [B][640][640][4] fp32
    const float* __restrict__ off,  // [B][18][160][160]
    const float* __restrict__ w,    // (64,3,3,3) fp32
    const float* __restrict__ bias, // b_d1
    const float* __restrict__ pool, // [B][3][25600] fp32
    const float* __restrict__ wsk,  // (64,3)
    const float* __restrict__ bsk,  // (64,)
    short* __restrict__ outh)       // NHWC bf16
{
    const int H = 640, W = 640, Ho = 160, Wo = 160, HW = 25600;
    __shared__ float samp[16][27];
    __shared__ int   sidx[144][4];
    __shared__ float swt[144][4];
    const int tid = threadIdx.x;
    const int pix0 = blockIdx.x * 16;
    const int b = pix0 / HW;
    const int r0 = pix0 - b * HW;

    if (tid < 144) {
        int p = tid / 9, tap = tid % 9;
        int r = r0 + p, ho = r / Wo, wo = r % Wo;
        float dy = off[((size_t)(b * 18 + 2 * tap) * Ho + ho) * Wo + wo];
        float dx = off[((size_t)(b * 18 + 2 * tap + 1) * Ho + ho) * Wo + wo];
        float ys = (float)(ho * 4 - 1 + tap / 3) + dy;
        float xs = (float)(wo * 4 - 1 + tap % 3) + dx;
        float y0f = floorf(ys), x0f = floorf(xs);
        float fy = ys - y0f, fx = xs - x0f;
        int y0 = (int)y0f, x0 = (int)x0f;
        float wts[4] = {(1.f - fy) * (1.f - fx), (1.f - fy) * fx,
                        fy * (1.f - fx),          fy * fx};
#pragma unroll
        for (int j = 0; j < 4; ++j) {
            int iy = y0 + (j >> 1), ix = x0 + (j & 1);
            bool v = (iy >= 0) && (iy < H) && (ix >= 0) && (ix < W);
            sidx[tid][j] = v ? (iy * W + ix) : -1;
            swt[tid][j]  = wts[j];
        }
    }
    __syncthreads();

    if (tid < 144) {
        int p = tid / 9, tap = tid % 9;
        const float* xb = x4 + (size_t)b * H * W * 4;
        float s0 = 0.f, s1 = 0.f, s2 = 0.f;
#pragma unroll
        for (int j = 0; j < 4; ++j) {
            int id = sidx[tid][j];
            if (id >= 0) {
                f32x4_t v = *(const f32x4_t*)&xb[(size_t)id * 4];
                float wj = swt[tid][j];
                s0 += wj * v[0];
                s1 += wj * v[1];
                s2 += wj * v[2];
            }
        }
        samp[p][0 * 9 + tap] = s0;
        samp[p][1 * 9 + tap] = s1;
        samp[p][2 * 9 + tap] = s2;
    }
    __syncthreads();

    int g = tid >> 6;      // wave -> 4-pixel group
    int o = tid & 63;
    float acc[4];
#pragma unroll
    for (int pi = 0; pi < 4; ++pi) acc[pi] = bias[o] + bsk[o];
#pragma unroll
    for (int c = 0; c < 3; ++c)
#pragma unroll
        for (int k = 0; k < 9; ++k) {
            float wv = w[((size_t)(o * 3 + c)) * 9 + k];
#pragma unroll
            for (int pi = 0; pi < 4; ++pi)
                acc[pi] += wv * samp[g * 4 + pi][c * 9 + k];
        }
#pragma unroll
    for (int pi = 0; pi < 4; ++pi) {
        int r = r0 + g * 4 + pi;
        float sv = wsk[o * 3 + 0] * pool[(size_t)(b * 3 + 0) * HW + r]
                 + wsk[o * 3 + 1] * pool[(size_t)(b * 3 + 1) * HW + r]
                 + wsk[o * 3 + 2] * pool[(size_t)(b * 3 + 2) * HW + r];
        outh[((size_t)(b * HW + r)) * 64 + o] = f_to_bf16(acc[pi] + sv);
    }
}

// ------------------------------------------------- deform MFMA: C=64 -> O
template <int O>
__global__ __launch_bounds__(256, 1) void deform_mfma_kernel(
    const short* __restrict__ xh,
    const float* __restrict__ off,  // [B][18][Ho][Wo]
    const short* __restrict__ wt,   // bf16 [O][576]
    const float* __restrict__ bias,
    float* __restrict__ out,        // [B][O][Ho][Wo]
    int H, int W, int Ho, int Wo, int stride)
{
    constexpr int NF = O / 64;
    constexpr int P  = 32;
    __shared__ alignas(16) short samp[P * 576];
    __shared__ int   sidx[P * 9][4];
    __shared__ float swt[P * 9][4];

    const int tid = threadIdx.x;
    const int HW = Ho * Wo;
    const int pix0 = blockIdx.x * P;
    const int b = pix0 / HW;
    const int r0 = pix0 - b * HW;

    for (int item = tid; item < P * 9; item += TPB) {
        int p = item / 9, tap = item % 9;
        int r = r0 + p, ho = r / Wo, wo = r % Wo;
        float dy = off[((size_t)(b * 18 + 2 * tap) * Ho + ho) * Wo + wo];
        float dx = off[((size_t)(b * 18 + 2 * tap + 1) * Ho + ho) * Wo + wo];
        float ys = (float)(ho * stride - 1 + tap / 3) + dy;
        float xs = (float)(wo * stride - 1 + tap % 3) + dx;
        float y0f = floorf(ys), x0f = floorf(xs);
        float fy = ys - y0f, fx = xs - x0f;
        int y0 = (int)y0f, x0 = (int)x0f;
        float wts[4] = {(1.f - fy) * (1.f - fx), (1.f - fy) * fx,
                        fy * (1.f - fx),          fy * fx};
#pragma unroll
        for (int j = 0; j < 4; ++j) {
            int iy = y0 + (j >> 1), ix = x0 + (j & 1);
            bool v = (iy >= 0) && (iy < H) && (ix >= 0) && (ix < W);
            sidx[item][j] = v ? (iy * W + ix) : -1;
            swt[item][j]  = wts[j];
        }
    }
    __syncthreads();

    {
        const int grp = tid >> 4;
        const int ic  = (tid & 15) * 4;
        const short* xb = xh + (size_t)b * H * W * 64;
#pragma unroll 2
        for (int i = 0; i < 18; ++i) {
            int e = grp * 18 + i;
            int p = e / 9, tap = e % 9;
            float v0 = 0.f, v1 = 0.f, v2 = 0.f, v3 = 0.f;
#pragma unroll
            for (int j = 0; j < 4; ++j) {
                int id = sidx[e][j];
                if (id >= 0) {
                    u16x4_t u = *(const u16x4_t*)&xb[(size_t)id * 64 + ic];
                    float wj = swt[e][j];
                    v0 += wj * bf16_to_f(u[0]);
                    v1 += wj * bf16_to_f(u[1]);
                    v2 += wj * bf16_to_f(u[2]);
                    v3 += wj * bf16_to_f(u[3]);
                }
            }
            int sw = (tap * 8 + ((ic >> 3) ^ (p & 7))) * 8 + (ic & 7);
            short* dst = &samp[p * 576 + sw];
            dst[0] = f_to_bf16(v0);
            dst[1] = f_to_bf16(v1);
            dst[2] = f_to_bf16(v2);
            dst[3] = f_to_bf16(v3);
        }
    }
    __syncthreads();

    const int wv = tid >> 6;
    const int l  = tid & 63;
    const int l15 = l & 15, lg = l >> 4;
    f32x4_t acc[2][NF];
#pragma unroll
    for (int mf = 0; mf < 2; ++mf)
#pragma unroll
        for (int nf = 0; nf < NF; ++nf)
            acc[mf][nf] = (f32x4_t){0.f, 0.f, 0.f, 0.f};

#pragma unroll 2
    for (int kc = 0; kc < 18; ++kc) {
        int tap = kc >> 1;
        int low = (((kc & 1) << 2) | lg) ^ (l15 & 7);
        bf16x8_t af0 = *(const bf16x8_t*)&samp[l15 * 576 + (tap * 8 + low) * 8];
        bf16x8_t af1 = *(const bf16x8_t*)&samp[(l15 + 16) * 576 + (tap * 8 + low) * 8];
#pragma unroll
        for (int nf = 0; nf < NF; ++nf) {
            int oc = (wv * NF + nf) * 16 + l15;
            bf16x8_t bf = *(const bf16x8_t*)(wt + (size_t)oc * 576 + kc * 32 + lg * 8);
            acc[0][nf] = __builtin_amdgcn_mfma_f32_16x16x32_bf16(af0, bf, acc[0][nf], 0, 0, 0);
            acc[1][nf] = __builtin_amdgcn_mfma_f32_16x16x32_bf16(af1, bf, acc[1][nf], 0, 0, 0);
        }
    }

#pragma unroll
    for (int mf = 0; mf < 2; ++mf)
#pragma unroll
        for (int nf = 0; nf < NF; ++nf) {
            int oc = (wv * NF + nf) * 16 + l15;
            float bv = bias[oc];
            f32x4_t v = acc[mf][nf];
            v[0] += bv; v[1] += bv; v[2] += bv; v[3] += bv;
            *(f32x4_t*)&out[((size_t)(b * O + oc)) * HW + r0 + mf * 16 + lg * 4] = v;
        }
}

// ---------------------------------------------------------------- avgpool 4x4
__global__ void avgpool4_kernel(const float* __restrict__ in,
                                float* __restrict__ out,
                                int BC, int Ho, int Wo, int H, int W)
{
    int idx = blockIdx.x * TPB + threadIdx.x;
    int total = BC * Ho * Wo;
    if (idx >= total) return;
    int wo = idx % Wo;
    int t = idx / Wo;
    int ho = t % Ho;
    int bc = t / Ho;
    const float* xp = in + (size_t)bc * H * W + (ho * 4) * W + wo * 4;
    float s = 0.f;
#pragma unroll
    for (int i = 0; i < 4; ++i)
#pragma unroll
        for (int j = 0; j < 4; ++j)
            s += xp[i * W + j];
    out[idx] = s * (1.0f / 16.0f);
}

__global__ void zero_stats_kernel(float* __restrict__ stats)
{
    if (threadIdx.x < 256) stats[threadIdx.x] = 0.f;
}

// ---------------------------------------------------------------- launch
extern "C" void kernel_launch(void* const* d_in, const int* in_sizes, int n_in,
                              void* d_out, int out_size, void* d_ws, size_t ws_size,
                              hipStream_t stream)
{
    const float* x      = (const float*)d_in[0];
    const float* w_off1 = (const float*)d_in[1];
    const float* b_off1 = (const float*)d_in[2];
    const float* w_d1   = (const float*)d_in[3];
    const float* b_d1   = (const float*)d_in[4];
    const float* w_skip = (const float*)d_in[5];
    const float* b_skip = (const float*)d_in[6];
    const float* w_bl1  = (const float*)d_in[7];
    const float* w_bl2  = (const float*)d_in[8];
    const float* w_off2 = (const float*)d_in[9];
    const float* b_off2 = (const float*)d_in[10];
    const float* w_d2   = (const float*)d_in[11];
    const float* b_d2   = (const float*)d_in[12];
    const float* w_off3 = (const float*)d_in[13];
    const float* b_off3 = (const float*)d_in[14];
    const float* w_d3   = (const float*)d_in[15];
    const float* b_d3   = (const float*)d_in[16];

    const int B = 8;
    float* A     = (float*)d_ws;          // 3,686,400 floats
    float* bufB  = A + 3686400;           // 13,107,200 floats
    float* bufC  = bufB + 13107200;       // 13,107,200 floats
    float* stats = bufC + 13107200;       // 256 floats (stats1 | stats2)

    // bf16 NHWC carriers inside bufB/bufC
    short* hB   = (short*)bufB;           // 13.1M shorts (uses 6.55M fl)
    short* hC   = (short*)bufC;
    float* pool = bufB + 8000000;         // 614,400 floats, disjoint from hB

    // weights inside A (above every later A write: offsets2/3 < 1M floats)
    short* wt1    = (short*)(A + 1000000);
    short* wt2    = wt1 + 64 * 576;
    short* wtd2   = (short*)(A + 1500000);
    short* wtd3   = (short*)(A + 1550000);
    short* wtoff2 = (short*)(A + 1700000);
    short* wtoff3 = (short*)(A + 1710000);

    float* out0 = (float*)d_out;          // feat_1_4  (8,64,160,160)
    float* out1 = out0 + 13107200;        // feat_1_8  (8,64,80,80)
    float* out2 = out1 + 3276800;         // feat_1_16 (8,256,40,40)

    const float invN = 1.0f / (B * 25600);

    // 0) x -> NHWC4 fp32 into bufC
    x_to_nhwc4_kernel<<<(8 * 409600 + TPB - 1) / TPB, TPB, 0, stream>>>(x, bufC);

    // 1) offset1 (exact fp32) -> A (covers all of A)
    offset1_kernel<<<(8 * 25600 + TPB - 1) / TPB, TPB, 0, stream>>>(
        bufC, w_off1, b_off1, A);

    // 2) pool = avgpool4(x) -> bufB+8M (disjoint from offset1 in A)
    avgpool4_kernel<<<(B * 3 * 25600 + TPB - 1) / TPB, TPB, 0, stream>>>(
        x, pool, B * 3, 160, 160, 640, 640);

    // 3) d1+skip = deform1(x4, offset1, pool) -> hB (bf16 NHWC). offset1 dead.
    deform1_kernel<<<8 * 25600 / 16, TPB, 0, stream>>>(
        bufC, A, w_d1, b_d1, pool, w_skip, b_skip, hB);

    // 3.5) repack weights (A free above 1M now)
    repack_w_kernel<<<(64 * 576 + TPB - 1) / TPB, TPB, 0, stream>>>(w_bl1, wt1, 64);
    repack_w_kernel<<<(64 * 576 + TPB - 1) / TPB, TPB, 0, stream>>>(w_bl2, wt2, 64);
    repack_w_kernel<<<(64 * 576 + TPB - 1) / TPB, TPB, 0, stream>>>(w_d2, wtd2, 64);
    repack_w_kernel<<<(256 * 576 + TPB - 1) / TPB, TPB, 0, stream>>>(w_d3, wtd3, 256);
    repack_w_kernel<<<(18 * 576 + TPB - 1) / TPB, TPB, 0, stream>>>(w_off2, wtoff2, 18);
    repack_w_kernel<<<(18 * 576 + TPB - 1) / TPB, TPB, 0, stream>>>(w_off3, wtoff3, 18);
    zero_stats_kernel<<<1, 256, 0, stream>>>(stats);

    // 4) conv1: hB -> bufC fp32 NCHW (+stats1). x4 in bufC dead.
    conv3x3_mfma_kernel<<<800, TPB, 0, stream>>>(hB, wt1, bufC, stats);

    // 5) apply1: bufC -> hB bf16 NHWC (conv1 input dead)
    bn_apply_nhwc_kernel<<<8 * 400, TPB, 0, stream>>>(bufC, stats, hB, 25600, invN);

    // 6) conv2: hB -> bufC fp32 NCHW (+stats2)
    conv3x3_mfma_kernel<<<800, TPB, 0, stream>>>(hB, wt2, bufC, stats + 128);

    // 7) apply2: bufC -> out0 fp32 NCHW + hB bf16 NHWC (feat4)
    bn_apply_dual_kernel<<<8 * 400, TPB, 0, stream>>>(
        bufC, stats + 128, out0, hB, 25600, invN);

    // 8) offset2 = offconv(feat4 hB) -> A
    offconv_mfma_kernel<<<8 * 6400 / 64, TPB, 0, stream>>>(
        hB, wtoff2, b_off2, A, 160, 160, 80, 80);

    // 9) feat_1_8 = deform2(feat4 hB, offset2) -> out1
    deform_mfma_kernel<64><<<8 * 6400 / 32, TPB, 0, stream>>>(
        hB, A, wtd2, b_d2, out1, 160, 160, 80, 80, 2);

    // 10) feat_1_8 -> NHWC bf16 into hC (bufC dead after apply2)
    nchw_to_nhwc_bf16_kernel<<<8 * (6400 / 64), TPB, 0, stream>>>(out1, hC, 6400);

    // 11) offset3 = offconv(feat8 hC) -> A
    offconv_mfma_kernel<<<8 * 1600 / 64, TPB, 0, stream>>>(
        hC, wtoff3, b_off3, A, 80, 80, 40, 40);

    // 12) feat_1_16 = deform3(feat8 hC, offset3) -> out2
    deform_mfma_kernel<256><<<8 * 1600 / 32, TPB, 0, stream>>>(
        hC, A, wtd3, b_d3, out2, 80, 80, 40, 40, 2);
}

// Round 10
// 365.077 us; speedup vs baseline: 19.6529x; 1.2172x over previous
//
#include <hip/hip_runtime.h>
#include <hip/hip_bf16.h>
#include <math.h>

#define TPB 256

typedef __attribute__((ext_vector_type(8))) short bf16x8_t;
typedef __attribute__((ext_vector_type(4))) float f32x4_t;
typedef __attribute__((ext_vector_type(4))) int i32x4_t;
typedef __attribute__((ext_vector_type(4))) unsigned short u16x4_t;

static __device__ __forceinline__ float bf16_to_f(unsigned short s) {
    union { unsigned u; float f; } cv;
    cv.u = ((unsigned)s) << 16;
    return cv.f;
}
static __device__ __forceinline__ short f_to_bf16(float v) {
    __hip_bfloat16 h = __float2bfloat16(v);
    return *(short*)&h;
}

// ------------------------------------------------- weight repack for MFMA
__global__ void repack_w_kernel(const float* __restrict__ w,
                                short* __restrict__ wt, int O)
{
    int idx = blockIdx.x * TPB + threadIdx.x;
    if (idx >= O * 64 * 9) return;
    int ic  = idx % 64;
    int t   = idx / 64;
    int tap = t % 9;
    int oc  = t / 9;
    wt[(size_t)oc * 576 + tap * 64 + ic] =
        f_to_bf16(w[((size_t)(oc * 64 + ic)) * 9 + tap]);
}

// ------------------------------------------------- MFMA conv 3x3 (64->64, s1)
// in: bf16 NHWC; out: fp32 NCHW; fused BN partial stats.
__global__ __launch_bounds__(256, 1) void conv3x3_mfma_kernel(
    const short* __restrict__ xh,
    const short* __restrict__ wt,
    float* __restrict__ out,
    float* __restrict__ stats)
{
    __shared__ short tile[18 * 18 * 64];
    __shared__ float sstat[128];
    const int H = 160, W = 160;
    int blk = blockIdx.x;
    int b  = blk / 100;
    int r  = blk % 100;
    int y0 = (r / 10) * 16;
    int x0 = (r % 10) * 16;
    const int tid = threadIdx.x;

    const short* inb = xh + (size_t)b * H * W * 64;
    for (int item = tid; item < 18 * 18 * 8; item += TPB) {
        int c8  = item & 7;
        int pix = item >> 3;
        int col = pix % 18, row = pix / 18;
        int y = y0 + row - 1;
        int x = x0 + col - 1;
        bf16x8_t v = {};
        if (y >= 0 && y < H && x >= 0 && x < W)
            v = *(const bf16x8_t*)&inb[((size_t)y * W + x) * 64 + c8 * 8];
        int ch = c8 ^ (col & 7);
        *(bf16x8_t*)&tile[(row * 18 + col) * 64 + ch * 8] = v;
    }
    if (tid < 128) sstat[tid] = 0.f;
    __syncthreads();

    const int wv  = tid >> 6;
    const int l   = tid & 63;
    const int l15 = l & 15;
    const int lg  = l >> 4;

    f32x4_t acc[4][4];
#pragma unroll
    for (int i = 0; i < 4; ++i)
#pragma unroll
        for (int j = 0; j < 4; ++j)
            acc[i][j] = (f32x4_t){0.f, 0.f, 0.f, 0.f};

#pragma unroll 2
    for (int kc = 0; kc < 18; ++kc) {
        int tap = kc >> 1;
        int dy  = tap / 3;
        int dx  = tap % 3;

        bf16x8_t bf[4];
#pragma unroll
        for (int nf = 0; nf < 4; ++nf) {
            int oc = nf * 16 + l15;
            bf[nf] = *(const bf16x8_t*)(wt + (size_t)oc * 576 + kc * 32 + lg * 8);
        }

        int colr  = l15 + dx;
        int chunk = (((kc & 1) << 2) + lg) ^ (colr & 7);
        bf16x8_t af[4];
#pragma unroll
        for (int mf = 0; mf < 4; ++mf) {
            int row = wv * 4 + mf + dy;
            af[mf] = *(const bf16x8_t*)&tile[(row * 18 + colr) * 64 + chunk * 8];
        }

#pragma unroll
        for (int mf = 0; mf < 4; ++mf)
#pragma unroll
            for (int nf = 0; nf < 4; ++nf)
                acc[mf][nf] = __builtin_amdgcn_mfma_f32_16x16x32_bf16(
                    af[mf], bf[nf], acc[mf][nf], 0, 0, 0);
    }

    float* outb = out + (size_t)b * 64 * H * W;
#pragma unroll
    for (int mf = 0; mf < 4; ++mf) {
        int y = y0 + wv * 4 + mf;
#pragma unroll
        for (int nf = 0; nf < 4; ++nf) {
            int oc = nf * 16 + l15;
            *(f32x4_t*)&outb[(size_t)oc * H * W + y * W + x0 + lg * 4] = acc[mf][nf];
        }
    }

#pragma unroll
    for (int nf = 0; nf < 4; ++nf) {
        float s = 0.f, s2 = 0.f;
#pragma unroll
        for (int mf = 0; mf < 4; ++mf)
#pragma unroll
            for (int k = 0; k < 4; ++k) {
                float v = acc[mf][nf][k];
                s += v; s2 += v * v;
            }
        s  += __shfl_xor(s, 16, 64);  s  += __shfl_xor(s, 32, 64);
        s2 += __shfl_xor(s2, 16, 64); s2 += __shfl_xor(s2, 32, 64);
        if (lg == 0) {
            int oc = nf * 16 + l15;
            atomicAdd(&sstat[oc], s);
            atomicAdd(&sstat[64 + oc], s2);
        }
    }
    __syncthreads();
    if (tid < 64) {
        atomicAdd(&stats[tid * 2],     sstat[tid]);
        atomicAdd(&stats[tid * 2 + 1], sstat[64 + tid]);
    }
}

// ------------------------------------------------- NCHW fp32 -> NHWC bf16 (C=64)
__global__ void nchw_to_nhwc_bf16_kernel(const float* __restrict__ in,
                                         short* __restrict__ out, int HW)
{
    __shared__ short tile[64][66];
    int nchunks = HW >> 6;
    int b  = blockIdx.x / nchunks;
    int p0 = (blockIdx.x % nchunks) << 6;
    int tid = threadIdx.x;
#pragma unroll
    for (int rep = 0; rep < 16; ++rep) {
        int item = rep * 256 + tid;
        int c = item >> 6, p = item & 63;
        tile[p][c] = f_to_bf16(in[((size_t)b * 64 + c) * HW + p0 + p]);
    }
    __syncthreads();
#pragma unroll
    for (int rep = 0; rep < 16; ++rep) {
        int item = rep * 256 + tid;
        int p = item >> 6, c = item & 63;
        out[((size_t)b * HW + p0 + p) * 64 + c] = tile[p][c];
    }
}

// ------------------------------------------------- BN apply -> NHWC bf16 only
__global__ void bn_apply_nhwc_kernel(const float* __restrict__ in,
                                     const float* __restrict__ stats,
                                     short* __restrict__ outh,
                                     int HW, float invN)
{
    __shared__ short tile[64][66];
    __shared__ float sm[64], sr[64];
    int nchunks = HW >> 6;
    int b  = blockIdx.x / nchunks;
    int p0 = (blockIdx.x % nchunks) << 6;
    int tid = threadIdx.x;
    if (tid < 64) {
        float mean = stats[tid * 2] * invN;
        float var  = stats[tid * 2 + 1] * invN - mean * mean;
        sm[tid] = mean;
        sr[tid] = rsqrtf(var + 1e-5f);
    }
    __syncthreads();
#pragma unroll
    for (int rep = 0; rep < 16; ++rep) {
        int item = rep * 256 + tid;
        int c = item >> 6, p = item & 63;
        float v = in[((size_t)b * 64 + c) * HW + p0 + p];
        v = (v - sm[c]) * sr[c];
        tile[p][c] = f_to_bf16(v > 0.f ? v : 0.f);
    }
    __syncthreads();
#pragma unroll
    for (int rep = 0; rep < 16; ++rep) {
        int item = rep * 256 + tid;
        int p = item >> 6, c = item & 63;
        outh[((size_t)b * HW + p0 + p) * 64 + c] = tile[p][c];
    }
}

// ------------------------------------------------- BN apply -> NCHW fp32 + NHWC bf16
__global__ void bn_apply_dual_kernel(const float* __restrict__ in,
                                     const float* __restrict__ stats,
                                     float* __restrict__ out,
                                     short* __restrict__ outh,
                                     int HW, float invN)
{
    __shared__ short tile[64][66];
    __shared__ float sm[64], sr[64];
    int nchunks = HW >> 6;
    int b  = blockIdx.x / nchunks;
    int p0 = (blockIdx.x % nchunks) << 6;
    int tid = threadIdx.x;
    if (tid < 64) {
        float mean = stats[tid * 2] * invN;
        float var  = stats[tid * 2 + 1] * invN - mean * mean;
        sm[tid] = mean;
        sr[tid] = rsqrtf(var + 1e-5f);
    }
    __syncthreads();
#pragma unroll
    for (int rep = 0; rep < 16; ++rep) {
        int item = rep * 256 + tid;
        int c = item >> 6, p = item & 63;
        size_t idx = ((size_t)b * 64 + c) * HW + p0 + p;
        float v = in[idx];
        v = (v - sm[c]) * sr[c];
        v = v > 0.f ? v : 0.f;
        out[idx] = v;
        tile[p][c] = f_to_bf16(v);
    }
    __syncthreads();
#pragma unroll
    for (int rep = 0; rep < 16; ++rep) {
        int item = rep * 256 + tid;
        int p = item >> 6, c = item & 63;
        outh[((size_t)b * HW + p0 + p) * 64 + c] = tile[p][c];
    }
}

// ------------------------------------------------- x NCHW (C=3) -> NHWC4 fp32
__global__ void x_to_nhwc4_kernel(const float* __restrict__ in,
                                  float* __restrict__ out)
{
    int idx = blockIdx.x * TPB + threadIdx.x;
    const int HW = 640 * 640;
    if (idx >= 8 * HW) return;
    int b = idx / HW, p = idx % HW;
    f32x4_t v;
    v[0] = in[((size_t)b * 3 + 0) * HW + p];
    v[1] = in[((size_t)b * 3 + 1) * HW + p];
    v[2] = in[((size_t)b * 3 + 2) * HW + p];
    v[3] = 0.f;
    *(f32x4_t*)&out[(size_t)idx * 4] = v;
}

// ------------------------------------------------- offset1: exact fp32, NHWC4
__global__ void offset1_kernel(const float* __restrict__ x4,
                               const float* __restrict__ w,   // (18,3,3,3)
                               const float* __restrict__ bias,
                               float* __restrict__ out)
{
    const int H = 640, W = 640, HW = 25600;
    int idx = blockIdx.x * TPB + threadIdx.x;
    if (idx >= 8 * HW) return;
    int b = idx / HW, r = idx % HW;
    int ho = r / 160, wo = r % 160;

    float acc[18];
#pragma unroll
    for (int o = 0; o < 18; ++o) acc[o] = bias[o];

    const float* xb = x4 + (size_t)b * H * W * 4;
#pragma unroll
    for (int tap = 0; tap < 9; ++tap) {
        int iy = ho * 4 - 1 + tap / 3;
        int ix = wo * 4 - 1 + tap % 3;
        if (iy < 0 || iy >= H || ix < 0 || ix >= W) continue;
        f32x4_t s = *(const f32x4_t*)&xb[((size_t)iy * W + ix) * 4];
#pragma unroll
        for (int c = 0; c < 3; ++c)
#pragma unroll
            for (int o = 0; o < 18; ++o)
                acc[o] += s[c] * w[(o * 3 + c) * 9 + tap];
    }
#pragma unroll
    for (int o = 0; o < 18; ++o)
        out[((size_t)(b * 18 + o)) * HW + r] = acc[o];
}

// ------------------------------------------------- offset2/3: MFMA conv, N=18
__global__ __launch_bounds__(256, 1) void offconv_mfma_kernel(
    const short* __restrict__ xh,
    const short* __restrict__ wt,    // bf16 [18][576]
    const float* __restrict__ bias,
    float* __restrict__ out,
    int H, int W, int Ho, int Wo)
{
    const int HW = Ho * Wo;
    const int tid = threadIdx.x;
    const int wv = tid >> 6, l = tid & 63;
    const int l15 = l & 15, lg = l >> 4;
    const int pix0 = blockIdx.x * 64 + wv * 16;
    const int b = pix0 / HW;
    const int r0 = pix0 - b * HW;

    int rp = r0 + l15;
    int ho = rp / Wo, wo = rp % Wo;
    const short* xb = xh + (size_t)b * H * W * 64;

    f32x4_t acc[2];
    acc[0] = (f32x4_t){0.f, 0.f, 0.f, 0.f};
    acc[1] = (f32x4_t){0.f, 0.f, 0.f, 0.f};

#pragma unroll 2
    for (int kc = 0; kc < 18; ++kc) {
        int tap = kc >> 1;
        int iy = ho * 2 - 1 + tap / 3;
        int ix = wo * 2 - 1 + tap % 3;
        bf16x8_t af = {};
        if (iy >= 0 && iy < H && ix >= 0 && ix < W)
            af = *(const bf16x8_t*)&xb[((size_t)iy * W + ix) * 64
                                       + (kc & 1) * 32 + lg * 8];
#pragma unroll
        for (int nf = 0; nf < 2; ++nf) {
            int oc = nf * 16 + l15;
            bf16x8_t bf = {};
            if (oc < 18)
                bf = *(const bf16x8_t*)(wt + (size_t)oc * 576 + kc * 32 + lg * 8);
            acc[nf] = __builtin_amdgcn_mfma_f32_16x16x32_bf16(af, bf, acc[nf], 0, 0, 0);
        }
    }

#pragma unroll
    for (int nf = 0; nf < 2; ++nf) {
        int oc = nf * 16 + l15;
        if (oc < 18) {
            float bv = bias[oc];
            f32x4_t v = acc[nf];
            v[0] += bv; v[1] += bv; v[2] += bv; v[3] += bv;
            *(f32x4_t*)&out[((size_t)(b * 18 + oc)) * HW + r0 + lg * 4] = v;
        }
    }
}

// ------------------------------------------------- deform1: C=3, fused skip,
// P=32 pixels/block, branchless clamped gather, writes bf16 NHWC
__global__ __launch_bounds__(256, 1) void deform1_kernel(
    const float* __restrict__ x4,   // [B][640][640][4] fp32
    const float* __restrict__ off,  // [B][18][160][160]
    const float* __restrict__ w,    // (64,3,3,3) fp32
    const float* __restrict__ bias, // b_d1
    const float* __restrict__ pool, // [B][3][25600] fp32
    const float* __restrict__ wsk,  // (64,3)
    const float* __restrict__ bsk,  // (64,)
    short* __restrict__ outh)       // NHWC bf16
{
    const int H = 640, W = 640, Ho = 160, Wo = 160, HW = 25600;
    constexpr int P = 32;
    __shared__ float samp[P][28];
    __shared__ int   sidx[P * 9][4];
    __shared__ float swt[P * 9][4];
    const int tid = threadIdx.x;
    const int pix0 = blockIdx.x * P;
    const int b = pix0 / HW;
    const int r0 = pix0 - b * HW;

    // phase 1: clamped corners (branchless downstream)
    for (int item = tid; item < P * 9; item += TPB) {
        int p = item / 9, tap = item % 9;
        int r = r0 + p, ho = r / Wo, wo = r % Wo;
        float dy = off[((size_t)(b * 18 + 2 * tap) * Ho + ho) * Wo + wo];
        float dx = off[((size_t)(b * 18 + 2 * tap + 1) * Ho + ho) * Wo + wo];
        float ys = (float)(ho * 4 - 1 + tap / 3) + dy;
        float xs = (float)(wo * 4 - 1 + tap % 3) + dx;
        float y0f = floorf(ys), x0f = floorf(xs);
        float fy = ys - y0f, fx = xs - x0f;
        int y0 = (int)y0f, x0 = (int)x0f;
        float wts[4] = {(1.f - fy) * (1.f - fx), (1.f - fy) * fx,
                        fy * (1.f - fx),          fy * fx};
#pragma unroll
        for (int j = 0; j < 4; ++j) {
            int iy = y0 + (j >> 1), ix = x0 + (j & 1);
            bool v = (iy >= 0) && (iy < H) && (ix >= 0) && (ix < W);
            sidx[item][j] = v ? (iy * W + ix) : 0;
            swt[item][j]  = v ? wts[j] : 0.f;
        }
    }
    __syncthreads();

    // phase 2: branchless vector gather (288 entries over 256 threads)
    const float* xb = x4 + (size_t)b * H * W * 4;
    for (int item = tid; item < P * 9; item += TPB) {
        int p = item / 9, tap = item % 9;
        i32x4_t id4 = *(const i32x4_t*)sidx[item];
        f32x4_t w4  = *(const f32x4_t*)swt[item];
        f32x4_t a0 = *(const f32x4_t*)&xb[(size_t)(unsigned)id4[0] * 4];
        f32x4_t a1 = *(const f32x4_t*)&xb[(size_t)(unsigned)id4[1] * 4];
        f32x4_t a2 = *(const f32x4_t*)&xb[(size_t)(unsigned)id4[2] * 4];
        f32x4_t a3 = *(const f32x4_t*)&xb[(size_t)(unsigned)id4[3] * 4];
        samp[p][0 * 9 + tap] = w4[0]*a0[0] + w4[1]*a1[0] + w4[2]*a2[0] + w4[3]*a3[0];
        samp[p][1 * 9 + tap] = w4[0]*a0[1] + w4[1]*a1[1] + w4[2]*a2[1] + w4[3]*a3[1];
        samp[p][2 * 9 + tap] = w4[0]*a0[2] + w4[1]*a1[2] + w4[2]*a2[2] + w4[3]*a3[2];
    }
    __syncthreads();

    // phase 3: MAC, wave -> 8-pixel group, thread -> oc
    int g = tid >> 6;
    int o = tid & 63;
    float acc[8];
#pragma unroll
    for (int pi = 0; pi < 8; ++pi) acc[pi] = bias[o] + bsk[o];
#pragma unroll
    for (int c = 0; c < 3; ++c)
#pragma unroll
        for (int k = 0; k < 9; ++k) {
            float wv = w[((size_t)(o * 3 + c)) * 9 + k];
#pragma unroll
            for (int pi = 0; pi < 8; ++pi)
                acc[pi] += wv * samp[g * 8 + pi][c * 9 + k];
        }
#pragma unroll
    for (int pi = 0; pi < 8; ++pi) {
        int r = r0 + g * 8 + pi;
        float sv = wsk[o * 3 + 0] * pool[(size_t)(b * 3 + 0) * HW + r]
                 + wsk[o * 3 + 1] * pool[(size_t)(b * 3 + 1) * HW + r]
                 + wsk[o * 3 + 2] * pool[(size_t)(b * 3 + 2) * HW + r];
        outh[((size_t)(b * HW + r)) * 64 + o] = f_to_bf16(acc[pi] + sv);
    }
}

// ------------------------------------------------- deform MFMA: C=64 -> O
// branchless clamped gather, vector meta reads, unroll 3
template <int O>
__global__ __launch_bounds__(256, 1) void deform_mfma_kernel(
    const short* __restrict__ xh,
    const float* __restrict__ off,  // [B][18][Ho][Wo]
    const short* __restrict__ wt,   // bf16 [O][576]
    const float* __restrict__ bias,
    float* __restrict__ out,        // [B][O][Ho][Wo]
    int H, int W, int Ho, int Wo, int stride)
{
    constexpr int NF = O / 64;
    constexpr int P  = 32;
    __shared__ alignas(16) short samp[P * 576];
    __shared__ int   sidx[P * 9][4];
    __shared__ float swt[P * 9][4];

    const int tid = threadIdx.x;
    const int HW = Ho * Wo;
    const int pix0 = blockIdx.x * P;
    const int b = pix0 / HW;
    const int r0 = pix0 - b * HW;

    // phase 1: clamped corners
    for (int item = tid; item < P * 9; item += TPB) {
        int p = item / 9, tap = item % 9;
        int r = r0 + p, ho = r / Wo, wo = r % Wo;
        float dy = off[((size_t)(b * 18 + 2 * tap) * Ho + ho) * Wo + wo];
        float dx = off[((size_t)(b * 18 + 2 * tap + 1) * Ho + ho) * Wo + wo];
        float ys = (float)(ho * stride - 1 + tap / 3) + dy;
        float xs = (float)(wo * stride - 1 + tap % 3) + dx;
        float y0f = floorf(ys), x0f = floorf(xs);
        float fy = ys - y0f, fx = xs - x0f;
        int y0 = (int)y0f, x0 = (int)x0f;
        float wts[4] = {(1.f - fy) * (1.f - fx), (1.f - fy) * fx,
                        fy * (1.f - fx),          fy * fx};
#pragma unroll
        for (int j = 0; j < 4; ++j) {
            int iy = y0 + (j >> 1), ix = x0 + (j & 1);
            bool v = (iy >= 0) && (iy < H) && (ix >= 0) && (ix < W);
            sidx[item][j] = v ? (iy * W + ix) : 0;
            swt[item][j]  = v ? wts[j] : 0.f;
        }
    }
    __syncthreads();

    // phase 2: branchless vectorized gather
    {
        const int grp = tid >> 4;
        const int ic  = (tid & 15) * 4;
        const short* xb = xh + (size_t)b * H * W * 64;
#pragma unroll 3
        for (int i = 0; i < 18; ++i) {
            int e = grp * 18 + i;
            int p = e / 9, tap = e % 9;
            i32x4_t id4 = *(const i32x4_t*)sidx[e];
            f32x4_t w4  = *(const f32x4_t*)swt[e];
            u16x4_t u0 = *(const u16x4_t*)&xb[(size_t)(unsigned)id4[0] * 64 + ic];
            u16x4_t u1 = *(const u16x4_t*)&xb[(size_t)(unsigned)id4[1] * 64 + ic];
            u16x4_t u2 = *(const u16x4_t*)&xb[(size_t)(unsigned)id4[2] * 64 + ic];
            u16x4_t u3 = *(const u16x4_t*)&xb[(size_t)(unsigned)id4[3] * 64 + ic];
            float v0 = w4[0]*bf16_to_f(u0[0]) + w4[1]*bf16_to_f(u1[0])
                     + w4[2]*bf16_to_f(u2[0]) + w4[3]*bf16_to_f(u3[0]);
            float v1 = w4[0]*bf16_to_f(u0[1]) + w4[1]*bf16_to_f(u1[1])
                     + w4[2]*bf16_to_f(u2[1]) + w4[3]*bf16_to_f(u3[1]);
            float v2 = w4[0]*bf16_to_f(u0[2]) + w4[1]*bf16_to_f(u1[2])
                     + w4[2]*bf16_to_f(u2[2]) + w4[3]*bf16_to_f(u3[2]);
            float v3 = w4[0]*bf16_to_f(u0[3]) + w4[1]*bf16_to_f(u1[3])
                     + w4[2]*bf16_to_f(u2[3]) + w4[3]*bf16_to_f(u3[3]);
            int sw = (tap * 8 + ((ic >> 3) ^ (p & 7))) * 8 + (ic & 7);
            short* dst = &samp[p * 576 + sw];
            dst[0] = f_to_bf16(v0);
            dst[1] = f_to_bf16(v1);
            dst[2] = f_to_bf16(v2);
            dst[3] = f_to_bf16(v3);
        }
    }
    __syncthreads();

    // phase 3: MFMA  (M=32, N=O, K=576)
    const int wv = tid >> 6;
    const int l  = tid & 63;
    const int l15 = l & 15, lg = l >> 4;
    f32x4_t acc[2][NF];
#pragma unroll
    for (int mf = 0; mf < 2; ++mf)
#pragma unroll
        for (int nf = 0; nf < NF; ++nf)
            acc[mf][nf] = (f32x4_t){0.f, 0.f, 0.f, 0.f};

#pragma unroll 2
    for (int kc = 0; kc < 18; ++kc) {
        int tap = kc >> 1;
        int low = (((kc & 1) << 2) | lg) ^ (l15 & 7);
        bf16x8_t af0 = *(const bf16x8_t*)&samp[l15 * 576 + (tap * 8 + low) * 8];
        bf16x8_t af1 = *(const bf16x8_t*)&samp[(l15 + 16) * 576 + (tap * 8 + low) * 8];
#pragma unroll
        for (int nf = 0; nf < NF; ++nf) {
            int oc = (wv * NF + nf) * 16 + l15;
            bf16x8_t bf = *(const bf16x8_t*)(wt + (size_t)oc * 576 + kc * 32 + lg * 8);
            acc[0][nf] = __builtin_amdgcn_mfma_f32_16x16x32_bf16(af0, bf, acc[0][nf], 0, 0, 0);
            acc[1][nf] = __builtin_amdgcn_mfma_f32_16x16x32_bf16(af1, bf, acc[1][nf], 0, 0, 0);
        }
    }

#pragma unroll
    for (int mf = 0; mf < 2; ++mf)
#pragma unroll
        for (int nf = 0; nf < NF; ++nf) {
            int oc = (wv * NF + nf) * 16 + l15;
            float bv = bias[oc];
            f32x4_t v = acc[mf][nf];
            v[0] += bv; v[1] += bv; v[2] += bv; v[3] += bv;
            *(f32x4_t*)&out[((size_t)(b * O + oc)) * HW + r0 + mf * 16 + lg * 4] = v;
        }
}

// ---------------------------------------------------------------- avgpool 4x4
__global__ void avgpool4_kernel(const float* __restrict__ in,
                                float* __restrict__ out,
                                int BC, int Ho, int Wo, int H, int W)
{
    int idx = blockIdx.x * TPB + threadIdx.x;
    int total = BC * Ho * Wo;
    if (idx >= total) return;
    int wo = idx % Wo;
    int t = idx / Wo;
    int ho = t % Ho;
    int bc = t / Ho;
    const float* xp = in + (size_t)bc * H * W + (ho * 4) * W + wo * 4;
    float s = 0.f;
#pragma unroll
    for (int i = 0; i < 4; ++i)
#pragma unroll
        for (int j = 0; j < 4; ++j)
            s += xp[i * W + j];
    out[idx] = s * (1.0f / 16.0f);
}

__global__ void zero_stats_kernel(float* __restrict__ stats)
{
    if (threadIdx.x < 256) stats[threadIdx.x] = 0.f;
}

// ---------------------------------------------------------------- launch
extern "C" void kernel_launch(void* const* d_in, const int* in_sizes, int n_in,
                              void* d_out, int out_size, void* d_ws, size_t ws_size,
                              hipStream_t stream)
{
    const float* x      = (const float*)d_in[0];
    const float* w_off1 = (const float*)d_in[1];
    const float* b_off1 = (const float*)d_in[2];
    const float* w_d1   = (const float*)d_in[3];
    const float* b_d1   = (const float*)d_in[4];
    const float* w_skip = (const float*)d_in[5];
    const float* b_skip = (const float*)d_in[6];
    const float* w_bl1  = (const float*)d_in[7];
    const float* w_bl2  = (const float*)d_in[8];
    const float* w_off2 = (const float*)d_in[9];
    const float* b_off2 = (const float*)d_in[10];
    const float* w_d2   = (const float*)d_in[11];
    const float* b_d2   = (const float*)d_in[12];
    const float* w_off3 = (const float*)d_in[13];
    const float* b_off3 = (const float*)d_in[14];
    const float* w_d3   = (const float*)d_in[15];
    const float* b_d3   = (const float*)d_in[16];

    const int B = 8;
    float* A     = (float*)d_ws;          // 3,686,400 floats
    float* bufB  = A + 3686400;           // 13,107,200 floats
    float* bufC  = bufB + 13107200;       // 13,107,200 floats
    float* stats = bufC + 13107200;       // 256 floats

    short* hB   = (short*)bufB;
    short* hC   = (short*)bufC;
    float* pool = bufB + 8000000;

    short* wt1    = (short*)(A + 1000000);
    short* wt2    = wt1 + 64 * 576;
    short* wtd2   = (short*)(A + 1500000);
    short* wtd3   = (short*)(A + 1550000);
    short* wtoff2 = (short*)(A + 1700000);
    short* wtoff3 = (short*)(A + 1710000);

    float* out0 = (float*)d_out;
    float* out1 = out0 + 13107200;
    float* out2 = out1 + 3276800;

    const float invN = 1.0f / (B * 25600);

    // 0) x -> NHWC4 fp32 into bufC
    x_to_nhwc4_kernel<<<(8 * 409600 + TPB - 1) / TPB, TPB, 0, stream>>>(x, bufC);

    // 1) offset1 (exact fp32) -> A
    offset1_kernel<<<(8 * 25600 + TPB - 1) / TPB, TPB, 0, stream>>>(
        bufC, w_off1, b_off1, A);

    // 2) pool = avgpool4(x) -> bufB+8M
    avgpool4_kernel<<<(B * 3 * 25600 + TPB - 1) / TPB, TPB, 0, stream>>>(
        x, pool, B * 3, 160, 160, 640, 640);

    // 3) d1+skip = deform1 -> hB (bf16 NHWC). offset1 dead after this.
    deform1_kernel<<<8 * 25600 / 32, TPB, 0, stream>>>(
        bufC, A, w_d1, b_d1, pool, w_skip, b_skip, hB);

    // 3.5) repack weights
    repack_w_kernel<<<(64 * 576 + TPB - 1) / TPB, TPB, 0, stream>>>(w_bl1, wt1, 64);
    repack_w_kernel<<<(64 * 576 + TPB - 1) / TPB, TPB, 0, stream>>>(w_bl2, wt2, 64);
    repack_w_kernel<<<(64 * 576 + TPB - 1) / TPB, TPB, 0, stream>>>(w_d2, wtd2, 64);
    repack_w_kernel<<<(256 * 576 + TPB - 1) / TPB, TPB, 0, stream>>>(w_d3, wtd3, 256);
    repack_w_kernel<<<(18 * 576 + TPB - 1) / TPB, TPB, 0, stream>>>(w_off2, wtoff2, 18);
    repack_w_kernel<<<(18 * 576 + TPB - 1) / TPB, TPB, 0, stream>>>(w_off3, wtoff3, 18);
    zero_stats_kernel<<<1, 256, 0, stream>>>(stats);

    // 4) conv1: hB -> bufC fp32 NCHW (+stats1)
    conv3x3_mfma_kernel<<<800, TPB, 0, stream>>>(hB, wt1, bufC, stats);

    // 5) apply1: bufC -> hB bf16 NHWC
    bn_apply_nhwc_kernel<<<8 * 400, TPB, 0, stream>>>(bufC, stats, hB, 25600, invN);

    // 6) conv2: hB -> bufC fp32 NCHW (+stats2)
    conv3x3_mfma_kernel<<<800, TPB, 0, stream>>>(hB, wt2, bufC, stats + 128);

    // 7) apply2: bufC -> out0 fp32 NCHW + hB bf16 NHWC (feat4)
    bn_apply_dual_kernel<<<8 * 400, TPB, 0, stream>>>(
        bufC, stats + 128, out0, hB, 25600, invN);

    // 8) offset2 = offconv(feat4 hB) -> A
    offconv_mfma_kernel<<<8 * 6400 / 64, TPB, 0, stream>>>(
        hB, wtoff2, b_off2, A, 160, 160, 80, 80);

    // 9) feat_1_8 = deform2(feat4 hB, offset2) -> out1
    deform_mfma_kernel<64><<<8 * 6400 / 32, TPB, 0, stream>>>(
        hB, A, wtd2, b_d2, out1, 160, 160, 80, 80, 2);

    // 10) feat_1_8 -> NHWC bf16 into hC
    nchw_to_nhwc_bf16_kernel<<<8 * (6400 / 64), TPB, 0, stream>>>(out1, hC, 6400);

    // 11) offset3 = offconv(feat8 hC) -> A
    offconv_mfma_kernel<<<8 * 1600 / 64, TPB, 0, stream>>>(
        hC, wtoff3, b_off3, A, 80, 80, 40, 40);

    // 12) feat_1_16 = deform3(feat8 hC, offset3) -> out2
    deform_mfma_kernel<256><<<8 * 1600 / 32, TPB, 0, stream>>>(
        hC, A, wtd3, b_d3, out2, 80, 80, 40, 40, 2);
}

// Round 11
// 331.609 us; speedup vs baseline: 21.6363x; 1.1009x over previous
//
#include <hip/hip_runtime.h>
#include <hip/hip_bf16.h>
#include <math.h>

#define TPB 256

typedef __attribute__((ext_vector_type(8))) short bf16x8_t;
typedef __attribute__((ext_vector_type(4))) float f32x4_t;
typedef __attribute__((ext_vector_type(4))) int i32x4_t;
typedef __attribute__((ext_vector_type(4))) unsigned short u16x4_t;

static __device__ __forceinline__ float bf16_to_f(unsigned short s) {
    union { unsigned u; float f; } cv;
    cv.u = ((unsigned)s) << 16;
    return cv.f;
}
static __device__ __forceinline__ short f_to_bf16(float v) {
    __hip_bfloat16 h = __float2bfloat16(v);
    return *(short*)&h;
}

// ------------------------------------------------- weight repack, FRAGMENT order
// w (Oreal, 64, 3, 3) fp32 -> wtf bf16 [18][NFRAG][64][8]:
//   lane l holds oc = ocf*16 + (l&15), k = kc*32 + (l>>4)*8 + j
// One wave B-frag load = coalesced 1KB. oc >= Oreal zero-padded.
__global__ void repack_frag_kernel(const float* __restrict__ w,
                                   short* __restrict__ wtf,
                                   int Oreal, int NFRAG)
{
    int idx = blockIdx.x * TPB + threadIdx.x;
    int total = 18 * NFRAG * 64 * 8;
    if (idx >= total) return;
    int j    = idx & 7;
    int lane = (idx >> 3) & 63;
    int t    = idx >> 9;          // kc*NFRAG + ocf
    int ocf  = t % NFRAG;
    int kc   = t / NFRAG;
    int oc   = ocf * 16 + (lane & 15);
    int tap  = kc >> 1;
    int ic   = (kc & 1) * 32 + (lane >> 4) * 8 + j;
    float v = 0.f;
    if (oc < Oreal)
        v = w[((size_t)(oc * 64 + ic)) * 9 + tap];
    wtf[idx] = f_to_bf16(v);
}

// ------------------------------------------------- MFMA conv 3x3 (64->64, s1)
// in: bf16 NHWC; out: fp32 NCHW; fused BN partial stats; frag-ordered weights.
__global__ __launch_bounds__(256, 1) void conv3x3_mfma_kernel(
    const short* __restrict__ xh,
    const short* __restrict__ wt,   // [18][4][64][8] frag order
    float* __restrict__ out,
    float* __restrict__ stats)
{
    __shared__ short tile[18 * 18 * 64];
    __shared__ float sstat[128];
    const int H = 160, W = 160;
    int blk = blockIdx.x;
    int b  = blk / 100;
    int r  = blk % 100;
    int y0 = (r / 10) * 16;
    int x0 = (r % 10) * 16;
    const int tid = threadIdx.x;

    const short* inb = xh + (size_t)b * H * W * 64;
    for (int item = tid; item < 18 * 18 * 8; item += TPB) {
        int c8  = item & 7;
        int pix = item >> 3;
        int col = pix % 18, row = pix / 18;
        int y = y0 + row - 1;
        int x = x0 + col - 1;
        bf16x8_t v = {};
        if (y >= 0 && y < H && x >= 0 && x < W)
            v = *(const bf16x8_t*)&inb[((size_t)y * W + x) * 64 + c8 * 8];
        int ch = c8 ^ (col & 7);
        *(bf16x8_t*)&tile[(row * 18 + col) * 64 + ch * 8] = v;
    }
    if (tid < 128) sstat[tid] = 0.f;
    __syncthreads();

    const int wv  = tid >> 6;
    const int l   = tid & 63;
    const int l15 = l & 15;
    const int lg  = l >> 4;

    f32x4_t acc[4][4];
#pragma unroll
    for (int i = 0; i < 4; ++i)
#pragma unroll
        for (int j = 0; j < 4; ++j)
            acc[i][j] = (f32x4_t){0.f, 0.f, 0.f, 0.f};

#pragma unroll 2
    for (int kc = 0; kc < 18; ++kc) {
        int tap = kc >> 1;
        int dy  = tap / 3;
        int dx  = tap % 3;

        bf16x8_t bf[4];
#pragma unroll
        for (int nf = 0; nf < 4; ++nf)
            bf[nf] = *(const bf16x8_t*)(wt + (((size_t)(kc * 4 + nf)) * 64 + l) * 8);

        int colr  = l15 + dx;
        int chunk = (((kc & 1) << 2) + lg) ^ (colr & 7);
        bf16x8_t af[4];
#pragma unroll
        for (int mf = 0; mf < 4; ++mf) {
            int row = wv * 4 + mf + dy;
            af[mf] = *(const bf16x8_t*)&tile[(row * 18 + colr) * 64 + chunk * 8];
        }

#pragma unroll
        for (int mf = 0; mf < 4; ++mf)
#pragma unroll
            for (int nf = 0; nf < 4; ++nf)
                acc[mf][nf] = __builtin_amdgcn_mfma_f32_16x16x32_bf16(
                    af[mf], bf[nf], acc[mf][nf], 0, 0, 0);
    }

    float* outb = out + (size_t)b * 64 * H * W;
#pragma unroll
    for (int mf = 0; mf < 4; ++mf) {
        int y = y0 + wv * 4 + mf;
#pragma unroll
        for (int nf = 0; nf < 4; ++nf) {
            int oc = nf * 16 + l15;
            *(f32x4_t*)&outb[(size_t)oc * H * W + y * W + x0 + lg * 4] = acc[mf][nf];
        }
    }

#pragma unroll
    for (int nf = 0; nf < 4; ++nf) {
        float s = 0.f, s2 = 0.f;
#pragma unroll
        for (int mf = 0; mf < 4; ++mf)
#pragma unroll
            for (int k = 0; k < 4; ++k) {
                float v = acc[mf][nf][k];
                s += v; s2 += v * v;
            }
        s  += __shfl_xor(s, 16, 64);  s  += __shfl_xor(s, 32, 64);
        s2 += __shfl_xor(s2, 16, 64); s2 += __shfl_xor(s2, 32, 64);
        if (lg == 0) {
            int oc = nf * 16 + l15;
            atomicAdd(&sstat[oc], s);
            atomicAdd(&sstat[64 + oc], s2);
        }
    }
    __syncthreads();
    if (tid < 64) {
        atomicAdd(&stats[tid * 2],     sstat[tid]);
        atomicAdd(&stats[tid * 2 + 1], sstat[64 + tid]);
    }
}

// ------------------------------------------------- NCHW fp32 -> NHWC bf16 (C=64)
__global__ void nchw_to_nhwc_bf16_kernel(const float* __restrict__ in,
                                         short* __restrict__ out, int HW)
{
    __shared__ short tile[64][66];
    int nchunks = HW >> 6;
    int b  = blockIdx.x / nchunks;
    int p0 = (blockIdx.x % nchunks) << 6;
    int tid = threadIdx.x;
#pragma unroll
    for (int rep = 0; rep < 16; ++rep) {
        int item = rep * 256 + tid;
        int c = item >> 6, p = item & 63;
        tile[p][c] = f_to_bf16(in[((size_t)b * 64 + c) * HW + p0 + p]);
    }
    __syncthreads();
#pragma unroll
    for (int rep = 0; rep < 16; ++rep) {
        int item = rep * 256 + tid;
        int p = item >> 6, c = item & 63;
        out[((size_t)b * HW + p0 + p) * 64 + c] = tile[p][c];
    }
}

// ------------------------------------------------- BN apply -> NHWC bf16 only
__global__ void bn_apply_nhwc_kernel(const float* __restrict__ in,
                                     const float* __restrict__ stats,
                                     short* __restrict__ outh,
                                     int HW, float invN)
{
    __shared__ short tile[64][66];
    __shared__ float sm[64], sr[64];
    int nchunks = HW >> 6;
    int b  = blockIdx.x / nchunks;
    int p0 = (blockIdx.x % nchunks) << 6;
    int tid = threadIdx.x;
    if (tid < 64) {
        float mean = stats[tid * 2] * invN;
        float var  = stats[tid * 2 + 1] * invN - mean * mean;
        sm[tid] = mean;
        sr[tid] = rsqrtf(var + 1e-5f);
    }
    __syncthreads();
#pragma unroll
    for (int rep = 0; rep < 16; ++rep) {
        int item = rep * 256 + tid;
        int c = item >> 6, p = item & 63;
        float v = in[((size_t)b * 64 + c) * HW + p0 + p];
        v = (v - sm[c]) * sr[c];
        tile[p][c] = f_to_bf16(v > 0.f ? v : 0.f);
    }
    __syncthreads();
#pragma unroll
    for (int rep = 0; rep < 16; ++rep) {
        int item = rep * 256 + tid;
        int p = item >> 6, c = item & 63;
        outh[((size_t)b * HW + p0 + p) * 64 + c] = tile[p][c];
    }
}

// ------------------------------------------------- BN apply -> NCHW fp32 + NHWC bf16
__global__ void bn_apply_dual_kernel(const float* __restrict__ in,
                                     const float* __restrict__ stats,
                                     float* __restrict__ out,
                                     short* __restrict__ outh,
                                     int HW, float invN)
{
    __shared__ short tile[64][66];
    __shared__ float sm[64], sr[64];
    int nchunks = HW >> 6;
    int b  = blockIdx.x / nchunks;
    int p0 = (blockIdx.x % nchunks) << 6;
    int tid = threadIdx.x;
    if (tid < 64) {
        float mean = stats[tid * 2] * invN;
        float var  = stats[tid * 2 + 1] * invN - mean * mean;
        sm[tid] = mean;
        sr[tid] = rsqrtf(var + 1e-5f);
    }
    __syncthreads();
#pragma unroll
    for (int rep = 0; rep < 16; ++rep) {
        int item = rep * 256 + tid;
        int c = item >> 6, p = item & 63;
        size_t idx = ((size_t)b * 64 + c) * HW + p0 + p;
        float v = in[idx];
        v = (v - sm[c]) * sr[c];
        v = v > 0.f ? v : 0.f;
        out[idx] = v;
        tile[p][c] = f_to_bf16(v);
    }
    __syncthreads();
#pragma unroll
    for (int rep = 0; rep < 16; ++rep) {
        int item = rep * 256 + tid;
        int p = item >> 6, c = item & 63;
        outh[((size_t)b * HW + p0 + p) * 64 + c] = tile[p][c];
    }
}

// ------------------------------------------------- x NCHW (C=3) -> NHWC4 fp32
__global__ void x_to_nhwc4_kernel(const float* __restrict__ in,
                                  float* __restrict__ out)
{
    int idx = blockIdx.x * TPB + threadIdx.x;
    const int HW = 640 * 640;
    if (idx >= 8 * HW) return;
    int b = idx / HW, p = idx % HW;
    f32x4_t v;
    v[0] = in[((size_t)b * 3 + 0) * HW + p];
    v[1] = in[((size_t)b * 3 + 1) * HW + p];
    v[2] = in[((size_t)b * 3 + 2) * HW + p];
    v[3] = 0.f;
    *(f32x4_t*)&out[(size_t)idx * 4] = v;
}

// ------------------------------------------------- offset1: exact fp32, NHWC4
__global__ void offset1_kernel(const float* __restrict__ x4,
                               const float* __restrict__ w,   // (18,3,3,3)
                               const float* __restrict__ bias,
                               float* __restrict__ out)
{
    const int H = 640, W = 640, HW = 25600;
    int idx = blockIdx.x * TPB + threadIdx.x;
    if (idx >= 8 * HW) return;
    int b = idx / HW, r = idx % HW;
    int ho = r / 160, wo = r % 160;

    float acc[18];
#pragma unroll
    for (int o = 0; o < 18; ++o) acc[o] = bias[o];

    const float* xb = x4 + (size_t)b * H * W * 4;
#pragma unroll
    for (int tap = 0; tap < 9; ++tap) {
        int iy = ho * 4 - 1 + tap / 3;
        int ix = wo * 4 - 1 + tap % 3;
        if (iy < 0 || iy >= H || ix < 0 || ix >= W) continue;
        f32x4_t s = *(const f32x4_t*)&xb[((size_t)iy * W + ix) * 4];
#pragma unroll
        for (int c = 0; c < 3; ++c)
#pragma unroll
            for (int o = 0; o < 18; ++o)
                acc[o] += s[c] * w[(o * 3 + c) * 9 + tap];
    }
#pragma unroll
    for (int o = 0; o < 18; ++o)
        out[((size_t)(b * 18 + o)) * HW + r] = acc[o];
}

// ------------------------------------------------- offset2/3: MFMA conv, N=18 (padded 32)
__global__ __launch_bounds__(256, 1) void offconv_mfma_kernel(
    const short* __restrict__ xh,
    const short* __restrict__ wt,    // [18][2][64][8] frag order, zero-padded
    const float* __restrict__ bias,
    float* __restrict__ out,
    int H, int W, int Ho, int Wo)
{
    const int HW = Ho * Wo;
    const int tid = threadIdx.x;
    const int wv = tid >> 6, l = tid & 63;
    const int l15 = l & 15, lg = l >> 4;
    const int pix0 = blockIdx.x * 64 + wv * 16;
    const int b = pix0 / HW;
    const int r0 = pix0 - b * HW;

    int rp = r0 + l15;
    int ho = rp / Wo, wo = rp % Wo;
    const short* xb = xh + (size_t)b * H * W * 64;

    f32x4_t acc[2];
    acc[0] = (f32x4_t){0.f, 0.f, 0.f, 0.f};
    acc[1] = (f32x4_t){0.f, 0.f, 0.f, 0.f};

#pragma unroll 2
    for (int kc = 0; kc < 18; ++kc) {
        int tap = kc >> 1;
        int iy = ho * 2 - 1 + tap / 3;
        int ix = wo * 2 - 1 + tap % 3;
        bf16x8_t af = {};
        if (iy >= 0 && iy < H && ix >= 0 && ix < W)
            af = *(const bf16x8_t*)&xb[((size_t)iy * W + ix) * 64
                                       + (kc & 1) * 32 + lg * 8];
#pragma unroll
        for (int nf = 0; nf < 2; ++nf) {
            bf16x8_t bf = *(const bf16x8_t*)(wt + (((size_t)(kc * 2 + nf)) * 64 + l) * 8);
            acc[nf] = __builtin_amdgcn_mfma_f32_16x16x32_bf16(af, bf, acc[nf], 0, 0, 0);
        }
    }

#pragma unroll
    for (int nf = 0; nf < 2; ++nf) {
        int oc = nf * 16 + l15;
        if (oc < 18) {
            float bv = bias[oc];
            f32x4_t v = acc[nf];
            v[0] += bv; v[1] += bv; v[2] += bv; v[3] += bv;
            *(f32x4_t*)&out[((size_t)(b * 18 + oc)) * HW + r0 + lg * 4] = v;
        }
    }
}

// ------------------------------------------------- deform1: C=3, fused skip
__global__ __launch_bounds__(256, 1) void deform1_kernel(
    const float* __restrict__ x4,   // [B][640][640][4] fp32
    const float* __restrict__ off,  // [B][18][160][160]
    const float* __restrict__ w,    // (64,3,3,3) fp32
    const float* __restrict__ bias, // b_d1
    const float* __restrict__ pool, // [B][3][25600] fp32
    const float* __restrict__ wsk,  // (64,3)
    const float* __restrict__ bsk,  // (64,)
    short* __restrict__ outh)       // NHWC bf16
{
    const int H = 640, W = 640, Ho = 160, Wo = 160, HW = 25600;
    constexpr int P = 32;
    __shared__ float samp[P][28];
    __shared__ int   sidx[P * 9][4];
    __shared__ float swt[P * 9][4];
    const int tid = threadIdx.x;
    const int pix0 = blockIdx.x * P;
    const int b = pix0 / HW;
    const int r0 = pix0 - b * HW;

    for (int item = tid; item < P * 9; item += TPB) {
        int p = item / 9, tap = item % 9;
        int r = r0 + p, ho = r / Wo, wo = r % Wo;
        float dy = off[((size_t)(b * 18 + 2 * tap) * Ho + ho) * Wo + wo];
        float dx = off[((size_t)(b * 18 + 2 * tap + 1) * Ho + ho) * Wo + wo];
        float ys = (float)(ho * 4 - 1 + tap / 3) + dy;
        float xs = (float)(wo * 4 - 1 + tap % 3) + dx;
        float y0f = floorf(ys), x0f = floorf(xs);
        float fy = ys - y0f, fx = xs - x0f;
        int y0 = (int)y0f, x0 = (int)x0f;
        float wts[4] = {(1.f - fy) * (1.f - fx), (1.f - fy) * fx,
                        fy * (1.f - fx),          fy * fx};
#pragma unroll
        for (int j = 0; j < 4; ++j) {
            int iy = y0 + (j >> 1), ix = x0 + (j & 1);
            bool v = (iy >= 0) && (iy < H) && (ix >= 0) && (ix < W);
            sidx[item][j] = v ? (iy * W + ix) : 0;
            swt[item][j]  = v ? wts[j] : 0.f;
        }
    }
    __syncthreads();

    const float* xb = x4 + (size_t)b * H * W * 4;
    for (int item = tid; item < P * 9; item += TPB) {
        int p = item / 9, tap = item % 9;
        i32x4_t id4 = *(const i32x4_t*)sidx[item];
        f32x4_t w4  = *(const f32x4_t*)swt[item];
        f32x4_t a0 = *(const f32x4_t*)&xb[(size_t)(unsigned)id4[0] * 4];
        f32x4_t a1 = *(const f32x4_t*)&xb[(size_t)(unsigned)id4[1] * 4];
        f32x4_t a2 = *(const f32x4_t*)&xb[(size_t)(unsigned)id4[2] * 4];
        f32x4_t a3 = *(const f32x4_t*)&xb[(size_t)(unsigned)id4[3] * 4];
        samp[p][0 * 9 + tap] = w4[0]*a0[0] + w4[1]*a1[0] + w4[2]*a2[0] + w4[3]*a3[0];
        samp[p][1 * 9 + tap] = w4[0]*a0[1] + w4[1]*a1[1] + w4[2]*a2[1] + w4[3]*a3[1];
        samp[p][2 * 9 + tap] = w4[0]*a0[2] + w4[1]*a1[2] + w4[2]*a2[2] + w4[3]*a3[2];
    }
    __syncthreads();

    int g = tid >> 6;
    int o = tid & 63;
    float acc[8];
#pragma unroll
    for (int pi = 0; pi < 8; ++pi) acc[pi] = bias[o] + bsk[o];
#pragma unroll
    for (int c = 0; c < 3; ++c)
#pragma unroll
        for (int k = 0; k < 9; ++k) {
            float wv = w[((size_t)(o * 3 + c)) * 9 + k];
#pragma unroll
            for (int pi = 0; pi < 8; ++pi)
                acc[pi] += wv * samp[g * 8 + pi][c * 9 + k];
        }
#pragma unroll
    for (int pi = 0; pi < 8; ++pi) {
        int r = r0 + g * 8 + pi;
        float sv = wsk[o * 3 + 0] * pool[(size_t)(b * 3 + 0) * HW + r]
                 + wsk[o * 3 + 1] * pool[(size_t)(b * 3 + 1) * HW + r]
                 + wsk[o * 3 + 2] * pool[(size_t)(b * 3 + 2) * HW + r];
        outh[((size_t)(b * HW + r)) * 64 + o] = f_to_bf16(acc[pi] + sv);
    }
}

// ------------------------------------------------- deform MFMA: C=64 -> O
template <int O>
__global__ __launch_bounds__(256, 1) void deform_mfma_kernel(
    const short* __restrict__ xh,
    const float* __restrict__ off,  // [B][18][Ho][Wo]
    const short* __restrict__ wt,   // [18][O/16][64][8] frag order
    const float* __restrict__ bias,
    float* __restrict__ out,        // [B][O][Ho][Wo]
    int H, int W, int Ho, int Wo, int stride)
{
    constexpr int NF = O / 64;
    constexpr int NFRAG = O / 16;
    constexpr int P  = 32;
    __shared__ alignas(16) short samp[P * 576];
    __shared__ int   sidx[P * 9][4];
    __shared__ float swt[P * 9][4];

    const int tid = threadIdx.x;
    const int HW = Ho * Wo;
    const int pix0 = blockIdx.x * P;
    const int b = pix0 / HW;
    const int r0 = pix0 - b * HW;

    for (int item = tid; item < P * 9; item += TPB) {
        int p = item / 9, tap = item % 9;
        int r = r0 + p, ho = r / Wo, wo = r % Wo;
        float dy = off[((size_t)(b * 18 + 2 * tap) * Ho + ho) * Wo + wo];
        float dx = off[((size_t)(b * 18 + 2 * tap + 1) * Ho + ho) * Wo + wo];
        float ys = (float)(ho * stride - 1 + tap / 3) + dy;
        float xs = (float)(wo * stride - 1 + tap % 3) + dx;
        float y0f = floorf(ys), x0f = floorf(xs);
        float fy = ys - y0f, fx = xs - x0f;
        int y0 = (int)y0f, x0 = (int)x0f;
        float wts[4] = {(1.f - fy) * (1.f - fx), (1.f - fy) * fx,
                        fy * (1.f - fx),          fy * fx};
#pragma unroll
        for (int j = 0; j < 4; ++j) {
            int iy = y0 + (j >> 1), ix = x0 + (j & 1);
            bool v = (iy >= 0) && (iy < H) && (ix >= 0) && (ix < W);
            sidx[item][j] = v ? (iy * W + ix) : 0;
            swt[item][j]  = v ? wts[j] : 0.f;
        }
    }
    __syncthreads();

    {
        const int grp = tid >> 4;
        const int ic  = (tid & 15) * 4;
        const short* xb = xh + (size_t)b * H * W * 64;
#pragma unroll 3
        for (int i = 0; i < 18; ++i) {
            int e = grp * 18 + i;
            int p = e / 9, tap = e % 9;
            i32x4_t id4 = *(const i32x4_t*)sidx[e];
            f32x4_t w4  = *(const f32x4_t*)swt[e];
            u16x4_t u0 = *(const u16x4_t*)&xb[(size_t)(unsigned)id4[0] * 64 + ic];
            u16x4_t u1 = *(const u16x4_t*)&xb[(size_t)(unsigned)id4[1] * 64 + ic];
            u16x4_t u2 = *(const u16x4_t*)&xb[(size_t)(unsigned)id4[2] * 64 + ic];
            u16x4_t u3 = *(const u16x4_t*)&xb[(size_t)(unsigned)id4[3] * 64 + ic];
            float v0 = w4[0]*bf16_to_f(u0[0]) + w4[1]*bf16_to_f(u1[0])
                     + w4[2]*bf16_to_f(u2[0]) + w4[3]*bf16_to_f(u3[0]);
            float v1 = w4[0]*bf16_to_f(u0[1]) + w4[1]*bf16_to_f(u1[1])
                     + w4[2]*bf16_to_f(u2[1]) + w4[3]*bf16_to_f(u3[1]);
            float v2 = w4[0]*bf16_to_f(u0[2]) + w4[1]*bf16_to_f(u1[2])
                     + w4[2]*bf16_to_f(u2[2]) + w4[3]*bf16_to_f(u3[2]);
            float v3 = w4[0]*bf16_to_f(u0[3]) + w4[1]*bf16_to_f(u1[3])
                     + w4[2]*bf16_to_f(u2[3]) + w4[3]*bf16_to_f(u3[3]);
            int sw = (tap * 8 + ((ic >> 3) ^ (p & 7))) * 8 + (ic & 7);
            short* dst = &samp[p * 576 + sw];
            dst[0] = f_to_bf16(v0);
            dst[1] = f_to_bf16(v1);
            dst[2] = f_to_bf16(v2);
            dst[3] = f_to_bf16(v3);
        }
    }
    __syncthreads();

    const int wv = tid >> 6;
    const int l  = tid & 63;
    const int l15 = l & 15, lg = l >> 4;
    f32x4_t acc[2][NF];
#pragma unroll
    for (int mf = 0; mf < 2; ++mf)
#pragma unroll
        for (int nf = 0; nf < NF; ++nf)
            acc[mf][nf] = (f32x4_t){0.f, 0.f, 0.f, 0.f};

#pragma unroll 2
    for (int kc = 0; kc < 18; ++kc) {
        int tap = kc >> 1;
        int low = (((kc & 1) << 2) | lg) ^ (l15 & 7);
        bf16x8_t af0 = *(const bf16x8_t*)&samp[l15 * 576 + (tap * 8 + low) * 8];
        bf16x8_t af1 = *(const bf16x8_t*)&samp[(l15 + 16) * 576 + (tap * 8 + low) * 8];
#pragma unroll
        for (int nf = 0; nf < NF; ++nf) {
            int ocf = wv * NF + nf;
            bf16x8_t bf = *(const bf16x8_t*)(wt + (((size_t)(kc * NFRAG + ocf)) * 64 + l) * 8);
            acc[0][nf] = __builtin_amdgcn_mfma_f32_16x16x32_bf16(af0, bf, acc[0][nf], 0, 0, 0);
            acc[1][nf] = __builtin_amdgcn_mfma_f32_16x16x32_bf16(af1, bf, acc[1][nf], 0, 0, 0);
        }
    }

#pragma unroll
    for (int mf = 0; mf < 2; ++mf)
#pragma unroll
        for (int nf = 0; nf < NF; ++nf) {
            int oc = (wv * NF + nf) * 16 + l15;
            float bv = bias[oc];
            f32x4_t v = acc[mf][nf];
            v[0] += bv; v[1] += bv; v[2] += bv; v[3] += bv;
            *(f32x4_t*)&out[((size_t)(b * O + oc)) * HW + r0 + mf * 16 + lg * 4] = v;
        }
}

// ---------------------------------------------------------------- avgpool 4x4
__global__ void avgpool4_kernel(const float* __restrict__ in,
                                float* __restrict__ out,
                                int BC, int Ho, int Wo, int H, int W)
{
    int idx = blockIdx.x * TPB + threadIdx.x;
    int total = BC * Ho * Wo;
    if (idx >= total) return;
    int wo = idx % Wo;
    int t = idx / Wo;
    int ho = t % Ho;
    int bc = t / Ho;
    const float* xp = in + (size_t)bc * H * W + (ho * 4) * W + wo * 4;
    float s = 0.f;
#pragma unroll
    for (int i = 0; i < 4; ++i)
#pragma unroll
        for (int j = 0; j < 4; ++j)
            s += xp[i * W + j];
    out[idx] = s * (1.0f / 16.0f);
}

__global__ void zero_stats_kernel(float* __restrict__ stats)
{
    if (threadIdx.x < 256) stats[threadIdx.x] = 0.f;
}

// ---------------------------------------------------------------- launch
extern "C" void kernel_launch(void* const* d_in, const int* in_sizes, int n_in,
                              void* d_out, int out_size, void* d_ws, size_t ws_size,
                              hipStream_t stream)
{
    const float* x      = (const float*)d_in[0];
    const float* w_off1 = (const float*)d_in[1];
    const float* b_off1 = (const float*)d_in[2];
    const float* w_d1   = (const float*)d_in[3];
    const float* b_d1   = (const float*)d_in[4];
    const float* w_skip = (const float*)d_in[5];
    const float* b_skip = (const float*)d_in[6];
    const float* w_bl1  = (const float*)d_in[7];
    const float* w_bl2  = (const float*)d_in[8];
    const float* w_off2 = (const float*)d_in[9];
    const float* b_off2 = (const float*)d_in[10];
    const float* w_d2   = (const float*)d_in[11];
    const float* b_d2   = (const float*)d_in[12];
    const float* w_off3 = (const float*)d_in[13];
    const float* b_off3 = (const float*)d_in[14];
    const float* w_d3   = (const float*)d_in[15];
    const float* b_d3   = (const float*)d_in[16];

    const int B = 8;
    float* A     = (float*)d_ws;          // 3,686,400 floats
    float* bufB  = A + 3686400;           // 13,107,200 floats
    float* bufC  = bufB + 13107200;       // 13,107,200 floats
    float* stats = bufC + 13107200;       // 256 floats

    short* hB   = (short*)bufB;
    short* hC   = (short*)bufC;
    float* pool = bufB + 8000000;

    // frag-ordered weights inside A (above all later A writes < 1M floats)
    short* wt1    = (short*)(A + 1000000);      // 36,864 shorts
    short* wt2    = wt1 + 18 * 4 * 512;
    short* wtd2   = (short*)(A + 1500000);      // 36,864 shorts
    short* wtd3   = (short*)(A + 1550000);      // 147,456 shorts
    short* wtoff2 = (short*)(A + 1700000);      // 18,432 shorts
    short* wtoff3 = (short*)(A + 1712000);      // 18,432 shorts

    float* out0 = (float*)d_out;
    float* out1 = out0 + 13107200;
    float* out2 = out1 + 3276800;

    const float invN = 1.0f / (B * 25600);

    // 0) x -> NHWC4 fp32 into bufC
    x_to_nhwc4_kernel<<<(8 * 409600 + TPB - 1) / TPB, TPB, 0, stream>>>(x, bufC);

    // 1) offset1 (exact fp32) -> A
    offset1_kernel<<<(8 * 25600 + TPB - 1) / TPB, TPB, 0, stream>>>(
        bufC, w_off1, b_off1, A);

    // 2) pool = avgpool4(x) -> bufB+8M
    avgpool4_kernel<<<(B * 3 * 25600 + TPB - 1) / TPB, TPB, 0, stream>>>(
        x, pool, B * 3, 160, 160, 640, 640);

    // 3) d1+skip = deform1 -> hB (bf16 NHWC). offset1 dead after this.
    deform1_kernel<<<8 * 25600 / 32, TPB, 0, stream>>>(
        bufC, A, w_d1, b_d1, pool, w_skip, b_skip, hB);

    // 3.5) repack weights (fragment order)
    repack_frag_kernel<<<(18 * 4 * 512 + TPB - 1) / TPB, TPB, 0, stream>>>(w_bl1, wt1, 64, 4);
    repack_frag_kernel<<<(18 * 4 * 512 + TPB - 1) / TPB, TPB, 0, stream>>>(w_bl2, wt2, 64, 4);
    repack_frag_kernel<<<(18 * 4 * 512 + TPB - 1) / TPB, TPB, 0, stream>>>(w_d2, wtd2, 64, 4);
    repack_frag_kernel<<<(18 * 16 * 512 + TPB - 1) / TPB, TPB, 0, stream>>>(w_d3, wtd3, 256, 16);
    repack_frag_kernel<<<(18 * 2 * 512 + TPB - 1) / TPB, TPB, 0, stream>>>(w_off2, wtoff2, 18, 2);
    repack_frag_kernel<<<(18 * 2 * 512 + TPB - 1) / TPB, TPB, 0, stream>>>(w_off3, wtoff3, 18, 2);
    zero_stats_kernel<<<1, 256, 0, stream>>>(stats);

    // 4) conv1: hB -> bufC fp32 NCHW (+stats1)
    conv3x3_mfma_kernel<<<800, TPB, 0, stream>>>(hB, wt1, bufC, stats);

    // 5) apply1: bufC -> hB bf16 NHWC
    bn_apply_nhwc_kernel<<<8 * 400, TPB, 0, stream>>>(bufC, stats, hB, 25600, invN);

    // 6) conv2: hB -> bufC fp32 NCHW (+stats2)
    conv3x3_mfma_kernel<<<800, TPB, 0, stream>>>(hB, wt2, bufC, stats + 128);

    // 7) apply2: bufC -> out0 fp32 NCHW + hB bf16 NHWC (feat4)
    bn_apply_dual_kernel<<<8 * 400, TPB, 0, stream>>>(
        bufC, stats + 128, out0, hB, 25600, invN);

    // 8) offset2 = offconv(feat4 hB) -> A
    offconv_mfma_kernel<<<8 * 6400 / 64, TPB, 0, stream>>>(
        hB, wtoff2, b_off2, A, 160, 160, 80, 80);

    // 9) feat_1_8 = deform2(feat4 hB, offset2) -> out1
    deform_mfma_kernel<64><<<8 * 6400 / 32, TPB, 0, stream>>>(
        hB, A, wtd2, b_d2, out1, 160, 160, 80, 80, 2);

    // 10) feat_1_8 -> NHWC bf16 into hC
    nchw_to_nhwc_bf16_kernel<<<8 * (6400 / 64), TPB, 0, stream>>>(out1, hC, 6400);

    // 11) offset3 = offconv(feat8 hC) -> A
    offconv_mfma_kernel<<<8 * 1600 / 64, TPB, 0, stream>>>(
        hC, wtoff3, b_off3, A, 80, 80, 40, 40);

    // 12) feat_1_16 = deform3(feat8 hC, offset3) -> out2
    deform_mfma_kernel<256><<<8 * 1600 / 32, TPB, 0, stream>>>(
        hC, A, wtd3, b_d3, out2, 80, 80, 40, 40, 2);
}

// Round 12
// 252.961 us; speedup vs baseline: 28.3632x; 1.3109x over previous
//
#include <hip/hip_runtime.h>
#include <hip/hip_bf16.h>
#include <math.h>

#define TPB 256

typedef __attribute__((ext_vector_type(8))) short bf16x8_t;
typedef __attribute__((ext_vector_type(4))) float f32x4_t;
typedef __attribute__((ext_vector_type(4))) int i32x4_t;
typedef __attribute__((ext_vector_type(4))) unsigned short u16x4_t;

static __device__ __forceinline__ float bf16_to_f(unsigned short s) {
    union { unsigned u; float f; } cv;
    cv.u = ((unsigned)s) << 16;
    return cv.f;
}
static __device__ __forceinline__ short f_to_bf16(float v) {
    __hip_bfloat16 h = __float2bfloat16(v);
    return *(short*)&h;
}

// ------------------------------------------------- weight repack, FRAGMENT order
__global__ void repack_frag_kernel(const float* __restrict__ w,
                                   short* __restrict__ wtf,
                                   int Oreal, int NFRAG)
{
    int idx = blockIdx.x * TPB + threadIdx.x;
    int total = 18 * NFRAG * 64 * 8;
    if (idx >= total) return;
    int j    = idx & 7;
    int lane = (idx >> 3) & 63;
    int t    = idx >> 9;
    int ocf  = t % NFRAG;
    int kc   = t / NFRAG;
    int oc   = ocf * 16 + (lane & 15);
    int tap  = kc >> 1;
    int ic   = (kc & 1) * 32 + (lane >> 4) * 8 + j;
    float v = 0.f;
    if (oc < Oreal)
        v = w[((size_t)(oc * 64 + ic)) * 9 + tap];
    wtf[idx] = f_to_bf16(v);
}

// ------------------------------------------------- MFMA conv 3x3 (64->64, s1)
// in: bf16 NHWC; out: bf16 NHWC (un-normalized); fused BN partial stats.
// Software-pipelined k-loop; stats spread over 8 slots.
__global__ __launch_bounds__(256, 1) void conv3x3_mfma_kernel(
    const short* __restrict__ xh,
    const short* __restrict__ wt,   // [18][4][64][8] frag order
    short* __restrict__ outh,       // bf16 NHWC
    float* __restrict__ stats)      // [8][128]
{
    __shared__ short tile[18 * 18 * 64];
    __shared__ float sstat[128];
    const int H = 160, W = 160, HW = 25600;
    int blk = blockIdx.x;
    int b  = blk / 100;
    int r  = blk % 100;
    int y0 = (r / 10) * 16;
    int x0 = (r % 10) * 16;
    const int tid = threadIdx.x;

    const short* inb = xh + (size_t)b * HW * 64;
    for (int item = tid; item < 18 * 18 * 8; item += TPB) {
        int c8  = item & 7;
        int pix = item >> 3;
        int col = pix % 18, row = pix / 18;
        int y = y0 + row - 1;
        int x = x0 + col - 1;
        bf16x8_t v = {};
        if (y >= 0 && y < H && x >= 0 && x < W)
            v = *(const bf16x8_t*)&inb[((size_t)y * W + x) * 64 + c8 * 8];
        int ch = c8 ^ (col & 7);
        *(bf16x8_t*)&tile[(row * 18 + col) * 64 + ch * 8] = v;
    }
    if (tid < 128) sstat[tid] = 0.f;
    __syncthreads();

    const int wv  = tid >> 6;
    const int l   = tid & 63;
    const int l15 = l & 15;
    const int lg  = l >> 4;

    f32x4_t acc[4][4];
#pragma unroll
    for (int i = 0; i < 4; ++i)
#pragma unroll
        for (int j = 0; j < 4; ++j)
            acc[i][j] = (f32x4_t){0.f, 0.f, 0.f, 0.f};

    // software-pipelined k-loop (full unroll -> static ping-pong indices)
    bf16x8_t bfp[2][4], afp[2][4];
#pragma unroll
    for (int nf = 0; nf < 4; ++nf)
        bfp[0][nf] = *(const bf16x8_t*)(wt + (((size_t)(0 * 4 + nf)) * 64 + l) * 8);
    {
        int colr = l15;                 // kc=0: dy=0, dx=0
        int chunk = lg ^ (colr & 7);
#pragma unroll
        for (int mf = 0; mf < 4; ++mf)
            afp[0][mf] = *(const bf16x8_t*)&tile[((wv * 4 + mf) * 18 + colr) * 64 + chunk * 8];
    }
#pragma unroll
    for (int kc = 0; kc < 18; ++kc) {
        const int cur = kc & 1, nxt = cur ^ 1;
        if (kc + 1 < 18) {
            int kn = kc + 1;
#pragma unroll
            for (int nf = 0; nf < 4; ++nf)
                bfp[nxt][nf] = *(const bf16x8_t*)(wt + (((size_t)(kn * 4 + nf)) * 64 + l) * 8);
            int tap = kn >> 1;
            int dy = tap / 3, dx = tap % 3;
            int colr = l15 + dx;
            int chunk = (((kn & 1) << 2) + lg) ^ (colr & 7);
#pragma unroll
            for (int mf = 0; mf < 4; ++mf)
                afp[nxt][mf] = *(const bf16x8_t*)&tile[((wv * 4 + mf + dy) * 18 + colr) * 64 + chunk * 8];
        }
#pragma unroll
        for (int mf = 0; mf < 4; ++mf)
#pragma unroll
            for (int nf = 0; nf < 4; ++nf)
                acc[mf][nf] = __builtin_amdgcn_mfma_f32_16x16x32_bf16(
                    afp[cur][mf], bfp[cur][nf], acc[mf][nf], 0, 0, 0);
    }

    // store bf16 NHWC (un-normalized conv output)
    short* outb = outh + (size_t)b * HW * 64;
#pragma unroll
    for (int mf = 0; mf < 4; ++mf) {
        int y = y0 + wv * 4 + mf;
#pragma unroll
        for (int nf = 0; nf < 4; ++nf) {
            int oc = nf * 16 + l15;
#pragma unroll
            for (int k = 0; k < 4; ++k)
                outb[((size_t)y * W + x0 + lg * 4 + k) * 64 + oc] = f_to_bf16(acc[mf][nf][k]);
        }
    }

    // fused BN partial stats (fp32 accumulators)
#pragma unroll
    for (int nf = 0; nf < 4; ++nf) {
        float s = 0.f, s2 = 0.f;
#pragma unroll
        for (int mf = 0; mf < 4; ++mf)
#pragma unroll
            for (int k = 0; k < 4; ++k) {
                float v = acc[mf][nf][k];
                s += v; s2 += v * v;
            }
        s  += __shfl_xor(s, 16, 64);  s  += __shfl_xor(s, 32, 64);
        s2 += __shfl_xor(s2, 16, 64); s2 += __shfl_xor(s2, 32, 64);
        if (lg == 0) {
            int oc = nf * 16 + l15;
            atomicAdd(&sstat[oc], s);
            atomicAdd(&sstat[64 + oc], s2);
        }
    }
    __syncthreads();
    float* st = stats + (size_t)(blockIdx.x & 7) * 128;
    if (tid < 128) atomicAdd(&st[tid], sstat[tid]);
}

// ------------------------------------------------- NCHW fp32 -> NHWC bf16 (C=64)
__global__ void nchw_to_nhwc_bf16_kernel(const float* __restrict__ in,
                                         short* __restrict__ out, int HW)
{
    __shared__ short tile[64][66];
    int nchunks = HW >> 6;
    int b  = blockIdx.x / nchunks;
    int p0 = (blockIdx.x % nchunks) << 6;
    int tid = threadIdx.x;
#pragma unroll
    for (int rep = 0; rep < 16; ++rep) {
        int item = rep * 256 + tid;
        int c = item >> 6, p = item & 63;
        tile[p][c] = f_to_bf16(in[((size_t)b * 64 + c) * HW + p0 + p]);
    }
    __syncthreads();
#pragma unroll
    for (int rep = 0; rep < 16; ++rep) {
        int item = rep * 256 + tid;
        int p = item >> 6, c = item & 63;
        out[((size_t)b * HW + p0 + p) * 64 + c] = tile[p][c];
    }
}

// ------------------------------------------------- BN apply, NHWC->NHWC elementwise
__global__ void bn_apply_elem_kernel(const short* __restrict__ in,
                                     const float* __restrict__ stats, // [8][128]
                                     short* __restrict__ outh,
                                     float invN)
{
    __shared__ float sm[64], sr[64];
    int tid = threadIdx.x;
    if (tid < 64) {
        float s = 0.f, s2 = 0.f;
#pragma unroll
        for (int k = 0; k < 8; ++k) {
            s  += stats[k * 128 + tid];
            s2 += stats[k * 128 + 64 + tid];
        }
        float mean = s * invN;
        float var  = s2 * invN - mean * mean;
        sm[tid] = mean;
        sr[tid] = rsqrtf(var + 1e-5f);
    }
    __syncthreads();
    int item = blockIdx.x * TPB + tid;       // one bf16x8 group
    int c0 = (item & 7) * 8;
    bf16x8_t v = *(const bf16x8_t*)&in[(size_t)item * 8];
    bf16x8_t o;
#pragma unroll
    for (int j = 0; j < 8; ++j) {
        float f = (bf16_to_f((unsigned short)v[j]) - sm[c0 + j]) * sr[c0 + j];
        o[j] = f_to_bf16(f > 0.f ? f : 0.f);
    }
    *(bf16x8_t*)&outh[(size_t)item * 8] = o;
}

// ------------------------------------------------- BN apply dual: NHWC bf16 in ->
// out0 NCHW fp32 + NHWC bf16
__global__ void bn_apply_dual_kernel(const short* __restrict__ in,
                                     const float* __restrict__ stats, // [8][128]
                                     float* __restrict__ out,         // NCHW fp32
                                     short* __restrict__ outh,        // NHWC bf16
                                     int HW, float invN)
{
    __shared__ float ftile[64][65];
    __shared__ float sm[64], sr[64];
    int nchunks = HW >> 6;
    int b  = blockIdx.x / nchunks;
    int p0 = (blockIdx.x % nchunks) << 6;
    int tid = threadIdx.x;
    if (tid < 64) {
        float s = 0.f, s2 = 0.f;
#pragma unroll
        for (int k = 0; k < 8; ++k) {
            s  += stats[k * 128 + tid];
            s2 += stats[k * 128 + 64 + tid];
        }
        float mean = s * invN;
        float var  = s2 * invN - mean * mean;
        sm[tid] = mean;
        sr[tid] = rsqrtf(var + 1e-5f);
    }
    __syncthreads();
#pragma unroll
    for (int it = 0; it < 2; ++it) {
        int item = it * 256 + tid;            // 512 groups = 64 px * 8
        int p = item >> 3, c0 = (item & 7) * 8;
        size_t gi = ((size_t)(b * HW + p0 + p)) * 64 + c0;
        bf16x8_t v = *(const bf16x8_t*)&in[gi];
        bf16x8_t o;
#pragma unroll
        for (int j = 0; j < 8; ++j) {
            float f = (bf16_to_f((unsigned short)v[j]) - sm[c0 + j]) * sr[c0 + j];
            f = f > 0.f ? f : 0.f;
            ftile[p][c0 + j] = f;
            o[j] = f_to_bf16(f);
        }
        *(bf16x8_t*)&outh[gi] = o;
    }
    __syncthreads();
#pragma unroll
    for (int rep = 0; rep < 16; ++rep) {
        int item = rep * 256 + tid;
        int c = item >> 6, p = item & 63;
        out[((size_t)b * 64 + c) * HW + p0 + p] = ftile[p][c];
    }
}

// ------------------------------------------------- x NCHW (C=3) -> NHWC4 fp32
__global__ void x_to_nhwc4_kernel(const float* __restrict__ in,
                                  float* __restrict__ out)
{
    int idx = blockIdx.x * TPB + threadIdx.x;
    const int HW = 640 * 640;
    if (idx >= 8 * HW) return;
    int b = idx / HW, p = idx % HW;
    f32x4_t v;
    v[0] = in[((size_t)b * 3 + 0) * HW + p];
    v[1] = in[((size_t)b * 3 + 1) * HW + p];
    v[2] = in[((size_t)b * 3 + 2) * HW + p];
    v[3] = 0.f;
    *(f32x4_t*)&out[(size_t)idx * 4] = v;
}

// ------------------------------------------------- offset1: exact fp32, NHWC4
__global__ void offset1_kernel(const float* __restrict__ x4,
                               const float* __restrict__ w,   // (18,3,3,3)
                               const float* __restrict__ bias,
                               float* __restrict__ out)
{
    const int H = 640, W = 640, HW = 25600;
    int idx = blockIdx.x * TPB + threadIdx.x;
    if (idx >= 8 * HW) return;
    int b = idx / HW, r = idx % HW;
    int ho = r / 160, wo = r % 160;

    float acc[18];
#pragma unroll
    for (int o = 0; o < 18; ++o) acc[o] = bias[o];

    const float* xb = x4 + (size_t)b * H * W * 4;
#pragma unroll
    for (int tap = 0; tap < 9; ++tap) {
        int iy = ho * 4 - 1 + tap / 3;
        int ix = wo * 4 - 1 + tap % 3;
        if (iy < 0 || iy >= H || ix < 0 || ix >= W) continue;
        f32x4_t s = *(const f32x4_t*)&xb[((size_t)iy * W + ix) * 4];
#pragma unroll
        for (int c = 0; c < 3; ++c)
#pragma unroll
            for (int o = 0; o < 18; ++o)
                acc[o] += s[c] * w[(o * 3 + c) * 9 + tap];
    }
#pragma unroll
    for (int o = 0; o < 18; ++o)
        out[((size_t)(b * 18 + o)) * HW + r] = acc[o];
}

// ------------------------------------------------- offset2/3: MFMA conv, N=18
__global__ __launch_bounds__(256, 1) void offconv_mfma_kernel(
    const short* __restrict__ xh,
    const short* __restrict__ wt,    // [18][2][64][8] frag order, zero-padded
    const float* __restrict__ bias,
    float* __restrict__ out,
    int H, int W, int Ho, int Wo)
{
    const int HW = Ho * Wo;
    const int tid = threadIdx.x;
    const int wv = tid >> 6, l = tid & 63;
    const int l15 = l & 15, lg = l >> 4;
    const int pix0 = blockIdx.x * 64 + wv * 16;
    const int b = pix0 / HW;
    const int r0 = pix0 - b * HW;

    int rp = r0 + l15;
    int ho = rp / Wo, wo = rp % Wo;
    const short* xb = xh + (size_t)b * H * W * 64;

    f32x4_t acc[2];
    acc[0] = (f32x4_t){0.f, 0.f, 0.f, 0.f};
    acc[1] = (f32x4_t){0.f, 0.f, 0.f, 0.f};

#pragma unroll 2
    for (int kc = 0; kc < 18; ++kc) {
        int tap = kc >> 1;
        int iy = ho * 2 - 1 + tap / 3;
        int ix = wo * 2 - 1 + tap % 3;
        bf16x8_t af = {};
        if (iy >= 0 && iy < H && ix >= 0 && ix < W)
            af = *(const bf16x8_t*)&xb[((size_t)iy * W + ix) * 64
                                       + (kc & 1) * 32 + lg * 8];
#pragma unroll
        for (int nf = 0; nf < 2; ++nf) {
            bf16x8_t bf = *(const bf16x8_t*)(wt + (((size_t)(kc * 2 + nf)) * 64 + l) * 8);
            acc[nf] = __builtin_amdgcn_mfma_f32_16x16x32_bf16(af, bf, acc[nf], 0, 0, 0);
        }
    }

#pragma unroll
    for (int nf = 0; nf < 2; ++nf) {
        int oc = nf * 16 + l15;
        if (oc < 18) {
            float bv = bias[oc];
            f32x4_t v = acc[nf];
            v[0] += bv; v[1] += bv; v[2] += bv; v[3] += bv;
            *(f32x4_t*)&out[((size_t)(b * 18 + oc)) * HW + r0 + lg * 4] = v;
        }
    }
}

// ------------------------------------------------- deform1: C=3, fused skip
__global__ __launch_bounds__(256, 1) void deform1_kernel(
    const float* __restrict__ x4,
    const float* __restrict__ off,
    const float* __restrict__ w,
    const float* __restrict__ bias,
    const float* __restrict__ pool,
    const float* __restrict__ wsk,
    const float* __restrict__ bsk,
    short* __restrict__ outh)
{
    const int H = 640, W = 640, Ho = 160, Wo = 160, HW = 25600;
    constexpr int P = 32;
    __shared__ float samp[P][28];
    __shared__ int   sidx[P * 9][4];
    __shared__ float swt[P * 9][4];
    const int tid = threadIdx.x;
    const int pix0 = blockIdx.x * P;
    const int b = pix0 / HW;
    const int r0 = pix0 - b * HW;

    for (int item = tid; item < P * 9; item += TPB) {
        int p = item / 9, tap = item % 9;
        int r = r0 + p, ho = r / Wo, wo = r % Wo;
        float dy = off[((size_t)(b * 18 + 2 * tap) * Ho + ho) * Wo + wo];
        float dx = off[((size_t)(b * 18 + 2 * tap + 1) * Ho + ho) * Wo + wo];
        float ys = (float)(ho * 4 - 1 + tap / 3) + dy;
        float xs = (float)(wo * 4 - 1 + tap % 3) + dx;
        float y0f = floorf(ys), x0f = floorf(xs);
        float fy = ys - y0f, fx = xs - x0f;
        int y0 = (int)y0f, x0 = (int)x0f;
        float wts[4] = {(1.f - fy) * (1.f - fx), (1.f - fy) * fx,
                        fy * (1.f - fx),          fy * fx};
#pragma unroll
        for (int j = 0; j < 4; ++j) {
            int iy = y0 + (j >> 1), ix = x0 + (j & 1);
            bool v = (iy >= 0) && (iy < H) && (ix >= 0) && (ix < W);
            sidx[item][j] = v ? (iy * W + ix) : 0;
            swt[item][j]  = v ? wts[j] : 0.f;
        }
    }
    __syncthreads();

    const float* xb = x4 + (size_t)b * H * W * 4;
    for (int item = tid; item < P * 9; item += TPB) {
        int p = item / 9, tap = item % 9;
        i32x4_t id4 = *(const i32x4_t*)sidx[item];
        f32x4_t w4  = *(const f32x4_t*)swt[item];
        f32x4_t a0 = *(const f32x4_t*)&xb[(size_t)(unsigned)id4[0] * 4];
        f32x4_t a1 = *(const f32x4_t*)&xb[(size_t)(unsigned)id4[1] * 4];
        f32x4_t a2 = *(const f32x4_t*)&xb[(size_t)(unsigned)id4[2] * 4];
        f32x4_t a3 = *(const f32x4_t*)&xb[(size_t)(unsigned)id4[3] * 4];
        samp[p][0 * 9 + tap] = w4[0]*a0[0] + w4[1]*a1[0] + w4[2]*a2[0] + w4[3]*a3[0];
        samp[p][1 * 9 + tap] = w4[0]*a0[1] + w4[1]*a1[1] + w4[2]*a2[1] + w4[3]*a3[1];
        samp[p][2 * 9 + tap] = w4[0]*a0[2] + w4[1]*a1[2] + w4[2]*a2[2] + w4[3]*a3[2];
    }
    __syncthreads();

    int g = tid >> 6;
    int o = tid & 63;
    float acc[8];
#pragma unroll
    for (int pi = 0; pi < 8; ++pi) acc[pi] = bias[o] + bsk[o];
#pragma unroll
    for (int c = 0; c < 3; ++c)
#pragma unroll
        for (int k = 0; k < 9; ++k) {
            float wv = w[((size_t)(o * 3 + c)) * 9 + k];
#pragma unroll
            for (int pi = 0; pi < 8; ++pi)
                acc[pi] += wv * samp[g * 8 + pi][c * 9 + k];
        }
#pragma unroll
    for (int pi = 0; pi < 8; ++pi) {
        int r = r0 + g * 8 + pi;
        float sv = wsk[o * 3 + 0] * pool[(size_t)(b * 3 + 0) * HW + r]
                 + wsk[o * 3 + 1] * pool[(size_t)(b * 3 + 1) * HW + r]
                 + wsk[o * 3 + 2] * pool[(size_t)(b * 3 + 2) * HW + r];
        outh[((size_t)(b * HW + r)) * 64 + o] = f_to_bf16(acc[pi] + sv);
    }
}

// ------------------------------------------------- deform MFMA: C=64 -> O
template <int O>
__global__ __launch_bounds__(256, 1) void deform_mfma_kernel(
    const short* __restrict__ xh,
    const float* __restrict__ off,
    const short* __restrict__ wt,   // [18][O/16][64][8] frag order
    const float* __restrict__ bias,
    float* __restrict__ out,
    int H, int W, int Ho, int Wo, int stride)
{
    constexpr int NF = O / 64;
    constexpr int NFRAG = O / 16;
    constexpr int P  = 32;
    __shared__ alignas(16) short samp[P * 576];
    __shared__ int   sidx[P * 9][4];
    __shared__ float swt[P * 9][4];

    const int tid = threadIdx.x;
    const int HW = Ho * Wo;
    const int pix0 = blockIdx.x * P;
    const int b = pix0 / HW;
    const int r0 = pix0 - b * HW;

    for (int item = tid; item < P * 9; item += TPB) {
        int p = item / 9, tap = item % 9;
        int r = r0 + p, ho = r / Wo, wo = r % Wo;
        float dy = off[((size_t)(b * 18 + 2 * tap) * Ho + ho) * Wo + wo];
        float dx = off[((size_t)(b * 18 + 2 * tap + 1) * Ho + ho) * Wo + wo];
        float ys = (float)(ho * stride - 1 + tap / 3) + dy;
        float xs = (float)(wo * stride - 1 + tap % 3) + dx;
        float y0f = floorf(ys), x0f = floorf(xs);
        float fy = ys - y0f, fx = xs - x0f;
        int y0 = (int)y0f, x0 = (int)x0f;
        float wts[4] = {(1.f - fy) * (1.f - fx), (1.f - fy) * fx,
                        fy * (1.f - fx),          fy * fx};
#pragma unroll
        for (int j = 0; j < 4; ++j) {
            int iy = y0 + (j >> 1), ix = x0 + (j & 1);
            bool v = (iy >= 0) && (iy < H) && (ix >= 0) && (ix < W);
            sidx[item][j] = v ? (iy * W + ix) : 0;
            swt[item][j]  = v ? wts[j] : 0.f;
        }
    }
    __syncthreads();

    {
        const int grp = tid >> 4;
        const int ic  = (tid & 15) * 4;
        const short* xb = xh + (size_t)b * H * W * 64;
#pragma unroll 3
        for (int i = 0; i < 18; ++i) {
            int e = grp * 18 + i;
            int p = e / 9, tap = e % 9;
            i32x4_t id4 = *(const i32x4_t*)sidx[e];
            f32x4_t w4  = *(const f32x4_t*)swt[e];
            u16x4_t u0 = *(const u16x4_t*)&xb[(size_t)(unsigned)id4[0] * 64 + ic];
            u16x4_t u1 = *(const u16x4_t*)&xb[(size_t)(unsigned)id4[1] * 64 + ic];
            u16x4_t u2 = *(const u16x4_t*)&xb[(size_t)(unsigned)id4[2] * 64 + ic];
            u16x4_t u3 = *(const u16x4_t*)&xb[(size_t)(unsigned)id4[3] * 64 + ic];
            float v0 = w4[0]*bf16_to_f(u0[0]) + w4[1]*bf16_to_f(u1[0])
                     + w4[2]*bf16_to_f(u2[0]) + w4[3]*bf16_to_f(u3[0]);
            float v1 = w4[0]*bf16_to_f(u0[1]) + w4[1]*bf16_to_f(u1[1])
                     + w4[2]*bf16_to_f(u2[1]) + w4[3]*bf16_to_f(u3[1]);
            float v2 = w4[0]*bf16_to_f(u0[2]) + w4[1]*bf16_to_f(u1[2])
                     + w4[2]*bf16_to_f(u2[2]) + w4[3]*bf16_to_f(u3[2]);
            float v3 = w4[0]*bf16_to_f(u0[3]) + w4[1]*bf16_to_f(u1[3])
                     + w4[2]*bf16_to_f(u2[3]) + w4[3]*bf16_to_f(u3[3]);
            int sw = (tap * 8 + ((ic >> 3) ^ (p & 7))) * 8 + (ic & 7);
            short* dst = &samp[p * 576 + sw];
            dst[0] = f_to_bf16(v0);
            dst[1] = f_to_bf16(v1);
            dst[2] = f_to_bf16(v2);
            dst[3] = f_to_bf16(v3);
        }
    }
    __syncthreads();

    const int wv = tid >> 6;
    const int l  = tid & 63;
    const int l15 = l & 15, lg = l >> 4;
    f32x4_t acc[2][NF];
#pragma unroll
    for (int mf = 0; mf < 2; ++mf)
#pragma unroll
        for (int nf = 0; nf < NF; ++nf)
            acc[mf][nf] = (f32x4_t){0.f, 0.f, 0.f, 0.f};

#pragma unroll 2
    for (int kc = 0; kc < 18; ++kc) {
        int tap = kc >> 1;
        int low = (((kc & 1) << 2) | lg) ^ (l15 & 7);
        bf16x8_t af0 = *(const bf16x8_t*)&samp[l15 * 576 + (tap * 8 + low) * 8];
        bf16x8_t af1 = *(const bf16x8_t*)&samp[(l15 + 16) * 576 + (tap * 8 + low) * 8];
#pragma unroll
        for (int nf = 0; nf < NF; ++nf) {
            int ocf = wv * NF + nf;
            bf16x8_t bf = *(const bf16x8_t*)(wt + (((size_t)(kc * NFRAG + ocf)) * 64 + l) * 8);
            acc[0][nf] = __builtin_amdgcn_mfma_f32_16x16x32_bf16(af0, bf, acc[0][nf], 0, 0, 0);
            acc[1][nf] = __builtin_amdgcn_mfma_f32_16x16x32_bf16(af1, bf, acc[1][nf], 0, 0, 0);
        }
    }

#pragma unroll
    for (int mf = 0; mf < 2; ++mf)
#pragma unroll
        for (int nf = 0; nf < NF; ++nf) {
            int oc = (wv * NF + nf) * 16 + l15;
            float bv = bias[oc];
            f32x4_t v = acc[mf][nf];
            v[0] += bv; v[1] += bv; v[2] += bv; v[3] += bv;
            *(f32x4_t*)&out[((size_t)(b * O + oc)) * HW + r0 + mf * 16 + lg * 4] = v;
        }
}

// ---------------------------------------------------------------- avgpool 4x4
__global__ void avgpool4_kernel(const float* __restrict__ in,
                                float* __restrict__ out,
                                int BC, int Ho, int Wo, int H, int W)
{
    int idx = blockIdx.x * TPB + threadIdx.x;
    int total = BC * Ho * Wo;
    if (idx >= total) return;
    int wo = idx % Wo;
    int t = idx / Wo;
    int ho = t % Ho;
    int bc = t / Ho;
    const float* xp = in + (size_t)bc * H * W + (ho * 4) * W + wo * 4;
    float s = 0.f;
#pragma unroll
    for (int i = 0; i < 4; ++i)
#pragma unroll
        for (int j = 0; j < 4; ++j)
            s += xp[i * W + j];
    out[idx] = s * (1.0f / 16.0f);
}

__global__ void zero_stats_kernel(float* __restrict__ stats)
{
    int i = threadIdx.x;
#pragma unroll
    for (int k = 0; k < 8; ++k) stats[k * 256 + i] = 0.f;
}

// ---------------------------------------------------------------- launch
extern "C" void kernel_launch(void* const* d_in, const int* in_sizes, int n_in,
                              void* d_out, int out_size, void* d_ws, size_t ws_size,
                              hipStream_t stream)
{
    const float* x      = (const float*)d_in[0];
    const float* w_off1 = (const float*)d_in[1];
    const float* b_off1 = (const float*)d_in[2];
    const float* w_d1   = (const float*)d_in[3];
    const float* b_d1   = (const float*)d_in[4];
    const float* w_skip = (const float*)d_in[5];
    const float* b_skip = (const float*)d_in[6];
    const float* w_bl1  = (const float*)d_in[7];
    const float* w_bl2  = (const float*)d_in[8];
    const float* w_off2 = (const float*)d_in[9];
    const float* b_off2 = (const float*)d_in[10];
    const float* w_d2   = (const float*)d_in[11];
    const float* b_d2   = (const float*)d_in[12];
    const float* w_off3 = (const float*)d_in[13];
    const float* b_off3 = (const float*)d_in[14];
    const float* w_d3   = (const float*)d_in[15];
    const float* b_d3   = (const float*)d_in[16];

    const int B = 8;
    float* A     = (float*)d_ws;          // 3,686,400 floats
    float* bufB  = A + 3686400;           // 13,107,200 floats
    float* bufC  = bufB + 13107200;       // 13,107,200 floats

    short* hB   = (short*)bufB;
    short* hC   = (short*)bufC;
    float* pool = bufB + 8000000;

    // frag-ordered weights + stats inside A (above all later A writes < 1M fl)
    short* wt1    = (short*)(A + 1000000);
    short* wt2    = wt1 + 18 * 4 * 512;
    short* wtd2   = (short*)(A + 1500000);
    short* wtd3   = (short*)(A + 1550000);
    short* wtoff2 = (short*)(A + 1700000);
    short* wtoff3 = (short*)(A + 1712000);
    float* stats1 = A + 1800000;          // [8][128]
    float* stats2 = stats1 + 1024;        // [8][128]

    float* out0 = (float*)d_out;
    float* out1 = out0 + 13107200;
    float* out2 = out1 + 3276800;

    const float invN = 1.0f / (B * 25600);

    // 0) x -> NHWC4 fp32 into bufC
    x_to_nhwc4_kernel<<<(8 * 409600 + TPB - 1) / TPB, TPB, 0, stream>>>(x, bufC);

    // 1) offset1 (exact fp32) -> A
    offset1_kernel<<<(8 * 25600 + TPB - 1) / TPB, TPB, 0, stream>>>(
        bufC, w_off1, b_off1, A);

    // 2) pool = avgpool4(x) -> bufB+8M
    avgpool4_kernel<<<(B * 3 * 25600 + TPB - 1) / TPB, TPB, 0, stream>>>(
        x, pool, B * 3, 160, 160, 640, 640);

    // 3) d1+skip = deform1 -> hB (bf16 NHWC). offset1 dead after this.
    deform1_kernel<<<8 * 25600 / 32, TPB, 0, stream>>>(
        bufC, A, w_d1, b_d1, pool, w_skip, b_skip, hB);

    // 3.5) repack weights + zero stats
    repack_frag_kernel<<<(18 * 4 * 512 + TPB - 1) / TPB, TPB, 0, stream>>>(w_bl1, wt1, 64, 4);
    repack_frag_kernel<<<(18 * 4 * 512 + TPB - 1) / TPB, TPB, 0, stream>>>(w_bl2, wt2, 64, 4);
    repack_frag_kernel<<<(18 * 4 * 512 + TPB - 1) / TPB, TPB, 0, stream>>>(w_d2, wtd2, 64, 4);
    repack_frag_kernel<<<(18 * 16 * 512 + TPB - 1) / TPB, TPB, 0, stream>>>(w_d3, wtd3, 256, 16);
    repack_frag_kernel<<<(18 * 2 * 512 + TPB - 1) / TPB, TPB, 0, stream>>>(w_off2, wtoff2, 18, 2);
    repack_frag_kernel<<<(18 * 2 * 512 + TPB - 1) / TPB, TPB, 0, stream>>>(w_off3, wtoff3, 18, 2);
    zero_stats_kernel<<<1, 256, 0, stream>>>(stats1);

    // 4) conv1: hB -> hC bf16 NHWC (+stats1). x4 in bufC dead.
    conv3x3_mfma_kernel<<<800, TPB, 0, stream>>>(hB, wt1, hC, stats1);

    // 5) apply1 (elementwise NHWC): hC -> hB bf16 NHWC
    bn_apply_elem_kernel<<<8 * 25600 * 8 / TPB, TPB, 0, stream>>>(
        hC, stats1, hB, invN);

    // 6) conv2: hB -> hC bf16 NHWC (+stats2)
    conv3x3_mfma_kernel<<<800, TPB, 0, stream>>>(hB, wt2, hC, stats2);

    // 7) apply2: hC -> out0 fp32 NCHW + hB bf16 NHWC (feat4)
    bn_apply_dual_kernel<<<8 * 400, TPB, 0, stream>>>(
        hC, stats2, out0, hB, 25600, invN);

    // 8) offset2 = offconv(feat4 hB) -> A
    offconv_mfma_kernel<<<8 * 6400 / 64, TPB, 0, stream>>>(
        hB, wtoff2, b_off2, A, 160, 160, 80, 80);

    // 9) feat_1_8 = deform2(feat4 hB, offset2) -> out1
    deform_mfma_kernel<64><<<8 * 6400 / 32, TPB, 0, stream>>>(
        hB, A, wtd2, b_d2, out1, 160, 160, 80, 80, 2);

    // 10) feat_1_8 -> NHWC bf16 into hC
    nchw_to_nhwc_bf16_kernel<<<8 * (6400 / 64), TPB, 0, stream>>>(out1, hC, 6400);

    // 11) offset3 = offconv(feat8 hC) -> A
    offconv_mfma_kernel<<<8 * 1600 / 64, TPB, 0, stream>>>(
        hC, wtoff3, b_off3, A, 80, 80, 40, 40);

    // 12) feat_1_16 = deform3(feat8 hC, offset3) -> out2
    deform_mfma_kernel<256><<<8 * 1600 / 32, TPB, 0, stream>>>(
        hC, A, wtd3, b_d3, out2, 80, 80, 40, 40, 2);
}

// Round 13
// 251.843 us; speedup vs baseline: 28.4892x; 1.0044x over previous
//
#include <hip/hip_runtime.h>
#include <hip/hip_bf16.h>
#include <math.h>

#define TPB 256

typedef __attribute__((ext_vector_type(8))) short bf16x8_t;
typedef __attribute__((ext_vector_type(4))) float f32x4_t;
typedef __attribute__((ext_vector_type(4))) int i32x4_t;
typedef __attribute__((ext_vector_type(4))) unsigned short u16x4_t;

static __device__ __forceinline__ float bf16_to_f(unsigned short s) {
    union { unsigned u; float f; } cv;
    cv.u = ((unsigned)s) << 16;
    return cv.f;
}
static __device__ __forceinline__ short f_to_bf16(float v) {
    __hip_bfloat16 h = __float2bfloat16(v);
    return *(short*)&h;
}

// ------------------------------------------------- weight repack, FRAGMENT order
__global__ void repack_frag_kernel(const float* __restrict__ w,
                                   short* __restrict__ wtf,
                                   int Oreal, int NFRAG)
{
    int idx = blockIdx.x * TPB + threadIdx.x;
    int total = 18 * NFRAG * 64 * 8;
    if (idx >= total) return;
    int j    = idx & 7;
    int lane = (idx >> 3) & 63;
    int t    = idx >> 9;
    int ocf  = t % NFRAG;
    int kc   = t / NFRAG;
    int oc   = ocf * 16 + (lane & 15);
    int tap  = kc >> 1;
    int ic   = (kc & 1) * 32 + (lane >> 4) * 8 + j;
    float v = 0.f;
    if (oc < Oreal)
        v = w[((size_t)(oc * 64 + ic)) * 9 + tap];
    wtf[idx] = f_to_bf16(v);
}

// ------------------------------------------------- MFMA conv 3x3 (64->64, s1)
// in: bf16 NHWC; out: bf16 NHWC (un-normalized); fused BN partial stats.
// Branchless zero-page staging; LDS-staged coalesced bf16 output.
__global__ __launch_bounds__(256, 2) void conv3x3_mfma_kernel(
    const short* __restrict__ xh,
    const short* __restrict__ wt,   // [18][4][64][8] frag order
    short* __restrict__ outh,       // bf16 NHWC
    float* __restrict__ stats,      // [8][128]
    const float* __restrict__ zp)   // 2KB zero page
{
    __shared__ short tile[2816 * 8];   // 45056 B (input tile, reused for output)
    __shared__ float sstat[128];
    const int H = 160, W = 160, HW = 25600;
    int blk = blockIdx.x;
    int b  = blk / 100;
    int r  = blk % 100;
    int y0 = (r / 10) * 16;
    int x0 = (r % 10) * 16;
    const int tid = threadIdx.x;
    const short* inb = xh + (size_t)b * HW * 64;

    // branchless staging: 2816 16B-chunks (324 real pixels + pad -> zero page)
#pragma unroll
    for (int it = 0; it < 11; ++it) {
        int item = it * 256 + tid;
        int c8  = item & 7;
        int pix = item >> 3;            // 0..351
        int row = pix / 18;
        int col = pix - row * 18;
        int y = y0 + row - 1;
        int x = x0 + col - 1;
        bool ok = (pix < 324) & (y >= 0) & (y < H) & (x >= 0) & (x < W);
        const short* src = ok
            ? &inb[((size_t)y * W + x) * 64 + ((c8 ^ (col & 7)) << 3)]
            : (const short*)zp;
        *(bf16x8_t*)&tile[item * 8] = *(const bf16x8_t*)src;
    }
    if (tid < 128) sstat[tid] = 0.f;
    __syncthreads();

    const int wv  = tid >> 6;
    const int l   = tid & 63;
    const int l15 = l & 15;
    const int lg  = l >> 4;

    f32x4_t acc[4][4];
#pragma unroll
    for (int i = 0; i < 4; ++i)
#pragma unroll
        for (int j = 0; j < 4; ++j)
            acc[i][j] = (f32x4_t){0.f, 0.f, 0.f, 0.f};

    // software-pipelined k-loop (full unroll -> static ping-pong indices)
    bf16x8_t bfp[2][4], afp[2][4];
#pragma unroll
    for (int nf = 0; nf < 4; ++nf)
        bfp[0][nf] = *(const bf16x8_t*)(wt + (((size_t)(0 * 4 + nf)) * 64 + l) * 8);
    {
        int colr = l15;                 // kc=0: dy=0, dx=0
        int chunk = lg ^ (colr & 7);
#pragma unroll
        for (int mf = 0; mf < 4; ++mf)
            afp[0][mf] = *(const bf16x8_t*)&tile[((wv * 4 + mf) * 18 + colr) * 64 + chunk * 8];
    }
#pragma unroll
    for (int kc = 0; kc < 18; ++kc) {
        const int cur = kc & 1, nxt = cur ^ 1;
        if (kc + 1 < 18) {
            int kn = kc + 1;
#pragma unroll
            for (int nf = 0; nf < 4; ++nf)
                bfp[nxt][nf] = *(const bf16x8_t*)(wt + (((size_t)(kn * 4 + nf)) * 64 + l) * 8);
            int tap = kn >> 1;
            int dy = tap / 3, dx = tap % 3;
            int colr = l15 + dx;
            int chunk = (((kn & 1) << 2) + lg) ^ (colr & 7);
#pragma unroll
            for (int mf = 0; mf < 4; ++mf)
                afp[nxt][mf] = *(const bf16x8_t*)&tile[((wv * 4 + mf + dy) * 18 + colr) * 64 + chunk * 8];
        }
#pragma unroll
        for (int mf = 0; mf < 4; ++mf)
#pragma unroll
            for (int nf = 0; nf < 4; ++nf)
                acc[mf][nf] = __builtin_amdgcn_mfma_f32_16x16x32_bf16(
                    afp[cur][mf], bfp[cur][nf], acc[mf][nf], 0, 0, 0);
    }

    // pack outputs into LDS [256 px][64 oc] bf16, then coalesced NHWC stores
    __syncthreads();
#pragma unroll
    for (int mf = 0; mf < 4; ++mf) {
        int py = wv * 4 + mf;
#pragma unroll
        for (int nf = 0; nf < 4; ++nf) {
            int oc = nf * 16 + l15;
#pragma unroll
            for (int k = 0; k < 4; ++k)
                tile[((py * 16) + lg * 4 + k) * 64 + oc] = f_to_bf16(acc[mf][nf][k]);
        }
    }
    __syncthreads();
    short* outb = outh + (size_t)b * HW * 64;
#pragma unroll
    for (int j = 0; j < 8; ++j) {
        int item = j * 256 + tid;       // 2048 groups
        int c8  = item & 7;
        int pix = item >> 3;            // 0..255
        int py  = pix >> 4, px = pix & 15;
        *(bf16x8_t*)&outb[((size_t)(y0 + py) * W + x0 + px) * 64 + c8 * 8] =
            *(bf16x8_t*)&tile[pix * 64 + c8 * 8];
    }

    // fused BN partial stats (fp32 accumulators)
#pragma unroll
    for (int nf = 0; nf < 4; ++nf) {
        float s = 0.f, s2 = 0.f;
#pragma unroll
        for (int mf = 0; mf < 4; ++mf)
#pragma unroll
            for (int k = 0; k < 4; ++k) {
                float v = acc[mf][nf][k];
                s += v; s2 += v * v;
            }
        s  += __shfl_xor(s, 16, 64);  s  += __shfl_xor(s, 32, 64);
        s2 += __shfl_xor(s2, 16, 64); s2 += __shfl_xor(s2, 32, 64);
        if (lg == 0) {
            int oc = nf * 16 + l15;
            atomicAdd(&sstat[oc], s);
            atomicAdd(&sstat[64 + oc], s2);
        }
    }
    __syncthreads();
    float* st = stats + (size_t)(blockIdx.x & 7) * 128;
    if (tid < 128) atomicAdd(&st[tid], sstat[tid]);
}

// ------------------------------------------------- NCHW fp32 -> NHWC bf16 (C=64)
__global__ void nchw_to_nhwc_bf16_kernel(const float* __restrict__ in,
                                         short* __restrict__ out, int HW)
{
    __shared__ short tile[64][66];
    int nchunks = HW >> 6;
    int b  = blockIdx.x / nchunks;
    int p0 = (blockIdx.x % nchunks) << 6;
    int tid = threadIdx.x;
#pragma unroll
    for (int rep = 0; rep < 16; ++rep) {
        int item = rep * 256 + tid;
        int c = item >> 6, p = item & 63;
        tile[p][c] = f_to_bf16(in[((size_t)b * 64 + c) * HW + p0 + p]);
    }
    __syncthreads();
#pragma unroll
    for (int rep = 0; rep < 16; ++rep) {
        int item = rep * 256 + tid;
        int p = item >> 6, c = item & 63;
        out[((size_t)b * HW + p0 + p) * 64 + c] = tile[p][c];
    }
}

// ------------------------------------------------- BN apply, NHWC->NHWC elementwise
__global__ void bn_apply_elem_kernel(const short* __restrict__ in,
                                     const float* __restrict__ stats, // [8][128]
                                     short* __restrict__ outh,
                                     float invN)
{
    __shared__ float sm[64], sr[64];
    int tid = threadIdx.x;
    if (tid < 64) {
        float s = 0.f, s2 = 0.f;
#pragma unroll
        for (int k = 0; k < 8; ++k) {
            s  += stats[k * 128 + tid];
            s2 += stats[k * 128 + 64 + tid];
        }
        float mean = s * invN;
        float var  = s2 * invN - mean * mean;
        sm[tid] = mean;
        sr[tid] = rsqrtf(var + 1e-5f);
    }
    __syncthreads();
    int item = blockIdx.x * TPB + tid;       // one bf16x8 group
    int c0 = (item & 7) * 8;
    bf16x8_t v = *(const bf16x8_t*)&in[(size_t)item * 8];
    bf16x8_t o;
#pragma unroll
    for (int j = 0; j < 8; ++j) {
        float f = (bf16_to_f((unsigned short)v[j]) - sm[c0 + j]) * sr[c0 + j];
        o[j] = f_to_bf16(f > 0.f ? f : 0.f);
    }
    *(bf16x8_t*)&outh[(size_t)item * 8] = o;
}

// ------------------------------------------------- BN apply dual: NHWC bf16 in ->
// out0 NCHW fp32 + NHWC bf16
__global__ void bn_apply_dual_kernel(const short* __restrict__ in,
                                     const float* __restrict__ stats, // [8][128]
                                     float* __restrict__ out,         // NCHW fp32
                                     short* __restrict__ outh,        // NHWC bf16
                                     int HW, float invN)
{
    __shared__ float ftile[64][65];
    __shared__ float sm[64], sr[64];
    int nchunks = HW >> 6;
    int b  = blockIdx.x / nchunks;
    int p0 = (blockIdx.x % nchunks) << 6;
    int tid = threadIdx.x;
    if (tid < 64) {
        float s = 0.f, s2 = 0.f;
#pragma unroll
        for (int k = 0; k < 8; ++k) {
            s  += stats[k * 128 + tid];
            s2 += stats[k * 128 + 64 + tid];
        }
        float mean = s * invN;
        float var  = s2 * invN - mean * mean;
        sm[tid] = mean;
        sr[tid] = rsqrtf(var + 1e-5f);
    }
    __syncthreads();
#pragma unroll
    for (int it = 0; it < 2; ++it) {
        int item = it * 256 + tid;            // 512 groups = 64 px * 8
        int p = item >> 3, c0 = (item & 7) * 8;
        size_t gi = ((size_t)(b * HW + p0 + p)) * 64 + c0;
        bf16x8_t v = *(const bf16x8_t*)&in[gi];
        bf16x8_t o;
#pragma unroll
        for (int j = 0; j < 8; ++j) {
            float f = (bf16_to_f((unsigned short)v[j]) - sm[c0 + j]) * sr[c0 + j];
            f = f > 0.f ? f : 0.f;
            ftile[p][c0 + j] = f;
            o[j] = f_to_bf16(f);
        }
        *(bf16x8_t*)&outh[gi] = o;
    }
    __syncthreads();
#pragma unroll
    for (int rep = 0; rep < 16; ++rep) {
        int item = rep * 256 + tid;
        int c = item >> 6, p = item & 63;
        out[((size_t)b * 64 + c) * HW + p0 + p] = ftile[p][c];
    }
}

// ------------------------------------------------- x NCHW (C=3) -> NHWC4 fp32
__global__ void x_to_nhwc4_kernel(const float* __restrict__ in,
                                  float* __restrict__ out)
{
    int idx = blockIdx.x * TPB + threadIdx.x;
    const int HW = 640 * 640;
    if (idx >= 8 * HW) return;
    int b = idx / HW, p = idx % HW;
    f32x4_t v;
    v[0] = in[((size_t)b * 3 + 0) * HW + p];
    v[1] = in[((size_t)b * 3 + 1) * HW + p];
    v[2] = in[((size_t)b * 3 + 2) * HW + p];
    v[3] = 0.f;
    *(f32x4_t*)&out[(size_t)idx * 4] = v;
}

// ------------------------------------------------- offset1: exact fp32, NHWC4
__global__ void offset1_kernel(const float* __restrict__ x4,
                               const float* __restrict__ w,   // (18,3,3,3)
                               const float* __restrict__ bias,
                               float* __restrict__ out)
{
    const int H = 640, W = 640, HW = 25600;
    int idx = blockIdx.x * TPB + threadIdx.x;
    if (idx >= 8 * HW) return;
    int b = idx / HW, r = idx % HW;
    int ho = r / 160, wo = r % 160;

    float acc[18];
#pragma unroll
    for (int o = 0; o < 18; ++o) acc[o] = bias[o];

    const float* xb = x4 + (size_t)b * H * W * 4;
#pragma unroll
    for (int tap = 0; tap < 9; ++tap) {
        int iy = ho * 4 - 1 + tap / 3;
        int ix = wo * 4 - 1 + tap % 3;
        if (iy < 0 || iy >= H || ix < 0 || ix >= W) continue;
        f32x4_t s = *(const f32x4_t*)&xb[((size_t)iy * W + ix) * 4];
#pragma unroll
        for (int c = 0; c < 3; ++c)
#pragma unroll
            for (int o = 0; o < 18; ++o)
                acc[o] += s[c] * w[(o * 3 + c) * 9 + tap];
    }
#pragma unroll
    for (int o = 0; o < 18; ++o)
        out[((size_t)(b * 18 + o)) * HW + r] = acc[o];
}

// ------------------------------------------------- offset2/3: MFMA conv, N=18
__global__ __launch_bounds__(256, 1) void offconv_mfma_kernel(
    const short* __restrict__ xh,
    const short* __restrict__ wt,    // [18][2][64][8] frag order, zero-padded
    const float* __restrict__ bias,
    float* __restrict__ out,
    int H, int W, int Ho, int Wo)
{
    const int HW = Ho * Wo;
    const int tid = threadIdx.x;
    const int wv = tid >> 6, l = tid & 63;
    const int l15 = l & 15, lg = l >> 4;
    const int pix0 = blockIdx.x * 64 + wv * 16;
    const int b = pix0 / HW;
    const int r0 = pix0 - b * HW;

    int rp = r0 + l15;
    int ho = rp / Wo, wo = rp % Wo;
    const short* xb = xh + (size_t)b * H * W * 64;

    f32x4_t acc[2];
    acc[0] = (f32x4_t){0.f, 0.f, 0.f, 0.f};
    acc[1] = (f32x4_t){0.f, 0.f, 0.f, 0.f};

#pragma unroll 2
    for (int kc = 0; kc < 18; ++kc) {
        int tap = kc >> 1;
        int iy = ho * 2 - 1 + tap / 3;
        int ix = wo * 2 - 1 + tap % 3;
        bf16x8_t af = {};
        if (iy >= 0 && iy < H && ix >= 0 && ix < W)
            af = *(const bf16x8_t*)&xb[((size_t)iy * W + ix) * 64
                                       + (kc & 1) * 32 + lg * 8];
#pragma unroll
        for (int nf = 0; nf < 2; ++nf) {
            bf16x8_t bf = *(const bf16x8_t*)(wt + (((size_t)(kc * 2 + nf)) * 64 + l) * 8);
            acc[nf] = __builtin_amdgcn_mfma_f32_16x16x32_bf16(af, bf, acc[nf], 0, 0, 0);
        }
    }

#pragma unroll
    for (int nf = 0; nf < 2; ++nf) {
        int oc = nf * 16 + l15;
        if (oc < 18) {
            float bv = bias[oc];
            f32x4_t v = acc[nf];
            v[0] += bv; v[1] += bv; v[2] += bv; v[3] += bv;
            *(f32x4_t*)&out[((size_t)(b * 18 + oc)) * HW + r0 + lg * 4] = v;
        }
    }
}

// ------------------------------------------------- deform1: C=3, fused skip
__global__ __launch_bounds__(256, 1) void deform1_kernel(
    const float* __restrict__ x4,
    const float* __restrict__ off,
    const float* __restrict__ w,
    const float* __restrict__ bias,
    const float* __restrict__ pool,
    const float* __restrict__ wsk,
    const float* __restrict__ bsk,
    short* __restrict__ outh)
{
    const int H = 640, W = 640, Ho = 160, Wo = 160, HW = 25600;
    constexpr int P = 32;
    __shared__ float samp[P][28];
    __shared__ int   sidx[P * 9][4];
    __shared__ float swt[P * 9][4];
    const int tid = threadIdx.x;
    const int pix0 = blockIdx.x * P;
    const int b = pix0 / HW;
    const int r0 = pix0 - b * HW;

    for (int item = tid; item < P * 9; item += TPB) {
        int p = item / 9, tap = item % 9;
        int r = r0 + p, ho = r / Wo, wo = r % Wo;
        float dy = off[((size_t)(b * 18 + 2 * tap) * Ho + ho) * Wo + wo];
        float dx = off[((size_t)(b * 18 + 2 * tap + 1) * Ho + ho) * Wo + wo];
        float ys = (float)(ho * 4 - 1 + tap / 3) + dy;
        float xs = (float)(wo * 4 - 1 + tap % 3) + dx;
        float y0f = floorf(ys), x0f = floorf(xs);
        float fy = ys - y0f, fx = xs - x0f;
        int y0 = (int)y0f, x0 = (int)x0f;
        float wts[4] = {(1.f - fy) * (1.f - fx), (1.f - fy) * fx,
                        fy * (1.f - fx),          fy * fx};
#pragma unroll
        for (int j = 0; j < 4; ++j) {
            int iy = y0 + (j >> 1), ix = x0 + (j & 1);
            bool v = (iy >= 0) && (iy < H) && (ix >= 0) && (ix < W);
            sidx[item][j] = v ? (iy * W + ix) : 0;
            swt[item][j]  = v ? wts[j] : 0.f;
        }
    }
    __syncthreads();

    const float* xb = x4 + (size_t)b * H * W * 4;
    for (int item = tid; item < P * 9; item += TPB) {
        int p = item / 9, tap = item % 9;
        i32x4_t id4 = *(const i32x4_t*)sidx[item];
        f32x4_t w4  = *(const f32x4_t*)swt[item];
        f32x4_t a0 = *(const f32x4_t*)&xb[(size_t)(unsigned)id4[0] * 4];
        f32x4_t a1 = *(const f32x4_t*)&xb[(size_t)(unsigned)id4[1] * 4];
        f32x4_t a2 = *(const f32x4_t*)&xb[(size_t)(unsigned)id4[2] * 4];
        f32x4_t a3 = *(const f32x4_t*)&xb[(size_t)(unsigned)id4[3] * 4];
        samp[p][0 * 9 + tap] = w4[0]*a0[0] + w4[1]*a1[0] + w4[2]*a2[0] + w4[3]*a3[0];
        samp[p][1 * 9 + tap] = w4[0]*a0[1] + w4[1]*a1[1] + w4[2]*a2[1] + w4[3]*a3[1];
        samp[p][2 * 9 + tap] = w4[0]*a0[2] + w4[1]*a1[2] + w4[2]*a2[2] + w4[3]*a3[2];
    }
    __syncthreads();

    int g = tid >> 6;
    int o = tid & 63;
    float acc[8];
#pragma unroll
    for (int pi = 0; pi < 8; ++pi) acc[pi] = bias[o] + bsk[o];
#pragma unroll
    for (int c = 0; c < 3; ++c)
#pragma unroll
        for (int k = 0; k < 9; ++k) {
            float wv = w[((size_t)(o * 3 + c)) * 9 + k];
#pragma unroll
            for (int pi = 0; pi < 8; ++pi)
                acc[pi] += wv * samp[g * 8 + pi][c * 9 + k];
        }
#pragma unroll
    for (int pi = 0; pi < 8; ++pi) {
        int r = r0 + g * 8 + pi;
        float sv = wsk[o * 3 + 0] * pool[(size_t)(b * 3 + 0) * HW + r]
                 + wsk[o * 3 + 1] * pool[(size_t)(b * 3 + 1) * HW + r]
                 + wsk[o * 3 + 2] * pool[(size_t)(b * 3 + 2) * HW + r];
        outh[((size_t)(b * HW + r)) * 64 + o] = f_to_bf16(acc[pi] + sv);
    }
}

// ------------------------------------------------- deform MFMA: C=64 -> O
template <int O>
__global__ __launch_bounds__(256, 1) void deform_mfma_kernel(
    const short* __restrict__ xh,
    const float* __restrict__ off,
    const short* __restrict__ wt,   // [18][O/16][64][8] frag order
    const float* __restrict__ bias,
    float* __restrict__ out,
    int H, int W, int Ho, int Wo, int stride)
{
    constexpr int NF = O / 64;
    constexpr int NFRAG = O / 16;
    constexpr int P  = 32;
    __shared__ alignas(16) short samp[P * 576];
    __shared__ int   sidx[P * 9][4];
    __shared__ float swt[P * 9][4];

    const int tid = threadIdx.x;
    const int HW = Ho * Wo;
    const int pix0 = blockIdx.x * P;
    const int b = pix0 / HW;
    const int r0 = pix0 - b * HW;

    for (int item = tid; item < P * 9; item += TPB) {
        int p = item / 9, tap = item % 9;
        int r = r0 + p, ho = r / Wo, wo = r % Wo;
        float dy = off[((size_t)(b * 18 + 2 * tap) * Ho + ho) * Wo + wo];
        float dx = off[((size_t)(b * 18 + 2 * tap + 1) * Ho + ho) * Wo + wo];
        float ys = (float)(ho * stride - 1 + tap / 3) + dy;
        float xs = (float)(wo * stride - 1 + tap % 3) + dx;
        float y0f = floorf(ys), x0f = floorf(xs);
        float fy = ys - y0f, fx = xs - x0f;
        int y0 = (int)y0f, x0 = (int)x0f;
        float wts[4] = {(1.f - fy) * (1.f - fx), (1.f - fy) * fx,
                        fy * (1.f - fx),          fy * fx};
#pragma unroll
        for (int j = 0; j < 4; ++j) {
            int iy = y0 + (j >> 1), ix = x0 + (j & 1);
            bool v = (iy >= 0) && (iy < H) && (ix >= 0) && (ix < W);
            sidx[item][j] = v ? (iy * W + ix) : 0;
            swt[item][j]  = v ? wts[j] : 0.f;
        }
    }
    __syncthreads();

    {
        const int grp = tid >> 4;
        const int ic  = (tid & 15) * 4;
        const short* xb = xh + (size_t)b * H * W * 64;
#pragma unroll 3
        for (int i = 0; i < 18; ++i) {
            int e = grp * 18 + i;
            int p = e / 9, tap = e % 9;
            i32x4_t id4 = *(const i32x4_t*)sidx[e];
            f32x4_t w4  = *(const f32x4_t*)swt[e];
            u16x4_t u0 = *(const u16x4_t*)&xb[(size_t)(unsigned)id4[0] * 64 + ic];
            u16x4_t u1 = *(const u16x4_t*)&xb[(size_t)(unsigned)id4[1] * 64 + ic];
            u16x4_t u2 = *(const u16x4_t*)&xb[(size_t)(unsigned)id4[2] * 64 + ic];
            u16x4_t u3 = *(const u16x4_t*)&xb[(size_t)(unsigned)id4[3] * 64 + ic];
            float v0 = w4[0]*bf16_to_f(u0[0]) + w4[1]*bf16_to_f(u1[0])
                     + w4[2]*bf16_to_f(u2[0]) + w4[3]*bf16_to_f(u3[0]);
            float v1 = w4[0]*bf16_to_f(u0[1]) + w4[1]*bf16_to_f(u1[1])
                     + w4[2]*bf16_to_f(u2[1]) + w4[3]*bf16_to_f(u3[1]);
            float v2 = w4[0]*bf16_to_f(u0[2]) + w4[1]*bf16_to_f(u1[2])
                     + w4[2]*bf16_to_f(u2[2]) + w4[3]*bf16_to_f(u3[2]);
            float v3 = w4[0]*bf16_to_f(u0[3]) + w4[1]*bf16_to_f(u1[3])
                     + w4[2]*bf16_to_f(u2[3]) + w4[3]*bf16_to_f(u3[3]);
            int sw = (tap * 8 + ((ic >> 3) ^ (p & 7))) * 8 + (ic & 7);
            short* dst = &samp[p * 576 + sw];
            dst[0] = f_to_bf16(v0);
            dst[1] = f_to_bf16(v1);
            dst[2] = f_to_bf16(v2);
            dst[3] = f_to_bf16(v3);
        }
    }
    __syncthreads();

    const int wv = tid >> 6;
    const int l  = tid & 63;
    const int l15 = l & 15, lg = l >> 4;
    f32x4_t acc[2][NF];
#pragma unroll
    for (int mf = 0; mf < 2; ++mf)
#pragma unroll
        for (int nf = 0; nf < NF; ++nf)
            acc[mf][nf] = (f32x4_t){0.f, 0.f, 0.f, 0.f};

#pragma unroll 2
    for (int kc = 0; kc < 18; ++kc) {
        int tap = kc >> 1;
        int low = (((kc & 1) << 2) | lg) ^ (l15 & 7);
        bf16x8_t af0 = *(const bf16x8_t*)&samp[l15 * 576 + (tap * 8 + low) * 8];
        bf16x8_t af1 = *(const bf16x8_t*)&samp[(l15 + 16) * 576 + (tap * 8 + low) * 8];
#pragma unroll
        for (int nf = 0; nf < NF; ++nf) {
            int ocf = wv * NF + nf;
            bf16x8_t bf = *(const bf16x8_t*)(wt + (((size_t)(kc * NFRAG + ocf)) * 64 + l) * 8);
            acc[0][nf] = __builtin_amdgcn_mfma_f32_16x16x32_bf16(af0, bf, acc[0][nf], 0, 0, 0);
            acc[1][nf] = __builtin_amdgcn_mfma_f32_16x16x32_bf16(af1, bf, acc[1][nf], 0, 0, 0);
        }
    }

#pragma unroll
    for (int mf = 0; mf < 2; ++mf)
#pragma unroll
        for (int nf = 0; nf < NF; ++nf) {
            int oc = (wv * NF + nf) * 16 + l15;
            float bv = bias[oc];
            f32x4_t v = acc[mf][nf];
            v[0] += bv; v[1] += bv; v[2] += bv; v[3] += bv;
            *(f32x4_t*)&out[((size_t)(b * O + oc)) * HW + r0 + mf * 16 + lg * 4] = v;
        }
}

// ---------------------------------------------------------------- avgpool 4x4
__global__ void avgpool4_kernel(const float* __restrict__ in,
                                float* __restrict__ out,
                                int BC, int Ho, int Wo, int H, int W)
{
    int idx = blockIdx.x * TPB + threadIdx.x;
    int total = BC * Ho * Wo;
    if (idx >= total) return;
    int wo = idx % Wo;
    int t = idx / Wo;
    int ho = t % Ho;
    int bc = t / Ho;
    const float* xp = in + (size_t)bc * H * W + (ho * 4) * W + wo * 4;
    float s = 0.f;
#pragma unroll
    for (int i = 0; i < 4; ++i)
#pragma unroll
        for (int j = 0; j < 4; ++j)
            s += xp[i * W + j];
    out[idx] = s * (1.0f / 16.0f);
}

__global__ void zero_stats_kernel(float* __restrict__ stats)
{
    int i = threadIdx.x;
#pragma unroll
    for (int k = 0; k < 8; ++k) stats[k * 256 + i] = 0.f;
    stats[2048 + i] = 0.f;          // zero page (512 floats)
    stats[2048 + 256 + i] = 0.f;
}

// ---------------------------------------------------------------- launch
extern "C" void kernel_launch(void* const* d_in, const int* in_sizes, int n_in,
                              void* d_out, int out_size, void* d_ws, size_t ws_size,
                              hipStream_t stream)
{
    const float* x      = (const float*)d_in[0];
    const float* w_off1 = (const float*)d_in[1];
    const float* b_off1 = (const float*)d_in[2];
    const float* w_d1   = (const float*)d_in[3];
    const float* b_d1   = (const float*)d_in[4];
    const float* w_skip = (const float*)d_in[5];
    const float* b_skip = (const float*)d_in[6];
    const float* w_bl1  = (const float*)d_in[7];
    const float* w_bl2  = (const float*)d_in[8];
    const float* w_off2 = (const float*)d_in[9];
    const float* b_off2 = (const float*)d_in[10];
    const float* w_d2   = (const float*)d_in[11];
    const float* b_d2   = (const float*)d_in[12];
    const float* w_off3 = (const float*)d_in[13];
    const float* b_off3 = (const float*)d_in[14];
    const float* w_d3   = (const float*)d_in[15];
    const float* b_d3   = (const float*)d_in[16];

    const int B = 8;
    float* A     = (float*)d_ws;          // 3,686,400 floats
    float* bufB  = A + 3686400;           // 13,107,200 floats
    float* bufC  = bufB + 13107200;       // 13,107,200 floats

    short* hB   = (short*)bufB;
    short* hC   = (short*)bufC;
    float* pool = bufB + 8000000;

    // frag-ordered weights + stats + zero page inside A (above all later
    // A writes, which stay below 1M floats)
    short* wt1    = (short*)(A + 1000000);
    short* wt2    = wt1 + 18 * 4 * 512;
    short* wtd2   = (short*)(A + 1500000);
    short* wtd3   = (short*)(A + 1550000);
    short* wtoff2 = (short*)(A + 1700000);
    short* wtoff3 = (short*)(A + 1712000);
    float* stats1 = A + 1800000;          // [8][128]
    float* stats2 = stats1 + 1024;        // [8][128]
    float* zpage  = stats1 + 2048;        // 512 floats (2KB zeros)

    float* out0 = (float*)d_out;
    float* out1 = out0 + 13107200;
    float* out2 = out1 + 3276800;

    const float invN = 1.0f / (B * 25600);

    // 0) x -> NHWC4 fp32 into bufC
    x_to_nhwc4_kernel<<<(8 * 409600 + TPB - 1) / TPB, TPB, 0, stream>>>(x, bufC);

    // 1) offset1 (exact fp32) -> A
    offset1_kernel<<<(8 * 25600 + TPB - 1) / TPB, TPB, 0, stream>>>(
        bufC, w_off1, b_off1, A);

    // 2) pool = avgpool4(x) -> bufB+8M
    avgpool4_kernel<<<(B * 3 * 25600 + TPB - 1) / TPB, TPB, 0, stream>>>(
        x, pool, B * 3, 160, 160, 640, 640);

    // 3) d1+skip = deform1 -> hB (bf16 NHWC). offset1 dead after this.
    deform1_kernel<<<8 * 25600 / 32, TPB, 0, stream>>>(
        bufC, A, w_d1, b_d1, pool, w_skip, b_skip, hB);

    // 3.5) repack weights + zero stats & zero page
    repack_frag_kernel<<<(18 * 4 * 512 + TPB - 1) / TPB, TPB, 0, stream>>>(w_bl1, wt1, 64, 4);
    repack_frag_kernel<<<(18 * 4 * 512 + TPB - 1) / TPB, TPB, 0, stream>>>(w_bl2, wt2, 64, 4);
    repack_frag_kernel<<<(18 * 4 * 512 + TPB - 1) / TPB, TPB, 0, stream>>>(w_d2, wtd2, 64, 4);
    repack_frag_kernel<<<(18 * 16 * 512 + TPB - 1) / TPB, TPB, 0, stream>>>(w_d3, wtd3, 256, 16);
    repack_frag_kernel<<<(18 * 2 * 512 + TPB - 1) / TPB, TPB, 0, stream>>>(w_off2, wtoff2, 18, 2);
    repack_frag_kernel<<<(18 * 2 * 512 + TPB - 1) / TPB, TPB, 0, stream>>>(w_off3, wtoff3, 18, 2);
    zero_stats_kernel<<<1, 256, 0, stream>>>(stats1);

    // 4) conv1: hB -> hC bf16 NHWC (+stats1). x4 in bufC dead.
    conv3x3_mfma_kernel<<<800, TPB, 0, stream>>>(hB, wt1, hC, stats1, zpage);

    // 5) apply1 (elementwise NHWC): hC -> hB bf16 NHWC
    bn_apply_elem_kernel<<<8 * 25600 * 8 / TPB, TPB, 0, stream>>>(
        hC, stats1, hB, invN);

    // 6) conv2: hB -> hC bf16 NHWC (+stats2)
    conv3x3_mfma_kernel<<<800, TPB, 0, stream>>>(hB, wt2, hC, stats2, zpage);

    // 7) apply2: hC -> out0 fp32 NCHW + hB bf16 NHWC (feat4)
    bn_apply_dual_kernel<<<8 * 400, TPB, 0, stream>>>(
        hC, stats2, out0, hB, 25600, invN);

    // 8) offset2 = offconv(feat4 hB) -> A
    offconv_mfma_kernel<<<8 * 6400 / 64, TPB, 0, stream>>>(
        hB, wtoff2, b_off2, A, 160, 160, 80, 80);

    // 9) feat_1_8 = deform2(feat4 hB, offset2) -> out1
    deform_mfma_kernel<64><<<8 * 6400 / 32, TPB, 0, stream>>>(
        hB, A, wtd2, b_d2, out1, 160, 160, 80, 80, 2);

    // 10) feat_1_8 -> NHWC bf16 into hC
    nchw_to_nhwc_bf16_kernel<<<8 * (6400 / 64), TPB, 0, stream>>>(out1, hC, 6400);

    // 11) offset3 = offconv(feat8 hC) -> A
    offconv_mfma_kernel<<<8 * 1600 / 64, TPB, 0, stream>>>(
        hC, wtoff3, b_off3, A, 80, 80, 40, 40);

    // 12) feat_1_16 = deform3(feat8 hC, offset3) -> out2
    deform_mfma_kernel<256><<<8 * 1600 / 32, TPB, 0, stream>>>(
        hC, A, wtd3, b_d3, out2, 80, 80, 40, 40, 2);
}

// Round 15
// 245.373 us; speedup vs baseline: 29.2404x; 1.0264x over previous
//
#include <hip/hip_runtime.h>
#include <hip/hip_bf16.h>
#include <math.h>

#define TPB 256

typedef __attribute__((ext_vector_type(8))) short bf16x8_t;
typedef __attribute__((ext_vector_type(4))) float f32x4_t;
typedef __attribute__((ext_vector_type(4))) int i32x4_t;
typedef __attribute__((ext_vector_type(4))) unsigned short u16x4_t;

static __device__ __forceinline__ float bf16_to_f(unsigned short s) {
    union { unsigned u; float f; } cv;
    cv.u = ((unsigned)s) << 16;
    return cv.f;
}
static __device__ __forceinline__ short f_to_bf16(float v) {
    __hip_bfloat16 h = __float2bfloat16(v);
    return *(short*)&h;
}

// ------------------------------------------------- weight repack, FRAGMENT order
__global__ void repack_frag_kernel(const float* __restrict__ w,
                                   short* __restrict__ wtf,
                                   int Oreal, int NFRAG)
{
    int idx = blockIdx.x * TPB + threadIdx.x;
    int total = 18 * NFRAG * 64 * 8;
    if (idx >= total) return;
    int j    = idx & 7;
    int lane = (idx >> 3) & 63;
    int t    = idx >> 9;
    int ocf  = t % NFRAG;
    int kc   = t / NFRAG;
    int oc   = ocf * 16 + (lane & 15);
    int tap  = kc >> 1;
    int ic   = (kc & 1) * 32 + (lane >> 4) * 8 + j;
    float v = 0.f;
    if (oc < Oreal)
        v = w[((size_t)(oc * 64 + ic)) * 9 + tap];
    wtf[idx] = f_to_bf16(v);
}

// ------------------------------------------------- MFMA conv 3x3 (64->64, s1)
// in: bf16 NHWC (raw or, if NORM, normalized during staging with stats_in);
// out: bf16 NHWC un-normalized; fused BN partial stats.
// NOTE: staging loads the swizzled channel group cs = c8^(col&7); the NORM
// path must therefore use stats of channels cs*8..cs*8+7 (round-14 bug fix).
template <int NORM>
__global__ __launch_bounds__(256, 2) void conv3x3_mfma_kernel(
    const short* __restrict__ xh,
    const short* __restrict__ wt,      // [18][4][64][8] frag order
    short* __restrict__ outh,          // bf16 NHWC
    float* __restrict__ stats,         // [8][128]
    const float* __restrict__ stats_in,// [8][128] (NORM only)
    float invN,
    const float* __restrict__ zp)      // 2KB zero page
{
    __shared__ short tile[2816 * 8];   // 45056 B (input tile, reused for output)
    __shared__ float sstat[128];
    __shared__ float sm[64], sr[64];
    const int H = 160, W = 160, HW = 25600;
    int blk = blockIdx.x;
    int b  = blk / 100;
    int r  = blk % 100;
    int y0 = (r / 10) * 16;
    int x0 = (r % 10) * 16;
    const int tid = threadIdx.x;
    const short* inb = xh + (size_t)b * HW * 64;

    if (tid < 128) sstat[tid] = 0.f;
    if (NORM) {
        if (tid < 64) {
            float s = 0.f, s2 = 0.f;
#pragma unroll
            for (int k = 0; k < 8; ++k) {
                s  += stats_in[k * 128 + tid];
                s2 += stats_in[k * 128 + 64 + tid];
            }
            float mean = s * invN;
            float var  = s2 * invN - mean * mean;
            sm[tid] = mean;
            sr[tid] = rsqrtf(var + 1e-5f);
        }
        __syncthreads();
    }

    // branchless staging: 2816 16B-chunks (324 real pixels + pad -> zero page)
#pragma unroll
    for (int it = 0; it < 11; ++it) {
        int item = it * 256 + tid;
        int c8  = item & 7;             // == tid & 7
        int pix = item >> 3;            // 0..351
        int row = pix / 18;
        int col = pix - row * 18;
        int y = y0 + row - 1;
        int x = x0 + col - 1;
        bool ok = (pix < 324) & (y >= 0) & (y < H) & (x >= 0) & (x < W);
        int cs = c8 ^ (col & 7);        // swizzled channel group actually loaded
        const short* src = ok
            ? &inb[((size_t)y * W + x) * 64 + (cs << 3)]
            : (const short*)zp;
        bf16x8_t v = *(const bf16x8_t*)src;
        if (NORM) {
            int cs8 = cs << 3;
            bf16x8_t o;
#pragma unroll
            for (int j = 0; j < 8; ++j) {
                float f = (bf16_to_f((unsigned short)v[j]) - sm[cs8 + j]) * sr[cs8 + j];
                f = f > 0.f ? f : 0.f;
                o[j] = ok ? f_to_bf16(f) : (short)0;
            }
            v = o;
        }
        *(bf16x8_t*)&tile[item * 8] = v;
    }
    __syncthreads();

    const int wv  = tid >> 6;
    const int l   = tid & 63;
    const int l15 = l & 15;
    const int lg  = l >> 4;

    f32x4_t acc[4][4];
#pragma unroll
    for (int i = 0; i < 4; ++i)
#pragma unroll
        for (int j = 0; j < 4; ++j)
            acc[i][j] = (f32x4_t){0.f, 0.f, 0.f, 0.f};

    // software-pipelined k-loop (full unroll -> static ping-pong indices)
    bf16x8_t bfp[2][4], afp[2][4];
#pragma unroll
    for (int nf = 0; nf < 4; ++nf)
        bfp[0][nf] = *(const bf16x8_t*)(wt + (((size_t)(0 * 4 + nf)) * 64 + l) * 8);
    {
        int colr = l15;                 // kc=0: dy=0, dx=0
        int chunk = lg ^ (colr & 7);
#pragma unroll
        for (int mf = 0; mf < 4; ++mf)
            afp[0][mf] = *(const bf16x8_t*)&tile[((wv * 4 + mf) * 18 + colr) * 64 + chunk * 8];
    }
#pragma unroll
    for (int kc = 0; kc < 18; ++kc) {
        const int cur = kc & 1, nxt = cur ^ 1;
        if (kc + 1 < 18) {
            int kn = kc + 1;
#pragma unroll
            for (int nf = 0; nf < 4; ++nf)
                bfp[nxt][nf] = *(const bf16x8_t*)(wt + (((size_t)(kn * 4 + nf)) * 64 + l) * 8);
            int tap = kn >> 1;
            int dy = tap / 3, dx = tap % 3;
            int colr = l15 + dx;
            int chunk = (((kn & 1) << 2) + lg) ^ (colr & 7);
#pragma unroll
            for (int mf = 0; mf < 4; ++mf)
                afp[nxt][mf] = *(const bf16x8_t*)&tile[((wv * 4 + mf + dy) * 18 + colr) * 64 + chunk * 8];
        }
#pragma unroll
        for (int mf = 0; mf < 4; ++mf)
#pragma unroll
            for (int nf = 0; nf < 4; ++nf)
                acc[mf][nf] = __builtin_amdgcn_mfma_f32_16x16x32_bf16(
                    afp[cur][mf], bfp[cur][nf], acc[mf][nf], 0, 0, 0);
    }

    // pack outputs into LDS [256 px][64 oc] bf16, then coalesced NHWC stores
    __syncthreads();
#pragma unroll
    for (int mf = 0; mf < 4; ++mf) {
        int py = wv * 4 + mf;
#pragma unroll
        for (int nf = 0; nf < 4; ++nf) {
            int oc = nf * 16 + l15;
#pragma unroll
            for (int k = 0; k < 4; ++k)
                tile[((py * 16) + lg * 4 + k) * 64 + oc] = f_to_bf16(acc[mf][nf][k]);
        }
    }
    __syncthreads();
    short* outb = outh + (size_t)b * HW * 64;
#pragma unroll
    for (int j = 0; j < 8; ++j) {
        int item = j * 256 + tid;       // 2048 groups
        int c8  = item & 7;
        int pix = item >> 3;            // 0..255
        int py  = pix >> 4, px = pix & 15;
        *(bf16x8_t*)&outb[((size_t)(y0 + py) * W + x0 + px) * 64 + c8 * 8] =
            *(bf16x8_t*)&tile[pix * 64 + c8 * 8];
    }

    // fused BN partial stats (fp32 accumulators)
#pragma unroll
    for (int nf = 0; nf < 4; ++nf) {
        float s = 0.f, s2 = 0.f;
#pragma unroll
        for (int mf = 0; mf < 4; ++mf)
#pragma unroll
            for (int k = 0; k < 4; ++k) {
                float v = acc[mf][nf][k];
                s += v; s2 += v * v;
            }
        s  += __shfl_xor(s, 16, 64);  s  += __shfl_xor(s, 32, 64);
        s2 += __shfl_xor(s2, 16, 64); s2 += __shfl_xor(s2, 32, 64);
        if (lg == 0) {
            int oc = nf * 16 + l15;
            atomicAdd(&sstat[oc], s);
            atomicAdd(&sstat[64 + oc], s2);
        }
    }
    __syncthreads();
    float* st = stats + (size_t)(blockIdx.x & 7) * 128;
    if (tid < 128) atomicAdd(&st[tid], sstat[tid]);
}

// ------------------------------------------------- NCHW fp32 -> NHWC bf16 (C=64)
__global__ void nchw_to_nhwc_bf16_kernel(const float* __restrict__ in,
                                         short* __restrict__ out, int HW)
{
    __shared__ short tile[64][66];
    int nchunks = HW >> 6;
    int b  = blockIdx.x / nchunks;
    int p0 = (blockIdx.x % nchunks) << 6;
    int tid = threadIdx.x;
#pragma unroll
    for (int rep = 0; rep < 16; ++rep) {
        int item = rep * 256 + tid;
        int c = item >> 6, p = item & 63;
        tile[p][c] = f_to_bf16(in[((size_t)b * 64 + c) * HW + p0 + p]);
    }
    __syncthreads();
#pragma unroll
    for (int rep = 0; rep < 16; ++rep) {
        int item = rep * 256 + tid;
        int p = item >> 6, c = item & 63;
        out[((size_t)b * HW + p0 + p) * 64 + c] = tile[p][c];
    }
}

// ------------------------------------------------- BN apply dual: NHWC bf16 in ->
// out0 NCHW fp32 + NHWC bf16
__global__ void bn_apply_dual_kernel(const short* __restrict__ in,
                                     const float* __restrict__ stats, // [8][128]
                                     float* __restrict__ out,         // NCHW fp32
                                     short* __restrict__ outh,        // NHWC bf16
                                     int HW, float invN)
{
    __shared__ float ftile[64][65];
    __shared__ float sm[64], sr[64];
    int nchunks = HW >> 6;
    int b  = blockIdx.x / nchunks;
    int p0 = (blockIdx.x % nchunks) << 6;
    int tid = threadIdx.x;
    if (tid < 64) {
        float s = 0.f, s2 = 0.f;
#pragma unroll
        for (int k = 0; k < 8; ++k) {
            s  += stats[k * 128 + tid];
            s2 += stats[k * 128 + 64 + tid];
        }
        float mean = s * invN;
        float var  = s2 * invN - mean * mean;
        sm[tid] = mean;
        sr[tid] = rsqrtf(var + 1e-5f);
    }
    __syncthreads();
#pragma unroll
    for (int it = 0; it < 2; ++it) {
        int item = it * 256 + tid;            // 512 groups = 64 px * 8
        int p = item >> 3, c0 = (item & 7) * 8;
        size_t gi = ((size_t)(b * HW + p0 + p)) * 64 + c0;
        bf16x8_t v = *(const bf16x8_t*)&in[gi];
        bf16x8_t o;
#pragma unroll
        for (int j = 0; j < 8; ++j) {
            float f = (bf16_to_f((unsigned short)v[j]) - sm[c0 + j]) * sr[c0 + j];
            f = f > 0.f ? f : 0.f;
            ftile[p][c0 + j] = f;
            o[j] = f_to_bf16(f);
        }
        *(bf16x8_t*)&outh[gi] = o;
    }
    __syncthreads();
#pragma unroll
    for (int rep = 0; rep < 16; ++rep) {
        int item = rep * 256 + tid;
        int c = item >> 6, p = item & 63;
        out[((size_t)b * 64 + c) * HW + p0 + p] = ftile[p][c];
    }
}

// ------------------------------------------------- x NCHW (C=3) -> NHWC4 fp32
__global__ void x_to_nhwc4_kernel(const float* __restrict__ in,
                                  float* __restrict__ out)
{
    int idx = blockIdx.x * TPB + threadIdx.x;
    const int HW = 640 * 640;
    if (idx >= 8 * HW) return;
    int b = idx / HW, p = idx % HW;
    f32x4_t v;
    v[0] = in[((size_t)b * 3 + 0) * HW + p];
    v[1] = in[((size_t)b * 3 + 1) * HW + p];
    v[2] = in[((size_t)b * 3 + 2) * HW + p];
    v[3] = 0.f;
    *(f32x4_t*)&out[(size_t)idx * 4] = v;
}

// ------------------------------------------------- offset2/3: MFMA conv, N=18
__global__ __launch_bounds__(256, 1) void offconv_mfma_kernel(
    const short* __restrict__ xh,
    const short* __restrict__ wt,    // [18][2][64][8] frag order, zero-padded
    const float* __restrict__ bias,
    float* __restrict__ out,
    int H, int W, int Ho, int Wo)
{
    const int HW = Ho * Wo;
    const int tid = threadIdx.x;
    const int wv = tid >> 6, l = tid & 63;
    const int l15 = l & 15, lg = l >> 4;
    const int pix0 = blockIdx.x * 64 + wv * 16;
    const int b = pix0 / HW;
    const int r0 = pix0 - b * HW;

    int rp = r0 + l15;
    int ho = rp / Wo, wo = rp % Wo;
    const short* xb = xh + (size_t)b * H * W * 64;

    f32x4_t acc[2];
    acc[0] = (f32x4_t){0.f, 0.f, 0.f, 0.f};
    acc[1] = (f32x4_t){0.f, 0.f, 0.f, 0.f};

#pragma unroll 2
    for (int kc = 0; kc < 18; ++kc) {
        int tap = kc >> 1;
        int iy = ho * 2 - 1 + tap / 3;
        int ix = wo * 2 - 1 + tap % 3;
        bf16x8_t af = {};
        if (iy >= 0 && iy < H && ix >= 0 && ix < W)
            af = *(const bf16x8_t*)&xb[((size_t)iy * W + ix) * 64
                                       + (kc & 1) * 32 + lg * 8];
#pragma unroll
        for (int nf = 0; nf < 2; ++nf) {
            bf16x8_t bf = *(const bf16x8_t*)(wt + (((size_t)(kc * 2 + nf)) * 64 + l) * 8);
            acc[nf] = __builtin_amdgcn_mfma_f32_16x16x32_bf16(af, bf, acc[nf], 0, 0, 0);
        }
    }

#pragma unroll
    for (int nf = 0; nf < 2; ++nf) {
        int oc = nf * 16 + l15;
        if (oc < 18) {
            float bv = bias[oc];
            f32x4_t v = acc[nf];
            v[0] += bv; v[1] += bv; v[2] += bv; v[3] += bv;
            *(f32x4_t*)&out[((size_t)(b * 18 + oc)) * HW + r0 + lg * 4] = v;
        }
    }
}

// ------------------------------------------------- deform1: fused offset1 +
// deform (C=3) + skip. Offsets computed in-block, numerically identical to
// the old standalone offset1 kernel (same FMA order; OOB taps add w*(+/-0)).
__global__ __launch_bounds__(256, 1) void deform1_kernel(
    const float* __restrict__ x4,   // [B][640][640][4] fp32
    const float* __restrict__ wof,  // (18,3,3,3) fp32
    const float* __restrict__ bof,  // (18,)
    const float* __restrict__ w,    // (64,3,3,3) fp32
    const float* __restrict__ bias, // b_d1
    const float* __restrict__ pool, // [B][3][25600] fp32
    const float* __restrict__ wsk,  // (64,3)
    const float* __restrict__ bsk,  // (64,)
    short* __restrict__ outh)       // NHWC bf16
{
    const int H = 640, W = 640, Ho = 160, Wo = 160, HW = 25600;
    constexpr int P = 32;
    __shared__ float xtap[P * 9][4];    // staged conv taps (fp32)
    __shared__ float swof[486];
    __shared__ float sbof[18];
    __shared__ float off1[P][18];
    __shared__ float samp[P][28];
    __shared__ int   sidx[P * 9][4];
    __shared__ float swt[P * 9][4];
    const int tid = threadIdx.x;
    const int pix0 = blockIdx.x * P;
    const int b = pix0 / HW;
    const int r0 = pix0 - b * HW;
    const float* xb = x4 + (size_t)b * H * W * 4;

    // 0a: stage 3x3 conv taps for 32 pixels (zero for OOB)
    for (int item = tid; item < P * 9; item += TPB) {
        int p = item / 9, tap = item % 9;
        int r = r0 + p, ho = r / Wo, wo = r % Wo;
        int iy = ho * 4 - 1 + tap / 3;
        int ix = wo * 4 - 1 + tap % 3;
        f32x4_t s = (f32x4_t){0.f, 0.f, 0.f, 0.f};
        if (iy >= 0 && iy < H && ix >= 0 && ix < W)
            s = *(const f32x4_t*)&xb[((size_t)iy * W + ix) * 4];
        *(f32x4_t*)xtap[item] = s;
    }
    // 0b: offset-conv weights to LDS
    for (int item = tid; item < 486; item += TPB) swof[item] = wof[item];
    if (tid < 18) sbof[tid] = bof[tid];
    __syncthreads();

    // 0c: offsets for 32 pixels x 18 channels (tap-outer, c-inner FMA order)
    for (int item = tid; item < P * 18; item += TPB) {
        int p = item / 18, o = item % 18;
        float acc = sbof[o];
#pragma unroll
        for (int tap = 0; tap < 9; ++tap) {
            const float* xt = xtap[p * 9 + tap];
#pragma unroll
            for (int c = 0; c < 3; ++c)
                acc += xt[c] * swof[(o * 3 + c) * 9 + tap];
        }
        off1[p][o] = acc;
    }
    __syncthreads();

    // 1: bilinear corners (clamped, zero weight when OOB)
    for (int item = tid; item < P * 9; item += TPB) {
        int p = item / 9, tap = item % 9;
        int r = r0 + p, ho = r / Wo, wo = r % Wo;
        float dy = off1[p][2 * tap];
        float dx = off1[p][2 * tap + 1];
        float ys = (float)(ho * 4 - 1 + tap / 3) + dy;
        float xs = (float)(wo * 4 - 1 + tap % 3) + dx;
        float y0f = floorf(ys), x0f = floorf(xs);
        float fy = ys - y0f, fx = xs - x0f;
        int y0 = (int)y0f, x0 = (int)x0f;
        float wts[4] = {(1.f - fy) * (1.f - fx), (1.f - fy) * fx,
                        fy * (1.f - fx),          fy * fx};
#pragma unroll
        for (int j = 0; j < 4; ++j) {
            int iy = y0 + (j >> 1), ix = x0 + (j & 1);
            bool v = (iy >= 0) && (iy < H) && (ix >= 0) && (ix < W);
            sidx[item][j] = v ? (iy * W + ix) : 0;
            swt[item][j]  = v ? wts[j] : 0.f;
        }
    }
    __syncthreads();

    // 2: branchless vector gather
    for (int item = tid; item < P * 9; item += TPB) {
        int p = item / 9, tap = item % 9;
        i32x4_t id4 = *(const i32x4_t*)sidx[item];
        f32x4_t w4  = *(const f32x4_t*)swt[item];
        f32x4_t a0 = *(const f32x4_t*)&xb[(size_t)(unsigned)id4[0] * 4];
        f32x4_t a1 = *(const f32x4_t*)&xb[(size_t)(unsigned)id4[1] * 4];
        f32x4_t a2 = *(const f32x4_t*)&xb[(size_t)(unsigned)id4[2] * 4];
        f32x4_t a3 = *(const f32x4_t*)&xb[(size_t)(unsigned)id4[3] * 4];
        samp[p][0 * 9 + tap] = w4[0]*a0[0] + w4[1]*a1[0] + w4[2]*a2[0] + w4[3]*a3[0];
        samp[p][1 * 9 + tap] = w4[0]*a0[1] + w4[1]*a1[1] + w4[2]*a2[1] + w4[3]*a3[1];
        samp[p][2 * 9 + tap] = w4[0]*a0[2] + w4[1]*a1[2] + w4[2]*a2[2] + w4[3]*a3[2];
    }
    __syncthreads();

    // 3: MAC, wave -> 8-pixel group, thread -> oc; fused skip branch
    int g = tid >> 6;
    int o = tid & 63;
    float acc[8];
#pragma unroll
    for (int pi = 0; pi < 8; ++pi) acc[pi] = bias[o] + bsk[o];
#pragma unroll
    for (int c = 0; c < 3; ++c)
#pragma unroll
        for (int k = 0; k < 9; ++k) {
            float wv = w[((size_t)(o * 3 + c)) * 9 + k];
#pragma unroll
            for (int pi = 0; pi < 8; ++pi)
                acc[pi] += wv * samp[g * 8 + pi][c * 9 + k];
        }
#pragma unroll
    for (int pi = 0; pi < 8; ++pi) {
        int r = r0 + g * 8 + pi;
        float sv = wsk[o * 3 + 0] * pool[(size_t)(b * 3 + 0) * HW + r]
                 + wsk[o * 3 + 1] * pool[(size_t)(b * 3 + 1) * HW + r]
                 + wsk[o * 3 + 2] * pool[(size_t)(b * 3 + 2) * HW + r];
        outh[((size_t)(b * HW + r)) * 64 + o] = f_to_bf16(acc[pi] + sv);
    }
}

// ------------------------------------------------- deform MFMA: C=64 -> O
template <int O>
__global__ __launch_bounds__(256, 1) void deform_mfma_kernel(
    const short* __restrict__ xh,
    const float* __restrict__ off,
    const short* __restrict__ wt,   // [18][O/16][64][8] frag order
    const float* __restrict__ bias,
    float* __restrict__ out,
    int H, int W, int Ho, int Wo, int stride)
{
    constexpr int NF = O / 64;
    constexpr int NFRAG = O / 16;
    constexpr int P  = 32;
    __shared__ alignas(16) short samp[P * 576];
    __shared__ int   sidx[P * 9][4];
    __shared__ float swt[P * 9][4];

    const int tid = threadIdx.x;
    const int HW = Ho * Wo;
    const int pix0 = blockIdx.x * P;
    const int b = pix0 / HW;
    const int r0 = pix0 - b * HW;

    for (int item = tid; item < P * 9; item += TPB) {
        int p = item / 9, tap = item % 9;
        int r = r0 + p, ho = r / Wo, wo = r % Wo;
        float dy = off[((size_t)(b * 18 + 2 * tap) * Ho + ho) * Wo + wo];
        float dx = off[((size_t)(b * 18 + 2 * tap + 1) * Ho + ho) * Wo + wo];
        float ys = (float)(ho * stride - 1 + tap / 3) + dy;
        float xs = (float)(wo * stride - 1 + tap % 3) + dx;
        float y0f = floorf(ys), x0f = floorf(xs);
        float fy = ys - y0f, fx = xs - x0f;
        int y0 = (int)y0f, x0 = (int)x0f;
        float wts[4] = {(1.f - fy) * (1.f - fx), (1.f - fy) * fx,
                        fy * (1.f - fx),          fy * fx};
#pragma unroll
        for (int j = 0; j < 4; ++j) {
            int iy = y0 + (j >> 1), ix = x0 + (j & 1);
            bool v = (iy >= 0) && (iy < H) && (ix >= 0) && (ix < W);
            sidx[item][j] = v ? (iy * W + ix) : 0;
            swt[item][j]  = v ? wts[j] : 0.f;
        }
    }
    __syncthreads();

    {
        const int grp = tid >> 4;
        const int ic  = (tid & 15) * 4;
        const short* xb = xh + (size_t)b * H * W * 64;
#pragma unroll 3
        for (int i = 0; i < 18; ++i) {
            int e = grp * 18 + i;
            int p = e / 9, tap = e % 9;
            i32x4_t id4 = *(const i32x4_t*)sidx[e];
            f32x4_t w4  = *(const f32x4_t*)swt[e];
            u16x4_t u0 = *(const u16x4_t*)&xb[(size_t)(unsigned)id4[0] * 64 + ic];
            u16x4_t u1 = *(const u16x4_t*)&xb[(size_t)(unsigned)id4[1] * 64 + ic];
            u16x4_t u2 = *(const u16x4_t*)&xb[(size_t)(unsigned)id4[2] * 64 + ic];
            u16x4_t u3 = *(const u16x4_t*)&xb[(size_t)(unsigned)id4[3] * 64 + ic];
            float v0 = w4[0]*bf16_to_f(u0[0]) + w4[1]*bf16_to_f(u1[0])
                     + w4[2]*bf16_to_f(u2[0]) + w4[3]*bf16_to_f(u3[0]);
            float v1 = w4[0]*bf16_to_f(u0[1]) + w4[1]*bf16_to_f(u1[1])
                     + w4[2]*bf16_to_f(u2[1]) + w4[3]*bf16_to_f(u3[1]);
            float v2 = w4[0]*bf16_to_f(u0[2]) + w4[1]*bf16_to_f(u1[2])
                     + w4[2]*bf16_to_f(u2[2]) + w4[3]*bf16_to_f(u3[2]);
            float v3 = w4[0]*bf16_to_f(u0[3]) + w4[1]*bf16_to_f(u1[3])
                     + w4[2]*bf16_to_f(u2[3]) + w4[3]*bf16_to_f(u3[3]);
            int sw = (tap * 8 + ((ic >> 3) ^ (p & 7))) * 8 + (ic & 7);
            short* dst = &samp[p * 576 + sw];
            dst[0] = f_to_bf16(v0);
            dst[1] = f_to_bf16(v1);
            dst[2] = f_to_bf16(v2);
            dst[3] = f_to_bf16(v3);
        }
    }
    __syncthreads();

    const int wv = tid >> 6;
    const int l  = tid & 63;
    const int l15 = l & 15, lg = l >> 4;
    f32x4_t acc[2][NF];
#pragma unroll
    for (int mf = 0; mf < 2; ++mf)
#pragma unroll
        for (int nf = 0; nf < NF; ++nf)
            acc[mf][nf] = (f32x4_t){0.f, 0.f, 0.f, 0.f};

#pragma unroll 2
    for (int kc = 0; kc < 18; ++kc) {
        int tap = kc >> 1;
        int low = (((kc & 1) << 2) | lg) ^ (l15 & 7);
        bf16x8_t af0 = *(const bf16x8_t*)&samp[l15 * 576 + (tap * 8 + low) * 8];
        bf16x8_t af1 = *(const bf16x8_t*)&samp[(l15 + 16) * 576 + (tap * 8 + low) * 8];
#pragma unroll
        for (int nf = 0; nf < NF; ++nf) {
            int ocf = wv * NF + nf;
            bf16x8_t bf = *(const bf16x8_t*)(wt + (((size_t)(kc * NFRAG + ocf)) * 64 + l) * 8);
            acc[0][nf] = __builtin_amdgcn_mfma_f32_16x16x32_bf16(af0, bf, acc[0][nf], 0, 0, 0);
            acc[1][nf] = __builtin_amdgcn_mfma_f32_16x16x32_bf16(af1, bf, acc[1][nf], 0, 0, 0);
        }
    }

#pragma unroll
    for (int mf = 0; mf < 2; ++mf)
#pragma unroll
        for (int nf = 0; nf < NF; ++nf) {
            int oc = (wv * NF + nf) * 16 + l15;
            float bv = bias[oc];
            f32x4_t v = acc[mf][nf];
            v[0] += bv; v[1] += bv; v[2] += bv; v[3] += bv;
            *(f32x4_t*)&out[((size_t)(b * O + oc)) * HW + r0 + mf * 16 + lg * 4] = v;
        }
}

// ---------------------------------------------------------------- avgpool 4x4
__global__ void avgpool4_kernel(const float* __restrict__ in,
                                float* __restrict__ out,
                                int BC, int Ho, int Wo, int H, int W)
{
    int idx = blockIdx.x * TPB + threadIdx.x;
    int total = BC * Ho * Wo;
    if (idx >= total) return;
    int wo = idx % Wo;
    int t = idx / Wo;
    int ho = t % Ho;
    int bc = t / Ho;
    const float* xp = in + (size_t)bc * H * W + (ho * 4) * W + wo * 4;
    float s = 0.f;
#pragma unroll
    for (int i = 0; i < 4; ++i)
#pragma unroll
        for (int j = 0; j < 4; ++j)
            s += xp[i * W + j];
    out[idx] = s * (1.0f / 16.0f);
}

__global__ void zero_stats_kernel(float* __restrict__ stats)
{
    int i = threadIdx.x;
#pragma unroll
    for (int k = 0; k < 8; ++k) stats[k * 256 + i] = 0.f;
    stats[2048 + i] = 0.f;          // zero page (512 floats)
    stats[2048 + 256 + i] = 0.f;
}

// ---------------------------------------------------------------- launch
extern "C" void kernel_launch(void* const* d_in, const int* in_sizes, int n_in,
                              void* d_out, int out_size, void* d_ws, size_t ws_size,
                              hipStream_t stream)
{
    const float* x      = (const float*)d_in[0];
    const float* w_off1 = (const float*)d_in[1];
    const float* b_off1 = (const float*)d_in[2];
    const float* w_d1   = (const float*)d_in[3];
    const float* b_d1   = (const float*)d_in[4];
    const float* w_skip = (const float*)d_in[5];
    const float* b_skip = (const float*)d_in[6];
    const float* w_bl1  = (const float*)d_in[7];
    const float* w_bl2  = (const float*)d_in[8];
    const float* w_off2 = (const float*)d_in[9];
    const float* b_off2 = (const float*)d_in[10];
    const float* w_d2   = (const float*)d_in[11];
    const float* b_d2   = (const float*)d_in[12];
    const float* w_off3 = (const float*)d_in[13];
    const float* b_off3 = (const float*)d_in[14];
    const float* w_d3   = (const float*)d_in[15];
    const float* b_d3   = (const float*)d_in[16];

    const int B = 8;
    float* A     = (float*)d_ws;          // 3,686,400 floats
    float* bufB  = A + 3686400;           // 13,107,200 floats
    float* bufC  = bufB + 13107200;       // 13,107,200 floats

    short* hB   = (short*)bufB;
    short* hC   = (short*)bufC;
    float* pool = bufB + 8000000;

    // frag-ordered weights + stats + zero page inside A (above all later
    // A writes: offset2 = 921,600 fl, offset3 = 230,400 fl)
    short* wt1    = (short*)(A + 1000000);
    short* wt2    = wt1 + 18 * 4 * 512;
    short* wtd2   = (short*)(A + 1500000);
    short* wtd3   = (short*)(A + 1550000);
    short* wtoff2 = (short*)(A + 1700000);
    short* wtoff3 = (short*)(A + 1712000);
    float* stats1 = A + 1800000;          // [8][128]
    float* stats2 = stats1 + 1024;        // [8][128]
    float* zpage  = stats1 + 2048;        // 512 floats (2KB zeros)

    float* out0 = (float*)d_out;
    float* out1 = out0 + 13107200;
    float* out2 = out1 + 3276800;

    const float invN = 1.0f / (B * 25600);

    // 0) x -> NHWC4 fp32 into bufC
    x_to_nhwc4_kernel<<<(8 * 409600 + TPB - 1) / TPB, TPB, 0, stream>>>(x, bufC);

    // 1) pool = avgpool4(x) -> bufB+8M
    avgpool4_kernel<<<(B * 3 * 25600 + TPB - 1) / TPB, TPB, 0, stream>>>(
        x, pool, B * 3, 160, 160, 640, 640);

    // 2) repack weights + zero stats & zero page
    repack_frag_kernel<<<(18 * 4 * 512 + TPB - 1) / TPB, TPB, 0, stream>>>(w_bl1, wt1, 64, 4);
    repack_frag_kernel<<<(18 * 4 * 512 + TPB - 1) / TPB, TPB, 0, stream>>>(w_bl2, wt2, 64, 4);
    repack_frag_kernel<<<(18 * 4 * 512 + TPB - 1) / TPB, TPB, 0, stream>>>(w_d2, wtd2, 64, 4);
    repack_frag_kernel<<<(18 * 16 * 512 + TPB - 1) / TPB, TPB, 0, stream>>>(w_d3, wtd3, 256, 16);
    repack_frag_kernel<<<(18 * 2 * 512 + TPB - 1) / TPB, TPB, 0, stream>>>(w_off2, wtoff2, 18, 2);
    repack_frag_kernel<<<(18 * 2 * 512 + TPB - 1) / TPB, TPB, 0, stream>>>(w_off3, wtoff3, 18, 2);
    zero_stats_kernel<<<1, 256, 0, stream>>>(stats1);

    // 3) deform1 (fused offset1 + skip): x4 -> hB bf16 NHWC
    deform1_kernel<<<8 * 25600 / 32, TPB, 0, stream>>>(
        bufC, w_off1, b_off1, w_d1, b_d1, pool, w_skip, b_skip, hB);

    // 4) conv1 (raw): hB -> hC bf16 NHWC (+stats1). x4 in bufC dead.
    conv3x3_mfma_kernel<0><<<800, TPB, 0, stream>>>(
        hB, wt1, hC, stats1, nullptr, invN, zpage);

    // 5) conv2 (normalizes input with stats1): hC -> hB bf16 NHWC (+stats2)
    conv3x3_mfma_kernel<1><<<800, TPB, 0, stream>>>(
        hC, wt2, hB, stats2, stats1, invN, zpage);

    // 6) apply2: hB -> out0 fp32 NCHW + hC bf16 NHWC (feat4)
    bn_apply_dual_kernel<<<8 * 400, TPB, 0, stream>>>(
        hB, stats2, out0, hC, 25600, invN);

    // 7) offset2 = offconv(feat4 hC) -> A
    offconv_mfma_kernel<<<8 * 6400 / 64, TPB, 0, stream>>>(
        hC, wtoff2, b_off2, A, 160, 160, 80, 80);

    // 8) feat_1_8 = deform2(feat4 hC, offset2) -> out1
    deform_mfma_kernel<64><<<8 * 6400 / 32, TPB, 0, stream>>>(
        hC, A, wtd2, b_d2, out1, 160, 160, 80, 80, 2);

    // 9) feat_1_8 -> NHWC bf16 into hB
    nchw_to_nhwc_bf16_kernel<<<8 * (6400 / 64), TPB, 0, stream>>>(out1, hB, 6400);

    // 10) offset3 = offconv(feat8 hB) -> A
    offconv_mfma_kernel<<<8 * 1600 / 64, TPB, 0, stream>>>(
        hB, wtoff3, b_off3, A, 80, 80, 40, 40);

    // 11) feat_1_16 = deform3(feat8 hB, offset3) -> out2
    deform_mfma_kernel<256><<<8 * 1600 / 32, TPB, 0, stream>>>(
        hB, A, wtd3, b_d3, out2, 80, 80, 40, 40, 2);
}

// Round 16
// 237.997 us; speedup vs baseline: 30.1466x; 1.0310x over previous
//
#include <hip/hip_runtime.h>
#include <hip/hip_bf16.h>
#include <math.h>

#define TPB 256

typedef __attribute__((ext_vector_type(8))) short bf16x8_t;
typedef __attribute__((ext_vector_type(4))) float f32x4_t;
typedef __attribute__((ext_vector_type(4))) int i32x4_t;
typedef __attribute__((ext_vector_type(4))) unsigned short u16x4_t;

static __device__ __forceinline__ float bf16_to_f(unsigned short s) {
    union { unsigned u; float f; } cv;
    cv.u = ((unsigned)s) << 16;
    return cv.f;
}
static __device__ __forceinline__ short f_to_bf16(float v) {
    __hip_bfloat16 h = __float2bfloat16(v);
    return *(short*)&h;
}

// ------------------------------------------------- weight repack, FRAGMENT order
__global__ void repack_frag_kernel(const float* __restrict__ w,
                                   short* __restrict__ wtf,
                                   int Oreal, int NFRAG)
{
    int idx = blockIdx.x * TPB + threadIdx.x;
    int total = 18 * NFRAG * 64 * 8;
    if (idx >= total) return;
    int j    = idx & 7;
    int lane = (idx >> 3) & 63;
    int t    = idx >> 9;
    int ocf  = t % NFRAG;
    int kc   = t / NFRAG;
    int oc   = ocf * 16 + (lane & 15);
    int tap  = kc >> 1;
    int ic   = (kc & 1) * 32 + (lane >> 4) * 8 + j;
    float v = 0.f;
    if (oc < Oreal)
        v = w[((size_t)(oc * 64 + ic)) * 9 + tap];
    wtf[idx] = f_to_bf16(v);
}

// ------------------------------------------------- deform1 weight repack
// w_d1 (64,3,3,3) -> [4 ocf][64 lane][8] bf16, K = c*9+tap padded 27->32
__global__ void repack_d1_kernel(const float* __restrict__ w,
                                 short* __restrict__ wtf)
{
    int idx = blockIdx.x * TPB + threadIdx.x;
    if (idx >= 2048) return;
    int j    = idx & 7;
    int lane = (idx >> 3) & 63;
    int ocf  = idx >> 9;
    int oc   = ocf * 16 + (lane & 15);
    int k    = (lane >> 4) * 8 + j;       // 0..31
    float v = 0.f;
    if (k < 27) v = w[(size_t)oc * 27 + k];   // k = c*9 + tap
    wtf[idx] = f_to_bf16(v);
}

// ------------------------------------------------- MFMA conv 3x3 (64->64, s1)
template <int NORM>
__global__ __launch_bounds__(256, 2) void conv3x3_mfma_kernel(
    const short* __restrict__ xh,
    const short* __restrict__ wt,      // [18][4][64][8] frag order
    short* __restrict__ outh,          // bf16 NHWC
    float* __restrict__ stats,         // [8][128]
    const float* __restrict__ stats_in,// [8][128] (NORM only)
    float invN,
    const float* __restrict__ zp)      // 2KB zero page
{
    __shared__ short tile[2816 * 8];
    __shared__ float sstat[128];
    __shared__ float sm[64], sr[64];
    const int H = 160, W = 160, HW = 25600;
    int blk = blockIdx.x;
    int b  = blk / 100;
    int r  = blk % 100;
    int y0 = (r / 10) * 16;
    int x0 = (r % 10) * 16;
    const int tid = threadIdx.x;
    const short* inb = xh + (size_t)b * HW * 64;

    if (tid < 128) sstat[tid] = 0.f;
    if (NORM) {
        if (tid < 64) {
            float s = 0.f, s2 = 0.f;
#pragma unroll
            for (int k = 0; k < 8; ++k) {
                s  += stats_in[k * 128 + tid];
                s2 += stats_in[k * 128 + 64 + tid];
            }
            float mean = s * invN;
            float var  = s2 * invN - mean * mean;
            sm[tid] = mean;
            sr[tid] = rsqrtf(var + 1e-5f);
        }
        __syncthreads();
    }

#pragma unroll
    for (int it = 0; it < 11; ++it) {
        int item = it * 256 + tid;
        int c8  = item & 7;
        int pix = item >> 3;
        int row = pix / 18;
        int col = pix - row * 18;
        int y = y0 + row - 1;
        int x = x0 + col - 1;
        bool ok = (pix < 324) & (y >= 0) & (y < H) & (x >= 0) & (x < W);
        int cs = c8 ^ (col & 7);
        const short* src = ok
            ? &inb[((size_t)y * W + x) * 64 + (cs << 3)]
            : (const short*)zp;
        bf16x8_t v = *(const bf16x8_t*)src;
        if (NORM) {
            int cs8 = cs << 3;
            bf16x8_t o;
#pragma unroll
            for (int j = 0; j < 8; ++j) {
                float f = (bf16_to_f((unsigned short)v[j]) - sm[cs8 + j]) * sr[cs8 + j];
                f = f > 0.f ? f : 0.f;
                o[j] = ok ? f_to_bf16(f) : (short)0;
            }
            v = o;
        }
        *(bf16x8_t*)&tile[item * 8] = v;
    }
    __syncthreads();

    const int wv  = tid >> 6;
    const int l   = tid & 63;
    const int l15 = l & 15;
    const int lg  = l >> 4;

    f32x4_t acc[4][4];
#pragma unroll
    for (int i = 0; i < 4; ++i)
#pragma unroll
        for (int j = 0; j < 4; ++j)
            acc[i][j] = (f32x4_t){0.f, 0.f, 0.f, 0.f};

    bf16x8_t bfp[2][4], afp[2][4];
#pragma unroll
    for (int nf = 0; nf < 4; ++nf)
        bfp[0][nf] = *(const bf16x8_t*)(wt + (((size_t)(0 * 4 + nf)) * 64 + l) * 8);
    {
        int colr = l15;
        int chunk = lg ^ (colr & 7);
#pragma unroll
        for (int mf = 0; mf < 4; ++mf)
            afp[0][mf] = *(const bf16x8_t*)&tile[((wv * 4 + mf) * 18 + colr) * 64 + chunk * 8];
    }
#pragma unroll
    for (int kc = 0; kc < 18; ++kc) {
        const int cur = kc & 1, nxt = cur ^ 1;
        if (kc + 1 < 18) {
            int kn = kc + 1;
#pragma unroll
            for (int nf = 0; nf < 4; ++nf)
                bfp[nxt][nf] = *(const bf16x8_t*)(wt + (((size_t)(kn * 4 + nf)) * 64 + l) * 8);
            int tap = kn >> 1;
            int dy = tap / 3, dx = tap % 3;
            int colr = l15 + dx;
            int chunk = (((kn & 1) << 2) + lg) ^ (colr & 7);
#pragma unroll
            for (int mf = 0; mf < 4; ++mf)
                afp[nxt][mf] = *(const bf16x8_t*)&tile[((wv * 4 + mf + dy) * 18 + colr) * 64 + chunk * 8];
        }
#pragma unroll
        for (int mf = 0; mf < 4; ++mf)
#pragma unroll
            for (int nf = 0; nf < 4; ++nf)
                acc[mf][nf] = __builtin_amdgcn_mfma_f32_16x16x32_bf16(
                    afp[cur][mf], bfp[cur][nf], acc[mf][nf], 0, 0, 0);
    }

    __syncthreads();
#pragma unroll
    for (int mf = 0; mf < 4; ++mf) {
        int py = wv * 4 + mf;
#pragma unroll
        for (int nf = 0; nf < 4; ++nf) {
            int oc = nf * 16 + l15;
#pragma unroll
            for (int k = 0; k < 4; ++k)
                tile[((py * 16) + lg * 4 + k) * 64 + oc] = f_to_bf16(acc[mf][nf][k]);
        }
    }
    __syncthreads();
    short* outb = outh + (size_t)b * HW * 64;
#pragma unroll
    for (int j = 0; j < 8; ++j) {
        int item = j * 256 + tid;
        int c8  = item & 7;
        int pix = item >> 3;
        int py  = pix >> 4, px = pix & 15;
        *(bf16x8_t*)&outb[((size_t)(y0 + py) * W + x0 + px) * 64 + c8 * 8] =
            *(bf16x8_t*)&tile[pix * 64 + c8 * 8];
    }

#pragma unroll
    for (int nf = 0; nf < 4; ++nf) {
        float s = 0.f, s2 = 0.f;
#pragma unroll
        for (int mf = 0; mf < 4; ++mf)
#pragma unroll
            for (int k = 0; k < 4; ++k) {
                float v = acc[mf][nf][k];
                s += v; s2 += v * v;
            }
        s  += __shfl_xor(s, 16, 64);  s  += __shfl_xor(s, 32, 64);
        s2 += __shfl_xor(s2, 16, 64); s2 += __shfl_xor(s2, 32, 64);
        if (lg == 0) {
            int oc = nf * 16 + l15;
            atomicAdd(&sstat[oc], s);
            atomicAdd(&sstat[64 + oc], s2);
        }
    }
    __syncthreads();
    float* st = stats + (size_t)(blockIdx.x & 7) * 128;
    if (tid < 128) atomicAdd(&st[tid], sstat[tid]);
}

// ------------------------------------------------- NCHW fp32 -> NHWC bf16 (C=64)
__global__ void nchw_to_nhwc_bf16_kernel(const float* __restrict__ in,
                                         short* __restrict__ out, int HW)
{
    __shared__ short tile[64][66];
    int nchunks = HW >> 6;
    int b  = blockIdx.x / nchunks;
    int p0 = (blockIdx.x % nchunks) << 6;
    int tid = threadIdx.x;
#pragma unroll
    for (int rep = 0; rep < 16; ++rep) {
        int item = rep * 256 + tid;
        int c = item >> 6, p = item & 63;
        tile[p][c] = f_to_bf16(in[((size_t)b * 64 + c) * HW + p0 + p]);
    }
    __syncthreads();
#pragma unroll
    for (int rep = 0; rep < 16; ++rep) {
        int item = rep * 256 + tid;
        int p = item >> 6, c = item & 63;
        out[((size_t)b * HW + p0 + p) * 64 + c] = tile[p][c];
    }
}

// ------------------------------------------------- BN apply dual
__global__ void bn_apply_dual_kernel(const short* __restrict__ in,
                                     const float* __restrict__ stats,
                                     float* __restrict__ out,
                                     short* __restrict__ outh,
                                     int HW, float invN)
{
    __shared__ float ftile[64][65];
    __shared__ float sm[64], sr[64];
    int nchunks = HW >> 6;
    int b  = blockIdx.x / nchunks;
    int p0 = (blockIdx.x % nchunks) << 6;
    int tid = threadIdx.x;
    if (tid < 64) {
        float s = 0.f, s2 = 0.f;
#pragma unroll
        for (int k = 0; k < 8; ++k) {
            s  += stats[k * 128 + tid];
            s2 += stats[k * 128 + 64 + tid];
        }
        float mean = s * invN;
        float var  = s2 * invN - mean * mean;
        sm[tid] = mean;
        sr[tid] = rsqrtf(var + 1e-5f);
    }
    __syncthreads();
#pragma unroll
    for (int it = 0; it < 2; ++it) {
        int item = it * 256 + tid;
        int p = item >> 3, c0 = (item & 7) * 8;
        size_t gi = ((size_t)(b * HW + p0 + p)) * 64 + c0;
        bf16x8_t v = *(const bf16x8_t*)&in[gi];
        bf16x8_t o;
#pragma unroll
        for (int j = 0; j < 8; ++j) {
            float f = (bf16_to_f((unsigned short)v[j]) - sm[c0 + j]) * sr[c0 + j];
            f = f > 0.f ? f : 0.f;
            ftile[p][c0 + j] = f;
            o[j] = f_to_bf16(f);
        }
        *(bf16x8_t*)&outh[gi] = o;
    }
    __syncthreads();
#pragma unroll
    for (int rep = 0; rep < 16; ++rep) {
        int item = rep * 256 + tid;
        int c = item >> 6, p = item & 63;
        out[((size_t)b * 64 + c) * HW + p0 + p] = ftile[p][c];
    }
}

// ------------------------------------------------- x NCHW (C=3) -> NHWC4 fp32
__global__ void x_to_nhwc4_kernel(const float* __restrict__ in,
                                  float* __restrict__ out)
{
    int idx = blockIdx.x * TPB + threadIdx.x;
    const int HW = 640 * 640;
    if (idx >= 8 * HW) return;
    int b = idx / HW, p = idx % HW;
    f32x4_t v;
    v[0] = in[((size_t)b * 3 + 0) * HW + p];
    v[1] = in[((size_t)b * 3 + 1) * HW + p];
    v[2] = in[((size_t)b * 3 + 2) * HW + p];
    v[3] = 0.f;
    *(f32x4_t*)&out[(size_t)idx * 4] = v;
}

// ------------------------------------------------- offset2/3: MFMA conv, N=18
__global__ __launch_bounds__(256, 1) void offconv_mfma_kernel(
    const short* __restrict__ xh,
    const short* __restrict__ wt,
    const float* __restrict__ bias,
    float* __restrict__ out,
    int H, int W, int Ho, int Wo)
{
    const int HW = Ho * Wo;
    const int tid = threadIdx.x;
    const int wv = tid >> 6, l = tid & 63;
    const int l15 = l & 15, lg = l >> 4;
    const int pix0 = blockIdx.x * 64 + wv * 16;
    const int b = pix0 / HW;
    const int r0 = pix0 - b * HW;

    int rp = r0 + l15;
    int ho = rp / Wo, wo = rp % Wo;
    const short* xb = xh + (size_t)b * H * W * 64;

    f32x4_t acc[2];
    acc[0] = (f32x4_t){0.f, 0.f, 0.f, 0.f};
    acc[1] = (f32x4_t){0.f, 0.f, 0.f, 0.f};

#pragma unroll 2
    for (int kc = 0; kc < 18; ++kc) {
        int tap = kc >> 1;
        int iy = ho * 2 - 1 + tap / 3;
        int ix = wo * 2 - 1 + tap % 3;
        bf16x8_t af = {};
        if (iy >= 0 && iy < H && ix >= 0 && ix < W)
            af = *(const bf16x8_t*)&xb[((size_t)iy * W + ix) * 64
                                       + (kc & 1) * 32 + lg * 8];
#pragma unroll
        for (int nf = 0; nf < 2; ++nf) {
            bf16x8_t bf = *(const bf16x8_t*)(wt + (((size_t)(kc * 2 + nf)) * 64 + l) * 8);
            acc[nf] = __builtin_amdgcn_mfma_f32_16x16x32_bf16(af, bf, acc[nf], 0, 0, 0);
        }
    }

#pragma unroll
    for (int nf = 0; nf < 2; ++nf) {
        int oc = nf * 16 + l15;
        if (oc < 18) {
            float bv = bias[oc];
            f32x4_t v = acc[nf];
            v[0] += bv; v[1] += bv; v[2] += bv; v[3] += bv;
            *(f32x4_t*)&out[((size_t)(b * 18 + oc)) * HW + r0 + lg * 4] = v;
        }
    }
}

// ------------------------------------------------- deform1: fused offset1 +
// deform (C=3, MFMA MAC) + skip. Offsets bit-identical to standalone kernel.
__global__ __launch_bounds__(256, 1) void deform1_kernel(
    const float* __restrict__ x4,   // [B][640][640][4] fp32
    const float* __restrict__ wof,  // (18,3,3,3) fp32
    const float* __restrict__ bof,  // (18,)
    const short* __restrict__ wtd1, // [4][64][8] bf16 frag order (K=27 pad 32)
    const float* __restrict__ bias, // b_d1
    const float* __restrict__ pool, // [B][3][25600] fp32
    const float* __restrict__ wsk,  // (64,3)
    const float* __restrict__ bsk,  // (64,)
    short* __restrict__ outh)       // NHWC bf16
{
    const int H = 640, W = 640, Ho = 160, Wo = 160, HW = 25600;
    constexpr int P = 32;
    __shared__ float xtap[P * 9][4];    // reused as output tile in epilogue
    __shared__ float swof[486];
    __shared__ float sbof[18];
    __shared__ float spool[3][P];
    __shared__ float off1[P][18];
    __shared__ alignas(16) short sampb[P][40];  // bf16, K padded 27->32
    __shared__ int   sidx[P * 9][4];
    __shared__ float swt[P * 9][4];
    const int tid = threadIdx.x;
    const int pix0 = blockIdx.x * P;
    const int b = pix0 / HW;
    const int r0 = pix0 - b * HW;
    const float* xb = x4 + (size_t)b * H * W * 4;

    // 0a: stage conv taps (zero for OOB) + zero sampb + stage pool
    for (int item = tid; item < P * 9; item += TPB) {
        int p = item / 9, tap = item % 9;
        int r = r0 + p, ho = r / Wo, wo = r % Wo;
        int iy = ho * 4 - 1 + tap / 3;
        int ix = wo * 4 - 1 + tap % 3;
        f32x4_t s = (f32x4_t){0.f, 0.f, 0.f, 0.f};
        if (iy >= 0 && iy < H && ix >= 0 && ix < W)
            s = *(const f32x4_t*)&xb[((size_t)iy * W + ix) * 4];
        *(f32x4_t*)xtap[item] = s;
    }
    for (int i = tid; i < P * 40; i += TPB) ((short*)sampb)[i] = 0;
    for (int i = tid; i < 96; i += TPB) {
        int c = i >> 5, p = i & 31;
        spool[c][p] = pool[((size_t)(b * 3 + c)) * HW + r0 + p];
    }
    for (int item = tid; item < 486; item += TPB) swof[item] = wof[item];
    if (tid < 18) sbof[tid] = bof[tid];
    __syncthreads();

    // 0c: offsets (same FMA order as original standalone offset1 kernel)
    for (int item = tid; item < P * 18; item += TPB) {
        int p = item / 18, o = item % 18;
        float acc = sbof[o];
#pragma unroll
        for (int tap = 0; tap < 9; ++tap) {
            const float* xt = xtap[p * 9 + tap];
#pragma unroll
            for (int c = 0; c < 3; ++c)
                acc += xt[c] * swof[(o * 3 + c) * 9 + tap];
        }
        off1[p][o] = acc;
    }
    __syncthreads();

    // 1: bilinear corners (clamped, zero weight when OOB)
    for (int item = tid; item < P * 9; item += TPB) {
        int p = item / 9, tap = item % 9;
        int r = r0 + p, ho = r / Wo, wo = r % Wo;
        float dy = off1[p][2 * tap];
        float dx = off1[p][2 * tap + 1];
        float ys = (float)(ho * 4 - 1 + tap / 3) + dy;
        float xs = (float)(wo * 4 - 1 + tap % 3) + dx;
        float y0f = floorf(ys), x0f = floorf(xs);
        float fy = ys - y0f, fx = xs - x0f;
        int y0 = (int)y0f, x0 = (int)x0f;
        float wts[4] = {(1.f - fy) * (1.f - fx), (1.f - fy) * fx,
                        fy * (1.f - fx),          fy * fx};
#pragma unroll
        for (int j = 0; j < 4; ++j) {
            int iy = y0 + (j >> 1), ix = x0 + (j & 1);
            bool v = (iy >= 0) && (iy < H) && (ix >= 0) && (ix < W);
            sidx[item][j] = v ? (iy * W + ix) : 0;
            swt[item][j]  = v ? wts[j] : 0.f;
        }
    }
    __syncthreads();

    // 2: branchless vector gather -> bf16 samples, K index = c*9+tap
    for (int item = tid; item < P * 9; item += TPB) {
        int p = item / 9, tap = item % 9;
        i32x4_t id4 = *(const i32x4_t*)sidx[item];
        f32x4_t w4  = *(const f32x4_t*)swt[item];
        f32x4_t a0 = *(const f32x4_t*)&xb[(size_t)(unsigned)id4[0] * 4];
        f32x4_t a1 = *(const f32x4_t*)&xb[(size_t)(unsigned)id4[1] * 4];
        f32x4_t a2 = *(const f32x4_t*)&xb[(size_t)(unsigned)id4[2] * 4];
        f32x4_t a3 = *(const f32x4_t*)&xb[(size_t)(unsigned)id4[3] * 4];
        sampb[p][0 * 9 + tap] = f_to_bf16(
            w4[0]*a0[0] + w4[1]*a1[0] + w4[2]*a2[0] + w4[3]*a3[0]);
        sampb[p][1 * 9 + tap] = f_to_bf16(
            w4[0]*a0[1] + w4[1]*a1[1] + w4[2]*a2[1] + w4[3]*a3[1]);
        sampb[p][2 * 9 + tap] = f_to_bf16(
            w4[0]*a0[2] + w4[1]*a1[2] + w4[2]*a2[2] + w4[3]*a3[2]);
    }
    __syncthreads();

    // 3: MFMA MAC — M=32 px, N=64 oc, K=32 (27 real)
    const int wv = tid >> 6;
    const int l  = tid & 63;
    const int l15 = l & 15, lg = l >> 4;
    bf16x8_t bf  = *(const bf16x8_t*)(wtd1 + (((size_t)wv * 64 + l)) * 8);
    bf16x8_t af0 = *(const bf16x8_t*)&sampb[l15][lg * 8];
    bf16x8_t af1 = *(const bf16x8_t*)&sampb[l15 + 16][lg * 8];
    f32x4_t z = (f32x4_t){0.f, 0.f, 0.f, 0.f};
    f32x4_t acc0 = __builtin_amdgcn_mfma_f32_16x16x32_bf16(af0, bf, z, 0, 0, 0);
    f32x4_t acc1 = __builtin_amdgcn_mfma_f32_16x16x32_bf16(af1, bf, z, 0, 0, 0);

    // epilogue: bias + skip, pack via LDS (reuse xtap), coalesced NHWC store
    int oc = wv * 16 + l15;
    float bb = bias[oc] + bsk[oc];
    float w0 = wsk[oc * 3 + 0], w1 = wsk[oc * 3 + 1], w2 = wsk[oc * 3 + 2];
    short* otile = (short*)xtap;        // 32*64 bf16 = 4KB, xtap dead
    __syncthreads();                    // all MFMA inputs consumed
#pragma unroll
    for (int mf = 0; mf < 2; ++mf) {
        f32x4_t a = mf ? acc1 : acc0;
#pragma unroll
        for (int k = 0; k < 4; ++k) {
            int px = mf * 16 + lg * 4 + k;
            float sv = w0 * spool[0][px] + w1 * spool[1][px] + w2 * spool[2][px];
            otile[px * 64 + oc] = f_to_bf16(a[k] + bb + sv);
        }
    }
    __syncthreads();
    {
        int c8 = tid & 7, px = tid >> 3;
        *(bf16x8_t*)&outh[((size_t)(b * HW + r0 + px)) * 64 + c8 * 8] =
            *(bf16x8_t*)&otile[px * 64 + c8 * 8];
    }
}

// ------------------------------------------------- deform MFMA: C=64 -> O
template <int O>
__global__ __launch_bounds__(256, 1) void deform_mfma_kernel(
    const short* __restrict__ xh,
    const float* __restrict__ off,
    const short* __restrict__ wt,
    const float* __restrict__ bias,
    float* __restrict__ out,
    int H, int W, int Ho, int Wo, int stride)
{
    constexpr int NF = O / 64;
    constexpr int NFRAG = O / 16;
    constexpr int P  = 32;
    __shared__ alignas(16) short samp[P * 576];
    __shared__ int   sidx[P * 9][4];
    __shared__ float swt[P * 9][4];

    const int tid = threadIdx.x;
    const int HW = Ho * Wo;
    const int pix0 = blockIdx.x * P;
    const int b = pix0 / HW;
    const int r0 = pix0 - b * HW;

    for (int item = tid; item < P * 9; item += TPB) {
        int p = item / 9, tap = item % 9;
        int r = r0 + p, ho = r / Wo, wo = r % Wo;
        float dy = off[((size_t)(b * 18 + 2 * tap) * Ho + ho) * Wo + wo];
        float dx = off[((size_t)(b * 18 + 2 * tap + 1) * Ho + ho) * Wo + wo];
        float ys = (float)(ho * stride - 1 + tap / 3) + dy;
        float xs = (float)(wo * stride - 1 + tap % 3) + dx;
        float y0f = floorf(ys), x0f = floorf(xs);
        float fy = ys - y0f, fx = xs - x0f;
        int y0 = (int)y0f, x0 = (int)x0f;
        float wts[4] = {(1.f - fy) * (1.f - fx), (1.f - fy) * fx,
                        fy * (1.f - fx),          fy * fx};
#pragma unroll
        for (int j = 0; j < 4; ++j) {
            int iy = y0 + (j >> 1), ix = x0 + (j & 1);
            bool v = (iy >= 0) && (iy < H) && (ix >= 0) && (ix < W);
            sidx[item][j] = v ? (iy * W + ix) : 0;
            swt[item][j]  = v ? wts[j] : 0.f;
        }
    }
    __syncthreads();

    {
        const int grp = tid >> 4;
        const int ic  = (tid & 15) * 4;
        const short* xb = xh + (size_t)b * H * W * 64;
#pragma unroll 3
        for (int i = 0; i < 18; ++i) {
            int e = grp * 18 + i;
            int p = e / 9, tap = e % 9;
            i32x4_t id4 = *(const i32x4_t*)sidx[e];
            f32x4_t w4  = *(const f32x4_t*)swt[e];
            u16x4_t u0 = *(const u16x4_t*)&xb[(size_t)(unsigned)id4[0] * 64 + ic];
            u16x4_t u1 = *(const u16x4_t*)&xb[(size_t)(unsigned)id4[1] * 64 + ic];
            u16x4_t u2 = *(const u16x4_t*)&xb[(size_t)(unsigned)id4[2] * 64 + ic];
            u16x4_t u3 = *(const u16x4_t*)&xb[(size_t)(unsigned)id4[3] * 64 + ic];
            float v0 = w4[0]*bf16_to_f(u0[0]) + w4[1]*bf16_to_f(u1[0])
                     + w4[2]*bf16_to_f(u2[0]) + w4[3]*bf16_to_f(u3[0]);
            float v1 = w4[0]*bf16_to_f(u0[1]) + w4[1]*bf16_to_f(u1[1])
                     + w4[2]*bf16_to_f(u2[1]) + w4[3]*bf16_to_f(u3[1]);
            float v2 = w4[0]*bf16_to_f(u0[2]) + w4[1]*bf16_to_f(u1[2])
                     + w4[2]*bf16_to_f(u2[2]) + w4[3]*bf16_to_f(u3[2]);
            float v3 = w4[0]*bf16_to_f(u0[3]) + w4[1]*bf16_to_f(u1[3])
                     + w4[2]*bf16_to_f(u2[3]) + w4[3]*bf16_to_f(u3[3]);
            int sw = (tap * 8 + ((ic >> 3) ^ (p & 7))) * 8 + (ic & 7);
            short* dst = &samp[p * 576 + sw];
            dst[0] = f_to_bf16(v0);
            dst[1] = f_to_bf16(v1);
            dst[2] = f_to_bf16(v2);
            dst[3] = f_to_bf16(v3);
        }
    }
    __syncthreads();

    const int wv = tid >> 6;
    const int l  = tid & 63;
    const int l15 = l & 15, lg = l >> 4;
    f32x4_t acc[2][NF];
#pragma unroll
    for (int mf = 0; mf < 2; ++mf)
#pragma unroll
        for (int nf = 0; nf < NF; ++nf)
            acc[mf][nf] = (f32x4_t){0.f, 0.f, 0.f, 0.f};

#pragma unroll 2
    for (int kc = 0; kc < 18; ++kc) {
        int tap = kc >> 1;
        int low = (((kc & 1) << 2) | lg) ^ (l15 & 7);
        bf16x8_t af0 = *(const bf16x8_t*)&samp[l15 * 576 + (tap * 8 + low) * 8];
        bf16x8_t af1 = *(const bf16x8_t*)&samp[(l15 + 16) * 576 + (tap * 8 + low) * 8];
#pragma unroll
        for (int nf = 0; nf < NF; ++nf) {
            int ocf = wv * NF + nf;
            bf16x8_t bf = *(const bf16x8_t*)(wt + (((size_t)(kc * NFRAG + ocf)) * 64 + l) * 8);
            acc[0][nf] = __builtin_amdgcn_mfma_f32_16x16x32_bf16(af0, bf, acc[0][nf], 0, 0, 0);
            acc[1][nf] = __builtin_amdgcn_mfma_f32_16x16x32_bf16(af1, bf, acc[1][nf], 0, 0, 0);
        }
    }

#pragma unroll
    for (int mf = 0; mf < 2; ++mf)
#pragma unroll
        for (int nf = 0; nf < NF; ++nf) {
            int oc = (wv * NF + nf) * 16 + l15;
            float bv = bias[oc];
            f32x4_t v = acc[mf][nf];
            v[0] += bv; v[1] += bv; v[2] += bv; v[3] += bv;
            *(f32x4_t*)&out[((size_t)(b * O + oc)) * HW + r0 + mf * 16 + lg * 4] = v;
        }
}

// ---------------------------------------------------------------- avgpool 4x4
__global__ void avgpool4_kernel(const float* __restrict__ in,
                                float* __restrict__ out,
                                int BC, int Ho, int Wo, int H, int W)
{
    int idx = blockIdx.x * TPB + threadIdx.x;
    int total = BC * Ho * Wo;
    if (idx >= total) return;
    int wo = idx % Wo;
    int t = idx / Wo;
    int ho = t % Ho;
    int bc = t / Ho;
    const float* xp = in + (size_t)bc * H * W + (ho * 4) * W + wo * 4;
    float s = 0.f;
#pragma unroll
    for (int i = 0; i < 4; ++i)
#pragma unroll
        for (int j = 0; j < 4; ++j)
            s += xp[i * W + j];
    out[idx] = s * (1.0f / 16.0f);
}

__global__ void zero_stats_kernel(float* __restrict__ stats)
{
    int i = threadIdx.x;
#pragma unroll
    for (int k = 0; k < 8; ++k) stats[k * 256 + i] = 0.f;
    stats[2048 + i] = 0.f;
    stats[2048 + 256 + i] = 0.f;
}

// ---------------------------------------------------------------- launch
extern "C" void kernel_launch(void* const* d_in, const int* in_sizes, int n_in,
                              void* d_out, int out_size, void* d_ws, size_t ws_size,
                              hipStream_t stream)
{
    const float* x      = (const float*)d_in[0];
    const float* w_off1 = (const float*)d_in[1];
    const float* b_off1 = (const float*)d_in[2];
    const float* w_d1   = (const float*)d_in[3];
    const float* b_d1   = (const float*)d_in[4];
    const float* w_skip = (const float*)d_in[5];
    const float* b_skip = (const float*)d_in[6];
    const float* w_bl1  = (const float*)d_in[7];
    const float* w_bl2  = (const float*)d_in[8];
    const float* w_off2 = (const float*)d_in[9];
    const float* b_off2 = (const float*)d_in[10];
    const float* w_d2   = (const float*)d_in[11];
    const float* b_d2   = (const float*)d_in[12];
    const float* w_off3 = (const float*)d_in[13];
    const float* b_off3 = (const float*)d_in[14];
    const float* w_d3   = (const float*)d_in[15];
    const float* b_d3   = (const float*)d_in[16];

    const int B = 8;
    float* A     = (float*)d_ws;
    float* bufB  = A + 3686400;
    float* bufC  = bufB + 13107200;

    short* hB   = (short*)bufB;
    short* hC   = (short*)bufC;
    float* pool = bufB + 8000000;

    short* wt1    = (short*)(A + 1000000);
    short* wt2    = wt1 + 18 * 4 * 512;
    short* wtd2   = (short*)(A + 1500000);
    short* wtd3   = (short*)(A + 1550000);
    short* wtoff2 = (short*)(A + 1700000);
    short* wtoff3 = (short*)(A + 1712000);
    short* wtd1   = (short*)(A + 1750000);    // 2048 shorts
    float* stats1 = A + 1800000;
    float* stats2 = stats1 + 1024;
    float* zpage  = stats1 + 2048;

    float* out0 = (float*)d_out;
    float* out1 = out0 + 13107200;
    float* out2 = out1 + 3276800;

    const float invN = 1.0f / (B * 25600);

    // 0) x -> NHWC4 fp32 into bufC
    x_to_nhwc4_kernel<<<(8 * 409600 + TPB - 1) / TPB, TPB, 0, stream>>>(x, bufC);

    // 1) pool = avgpool4(x)
    avgpool4_kernel<<<(B * 3 * 25600 + TPB - 1) / TPB, TPB, 0, stream>>>(
        x, pool, B * 3, 160, 160, 640, 640);

    // 2) repack weights + zero stats & zero page
    repack_frag_kernel<<<(18 * 4 * 512 + TPB - 1) / TPB, TPB, 0, stream>>>(w_bl1, wt1, 64, 4);
    repack_frag_kernel<<<(18 * 4 * 512 + TPB - 1) / TPB, TPB, 0, stream>>>(w_bl2, wt2, 64, 4);
    repack_frag_kernel<<<(18 * 4 * 512 + TPB - 1) / TPB, TPB, 0, stream>>>(w_d2, wtd2, 64, 4);
    repack_frag_kernel<<<(18 * 16 * 512 + TPB - 1) / TPB, TPB, 0, stream>>>(w_d3, wtd3, 256, 16);
    repack_frag_kernel<<<(18 * 2 * 512 + TPB - 1) / TPB, TPB, 0, stream>>>(w_off2, wtoff2, 18, 2);
    repack_frag_kernel<<<(18 * 2 * 512 + TPB - 1) / TPB, TPB, 0, stream>>>(w_off3, wtoff3, 18, 2);
    repack_d1_kernel<<<8, TPB, 0, stream>>>(w_d1, wtd1);
    zero_stats_kernel<<<1, 256, 0, stream>>>(stats1);

    // 3) deform1 (fused offset1 + MFMA MAC + skip): x4 -> hB bf16 NHWC
    deform1_kernel<<<8 * 25600 / 32, TPB, 0, stream>>>(
        bufC, w_off1, b_off1, wtd1, b_d1, pool, w_skip, b_skip, hB);

    // 4) conv1 (raw): hB -> hC bf16 NHWC (+stats1)
    conv3x3_mfma_kernel<0><<<800, TPB, 0, stream>>>(
        hB, wt1, hC, stats1, nullptr, invN, zpage);

    // 5) conv2 (normalizes input with stats1): hC -> hB bf16 NHWC (+stats2)
    conv3x3_mfma_kernel<1><<<800, TPB, 0, stream>>>(
        hC, wt2, hB, stats2, stats1, invN, zpage);

    // 6) apply2: hB -> out0 fp32 NCHW + hC bf16 NHWC (feat4)
    bn_apply_dual_kernel<<<8 * 400, TPB, 0, stream>>>(
        hB, stats2, out0, hC, 25600, invN);

    // 7) offset2 = offconv(feat4 hC) -> A
    offconv_mfma_kernel<<<8 * 6400 / 64, TPB, 0, stream>>>(
        hC, wtoff2, b_off2, A, 160, 160, 80, 80);

    // 8) feat_1_8 = deform2(feat4 hC, offset2) -> out1
    deform_mfma_kernel<64><<<8 * 6400 / 32, TPB, 0, stream>>>(
        hC, A, wtd2, b_d2, out1, 160, 160, 80, 80, 2);

    // 9) feat_1_8 -> NHWC bf16 into hB
    nchw_to_nhwc_bf16_kernel<<<8 * (6400 / 64), TPB, 0, stream>>>(out1, hB, 6400);

    // 10) offset3 = offconv(feat8 hB) -> A
    offconv_mfma_kernel<<<8 * 1600 / 64, TPB, 0, stream>>>(
        hB, wtoff3, b_off3, A, 80, 80, 40, 40);

    // 11) feat_1_16 = deform3(feat8 hB, offset3) -> out2
    deform_mfma_kernel<256><<<8 * 1600 / 32, TPB, 0, stream>>>(
        hB, A, wtd3, b_d3, out2, 80, 80, 40, 40, 2);
}

// Round 17
// 224.693 us; speedup vs baseline: 31.9315x; 1.0592x over previous
//
#include <hip/hip_runtime.h>
#include <hip/hip_bf16.h>
#include <math.h>

#define TPB 256

typedef __attribute__((ext_vector_type(8))) short bf16x8_t;
typedef __attribute__((ext_vector_type(4))) float f32x4_t;
typedef __attribute__((ext_vector_type(4))) int i32x4_t;
typedef __attribute__((ext_vector_type(4))) unsigned short u16x4_t;

static __device__ __forceinline__ float bf16_to_f(unsigned short s) {
    union { unsigned u; float f; } cv;
    cv.u = ((unsigned)s) << 16;
    return cv.f;
}
static __device__ __forceinline__ short f_to_bf16(float v) {
    __hip_bfloat16 h = __float2bfloat16(v);
    return *(short*)&h;
}

// ------------------------------------------------- prep: x NCHW -> x4 NHWC4 + pool
// thread = one pool pixel (b,ho,wo); covers its 4x4 input block.
__global__ void prep_kernel(const float* __restrict__ in,
                            float* __restrict__ x4,
                            float* __restrict__ pool)
{
    const int HWo = 25600, H = 640, W = 640;
    int idx = blockIdx.x * TPB + threadIdx.x;
    if (idx >= 8 * HWo) return;
    int b = idx / HWo, r = idx % HWo;
    int ho = r / 160, wo = r % 160;
    float s0 = 0.f, s1 = 0.f, s2 = 0.f;
    float* x4b = x4 + (size_t)b * H * W * 4;
#pragma unroll
    for (int dy = 0; dy < 4; ++dy) {
        int row = ho * 4 + dy;
        size_t base = ((size_t)row * W + wo * 4);
        f32x4_t a0 = *(const f32x4_t*)&in[((size_t)(b * 3 + 0) * H * W) + base];
        f32x4_t a1 = *(const f32x4_t*)&in[((size_t)(b * 3 + 1) * H * W) + base];
        f32x4_t a2 = *(const f32x4_t*)&in[((size_t)(b * 3 + 2) * H * W) + base];
        s0 += a0[0] + a0[1] + a0[2] + a0[3];
        s1 += a1[0] + a1[1] + a1[2] + a1[3];
        s2 += a2[0] + a2[1] + a2[2] + a2[3];
#pragma unroll
        for (int dx = 0; dx < 4; ++dx) {
            f32x4_t v = (f32x4_t){a0[dx], a1[dx], a2[dx], 0.f};
            *(f32x4_t*)&x4b[(base + dx) * 4] = v;
        }
    }
    pool[((size_t)(b * 3 + 0)) * HWo + r] = s0 * (1.0f / 16.0f);
    pool[((size_t)(b * 3 + 1)) * HWo + r] = s1 * (1.0f / 16.0f);
    pool[((size_t)(b * 3 + 2)) * HWo + r] = s2 * (1.0f / 16.0f);
}

// ------------------------------------------------- single repack-everything kernel
static __device__ __forceinline__ void repack_one(
    const float* __restrict__ w, short* __restrict__ wtf,
    int idx, int Oreal, int NFRAG)
{
    int j    = idx & 7;
    int lane = (idx >> 3) & 63;
    int t    = idx >> 9;
    int ocf  = t % NFRAG;
    int kc   = t / NFRAG;
    int oc   = ocf * 16 + (lane & 15);
    int tap  = kc >> 1;
    int ic   = (kc & 1) * 32 + (lane >> 4) * 8 + j;
    float v = 0.f;
    if (oc < Oreal)
        v = w[((size_t)(oc * 64 + ic)) * 9 + tap];
    wtf[idx] = f_to_bf16(v);
}

__global__ void repack_all_kernel(
    const float* __restrict__ w_bl1, short* __restrict__ wt1,
    const float* __restrict__ w_bl2, short* __restrict__ wt2,
    const float* __restrict__ w_d2,  short* __restrict__ wtd2,
    const float* __restrict__ w_d3,  short* __restrict__ wtd3,
    const float* __restrict__ w_off2, short* __restrict__ wtoff2,
    const float* __restrict__ w_off3, short* __restrict__ wtoff3,
    const float* __restrict__ w_d1,  short* __restrict__ wtd1,
    float* __restrict__ stats)       // 2048 stats + 512 zero page
{
    int idx = blockIdx.x * TPB + threadIdx.x;
    if (idx < 36864) { repack_one(w_bl1, wt1, idx, 64, 4); return; }
    idx -= 36864;
    if (idx < 36864) { repack_one(w_bl2, wt2, idx, 64, 4); return; }
    idx -= 36864;
    if (idx < 36864) { repack_one(w_d2, wtd2, idx, 64, 4); return; }
    idx -= 36864;
    if (idx < 147456) { repack_one(w_d3, wtd3, idx, 256, 16); return; }
    idx -= 147456;
    if (idx < 18432) { repack_one(w_off2, wtoff2, idx, 18, 2); return; }
    idx -= 18432;
    if (idx < 18432) { repack_one(w_off3, wtoff3, idx, 18, 2); return; }
    idx -= 18432;
    if (idx < 2048) {
        int j = idx & 7, lane = (idx >> 3) & 63, ocf = idx >> 9;
        int oc = ocf * 16 + (lane & 15);
        int k  = (lane >> 4) * 8 + j;
        float v = 0.f;
        if (k < 27) v = w_d1[(size_t)oc * 27 + k];
        wtd1[idx] = f_to_bf16(v);
        return;
    }
    idx -= 2048;
    if (idx < 2560) stats[idx] = 0.f;
}

// ------------------------------------------------- MFMA conv 3x3 (64->64, s1)
template <int NORM>
__global__ __launch_bounds__(256, 2) void conv3x3_mfma_kernel(
    const short* __restrict__ xh,
    const short* __restrict__ wt,      // [18][4][64][8] frag order
    short* __restrict__ outh,          // bf16 NHWC
    float* __restrict__ stats,         // [8][128]
    const float* __restrict__ stats_in,// [8][128] (NORM only)
    float invN,
    const float* __restrict__ zp)      // 2KB zero page
{
    __shared__ short tile[2816 * 8];
    __shared__ float sstat[128];
    __shared__ float sm[64], sr[64];
    const int H = 160, W = 160, HW = 25600;
    int blk = blockIdx.x;
    int b  = blk / 100;
    int r  = blk % 100;
    int y0 = (r / 10) * 16;
    int x0 = (r % 10) * 16;
    const int tid = threadIdx.x;
    const short* inb = xh + (size_t)b * HW * 64;

    if (tid < 128) sstat[tid] = 0.f;
    if (NORM) {
        if (tid < 64) {
            float s = 0.f, s2 = 0.f;
#pragma unroll
            for (int k = 0; k < 8; ++k) {
                s  += stats_in[k * 128 + tid];
                s2 += stats_in[k * 128 + 64 + tid];
            }
            float mean = s * invN;
            float var  = s2 * invN - mean * mean;
            sm[tid] = mean;
            sr[tid] = rsqrtf(var + 1e-5f);
        }
        __syncthreads();
    }

#pragma unroll
    for (int it = 0; it < 11; ++it) {
        int item = it * 256 + tid;
        int c8  = item & 7;
        int pix = item >> 3;
        int row = pix / 18;
        int col = pix - row * 18;
        int y = y0 + row - 1;
        int x = x0 + col - 1;
        bool ok = (pix < 324) & (y >= 0) & (y < H) & (x >= 0) & (x < W);
        int cs = c8 ^ (col & 7);
        const short* src = ok
            ? &inb[((size_t)y * W + x) * 64 + (cs << 3)]
            : (const short*)zp;
        bf16x8_t v = *(const bf16x8_t*)src;
        if (NORM) {
            int cs8 = cs << 3;
            bf16x8_t o;
#pragma unroll
            for (int j = 0; j < 8; ++j) {
                float f = (bf16_to_f((unsigned short)v[j]) - sm[cs8 + j]) * sr[cs8 + j];
                f = f > 0.f ? f : 0.f;
                o[j] = ok ? f_to_bf16(f) : (short)0;
            }
            v = o;
        }
        *(bf16x8_t*)&tile[item * 8] = v;
    }
    __syncthreads();

    const int wv  = tid >> 6;
    const int l   = tid & 63;
    const int l15 = l & 15;
    const int lg  = l >> 4;

    f32x4_t acc[4][4];
#pragma unroll
    for (int i = 0; i < 4; ++i)
#pragma unroll
        for (int j = 0; j < 4; ++j)
            acc[i][j] = (f32x4_t){0.f, 0.f, 0.f, 0.f};

    bf16x8_t bfp[2][4], afp[2][4];
#pragma unroll
    for (int nf = 0; nf < 4; ++nf)
        bfp[0][nf] = *(const bf16x8_t*)(wt + (((size_t)(0 * 4 + nf)) * 64 + l) * 8);
    {
        int colr = l15;
        int chunk = lg ^ (colr & 7);
#pragma unroll
        for (int mf = 0; mf < 4; ++mf)
            afp[0][mf] = *(const bf16x8_t*)&tile[((wv * 4 + mf) * 18 + colr) * 64 + chunk * 8];
    }
#pragma unroll
    for (int kc = 0; kc < 18; ++kc) {
        const int cur = kc & 1, nxt = cur ^ 1;
        if (kc + 1 < 18) {
            int kn = kc + 1;
#pragma unroll
            for (int nf = 0; nf < 4; ++nf)
                bfp[nxt][nf] = *(const bf16x8_t*)(wt + (((size_t)(kn * 4 + nf)) * 64 + l) * 8);
            int tap = kn >> 1;
            int dy = tap / 3, dx = tap % 3;
            int colr = l15 + dx;
            int chunk = (((kn & 1) << 2) + lg) ^ (colr & 7);
#pragma unroll
            for (int mf = 0; mf < 4; ++mf)
                afp[nxt][mf] = *(const bf16x8_t*)&tile[((wv * 4 + mf + dy) * 18 + colr) * 64 + chunk * 8];
        }
#pragma unroll
        for (int mf = 0; mf < 4; ++mf)
#pragma unroll
            for (int nf = 0; nf < 4; ++nf)
                acc[mf][nf] = __builtin_amdgcn_mfma_f32_16x16x32_bf16(
                    afp[cur][mf], bfp[cur][nf], acc[mf][nf], 0, 0, 0);
    }

    __syncthreads();
#pragma unroll
    for (int mf = 0; mf < 4; ++mf) {
        int py = wv * 4 + mf;
#pragma unroll
        for (int nf = 0; nf < 4; ++nf) {
            int oc = nf * 16 + l15;
#pragma unroll
            for (int k = 0; k < 4; ++k)
                tile[((py * 16) + lg * 4 + k) * 64 + oc] = f_to_bf16(acc[mf][nf][k]);
        }
    }
    __syncthreads();
    short* outb = outh + (size_t)b * HW * 64;
#pragma unroll
    for (int j = 0; j < 8; ++j) {
        int item = j * 256 + tid;
        int c8  = item & 7;
        int pix = item >> 3;
        int py  = pix >> 4, px = pix & 15;
        *(bf16x8_t*)&outb[((size_t)(y0 + py) * W + x0 + px) * 64 + c8 * 8] =
            *(bf16x8_t*)&tile[pix * 64 + c8 * 8];
    }

#pragma unroll
    for (int nf = 0; nf < 4; ++nf) {
        float s = 0.f, s2 = 0.f;
#pragma unroll
        for (int mf = 0; mf < 4; ++mf)
#pragma unroll
            for (int k = 0; k < 4; ++k) {
                float v = acc[mf][nf][k];
                s += v; s2 += v * v;
            }
        s  += __shfl_xor(s, 16, 64);  s  += __shfl_xor(s, 32, 64);
        s2 += __shfl_xor(s2, 16, 64); s2 += __shfl_xor(s2, 32, 64);
        if (lg == 0) {
            int oc = nf * 16 + l15;
            atomicAdd(&sstat[oc], s);
            atomicAdd(&sstat[64 + oc], s2);
        }
    }
    __syncthreads();
    float* st = stats + (size_t)(blockIdx.x & 7) * 128;
    if (tid < 128) atomicAdd(&st[tid], sstat[tid]);
}

// ------------------------------------------------- BN apply dual
__global__ void bn_apply_dual_kernel(const short* __restrict__ in,
                                     const float* __restrict__ stats,
                                     float* __restrict__ out,
                                     short* __restrict__ outh,
                                     int HW, float invN)
{
    __shared__ float ftile[64][65];
    __shared__ float sm[64], sr[64];
    int nchunks = HW >> 6;
    int b  = blockIdx.x / nchunks;
    int p0 = (blockIdx.x % nchunks) << 6;
    int tid = threadIdx.x;
    if (tid < 64) {
        float s = 0.f, s2 = 0.f;
#pragma unroll
        for (int k = 0; k < 8; ++k) {
            s  += stats[k * 128 + tid];
            s2 += stats[k * 128 + 64 + tid];
        }
        float mean = s * invN;
        float var  = s2 * invN - mean * mean;
        sm[tid] = mean;
        sr[tid] = rsqrtf(var + 1e-5f);
    }
    __syncthreads();
#pragma unroll
    for (int it = 0; it < 2; ++it) {
        int item = it * 256 + tid;
        int p = item >> 3, c0 = (item & 7) * 8;
        size_t gi = ((size_t)(b * HW + p0 + p)) * 64 + c0;
        bf16x8_t v = *(const bf16x8_t*)&in[gi];
        bf16x8_t o;
#pragma unroll
        for (int j = 0; j < 8; ++j) {
            float f = (bf16_to_f((unsigned short)v[j]) - sm[c0 + j]) * sr[c0 + j];
            f = f > 0.f ? f : 0.f;
            ftile[p][c0 + j] = f;
            o[j] = f_to_bf16(f);
        }
        *(bf16x8_t*)&outh[gi] = o;
    }
    __syncthreads();
#pragma unroll
    for (int rep = 0; rep < 16; ++rep) {
        int item = rep * 256 + tid;
        int c = item >> 6, p = item & 63;
        out[((size_t)b * 64 + c) * HW + p0 + p] = ftile[p][c];
    }
}

// ------------------------------------------------- offset2/3: MFMA conv, N=18
__global__ __launch_bounds__(256, 1) void offconv_mfma_kernel(
    const short* __restrict__ xh,
    const short* __restrict__ wt,
    const float* __restrict__ bias,
    float* __restrict__ out,
    int H, int W, int Ho, int Wo)
{
    const int HW = Ho * Wo;
    const int tid = threadIdx.x;
    const int wv = tid >> 6, l = tid & 63;
    const int l15 = l & 15, lg = l >> 4;
    const int pix0 = blockIdx.x * 64 + wv * 16;
    const int b = pix0 / HW;
    const int r0 = pix0 - b * HW;

    int rp = r0 + l15;
    int ho = rp / Wo, wo = rp % Wo;
    const short* xb = xh + (size_t)b * H * W * 64;

    f32x4_t acc[2];
    acc[0] = (f32x4_t){0.f, 0.f, 0.f, 0.f};
    acc[1] = (f32x4_t){0.f, 0.f, 0.f, 0.f};

#pragma unroll 2
    for (int kc = 0; kc < 18; ++kc) {
        int tap = kc >> 1;
        int iy = ho * 2 - 1 + tap / 3;
        int ix = wo * 2 - 1 + tap % 3;
        bf16x8_t af = {};
        if (iy >= 0 && iy < H && ix >= 0 && ix < W)
            af = *(const bf16x8_t*)&xb[((size_t)iy * W + ix) * 64
                                       + (kc & 1) * 32 + lg * 8];
#pragma unroll
        for (int nf = 0; nf < 2; ++nf) {
            bf16x8_t bf = *(const bf16x8_t*)(wt + (((size_t)(kc * 2 + nf)) * 64 + l) * 8);
            acc[nf] = __builtin_amdgcn_mfma_f32_16x16x32_bf16(af, bf, acc[nf], 0, 0, 0);
        }
    }

#pragma unroll
    for (int nf = 0; nf < 2; ++nf) {
        int oc = nf * 16 + l15;
        if (oc < 18) {
            float bv = bias[oc];
            f32x4_t v = acc[nf];
            v[0] += bv; v[1] += bv; v[2] += bv; v[3] += bv;
            *(f32x4_t*)&out[((size_t)(b * 18 + oc)) * HW + r0 + lg * 4] = v;
        }
    }
}

// ------------------------------------------------- deform1: fused offset1 +
// deform (C=3, MFMA MAC) + skip
__global__ __launch_bounds__(256, 1) void deform1_kernel(
    const float* __restrict__ x4,
    const float* __restrict__ wof,
    const float* __restrict__ bof,
    const short* __restrict__ wtd1,
    const float* __restrict__ bias,
    const float* __restrict__ pool,
    const float* __restrict__ wsk,
    const float* __restrict__ bsk,
    short* __restrict__ outh)
{
    const int H = 640, W = 640, Ho = 160, Wo = 160, HW = 25600;
    constexpr int P = 32;
    __shared__ float xtap[P * 9][4];
    __shared__ float swof[486];
    __shared__ float sbof[18];
    __shared__ float spool[3][P];
    __shared__ float off1[P][18];
    __shared__ alignas(16) short sampb[P][40];
    __shared__ int   sidx[P * 9][4];
    __shared__ float swt[P * 9][4];
    const int tid = threadIdx.x;
    const int pix0 = blockIdx.x * P;
    const int b = pix0 / HW;
    const int r0 = pix0 - b * HW;
    const float* xb = x4 + (size_t)b * H * W * 4;

    for (int item = tid; item < P * 9; item += TPB) {
        int p = item / 9, tap = item % 9;
        int r = r0 + p, ho = r / Wo, wo = r % Wo;
        int iy = ho * 4 - 1 + tap / 3;
        int ix = wo * 4 - 1 + tap % 3;
        f32x4_t s = (f32x4_t){0.f, 0.f, 0.f, 0.f};
        if (iy >= 0 && iy < H && ix >= 0 && ix < W)
            s = *(const f32x4_t*)&xb[((size_t)iy * W + ix) * 4];
        *(f32x4_t*)xtap[item] = s;
    }
    for (int i = tid; i < P * 40; i += TPB) ((short*)sampb)[i] = 0;
    for (int i = tid; i < 96; i += TPB) {
        int c = i >> 5, p = i & 31;
        spool[c][p] = pool[((size_t)(b * 3 + c)) * HW + r0 + p];
    }
    for (int item = tid; item < 486; item += TPB) swof[item] = wof[item];
    if (tid < 18) sbof[tid] = bof[tid];
    __syncthreads();

    for (int item = tid; item < P * 18; item += TPB) {
        int p = item / 18, o = item % 18;
        float acc = sbof[o];
#pragma unroll
        for (int tap = 0; tap < 9; ++tap) {
            const float* xt = xtap[p * 9 + tap];
#pragma unroll
            for (int c = 0; c < 3; ++c)
                acc += xt[c] * swof[(o * 3 + c) * 9 + tap];
        }
        off1[p][o] = acc;
    }
    __syncthreads();

    for (int item = tid; item < P * 9; item += TPB) {
        int p = item / 9, tap = item % 9;
        int r = r0 + p, ho = r / Wo, wo = r % Wo;
        float dy = off1[p][2 * tap];
        float dx = off1[p][2 * tap + 1];
        float ys = (float)(ho * 4 - 1 + tap / 3) + dy;
        float xs = (float)(wo * 4 - 1 + tap % 3) + dx;
        float y0f = floorf(ys), x0f = floorf(xs);
        float fy = ys - y0f, fx = xs - x0f;
        int y0 = (int)y0f, x0 = (int)x0f;
        float wts[4] = {(1.f - fy) * (1.f - fx), (1.f - fy) * fx,
                        fy * (1.f - fx),          fy * fx};
#pragma unroll
        for (int j = 0; j < 4; ++j) {
            int iy = y0 + (j >> 1), ix = x0 + (j & 1);
            bool v = (iy >= 0) && (iy < H) && (ix >= 0) && (ix < W);
            sidx[item][j] = v ? (iy * W + ix) : 0;
            swt[item][j]  = v ? wts[j] : 0.f;
        }
    }
    __syncthreads();

    for (int item = tid; item < P * 9; item += TPB) {
        int p = item / 9, tap = item % 9;
        i32x4_t id4 = *(const i32x4_t*)sidx[item];
        f32x4_t w4  = *(const f32x4_t*)swt[item];
        f32x4_t a0 = *(const f32x4_t*)&xb[(size_t)(unsigned)id4[0] * 4];
        f32x4_t a1 = *(const f32x4_t*)&xb[(size_t)(unsigned)id4[1] * 4];
        f32x4_t a2 = *(const f32x4_t*)&xb[(size_t)(unsigned)id4[2] * 4];
        f32x4_t a3 = *(const f32x4_t*)&xb[(size_t)(unsigned)id4[3] * 4];
        sampb[p][0 * 9 + tap] = f_to_bf16(
            w4[0]*a0[0] + w4[1]*a1[0] + w4[2]*a2[0] + w4[3]*a3[0]);
        sampb[p][1 * 9 + tap] = f_to_bf16(
            w4[0]*a0[1] + w4[1]*a1[1] + w4[2]*a2[1] + w4[3]*a3[1]);
        sampb[p][2 * 9 + tap] = f_to_bf16(
            w4[0]*a0[2] + w4[1]*a1[2] + w4[2]*a2[2] + w4[3]*a3[2]);
    }
    __syncthreads();

    const int wv = tid >> 6;
    const int l  = tid & 63;
    const int l15 = l & 15, lg = l >> 4;
    bf16x8_t bf  = *(const bf16x8_t*)(wtd1 + (((size_t)wv * 64 + l)) * 8);
    bf16x8_t af0 = *(const bf16x8_t*)&sampb[l15][lg * 8];
    bf16x8_t af1 = *(const bf16x8_t*)&sampb[l15 + 16][lg * 8];
    f32x4_t z = (f32x4_t){0.f, 0.f, 0.f, 0.f};
    f32x4_t acc0 = __builtin_amdgcn_mfma_f32_16x16x32_bf16(af0, bf, z, 0, 0, 0);
    f32x4_t acc1 = __builtin_amdgcn_mfma_f32_16x16x32_bf16(af1, bf, z, 0, 0, 0);

    int oc = wv * 16 + l15;
    float bb = bias[oc] + bsk[oc];
    float w0 = wsk[oc * 3 + 0], w1 = wsk[oc * 3 + 1], w2 = wsk[oc * 3 + 2];
    short* otile = (short*)xtap;
    __syncthreads();
#pragma unroll
    for (int mf = 0; mf < 2; ++mf) {
        f32x4_t a = mf ? acc1 : acc0;
#pragma unroll
        for (int k = 0; k < 4; ++k) {
            int px = mf * 16 + lg * 4 + k;
            float sv = w0 * spool[0][px] + w1 * spool[1][px] + w2 * spool[2][px];
            otile[px * 64 + oc] = f_to_bf16(a[k] + bb + sv);
        }
    }
    __syncthreads();
    {
        int c8 = tid & 7, px = tid >> 3;
        *(bf16x8_t*)&outh[((size_t)(b * HW + r0 + px)) * 64 + c8 * 8] =
            *(bf16x8_t*)&otile[px * 64 + c8 * 8];
    }
}

// ------------------------------------------------- deform MFMA: C=64 -> O
// DUAL: additionally write bf16 NHWC (kills the separate transpose pass)
template <int O, int DUAL>
__global__ __launch_bounds__(256, 1) void deform_mfma_kernel(
    const short* __restrict__ xh,
    const float* __restrict__ off,
    const short* __restrict__ wt,
    const float* __restrict__ bias,
    float* __restrict__ out,
    short* __restrict__ outh,       // DUAL only
    int H, int W, int Ho, int Wo, int stride)
{
    constexpr int NF = O / 64;
    constexpr int NFRAG = O / 16;
    constexpr int P  = 32;
    __shared__ alignas(16) short samp[P * 576];
    __shared__ int   sidx[P * 9][4];
    __shared__ float swt[P * 9][4];

    const int tid = threadIdx.x;
    const int HW = Ho * Wo;
    const int pix0 = blockIdx.x * P;
    const int b = pix0 / HW;
    const int r0 = pix0 - b * HW;

    for (int item = tid; item < P * 9; item += TPB) {
        int p = item / 9, tap = item % 9;
        int r = r0 + p, ho = r / Wo, wo = r % Wo;
        float dy = off[((size_t)(b * 18 + 2 * tap) * Ho + ho) * Wo + wo];
        float dx = off[((size_t)(b * 18 + 2 * tap + 1) * Ho + ho) * Wo + wo];
        float ys = (float)(ho * stride - 1 + tap / 3) + dy;
        float xs = (float)(wo * stride - 1 + tap % 3) + dx;
        float y0f = floorf(ys), x0f = floorf(xs);
        float fy = ys - y0f, fx = xs - x0f;
        int y0 = (int)y0f, x0 = (int)x0f;
        float wts[4] = {(1.f - fy) * (1.f - fx), (1.f - fy) * fx,
                        fy * (1.f - fx),          fy * fx};
#pragma unroll
        for (int j = 0; j < 4; ++j) {
            int iy = y0 + (j >> 1), ix = x0 + (j & 1);
            bool v = (iy >= 0) && (iy < H) && (ix >= 0) && (ix < W);
            sidx[item][j] = v ? (iy * W + ix) : 0;
            swt[item][j]  = v ? wts[j] : 0.f;
        }
    }
    __syncthreads();

    {
        const int grp = tid >> 4;
        const int ic  = (tid & 15) * 4;
        const short* xb = xh + (size_t)b * H * W * 64;
#pragma unroll 3
        for (int i = 0; i < 18; ++i) {
            int e = grp * 18 + i;
            int p = e / 9, tap = e % 9;
            i32x4_t id4 = *(const i32x4_t*)sidx[e];
            f32x4_t w4  = *(const f32x4_t*)swt[e];
            u16x4_t u0 = *(const u16x4_t*)&xb[(size_t)(unsigned)id4[0] * 64 + ic];
            u16x4_t u1 = *(const u16x4_t*)&xb[(size_t)(unsigned)id4[1] * 64 + ic];
            u16x4_t u2 = *(const u16x4_t*)&xb[(size_t)(unsigned)id4[2] * 64 + ic];
            u16x4_t u3 = *(const u16x4_t*)&xb[(size_t)(unsigned)id4[3] * 64 + ic];
            float v0 = w4[0]*bf16_to_f(u0[0]) + w4[1]*bf16_to_f(u1[0])
                     + w4[2]*bf16_to_f(u2[0]) + w4[3]*bf16_to_f(u3[0]);
            float v1 = w4[0]*bf16_to_f(u0[1]) + w4[1]*bf16_to_f(u1[1])
                     + w4[2]*bf16_to_f(u2[1]) + w4[3]*bf16_to_f(u3[1]);
            float v2 = w4[0]*bf16_to_f(u0[2]) + w4[1]*bf16_to_f(u1[2])
                     + w4[2]*bf16_to_f(u2[2]) + w4[3]*bf16_to_f(u3[2]);
            float v3 = w4[0]*bf16_to_f(u0[3]) + w4[1]*bf16_to_f(u1[3])
                     + w4[2]*bf16_to_f(u2[3]) + w4[3]*bf16_to_f(u3[3]);
            int sw = (tap * 8 + ((ic >> 3) ^ (p & 7))) * 8 + (ic & 7);
            short* dst = &samp[p * 576 + sw];
            dst[0] = f_to_bf16(v0);
            dst[1] = f_to_bf16(v1);
            dst[2] = f_to_bf16(v2);
            dst[3] = f_to_bf16(v3);
        }
    }
    __syncthreads();

    const int wv = tid >> 6;
    const int l  = tid & 63;
    const int l15 = l & 15, lg = l >> 4;
    f32x4_t acc[2][NF];
#pragma unroll
    for (int mf = 0; mf < 2; ++mf)
#pragma unroll
        for (int nf = 0; nf < NF; ++nf)
            acc[mf][nf] = (f32x4_t){0.f, 0.f, 0.f, 0.f};

#pragma unroll 2
    for (int kc = 0; kc < 18; ++kc) {
        int tap = kc >> 1;
        int low = (((kc & 1) << 2) | lg) ^ (l15 & 7);
        bf16x8_t af0 = *(const bf16x8_t*)&samp[l15 * 576 + (tap * 8 + low) * 8];
        bf16x8_t af1 = *(const bf16x8_t*)&samp[(l15 + 16) * 576 + (tap * 8 + low) * 8];
#pragma unroll
        for (int nf = 0; nf < NF; ++nf) {
            int ocf = wv * NF + nf;
            bf16x8_t bf = *(const bf16x8_t*)(wt + (((size_t)(kc * NFRAG + ocf)) * 64 + l) * 8);
            acc[0][nf] = __builtin_amdgcn_mfma_f32_16x16x32_bf16(af0, bf, acc[0][nf], 0, 0, 0);
            acc[1][nf] = __builtin_amdgcn_mfma_f32_16x16x32_bf16(af1, bf, acc[1][nf], 0, 0, 0);
        }
    }

#pragma unroll
    for (int mf = 0; mf < 2; ++mf)
#pragma unroll
        for (int nf = 0; nf < NF; ++nf) {
            int oc = (wv * NF + nf) * 16 + l15;
            float bv = bias[oc];
            f32x4_t v = acc[mf][nf];
            v[0] += bv; v[1] += bv; v[2] += bv; v[3] += bv;
            acc[mf][nf] = v;
            *(f32x4_t*)&out[((size_t)(b * O + oc)) * HW + r0 + mf * 16 + lg * 4] = v;
        }

    if (DUAL) {
        // pack bf16 NHWC via samp (dead now), coalesced store
        __syncthreads();
        short* otile = samp;            // 32*64 = 2048 shorts
#pragma unroll
        for (int mf = 0; mf < 2; ++mf) {
            int oc = wv * 16 + l15;     // NF==1 for DUAL
#pragma unroll
            for (int k = 0; k < 4; ++k) {
                int px = mf * 16 + lg * 4 + k;
                otile[px * 64 + oc] = f_to_bf16(acc[mf][0][k]);
            }
        }
        __syncthreads();
        int c8 = tid & 7, px = tid >> 3;
        *(bf16x8_t*)&outh[((size_t)(b * HW + r0 + px)) * 64 + c8 * 8] =
            *(bf16x8_t*)&otile[px * 64 + c8 * 8];
    }
}

// ---------------------------------------------------------------- launch
extern "C" void kernel_launch(void* const* d_in, const int* in_sizes, int n_in,
                              void* d_out, int out_size, void* d_ws, size_t ws_size,
                              hipStream_t stream)
{
    const float* x      = (const float*)d_in[0];
    const float* w_off1 = (const float*)d_in[1];
    const float* b_off1 = (const float*)d_in[2];
    const float* w_d1   = (const float*)d_in[3];
    const float* b_d1   = (const float*)d_in[4];
    const float* w_skip = (const float*)d_in[5];
    const float* b_skip = (const float*)d_in[6];
    const float* w_bl1  = (const float*)d_in[7];
    const float* w_bl2  = (const float*)d_in[8];
    const float* w_off2 = (const float*)d_in[9];
    const float* b_off2 = (const float*)d_in[10];
    const float* w_d2   = (const float*)d_in[11];
    const float* b_d2   = (const float*)d_in[12];
    const float* w_off3 = (const float*)d_in[13];
    const float* b_off3 = (const float*)d_in[14];
    const float* w_d3   = (const float*)d_in[15];
    const float* b_d3   = (const float*)d_in[16];

    const int B = 8;
    float* A     = (float*)d_ws;
    float* bufB  = A + 3686400;
    float* bufC  = bufB + 13107200;

    short* hB   = (short*)bufB;
    short* hC   = (short*)bufC;
    float* pool = bufB + 8000000;

    short* wt1    = (short*)(A + 1000000);
    short* wt2    = wt1 + 18 * 4 * 512;
    short* wtd2   = (short*)(A + 1500000);
    short* wtd3   = (short*)(A + 1550000);
    short* wtoff2 = (short*)(A + 1700000);
    short* wtoff3 = (short*)(A + 1712000);
    short* wtd1   = (short*)(A + 1750000);
    float* stats1 = A + 1800000;          // [8][128]
    float* stats2 = stats1 + 1024;        // [8][128]
    float* zpage  = stats1 + 2048;        // 512 floats zeros

    float* out0 = (float*)d_out;
    float* out1 = out0 + 13107200;
    float* out2 = out1 + 3276800;

    const float invN = 1.0f / (B * 25600);

    // 0) prep: x -> x4 (bufC) + pool, one pass over x
    prep_kernel<<<(8 * 25600 + TPB - 1) / TPB, TPB, 0, stream>>>(x, bufC, pool);

    // 1) all weight repacks + stats/zero-page init in one launch
    repack_all_kernel<<<(299520 + TPB - 1) / TPB, TPB, 0, stream>>>(
        w_bl1, wt1, w_bl2, wt2, w_d2, wtd2, w_d3, wtd3,
        w_off2, wtoff2, w_off3, wtoff3, w_d1, wtd1, stats1);

    // 2) deform1 (fused offset1 + MFMA MAC + skip): x4 -> hB bf16 NHWC
    deform1_kernel<<<8 * 25600 / 32, TPB, 0, stream>>>(
        bufC, w_off1, b_off1, wtd1, b_d1, pool, w_skip, b_skip, hB);

    // 3) conv1 (raw): hB -> hC bf16 NHWC (+stats1). x4 in bufC dead.
    conv3x3_mfma_kernel<0><<<800, TPB, 0, stream>>>(
        hB, wt1, hC, stats1, nullptr, invN, zpage);

    // 4) conv2 (normalizes input with stats1): hC -> hB bf16 NHWC (+stats2)
    conv3x3_mfma_kernel<1><<<800, TPB, 0, stream>>>(
        hC, wt2, hB, stats2, stats1, invN, zpage);

    // 5) apply2: hB -> out0 fp32 NCHW + hC bf16 NHWC (feat4)
    bn_apply_dual_kernel<<<8 * 400, TPB, 0, stream>>>(
        hB, stats2, out0, hC, 25600, invN);

    // 6) offset2 = offconv(feat4 hC) -> A
    offconv_mfma_kernel<<<8 * 6400 / 64, TPB, 0, stream>>>(
        hC, wtoff2, b_off2, A, 160, 160, 80, 80);

    // 7) feat_1_8 = deform2(feat4 hC, offset2) -> out1 fp32 + hB bf16 NHWC
    deform_mfma_kernel<64, 1><<<8 * 6400 / 32, TPB, 0, stream>>>(
        hC, A, wtd2, b_d2, out1, hB, 160, 160, 80, 80, 2);

    // 8) offset3 = offconv(feat8 hB) -> A
    offconv_mfma_kernel<<<8 * 1600 / 64, TPB, 0, stream>>>(
        hB, wtoff3, b_off3, A, 80, 80, 40, 40);

    // 9) feat_1_16 = deform3(feat8 hB, offset3) -> out2
    deform_mfma_kernel<256, 0><<<8 * 1600 / 32, TPB, 0, stream>>>(
        hB, A, wtd3, b_d3, out2, nullptr, 80, 80, 40, 40, 2);
}

// Round 18
// 216.392 us; speedup vs baseline: 33.1565x; 1.0384x over previous
//
#include <hip/hip_runtime.h>
#include <hip/hip_bf16.h>
#include <math.h>

#define TPB 256

typedef __attribute__((ext_vector_type(8))) short bf16x8_t;
typedef __attribute__((ext_vector_type(4))) float f32x4_t;
typedef __attribute__((ext_vector_type(4))) int i32x4_t;
typedef __attribute__((ext_vector_type(4))) unsigned short u16x4_t;
typedef __attribute__((ext_vector_type(8))) unsigned short u16x8_t;

#if defined(__has_builtin)
#if __has_builtin(__builtin_amdgcn_global_load_lds)
#define HAS_GLOAD_LDS 1
#endif
#endif

static __device__ __forceinline__ float bf16_to_f(unsigned short s) {
    union { unsigned u; float f; } cv;
    cv.u = ((unsigned)s) << 16;
    return cv.f;
}
static __device__ __forceinline__ short f_to_bf16(float v) {
    __hip_bfloat16 h = __float2bfloat16(v);
    return *(short*)&h;
}

// ------------------------------------------------- prep: x NCHW -> x4 NHWC4 + pool
__global__ void prep_kernel(const float* __restrict__ in,
                            float* __restrict__ x4,
                            float* __restrict__ pool)
{
    const int HWo = 25600, H = 640, W = 640;
    int idx = blockIdx.x * TPB + threadIdx.x;
    if (idx >= 8 * HWo) return;
    int b = idx / HWo, r = idx % HWo;
    int ho = r / 160, wo = r % 160;
    float s0 = 0.f, s1 = 0.f, s2 = 0.f;
    float* x4b = x4 + (size_t)b * H * W * 4;
#pragma unroll
    for (int dy = 0; dy < 4; ++dy) {
        int row = ho * 4 + dy;
        size_t base = ((size_t)row * W + wo * 4);
        f32x4_t a0 = *(const f32x4_t*)&in[((size_t)(b * 3 + 0) * H * W) + base];
        f32x4_t a1 = *(const f32x4_t*)&in[((size_t)(b * 3 + 1) * H * W) + base];
        f32x4_t a2 = *(const f32x4_t*)&in[((size_t)(b * 3 + 2) * H * W) + base];
        s0 += a0[0] + a0[1] + a0[2] + a0[3];
        s1 += a1[0] + a1[1] + a1[2] + a1[3];
        s2 += a2[0] + a2[1] + a2[2] + a2[3];
#pragma unroll
        for (int dx = 0; dx < 4; ++dx) {
            f32x4_t v = (f32x4_t){a0[dx], a1[dx], a2[dx], 0.f};
            *(f32x4_t*)&x4b[(base + dx) * 4] = v;
        }
    }
    pool[((size_t)(b * 3 + 0)) * HWo + r] = s0 * (1.0f / 16.0f);
    pool[((size_t)(b * 3 + 1)) * HWo + r] = s1 * (1.0f / 16.0f);
    pool[((size_t)(b * 3 + 2)) * HWo + r] = s2 * (1.0f / 16.0f);
}

// ------------------------------------------------- single repack-everything kernel
static __device__ __forceinline__ void repack_one(
    const float* __restrict__ w, short* __restrict__ wtf,
    int idx, int Oreal, int NFRAG)
{
    int j    = idx & 7;
    int lane = (idx >> 3) & 63;
    int t    = idx >> 9;
    int ocf  = t % NFRAG;
    int kc   = t / NFRAG;
    int oc   = ocf * 16 + (lane & 15);
    int tap  = kc >> 1;
    int ic   = (kc & 1) * 32 + (lane >> 4) * 8 + j;
    float v = 0.f;
    if (oc < Oreal)
        v = w[((size_t)(oc * 64 + ic)) * 9 + tap];
    wtf[idx] = f_to_bf16(v);
}

__global__ void repack_all_kernel(
    const float* __restrict__ w_bl1, short* __restrict__ wt1,
    const float* __restrict__ w_bl2, short* __restrict__ wt2,
    const float* __restrict__ w_d2,  short* __restrict__ wtd2,
    const float* __restrict__ w_d3,  short* __restrict__ wtd3,
    const float* __restrict__ w_off2, short* __restrict__ wtoff2,
    const float* __restrict__ w_off3, short* __restrict__ wtoff3,
    const float* __restrict__ w_d1,  short* __restrict__ wtd1,
    float* __restrict__ stats)
{
    int idx = blockIdx.x * TPB + threadIdx.x;
    if (idx < 36864) { repack_one(w_bl1, wt1, idx, 64, 4); return; }
    idx -= 36864;
    if (idx < 36864) { repack_one(w_bl2, wt2, idx, 64, 4); return; }
    idx -= 36864;
    if (idx < 36864) { repack_one(w_d2, wtd2, idx, 64, 4); return; }
    idx -= 36864;
    if (idx < 147456) { repack_one(w_d3, wtd3, idx, 256, 16); return; }
    idx -= 147456;
    if (idx < 18432) { repack_one(w_off2, wtoff2, idx, 18, 2); return; }
    idx -= 18432;
    if (idx < 18432) { repack_one(w_off3, wtoff3, idx, 18, 2); return; }
    idx -= 18432;
    if (idx < 2048) {
        int j = idx & 7, lane = (idx >> 3) & 63, ocf = idx >> 9;
        int oc = ocf * 16 + (lane & 15);
        int k  = (lane >> 4) * 8 + j;
        float v = 0.f;
        if (k < 27) v = w_d1[(size_t)oc * 27 + k];
        wtd1[idx] = f_to_bf16(v);
        return;
    }
    idx -= 2048;
    if (idx < 2560) stats[idx] = 0.f;
}

// ------------------------------------------------- MFMA conv 3x3 (64->64, s1)
template <int NORM>
__global__ __launch_bounds__(256, 2) void conv3x3_mfma_kernel(
    const short* __restrict__ xh,
    const short* __restrict__ wt,
    short* __restrict__ outh,
    float* __restrict__ stats,
    const float* __restrict__ stats_in,
    float invN,
    const float* __restrict__ zp)
{
    __shared__ short tile[2816 * 8];
    __shared__ float sstat[128];
    __shared__ float sm[64], sr[64];
    const int H = 160, W = 160, HW = 25600;
    int blk = blockIdx.x;
    int b  = blk / 100;
    int r  = blk % 100;
    int y0 = (r / 10) * 16;
    int x0 = (r % 10) * 16;
    const int tid = threadIdx.x;
    const short* inb = xh + (size_t)b * HW * 64;

    if (tid < 128) sstat[tid] = 0.f;
    if (NORM) {
        if (tid < 64) {
            float s = 0.f, s2 = 0.f;
#pragma unroll
            for (int k = 0; k < 8; ++k) {
                s  += stats_in[k * 128 + tid];
                s2 += stats_in[k * 128 + 64 + tid];
            }
            float mean = s * invN;
            float var  = s2 * invN - mean * mean;
            sm[tid] = mean;
            sr[tid] = rsqrtf(var + 1e-5f);
        }
        __syncthreads();
    }

    if (NORM == 0) {
#ifdef HAS_GLOAD_LDS
        // async streaming: linear LDS dest (lane-consecutive 16B) + per-lane
        // pre-swizzled global source. vmcnt drained by __syncthreads.
#pragma unroll
        for (int it = 0; it < 11; ++it) {
            int item = it * 256 + tid;
            int c8  = item & 7;
            int pix = item >> 3;
            int row = pix / 18;
            int col = pix - row * 18;
            int y = y0 + row - 1;
            int x = x0 + col - 1;
            bool ok = (pix < 324) & (y >= 0) & (y < H) & (x >= 0) & (x < W);
            int cs = c8 ^ (col & 7);
            const short* src = ok
                ? &inb[((size_t)y * W + x) * 64 + (cs << 3)]
                : (const short*)zp;
            __builtin_amdgcn_global_load_lds(
                (const __attribute__((address_space(1))) unsigned int*)src,
                (__attribute__((address_space(3))) unsigned int*)
                    &tile[(it * 256 + (tid & 192)) * 8],
                16, 0, 0);
        }
#else
#pragma unroll
        for (int it = 0; it < 11; ++it) {
            int item = it * 256 + tid;
            int c8  = item & 7;
            int pix = item >> 3;
            int row = pix / 18;
            int col = pix - row * 18;
            int y = y0 + row - 1;
            int x = x0 + col - 1;
            bool ok = (pix < 324) & (y >= 0) & (y < H) & (x >= 0) & (x < W);
            int cs = c8 ^ (col & 7);
            const short* src = ok
                ? &inb[((size_t)y * W + x) * 64 + (cs << 3)]
                : (const short*)zp;
            *(bf16x8_t*)&tile[item * 8] = *(const bf16x8_t*)src;
        }
#endif
    } else {
#pragma unroll
        for (int it = 0; it < 11; ++it) {
            int item = it * 256 + tid;
            int c8  = item & 7;
            int pix = item >> 3;
            int row = pix / 18;
            int col = pix - row * 18;
            int y = y0 + row - 1;
            int x = x0 + col - 1;
            bool ok = (pix < 324) & (y >= 0) & (y < H) & (x >= 0) & (x < W);
            int cs = c8 ^ (col & 7);
            const short* src = ok
                ? &inb[((size_t)y * W + x) * 64 + (cs << 3)]
                : (const short*)zp;
            bf16x8_t v = *(const bf16x8_t*)src;
            int cs8 = cs << 3;
            bf16x8_t o;
#pragma unroll
            for (int j = 0; j < 8; ++j) {
                float f = (bf16_to_f((unsigned short)v[j]) - sm[cs8 + j]) * sr[cs8 + j];
                f = f > 0.f ? f : 0.f;
                o[j] = ok ? f_to_bf16(f) : (short)0;
            }
            *(bf16x8_t*)&tile[item * 8] = o;
        }
    }
    __syncthreads();

    const int wv  = tid >> 6;
    const int l   = tid & 63;
    const int l15 = l & 15;
    const int lg  = l >> 4;

    f32x4_t acc[4][4];
#pragma unroll
    for (int i = 0; i < 4; ++i)
#pragma unroll
        for (int j = 0; j < 4; ++j)
            acc[i][j] = (f32x4_t){0.f, 0.f, 0.f, 0.f};

    bf16x8_t bfp[2][4], afp[2][4];
#pragma unroll
    for (int nf = 0; nf < 4; ++nf)
        bfp[0][nf] = *(const bf16x8_t*)(wt + (((size_t)(0 * 4 + nf)) * 64 + l) * 8);
    {
        int colr = l15;
        int chunk = lg ^ (colr & 7);
#pragma unroll
        for (int mf = 0; mf < 4; ++mf)
            afp[0][mf] = *(const bf16x8_t*)&tile[((wv * 4 + mf) * 18 + colr) * 64 + chunk * 8];
    }
#pragma unroll
    for (int kc = 0; kc < 18; ++kc) {
        const int cur = kc & 1, nxt = cur ^ 1;
        if (kc + 1 < 18) {
            int kn = kc + 1;
#pragma unroll
            for (int nf = 0; nf < 4; ++nf)
                bfp[nxt][nf] = *(const bf16x8_t*)(wt + (((size_t)(kn * 4 + nf)) * 64 + l) * 8);
            int tap = kn >> 1;
            int dy = tap / 3, dx = tap % 3;
            int colr = l15 + dx;
            int chunk = (((kn & 1) << 2) + lg) ^ (colr & 7);
#pragma unroll
            for (int mf = 0; mf < 4; ++mf)
                afp[nxt][mf] = *(const bf16x8_t*)&tile[((wv * 4 + mf + dy) * 18 + colr) * 64 + chunk * 8];
        }
#pragma unroll
        for (int mf = 0; mf < 4; ++mf)
#pragma unroll
            for (int nf = 0; nf < 4; ++nf)
                acc[mf][nf] = __builtin_amdgcn_mfma_f32_16x16x32_bf16(
                    afp[cur][mf], bfp[cur][nf], acc[mf][nf], 0, 0, 0);
    }

    __syncthreads();
#pragma unroll
    for (int mf = 0; mf < 4; ++mf) {
        int py = wv * 4 + mf;
#pragma unroll
        for (int nf = 0; nf < 4; ++nf) {
            int oc = nf * 16 + l15;
#pragma unroll
            for (int k = 0; k < 4; ++k)
                tile[((py * 16) + lg * 4 + k) * 64 + oc] = f_to_bf16(acc[mf][nf][k]);
        }
    }
    __syncthreads();
    short* outb = outh + (size_t)b * HW * 64;
#pragma unroll
    for (int j = 0; j < 8; ++j) {
        int item = j * 256 + tid;
        int c8  = item & 7;
        int pix = item >> 3;
        int py  = pix >> 4, px = pix & 15;
        *(bf16x8_t*)&outb[((size_t)(y0 + py) * W + x0 + px) * 64 + c8 * 8] =
            *(bf16x8_t*)&tile[pix * 64 + c8 * 8];
    }

#pragma unroll
    for (int nf = 0; nf < 4; ++nf) {
        float s = 0.f, s2 = 0.f;
#pragma unroll
        for (int mf = 0; mf < 4; ++mf)
#pragma unroll
            for (int k = 0; k < 4; ++k) {
                float v = acc[mf][nf][k];
                s += v; s2 += v * v;
            }
        s  += __shfl_xor(s, 16, 64);  s  += __shfl_xor(s, 32, 64);
        s2 += __shfl_xor(s2, 16, 64); s2 += __shfl_xor(s2, 32, 64);
        if (lg == 0) {
            int oc = nf * 16 + l15;
            atomicAdd(&sstat[oc], s);
            atomicAdd(&sstat[64 + oc], s2);
        }
    }
    __syncthreads();
    float* st = stats + (size_t)(blockIdx.x & 7) * 128;
    if (tid < 128) atomicAdd(&st[tid], sstat[tid]);
}

// ------------------------------------------------- BN apply dual
__global__ void bn_apply_dual_kernel(const short* __restrict__ in,
                                     const float* __restrict__ stats,
                                     float* __restrict__ out,
                                     short* __restrict__ outh,
                                     int HW, float invN)
{
    __shared__ float ftile[64][65];
    __shared__ float sm[64], sr[64];
    int nchunks = HW >> 6;
    int b  = blockIdx.x / nchunks;
    int p0 = (blockIdx.x % nchunks) << 6;
    int tid = threadIdx.x;
    if (tid < 64) {
        float s = 0.f, s2 = 0.f;
#pragma unroll
        for (int k = 0; k < 8; ++k) {
            s  += stats[k * 128 + tid];
            s2 += stats[k * 128 + 64 + tid];
        }
        float mean = s * invN;
        float var  = s2 * invN - mean * mean;
        sm[tid] = mean;
        sr[tid] = rsqrtf(var + 1e-5f);
    }
    __syncthreads();
#pragma unroll
    for (int it = 0; it < 2; ++it) {
        int item = it * 256 + tid;
        int p = item >> 3, c0 = (item & 7) * 8;
        size_t gi = ((size_t)(b * HW + p0 + p)) * 64 + c0;
        bf16x8_t v = *(const bf16x8_t*)&in[gi];
        bf16x8_t o;
#pragma unroll
        for (int j = 0; j < 8; ++j) {
            float f = (bf16_to_f((unsigned short)v[j]) - sm[c0 + j]) * sr[c0 + j];
            f = f > 0.f ? f : 0.f;
            ftile[p][c0 + j] = f;
            o[j] = f_to_bf16(f);
        }
        *(bf16x8_t*)&outh[gi] = o;
    }
    __syncthreads();
#pragma unroll
    for (int rep = 0; rep < 16; ++rep) {
        int item = rep * 256 + tid;
        int c = item >> 6, p = item & 63;
        out[((size_t)b * 64 + c) * HW + p0 + p] = ftile[p][c];
    }
}

// ------------------------------------------------- offset2/3: MFMA conv, N=18
__global__ __launch_bounds__(256, 1) void offconv_mfma_kernel(
    const short* __restrict__ xh,
    const short* __restrict__ wt,
    const float* __restrict__ bias,
    float* __restrict__ out,
    int H, int W, int Ho, int Wo)
{
    const int HW = Ho * Wo;
    const int tid = threadIdx.x;
    const int wv = tid >> 6, l = tid & 63;
    const int l15 = l & 15, lg = l >> 4;
    const int pix0 = blockIdx.x * 64 + wv * 16;
    const int b = pix0 / HW;
    const int r0 = pix0 - b * HW;

    int rp = r0 + l15;
    int ho = rp / Wo, wo = rp % Wo;
    const short* xb = xh + (size_t)b * H * W * 64;

    f32x4_t acc[2];
    acc[0] = (f32x4_t){0.f, 0.f, 0.f, 0.f};
    acc[1] = (f32x4_t){0.f, 0.f, 0.f, 0.f};

#pragma unroll 2
    for (int kc = 0; kc < 18; ++kc) {
        int tap = kc >> 1;
        int iy = ho * 2 - 1 + tap / 3;
        int ix = wo * 2 - 1 + tap % 3;
        bf16x8_t af = {};
        if (iy >= 0 && iy < H && ix >= 0 && ix < W)
            af = *(const bf16x8_t*)&xb[((size_t)iy * W + ix) * 64
                                       + (kc & 1) * 32 + lg * 8];
#pragma unroll
        for (int nf = 0; nf < 2; ++nf) {
            bf16x8_t bf = *(const bf16x8_t*)(wt + (((size_t)(kc * 2 + nf)) * 64 + l) * 8);
            acc[nf] = __builtin_amdgcn_mfma_f32_16x16x32_bf16(af, bf, acc[nf], 0, 0, 0);
        }
    }

#pragma unroll
    for (int nf = 0; nf < 2; ++nf) {
        int oc = nf * 16 + l15;
        if (oc < 18) {
            float bv = bias[oc];
            f32x4_t v = acc[nf];
            v[0] += bv; v[1] += bv; v[2] += bv; v[3] += bv;
            *(f32x4_t*)&out[((size_t)(b * 18 + oc)) * HW + r0 + lg * 4] = v;
        }
    }
}

// ------------------------------------------------- deform1: fused offset1 +
// deform (C=3, MFMA MAC) + skip
__global__ __launch_bounds__(256, 1) void deform1_kernel(
    const float* __restrict__ x4,
    const float* __restrict__ wof,
    const float* __restrict__ bof,
    const short* __restrict__ wtd1,
    const float* __restrict__ bias,
    const float* __restrict__ pool,
    const float* __restrict__ wsk,
    const float* __restrict__ bsk,
    short* __restrict__ outh)
{
    const int H = 640, W = 640, Ho = 160, Wo = 160, HW = 25600;
    constexpr int P = 32;
    __shared__ float xtap[P * 9][4];
    __shared__ float swof[486];
    __shared__ float sbof[18];
    __shared__ float spool[3][P];
    __shared__ float off1[P][18];
    __shared__ alignas(16) short sampb[P][40];
    __shared__ int   sidx[P * 9][4];
    __shared__ float swt[P * 9][4];
    const int tid = threadIdx.x;
    const int pix0 = blockIdx.x * P;
    const int b = pix0 / HW;
    const int r0 = pix0 - b * HW;
    const float* xb = x4 + (size_t)b * H * W * 4;

    for (int item = tid; item < P * 9; item += TPB) {
        int p = item / 9, tap = item % 9;
        int r = r0 + p, ho = r / Wo, wo = r % Wo;
        int iy = ho * 4 - 1 + tap / 3;
        int ix = wo * 4 - 1 + tap % 3;
        f32x4_t s = (f32x4_t){0.f, 0.f, 0.f, 0.f};
        if (iy >= 0 && iy < H && ix >= 0 && ix < W)
            s = *(const f32x4_t*)&xb[((size_t)iy * W + ix) * 4];
        *(f32x4_t*)xtap[item] = s;
    }
    for (int i = tid; i < P * 40; i += TPB) ((short*)sampb)[i] = 0;
    for (int i = tid; i < 96; i += TPB) {
        int c = i >> 5, p = i & 31;
        spool[c][p] = pool[((size_t)(b * 3 + c)) * HW + r0 + p];
    }
    for (int item = tid; item < 486; item += TPB) swof[item] = wof[item];
    if (tid < 18) sbof[tid] = bof[tid];
    __syncthreads();

    for (int item = tid; item < P * 18; item += TPB) {
        int p = item / 18, o = item % 18;
        float acc = sbof[o];
#pragma unroll
        for (int tap = 0; tap < 9; ++tap) {
            const float* xt = xtap[p * 9 + tap];
#pragma unroll
            for (int c = 0; c < 3; ++c)
                acc += xt[c] * swof[(o * 3 + c) * 9 + tap];
        }
        off1[p][o] = acc;
    }
    __syncthreads();

    for (int item = tid; item < P * 9; item += TPB) {
        int p = item / 9, tap = item % 9;
        int r = r0 + p, ho = r / Wo, wo = r % Wo;
        float dy = off1[p][2 * tap];
        float dx = off1[p][2 * tap + 1];
        float ys = (float)(ho * 4 - 1 + tap / 3) + dy;
        float xs = (float)(wo * 4 - 1 + tap % 3) + dx;
        float y0f = floorf(ys), x0f = floorf(xs);
        float fy = ys - y0f, fx = xs - x0f;
        int y0 = (int)y0f, x0 = (int)x0f;
        float wts[4] = {(1.f - fy) * (1.f - fx), (1.f - fy) * fx,
                        fy * (1.f - fx),          fy * fx};
#pragma unroll
        for (int j = 0; j < 4; ++j) {
            int iy = y0 + (j >> 1), ix = x0 + (j & 1);
            bool v = (iy >= 0) && (iy < H) && (ix >= 0) && (ix < W);
            sidx[item][j] = v ? (iy * W + ix) : 0;
            swt[item][j]  = v ? wts[j] : 0.f;
        }
    }
    __syncthreads();

    for (int item = tid; item < P * 9; item += TPB) {
        int p = item / 9, tap = item % 9;
        i32x4_t id4 = *(const i32x4_t*)sidx[item];
        f32x4_t w4  = *(const f32x4_t*)swt[item];
        f32x4_t a0 = *(const f32x4_t*)&xb[(size_t)(unsigned)id4[0] * 4];
        f32x4_t a1 = *(const f32x4_t*)&xb[(size_t)(unsigned)id4[1] * 4];
        f32x4_t a2 = *(const f32x4_t*)&xb[(size_t)(unsigned)id4[2] * 4];
        f32x4_t a3 = *(const f32x4_t*)&xb[(size_t)(unsigned)id4[3] * 4];
        sampb[p][0 * 9 + tap] = f_to_bf16(
            w4[0]*a0[0] + w4[1]*a1[0] + w4[2]*a2[0] + w4[3]*a3[0]);
        sampb[p][1 * 9 + tap] = f_to_bf16(
            w4[0]*a0[1] + w4[1]*a1[1] + w4[2]*a2[1] + w4[3]*a3[1]);
        sampb[p][2 * 9 + tap] = f_to_bf16(
            w4[0]*a0[2] + w4[1]*a1[2] + w4[2]*a2[2] + w4[3]*a3[2]);
    }
    __syncthreads();

    const int wv = tid >> 6;
    const int l  = tid & 63;
    const int l15 = l & 15, lg = l >> 4;
    bf16x8_t bf  = *(const bf16x8_t*)(wtd1 + (((size_t)wv * 64 + l)) * 8);
    bf16x8_t af0 = *(const bf16x8_t*)&sampb[l15][lg * 8];
    bf16x8_t af1 = *(const bf16x8_t*)&sampb[l15 + 16][lg * 8];
    f32x4_t z = (f32x4_t){0.f, 0.f, 0.f, 0.f};
    f32x4_t acc0 = __builtin_amdgcn_mfma_f32_16x16x32_bf16(af0, bf, z, 0, 0, 0);
    f32x4_t acc1 = __builtin_amdgcn_mfma_f32_16x16x32_bf16(af1, bf, z, 0, 0, 0);

    int oc = wv * 16 + l15;
    float bb = bias[oc] + bsk[oc];
    float w0 = wsk[oc * 3 + 0], w1 = wsk[oc * 3 + 1], w2 = wsk[oc * 3 + 2];
    short* otile = (short*)xtap;
    __syncthreads();
#pragma unroll
    for (int mf = 0; mf < 2; ++mf) {
        f32x4_t a = mf ? acc1 : acc0;
#pragma unroll
        for (int k = 0; k < 4; ++k) {
            int px = mf * 16 + lg * 4 + k;
            float sv = w0 * spool[0][px] + w1 * spool[1][px] + w2 * spool[2][px];
            otile[px * 64 + oc] = f_to_bf16(a[k] + bb + sv);
        }
    }
    __syncthreads();
    {
        int c8 = tid & 7, px = tid >> 3;
        *(bf16x8_t*)&outh[((size_t)(b * HW + r0 + px)) * 64 + c8 * 8] =
            *(bf16x8_t*)&otile[px * 64 + c8 * 8];
    }
}

// ------------------------------------------------- deform MFMA: C=64 -> O
template <int O, int DUAL>
__global__ __launch_bounds__(256, 1) void deform_mfma_kernel(
    const short* __restrict__ xh,
    const float* __restrict__ off,
    const short* __restrict__ wt,
    const float* __restrict__ bias,
    float* __restrict__ out,
    short* __restrict__ outh,
    int H, int W, int Ho, int Wo, int stride)
{
    constexpr int NF = O / 64;
    constexpr int NFRAG = O / 16;
    constexpr int P  = 32;
    __shared__ alignas(16) short samp[P * 576];
    __shared__ int   sidx[P * 9][4];
    __shared__ float swt[P * 9][4];

    const int tid = threadIdx.x;
    const int HW = Ho * Wo;
    const int pix0 = blockIdx.x * P;
    const int b = pix0 / HW;
    const int r0 = pix0 - b * HW;

    for (int item = tid; item < P * 9; item += TPB) {
        int p = item / 9, tap = item % 9;
        int r = r0 + p, ho = r / Wo, wo = r % Wo;
        float dy = off[((size_t)(b * 18 + 2 * tap) * Ho + ho) * Wo + wo];
        float dx = off[((size_t)(b * 18 + 2 * tap + 1) * Ho + ho) * Wo + wo];
        float ys = (float)(ho * stride - 1 + tap / 3) + dy;
        float xs = (float)(wo * stride - 1 + tap % 3) + dx;
        float y0f = floorf(ys), x0f = floorf(xs);
        float fy = ys - y0f, fx = xs - x0f;
        int y0 = (int)y0f, x0 = (int)x0f;
        float wts[4] = {(1.f - fy) * (1.f - fx), (1.f - fy) * fx,
                        fy * (1.f - fx),          fy * fx};
#pragma unroll
        for (int j = 0; j < 4; ++j) {
            int iy = y0 + (j >> 1), ix = x0 + (j & 1);
            bool v = (iy >= 0) && (iy < H) && (ix >= 0) && (ix < W);
            sidx[item][j] = v ? (iy * W + ix) : 0;
            swt[item][j]  = v ? wts[j] : 0.f;
        }
    }
    __syncthreads();

    // gather: 8-lane group = one pixel; lane loads 8 channels (16B)
    {
        const int p  = tid >> 3;        // pixel 0..31
        const int ic = (tid & 7) * 8;   // channel octet
        const int swc = (ic >> 3) ^ (p & 7);
        const short* xb = xh + (size_t)b * H * W * 64;
#pragma unroll 3
        for (int tap = 0; tap < 9; ++tap) {
            int e = p * 9 + tap;
            i32x4_t id4 = *(const i32x4_t*)sidx[e];
            f32x4_t w4  = *(const f32x4_t*)swt[e];
            u16x8_t u0 = *(const u16x8_t*)&xb[(size_t)(unsigned)id4[0] * 64 + ic];
            u16x8_t u1 = *(const u16x8_t*)&xb[(size_t)(unsigned)id4[1] * 64 + ic];
            u16x8_t u2 = *(const u16x8_t*)&xb[(size_t)(unsigned)id4[2] * 64 + ic];
            u16x8_t u3 = *(const u16x8_t*)&xb[(size_t)(unsigned)id4[3] * 64 + ic];
            bf16x8_t o;
#pragma unroll
            for (int j = 0; j < 8; ++j) {
                float v = w4[0]*bf16_to_f(u0[j]) + w4[1]*bf16_to_f(u1[j])
                        + w4[2]*bf16_to_f(u2[j]) + w4[3]*bf16_to_f(u3[j]);
                o[j] = f_to_bf16(v);
            }
            *(bf16x8_t*)&samp[p * 576 + (tap * 8 + swc) * 8] = o;
        }
    }
    __syncthreads();

    const int wv = tid >> 6;
    const int l  = tid & 63;
    const int l15 = l & 15, lg = l >> 4;
    f32x4_t acc[2][NF];
#pragma unroll
    for (int mf = 0; mf < 2; ++mf)
#pragma unroll
        for (int nf = 0; nf < NF; ++nf)
            acc[mf][nf] = (f32x4_t){0.f, 0.f, 0.f, 0.f};

#pragma unroll 2
    for (int kc = 0; kc < 18; ++kc) {
        int tap = kc >> 1;
        int low = (((kc & 1) << 2) | lg) ^ (l15 & 7);
        bf16x8_t af0 = *(const bf16x8_t*)&samp[l15 * 576 + (tap * 8 + low) * 8];
        bf16x8_t af1 = *(const bf16x8_t*)&samp[(l15 + 16) * 576 + (tap * 8 + low) * 8];
#pragma unroll
        for (int nf = 0; nf < NF; ++nf) {
            int ocf = wv * NF + nf;
            bf16x8_t bf = *(const bf16x8_t*)(wt + (((size_t)(kc * NFRAG + ocf)) * 64 + l) * 8);
            acc[0][nf] = __builtin_amdgcn_mfma_f32_16x16x32_bf16(af0, bf, acc[0][nf], 0, 0, 0);
            acc[1][nf] = __builtin_amdgcn_mfma_f32_16x16x32_bf16(af1, bf, acc[1][nf], 0, 0, 0);
        }
    }

#pragma unroll
    for (int mf = 0; mf < 2; ++mf)
#pragma unroll
        for (int nf = 0; nf < NF; ++nf) {
            int oc = (wv * NF + nf) * 16 + l15;
            float bv = bias[oc];
            f32x4_t v = acc[mf][nf];
            v[0] += bv; v[1] += bv; v[2] += bv; v[3] += bv;
            acc[mf][nf] = v;
            *(f32x4_t*)&out[((size_t)(b * O + oc)) * HW + r0 + mf * 16 + lg * 4] = v;
        }

    if (DUAL) {
        __syncthreads();
        short* otile = samp;
#pragma unroll
        for (int mf = 0; mf < 2; ++mf) {
            int oc = wv * 16 + l15;
#pragma unroll
            for (int k = 0; k < 4; ++k) {
                int px = mf * 16 + lg * 4 + k;
                otile[px * 64 + oc] = f_to_bf16(acc[mf][0][k]);
            }
        }
        __syncthreads();
        int c8 = tid & 7, px = tid >> 3;
        *(bf16x8_t*)&outh[((size_t)(b * HW + r0 + px)) * 64 + c8 * 8] =
            *(bf16x8_t*)&otile[px * 64 + c8 * 8];
    }
}

// ---------------------------------------------------------------- launch
extern "C" void kernel_launch(void* const* d_in, const int* in_sizes, int n_in,
                              void* d_out, int out_size, void* d_ws, size_t ws_size,
                              hipStream_t stream)
{
    const float* x      = (const float*)d_in[0];
    const float* w_off1 = (const float*)d_in[1];
    const float* b_off1 = (const float*)d_in[2];
    const float* w_d1   = (const float*)d_in[3];
    const float* b_d1   = (const float*)d_in[4];
    const float* w_skip = (const float*)d_in[5];
    const float* b_skip = (const float*)d_in[6];
    const float* w_bl1  = (const float*)d_in[7];
    const float* w_bl2  = (const float*)d_in[8];
    const float* w_off2 = (const float*)d_in[9];
    const float* b_off2 = (const float*)d_in[10];
    const float* w_d2   = (const float*)d_in[11];
    const float* b_d2   = (const float*)d_in[12];
    const float* w_off3 = (const float*)d_in[13];
    const float* b_off3 = (const float*)d_in[14];
    const float* w_d3   = (const float*)d_in[15];
    const float* b_d3   = (const float*)d_in[16];

    const int B = 8;
    float* A     = (float*)d_ws;
    float* bufB  = A + 3686400;
    float* bufC  = bufB + 13107200;

    short* hB   = (short*)bufB;
    short* hC   = (short*)bufC;
    float* pool = bufB + 8000000;

    short* wt1    = (short*)(A + 1000000);
    short* wt2    = wt1 + 18 * 4 * 512;
    short* wtd2   = (short*)(A + 1500000);
    short* wtd3   = (short*)(A + 1550000);
    short* wtoff2 = (short*)(A + 1700000);
    short* wtoff3 = (short*)(A + 1712000);
    short* wtd1   = (short*)(A + 1750000);
    float* stats1 = A + 1800000;
    float* stats2 = stats1 + 1024;
    float* zpage  = stats1 + 2048;

    float* out0 = (float*)d_out;
    float* out1 = out0 + 13107200;
    float* out2 = out1 + 3276800;

    const float invN = 1.0f / (B * 25600);

    prep_kernel<<<(8 * 25600 + TPB - 1) / TPB, TPB, 0, stream>>>(x, bufC, pool);

    repack_all_kernel<<<(299520 + TPB - 1) / TPB, TPB, 0, stream>>>(
        w_bl1, wt1, w_bl2, wt2, w_d2, wtd2, w_d3, wtd3,
        w_off2, wtoff2, w_off3, wtoff3, w_d1, wtd1, stats1);

    deform1_kernel<<<8 * 25600 / 32, TPB, 0, stream>>>(
        bufC, w_off1, b_off1, wtd1, b_d1, pool, w_skip, b_skip, hB);

    conv3x3_mfma_kernel<0><<<800, TPB, 0, stream>>>(
        hB, wt1, hC, stats1, nullptr, invN, zpage);

    conv3x3_mfma_kernel<1><<<800, TPB, 0, stream>>>(
        hC, wt2, hB, stats2, stats1, invN, zpage);

    bn_apply_dual_kernel<<<8 * 400, TPB, 0, stream>>>(
        hB, stats2, out0, hC, 25600, invN);

    offconv_mfma_kernel<<<8 * 6400 / 64, TPB, 0, stream>>>(
        hC, wtoff2, b_off2, A, 160, 160, 80, 80);

    deform_mfma_kernel<64, 1><<<8 * 6400 / 32, TPB, 0, stream>>>(
        hC, A, wtd2, b_d2, out1, hB, 160, 160, 80, 80, 2);

    offconv_mfma_kernel<<<8 * 1600 / 64, TPB, 0, stream>>>(
        hB, wtoff3, b_off3, A, 80, 80, 40, 40);

    deform_mfma_kernel<256, 0><<<8 * 1600 / 32, TPB, 0, stream>>>(
        hB, A, wtd3, b_d3, out2, nullptr, 80, 80, 40, 40, 2);
}

// Round 19
// 206.216 us; speedup vs baseline: 34.7926x; 1.0493x over previous
//
#include <hip/hip_runtime.h>
#include <hip/hip_bf16.h>
#include <math.h>

#define TPB 256

typedef __attribute__((ext_vector_type(8))) short bf16x8_t;
typedef __attribute__((ext_vector_type(4))) float f32x4_t;
typedef __attribute__((ext_vector_type(4))) int i32x4_t;
typedef __attribute__((ext_vector_type(4))) unsigned short u16x4_t;
typedef __attribute__((ext_vector_type(8))) unsigned short u16x8_t;

#if defined(__has_builtin)
#if __has_builtin(__builtin_amdgcn_global_load_lds)
#define HAS_GLOAD_LDS 1
#endif
#endif

static __device__ __forceinline__ float bf16_to_f(unsigned short s) {
    union { unsigned u; float f; } cv;
    cv.u = ((unsigned)s) << 16;
    return cv.f;
}
static __device__ __forceinline__ short f_to_bf16(float v) {
    __hip_bfloat16 h = __float2bfloat16(v);
    return *(short*)&h;
}

// ------------------------------------------------- prep: x NCHW -> x4 NHWC4 bf16 + pool
__global__ void prep_kernel(const float* __restrict__ in,
                            unsigned short* __restrict__ x4,
                            float* __restrict__ pool)
{
    const int HWo = 25600, H = 640, W = 640;
    int idx = blockIdx.x * TPB + threadIdx.x;
    if (idx >= 8 * HWo) return;
    int b = idx / HWo, r = idx % HWo;
    int ho = r / 160, wo = r % 160;
    float s0 = 0.f, s1 = 0.f, s2 = 0.f;
    unsigned short* x4b = x4 + (size_t)b * H * W * 4;
#pragma unroll
    for (int dy = 0; dy < 4; ++dy) {
        int row = ho * 4 + dy;
        size_t base = ((size_t)row * W + wo * 4);
        f32x4_t a0 = *(const f32x4_t*)&in[((size_t)(b * 3 + 0) * H * W) + base];
        f32x4_t a1 = *(const f32x4_t*)&in[((size_t)(b * 3 + 1) * H * W) + base];
        f32x4_t a2 = *(const f32x4_t*)&in[((size_t)(b * 3 + 2) * H * W) + base];
        s0 += a0[0] + a0[1] + a0[2] + a0[3];
        s1 += a1[0] + a1[1] + a1[2] + a1[3];
        s2 += a2[0] + a2[1] + a2[2] + a2[3];
#pragma unroll
        for (int dx = 0; dx < 4; ++dx) {
            u16x4_t v;
            v[0] = (unsigned short)f_to_bf16(a0[dx]);
            v[1] = (unsigned short)f_to_bf16(a1[dx]);
            v[2] = (unsigned short)f_to_bf16(a2[dx]);
            v[3] = 0;
            *(u16x4_t*)&x4b[(base + dx) * 4] = v;
        }
    }
    pool[((size_t)(b * 3 + 0)) * HWo + r] = s0 * (1.0f / 16.0f);
    pool[((size_t)(b * 3 + 1)) * HWo + r] = s1 * (1.0f / 16.0f);
    pool[((size_t)(b * 3 + 2)) * HWo + r] = s2 * (1.0f / 16.0f);
}

// ------------------------------------------------- single repack-everything kernel
static __device__ __forceinline__ void repack_one(
    const float* __restrict__ w, short* __restrict__ wtf,
    int idx, int Oreal, int NFRAG)
{
    int j    = idx & 7;
    int lane = (idx >> 3) & 63;
    int t    = idx >> 9;
    int ocf  = t % NFRAG;
    int kc   = t / NFRAG;
    int oc   = ocf * 16 + (lane & 15);
    int tap  = kc >> 1;
    int ic   = (kc & 1) * 32 + (lane >> 4) * 8 + j;
    float v = 0.f;
    if (oc < Oreal)
        v = w[((size_t)(oc * 64 + ic)) * 9 + tap];
    wtf[idx] = f_to_bf16(v);
}

__global__ void repack_all_kernel(
    const float* __restrict__ w_bl1, short* __restrict__ wt1,
    const float* __restrict__ w_bl2, short* __restrict__ wt2,
    const float* __restrict__ w_d2,  short* __restrict__ wtd2,
    const float* __restrict__ w_d3,  short* __restrict__ wtd3,
    const float* __restrict__ w_off2, short* __restrict__ wtoff2,
    const float* __restrict__ w_off3, short* __restrict__ wtoff3,
    const float* __restrict__ w_d1,  short* __restrict__ wtd1,
    float* __restrict__ stats)
{
    int idx = blockIdx.x * TPB + threadIdx.x;
    if (idx < 36864) { repack_one(w_bl1, wt1, idx, 64, 4); return; }
    idx -= 36864;
    if (idx < 36864) { repack_one(w_bl2, wt2, idx, 64, 4); return; }
    idx -= 36864;
    if (idx < 36864) { repack_one(w_d2, wtd2, idx, 64, 4); return; }
    idx -= 36864;
    if (idx < 147456) { repack_one(w_d3, wtd3, idx, 256, 16); return; }
    idx -= 147456;
    if (idx < 18432) { repack_one(w_off2, wtoff2, idx, 18, 2); return; }
    idx -= 18432;
    if (idx < 18432) { repack_one(w_off3, wtoff3, idx, 18, 2); return; }
    idx -= 18432;
    if (idx < 2048) {
        int j = idx & 7, lane = (idx >> 3) & 63, ocf = idx >> 9;
        int oc = ocf * 16 + (lane & 15);
        int k  = (lane >> 4) * 8 + j;
        float v = 0.f;
        if (k < 27) v = w_d1[(size_t)oc * 27 + k];
        wtd1[idx] = f_to_bf16(v);
        return;
    }
    idx -= 2048;
    if (idx < 2560) stats[idx] = 0.f;
}

// ------------------------------------------------- MFMA conv 3x3 (64->64, s1)
template <int NORM>
__global__ __launch_bounds__(256, 2) void conv3x3_mfma_kernel(
    const short* __restrict__ xh,
    const short* __restrict__ wt,
    short* __restrict__ outh,
    float* __restrict__ stats,
    const float* __restrict__ stats_in,
    float invN,
    const float* __restrict__ zp)
{
    __shared__ short tile[2816 * 8];
    __shared__ float sstat[128];
    __shared__ float sm[64], sr[64];
    const int H = 160, W = 160, HW = 25600;
    int blk = blockIdx.x;
    int b  = blk / 100;
    int r  = blk % 100;
    int y0 = (r / 10) * 16;
    int x0 = (r % 10) * 16;
    const int tid = threadIdx.x;
    const short* inb = xh + (size_t)b * HW * 64;

    if (tid < 128) sstat[tid] = 0.f;
    if (NORM) {
        if (tid < 64) {
            float s = 0.f, s2 = 0.f;
#pragma unroll
            for (int k = 0; k < 8; ++k) {
                s  += stats_in[k * 128 + tid];
                s2 += stats_in[k * 128 + 64 + tid];
            }
            float mean = s * invN;
            float var  = s2 * invN - mean * mean;
            sm[tid] = mean;
            sr[tid] = rsqrtf(var + 1e-5f);
        }
        __syncthreads();
    }

    if (NORM == 0) {
#ifdef HAS_GLOAD_LDS
#pragma unroll
        for (int it = 0; it < 11; ++it) {
            int item = it * 256 + tid;
            int c8  = item & 7;
            int pix = item >> 3;
            int row = pix / 18;
            int col = pix - row * 18;
            int y = y0 + row - 1;
            int x = x0 + col - 1;
            bool ok = (pix < 324) & (y >= 0) & (y < H) & (x >= 0) & (x < W);
            int cs = c8 ^ (col & 7);
            const short* src = ok
                ? &inb[((size_t)y * W + x) * 64 + (cs << 3)]
                : (const short*)zp;
            __builtin_amdgcn_global_load_lds(
                (const __attribute__((address_space(1))) unsigned int*)src,
                (__attribute__((address_space(3))) unsigned int*)
                    &tile[(it * 256 + (tid & 192)) * 8],
                16, 0, 0);
        }
#else
#pragma unroll
        for (int it = 0; it < 11; ++it) {
            int item = it * 256 + tid;
            int c8  = item & 7;
            int pix = item >> 3;
            int row = pix / 18;
            int col = pix - row * 18;
            int y = y0 + row - 1;
            int x = x0 + col - 1;
            bool ok = (pix < 324) & (y >= 0) & (y < H) & (x >= 0) & (x < W);
            int cs = c8 ^ (col & 7);
            const short* src = ok
                ? &inb[((size_t)y * W + x) * 64 + (cs << 3)]
                : (const short*)zp;
            *(bf16x8_t*)&tile[item * 8] = *(const bf16x8_t*)src;
        }
#endif
    } else {
#pragma unroll
        for (int it = 0; it < 11; ++it) {
            int item = it * 256 + tid;
            int c8  = item & 7;
            int pix = item >> 3;
            int row = pix / 18;
            int col = pix - row * 18;
            int y = y0 + row - 1;
            int x = x0 + col - 1;
            bool ok = (pix < 324) & (y >= 0) & (y < H) & (x >= 0) & (x < W);
            int cs = c8 ^ (col & 7);
            const short* src = ok
                ? &inb[((size_t)y * W + x) * 64 + (cs << 3)]
                : (const short*)zp;
            bf16x8_t v = *(const bf16x8_t*)src;
            int cs8 = cs << 3;
            bf16x8_t o;
#pragma unroll
            for (int j = 0; j < 8; ++j) {
                float f = (bf16_to_f((unsigned short)v[j]) - sm[cs8 + j]) * sr[cs8 + j];
                f = f > 0.f ? f : 0.f;
                o[j] = ok ? f_to_bf16(f) : (short)0;
            }
            *(bf16x8_t*)&tile[item * 8] = o;
        }
    }
    __syncthreads();

    const int wv  = tid >> 6;
    const int l   = tid & 63;
    const int l15 = l & 15;
    const int lg  = l >> 4;

    f32x4_t acc[4][4];
#pragma unroll
    for (int i = 0; i < 4; ++i)
#pragma unroll
        for (int j = 0; j < 4; ++j)
            acc[i][j] = (f32x4_t){0.f, 0.f, 0.f, 0.f};

    bf16x8_t bfp[2][4], afp[2][4];
#pragma unroll
    for (int nf = 0; nf < 4; ++nf)
        bfp[0][nf] = *(const bf16x8_t*)(wt + (((size_t)(0 * 4 + nf)) * 64 + l) * 8);
    {
        int colr = l15;
        int chunk = lg ^ (colr & 7);
#pragma unroll
        for (int mf = 0; mf < 4; ++mf)
            afp[0][mf] = *(const bf16x8_t*)&tile[((wv * 4 + mf) * 18 + colr) * 64 + chunk * 8];
    }
#pragma unroll
    for (int kc = 0; kc < 18; ++kc) {
        const int cur = kc & 1, nxt = cur ^ 1;
        if (kc + 1 < 18) {
            int kn = kc + 1;
#pragma unroll
            for (int nf = 0; nf < 4; ++nf)
                bfp[nxt][nf] = *(const bf16x8_t*)(wt + (((size_t)(kn * 4 + nf)) * 64 + l) * 8);
            int tap = kn >> 1;
            int dy = tap / 3, dx = tap % 3;
            int colr = l15 + dx;
            int chunk = (((kn & 1) << 2) + lg) ^ (colr & 7);
#pragma unroll
            for (int mf = 0; mf < 4; ++mf)
                afp[nxt][mf] = *(const bf16x8_t*)&tile[((wv * 4 + mf + dy) * 18 + colr) * 64 + chunk * 8];
        }
#pragma unroll
        for (int mf = 0; mf < 4; ++mf)
#pragma unroll
            for (int nf = 0; nf < 4; ++nf)
                acc[mf][nf] = __builtin_amdgcn_mfma_f32_16x16x32_bf16(
                    afp[cur][mf], bfp[cur][nf], acc[mf][nf], 0, 0, 0);
    }

    __syncthreads();
#pragma unroll
    for (int mf = 0; mf < 4; ++mf) {
        int py = wv * 4 + mf;
#pragma unroll
        for (int nf = 0; nf < 4; ++nf) {
            int oc = nf * 16 + l15;
#pragma unroll
            for (int k = 0; k < 4; ++k)
                tile[((py * 16) + lg * 4 + k) * 64 + oc] = f_to_bf16(acc[mf][nf][k]);
        }
    }
    __syncthreads();
    short* outb = outh + (size_t)b * HW * 64;
#pragma unroll
    for (int j = 0; j < 8; ++j) {
        int item = j * 256 + tid;
        int c8  = item & 7;
        int pix = item >> 3;
        int py  = pix >> 4, px = pix & 15;
        *(bf16x8_t*)&outb[((size_t)(y0 + py) * W + x0 + px) * 64 + c8 * 8] =
            *(bf16x8_t*)&tile[pix * 64 + c8 * 8];
    }

#pragma unroll
    for (int nf = 0; nf < 4; ++nf) {
        float s = 0.f, s2 = 0.f;
#pragma unroll
        for (int mf = 0; mf < 4; ++mf)
#pragma unroll
            for (int k = 0; k < 4; ++k) {
                float v = acc[mf][nf][k];
                s += v; s2 += v * v;
            }
        s  += __shfl_xor(s, 16, 64);  s  += __shfl_xor(s, 32, 64);
        s2 += __shfl_xor(s2, 16, 64); s2 += __shfl_xor(s2, 32, 64);
        if (lg == 0) {
            int oc = nf * 16 + l15;
            atomicAdd(&sstat[oc], s);
            atomicAdd(&sstat[64 + oc], s2);
        }
    }
    __syncthreads();
    float* st = stats + (size_t)(blockIdx.x & 7) * 128;
    if (tid < 128) atomicAdd(&st[tid], sstat[tid]);
}

// ------------------------------------------------- BN apply dual
__global__ void bn_apply_dual_kernel(const short* __restrict__ in,
                                     const float* __restrict__ stats,
                                     float* __restrict__ out,
                                     short* __restrict__ outh,
                                     int HW, float invN)
{
    __shared__ float ftile[64][65];
    __shared__ float sm[64], sr[64];
    int nchunks = HW >> 6;
    int b  = blockIdx.x / nchunks;
    int p0 = (blockIdx.x % nchunks) << 6;
    int tid = threadIdx.x;
    if (tid < 64) {
        float s = 0.f, s2 = 0.f;
#pragma unroll
        for (int k = 0; k < 8; ++k) {
            s  += stats[k * 128 + tid];
            s2 += stats[k * 128 + 64 + tid];
        }
        float mean = s * invN;
        float var  = s2 * invN - mean * mean;
        sm[tid] = mean;
        sr[tid] = rsqrtf(var + 1e-5f);
    }
    __syncthreads();
#pragma unroll
    for (int it = 0; it < 2; ++it) {
        int item = it * 256 + tid;
        int p = item >> 3, c0 = (item & 7) * 8;
        size_t gi = ((size_t)(b * HW + p0 + p)) * 64 + c0;
        bf16x8_t v = *(const bf16x8_t*)&in[gi];
        bf16x8_t o;
#pragma unroll
        for (int j = 0; j < 8; ++j) {
            float f = (bf16_to_f((unsigned short)v[j]) - sm[c0 + j]) * sr[c0 + j];
            f = f > 0.f ? f : 0.f;
            ftile[p][c0 + j] = f;
            o[j] = f_to_bf16(f);
        }
        *(bf16x8_t*)&outh[gi] = o;
    }
    __syncthreads();
#pragma unroll
    for (int rep = 0; rep < 16; ++rep) {
        int item = rep * 256 + tid;
        int c = item >> 6, p = item & 63;
        out[((size_t)b * 64 + c) * HW + p0 + p] = ftile[p][c];
    }
}

// ------------------------------------------------- offset2/3: MFMA conv, N=18
__global__ __launch_bounds__(256, 1) void offconv_mfma_kernel(
    const short* __restrict__ xh,
    const short* __restrict__ wt,
    const float* __restrict__ bias,
    float* __restrict__ out,
    int H, int W, int Ho, int Wo)
{
    const int HW = Ho * Wo;
    const int tid = threadIdx.x;
    const int wv = tid >> 6, l = tid & 63;
    const int l15 = l & 15, lg = l >> 4;
    const int pix0 = blockIdx.x * 64 + wv * 16;
    const int b = pix0 / HW;
    const int r0 = pix0 - b * HW;

    int rp = r0 + l15;
    int ho = rp / Wo, wo = rp % Wo;
    const short* xb = xh + (size_t)b * H * W * 64;

    f32x4_t acc[2];
    acc[0] = (f32x4_t){0.f, 0.f, 0.f, 0.f};
    acc[1] = (f32x4_t){0.f, 0.f, 0.f, 0.f};

#pragma unroll 2
    for (int kc = 0; kc < 18; ++kc) {
        int tap = kc >> 1;
        int iy = ho * 2 - 1 + tap / 3;
        int ix = wo * 2 - 1 + tap % 3;
        bf16x8_t af = {};
        if (iy >= 0 && iy < H && ix >= 0 && ix < W)
            af = *(const bf16x8_t*)&xb[((size_t)iy * W + ix) * 64
                                       + (kc & 1) * 32 + lg * 8];
#pragma unroll
        for (int nf = 0; nf < 2; ++nf) {
            bf16x8_t bf = *(const bf16x8_t*)(wt + (((size_t)(kc * 2 + nf)) * 64 + l) * 8);
            acc[nf] = __builtin_amdgcn_mfma_f32_16x16x32_bf16(af, bf, acc[nf], 0, 0, 0);
        }
    }

#pragma unroll
    for (int nf = 0; nf < 2; ++nf) {
        int oc = nf * 16 + l15;
        if (oc < 18) {
            float bv = bias[oc];
            f32x4_t v = acc[nf];
            v[0] += bv; v[1] += bv; v[2] += bv; v[3] += bv;
            *(f32x4_t*)&out[((size_t)(b * 18 + oc)) * HW + r0 + lg * 4] = v;
        }
    }
}

// ------------------------------------------------- deform1: fused offset1 +
// deform (C=3, MFMA MAC) + skip; x4 is bf16 NHWC4
__global__ __launch_bounds__(256, 1) void deform1_kernel(
    const unsigned short* __restrict__ x4,   // [B][640][640][4] bf16
    const float* __restrict__ wof,
    const float* __restrict__ bof,
    const short* __restrict__ wtd1,
    const float* __restrict__ bias,
    const float* __restrict__ pool,
    const float* __restrict__ wsk,
    const float* __restrict__ bsk,
    short* __restrict__ outh)
{
    const int H = 640, W = 640, Ho = 160, Wo = 160, HW = 25600;
    constexpr int P = 32;
    __shared__ float xtap[P * 9][4];
    __shared__ float swof[486];
    __shared__ float sbof[18];
    __shared__ float spool[3][P];
    __shared__ float off1[P][18];
    __shared__ alignas(16) short sampb[P][40];
    __shared__ int   sidx[P * 9][4];
    __shared__ float swt[P * 9][4];
    const int tid = threadIdx.x;
    const int pix0 = blockIdx.x * P;
    const int b = pix0 / HW;
    const int r0 = pix0 - b * HW;
    const unsigned short* xb = x4 + (size_t)b * H * W * 4;

    for (int item = tid; item < P * 9; item += TPB) {
        int p = item / 9, tap = item % 9;
        int r = r0 + p, ho = r / Wo, wo = r % Wo;
        int iy = ho * 4 - 1 + tap / 3;
        int ix = wo * 4 - 1 + tap % 3;
        f32x4_t s = (f32x4_t){0.f, 0.f, 0.f, 0.f};
        if (iy >= 0 && iy < H && ix >= 0 && ix < W) {
            u16x4_t u = *(const u16x4_t*)&xb[((size_t)iy * W + ix) * 4];
            s[0] = bf16_to_f(u[0]);
            s[1] = bf16_to_f(u[1]);
            s[2] = bf16_to_f(u[2]);
        }
        *(f32x4_t*)xtap[item] = s;
    }
    for (int i = tid; i < P * 40; i += TPB) ((short*)sampb)[i] = 0;
    for (int i = tid; i < 96; i += TPB) {
        int c = i >> 5, p = i & 31;
        spool[c][p] = pool[((size_t)(b * 3 + c)) * HW + r0 + p];
    }
    for (int item = tid; item < 486; item += TPB) swof[item] = wof[item];
    if (tid < 18) sbof[tid] = bof[tid];
    __syncthreads();

    for (int item = tid; item < P * 18; item += TPB) {
        int p = item / 18, o = item % 18;
        float acc = sbof[o];
#pragma unroll
        for (int tap = 0; tap < 9; ++tap) {
            const float* xt = xtap[p * 9 + tap];
#pragma unroll
            for (int c = 0; c < 3; ++c)
                acc += xt[c] * swof[(o * 3 + c) * 9 + tap];
        }
        off1[p][o] = acc;
    }
    __syncthreads();

    for (int item = tid; item < P * 9; item += TPB) {
        int p = item / 9, tap = item % 9;
        int r = r0 + p, ho = r / Wo, wo = r % Wo;
        float dy = off1[p][2 * tap];
        float dx = off1[p][2 * tap + 1];
        float ys = (float)(ho * 4 - 1 + tap / 3) + dy;
        float xs = (float)(wo * 4 - 1 + tap % 3) + dx;
        float y0f = floorf(ys), x0f = floorf(xs);
        float fy = ys - y0f, fx = xs - x0f;
        int y0 = (int)y0f, x0 = (int)x0f;
        float wts[4] = {(1.f - fy) * (1.f - fx), (1.f - fy) * fx,
                        fy * (1.f - fx),          fy * fx};
#pragma unroll
        for (int j = 0; j < 4; ++j) {
            int iy = y0 + (j >> 1), ix = x0 + (j & 1);
            bool v = (iy >= 0) && (iy < H) && (ix >= 0) && (ix < W);
            sidx[item][j] = v ? (iy * W + ix) : 0;
            swt[item][j]  = v ? wts[j] : 0.f;
        }
    }
    __syncthreads();

    for (int item = tid; item < P * 9; item += TPB) {
        int p = item / 9, tap = item % 9;
        i32x4_t id4 = *(const i32x4_t*)sidx[item];
        f32x4_t w4  = *(const f32x4_t*)swt[item];
        u16x4_t a0 = *(const u16x4_t*)&xb[(size_t)(unsigned)id4[0] * 4];
        u16x4_t a1 = *(const u16x4_t*)&xb[(size_t)(unsigned)id4[1] * 4];
        u16x4_t a2 = *(const u16x4_t*)&xb[(size_t)(unsigned)id4[2] * 4];
        u16x4_t a3 = *(const u16x4_t*)&xb[(size_t)(unsigned)id4[3] * 4];
        sampb[p][0 * 9 + tap] = f_to_bf16(
            w4[0]*bf16_to_f(a0[0]) + w4[1]*bf16_to_f(a1[0])
          + w4[2]*bf16_to_f(a2[0]) + w4[3]*bf16_to_f(a3[0]));
        sampb[p][1 * 9 + tap] = f_to_bf16(
            w4[0]*bf16_to_f(a0[1]) + w4[1]*bf16_to_f(a1[1])
          + w4[2]*bf16_to_f(a2[1]) + w4[3]*bf16_to_f(a3[1]));
        sampb[p][2 * 9 + tap] = f_to_bf16(
            w4[0]*bf16_to_f(a0[2]) + w4[1]*bf16_to_f(a1[2])
          + w4[2]*bf16_to_f(a2[2]) + w4[3]*bf16_to_f(a3[2]));
    }
    __syncthreads();

    const int wv = tid >> 6;
    const int l  = tid & 63;
    const int l15 = l & 15, lg = l >> 4;
    bf16x8_t bf  = *(const bf16x8_t*)(wtd1 + (((size_t)wv * 64 + l)) * 8);
    bf16x8_t af0 = *(const bf16x8_t*)&sampb[l15][lg * 8];
    bf16x8_t af1 = *(const bf16x8_t*)&sampb[l15 + 16][lg * 8];
    f32x4_t z = (f32x4_t){0.f, 0.f, 0.f, 0.f};
    f32x4_t acc0 = __builtin_amdgcn_mfma_f32_16x16x32_bf16(af0, bf, z, 0, 0, 0);
    f32x4_t acc1 = __builtin_amdgcn_mfma_f32_16x16x32_bf16(af1, bf, z, 0, 0, 0);

    int oc = wv * 16 + l15;
    float bb = bias[oc] + bsk[oc];
    float w0 = wsk[oc * 3 + 0], w1 = wsk[oc * 3 + 1], w2 = wsk[oc * 3 + 2];
    short* otile = (short*)xtap;
    __syncthreads();
#pragma unroll
    for (int mf = 0; mf < 2; ++mf) {
        f32x4_t a = mf ? acc1 : acc0;
#pragma unroll
        for (int k = 0; k < 4; ++k) {
            int px = mf * 16 + lg * 4 + k;
            float sv = w0 * spool[0][px] + w1 * spool[1][px] + w2 * spool[2][px];
            otile[px * 64 + oc] = f_to_bf16(a[k] + bb + sv);
        }
    }
    __syncthreads();
    {
        int c8 = tid & 7, px = tid >> 3;
        *(bf16x8_t*)&outh[((size_t)(b * HW + r0 + px)) * 64 + c8 * 8] =
            *(bf16x8_t*)&otile[px * 64 + c8 * 8];
    }
}

// ------------------------------------------------- deform MFMA: C=64 -> O
template <int O, int DUAL>
__global__ __launch_bounds__(256, 1) void deform_mfma_kernel(
    const short* __restrict__ xh,
    const float* __restrict__ off,
    const short* __restrict__ wt,
    const float* __restrict__ bias,
    float* __restrict__ out,
    short* __restrict__ outh,
    int H, int W, int Ho, int Wo, int stride)
{
    constexpr int NF = O / 64;
    constexpr int NFRAG = O / 16;
    constexpr int P  = 32;
    __shared__ alignas(16) short samp[P * 576];
    __shared__ int   sidx[P * 9][4];
    __shared__ float swt[P * 9][4];

    const int tid = threadIdx.x;
    const int HW = Ho * Wo;
    const int pix0 = blockIdx.x * P;
    const int b = pix0 / HW;
    const int r0 = pix0 - b * HW;

    for (int item = tid; item < P * 9; item += TPB) {
        int p = item / 9, tap = item % 9;
        int r = r0 + p, ho = r / Wo, wo = r % Wo;
        float dy = off[((size_t)(b * 18 + 2 * tap) * Ho + ho) * Wo + wo];
        float dx = off[((size_t)(b * 18 + 2 * tap + 1) * Ho + ho) * Wo + wo];
        float ys = (float)(ho * stride - 1 + tap / 3) + dy;
        float xs = (float)(wo * stride - 1 + tap % 3) + dx;
        float y0f = floorf(ys), x0f = floorf(xs);
        float fy = ys - y0f, fx = xs - x0f;
        int y0 = (int)y0f, x0 = (int)x0f;
        float wts[4] = {(1.f - fy) * (1.f - fx), (1.f - fy) * fx,
                        fy * (1.f - fx),          fy * fx};
#pragma unroll
        for (int j = 0; j < 4; ++j) {
            int iy = y0 + (j >> 1), ix = x0 + (j & 1);
            bool v = (iy >= 0) && (iy < H) && (ix >= 0) && (ix < W);
            sidx[item][j] = v ? (iy * W + ix) : 0;
            swt[item][j]  = v ? wts[j] : 0.f;
        }
    }
    __syncthreads();

    {
        const int p  = tid >> 3;
        const int ic = (tid & 7) * 8;
        const int swc = (ic >> 3) ^ (p & 7);
        const short* xb = xh + (size_t)b * H * W * 64;
#pragma unroll 3
        for (int tap = 0; tap < 9; ++tap) {
            int e = p * 9 + tap;
            i32x4_t id4 = *(const i32x4_t*)sidx[e];
            f32x4_t w4  = *(const f32x4_t*)swt[e];
            u16x8_t u0 = *(const u16x8_t*)&xb[(size_t)(unsigned)id4[0] * 64 + ic];
            u16x8_t u1 = *(const u16x8_t*)&xb[(size_t)(unsigned)id4[1] * 64 + ic];
            u16x8_t u2 = *(const u16x8_t*)&xb[(size_t)(unsigned)id4[2] * 64 + ic];
            u16x8_t u3 = *(const u16x8_t*)&xb[(size_t)(unsigned)id4[3] * 64 + ic];
            bf16x8_t o;
#pragma unroll
            for (int j = 0; j < 8; ++j) {
                float v = w4[0]*bf16_to_f(u0[j]) + w4[1]*bf16_to_f(u1[j])
                        + w4[2]*bf16_to_f(u2[j]) + w4[3]*bf16_to_f(u3[j]);
                o[j] = f_to_bf16(v);
            }
            *(bf16x8_t*)&samp[p * 576 + (tap * 8 + swc) * 8] = o;
        }
    }
    __syncthreads();

    const int wv = tid >> 6;
    const int l  = tid & 63;
    const int l15 = l & 15, lg = l >> 4;
    f32x4_t acc[2][NF];
#pragma unroll
    for (int mf = 0; mf < 2; ++mf)
#pragma unroll
        for (int nf = 0; nf < NF; ++nf)
            acc[mf][nf] = (f32x4_t){0.f, 0.f, 0.f, 0.f};

#pragma unroll 2
    for (int kc = 0; kc < 18; ++kc) {
        int tap = kc >> 1;
        int low = (((kc & 1) << 2) | lg) ^ (l15 & 7);
        bf16x8_t af0 = *(const bf16x8_t*)&samp[l15 * 576 + (tap * 8 + low) * 8];
        bf16x8_t af1 = *(const bf16x8_t*)&samp[(l15 + 16) * 576 + (tap * 8 + low) * 8];
#pragma unroll
        for (int nf = 0; nf < NF; ++nf) {
            int ocf = wv * NF + nf;
            bf16x8_t bf = *(const bf16x8_t*)(wt + (((size_t)(kc * NFRAG + ocf)) * 64 + l) * 8);
            acc[0][nf] = __builtin_amdgcn_mfma_f32_16x16x32_bf16(af0, bf, acc[0][nf], 0, 0, 0);
            acc[1][nf] = __builtin_amdgcn_mfma_f32_16x16x32_bf16(af1, bf, acc[1][nf], 0, 0, 0);
        }
    }

#pragma unroll
    for (int mf = 0; mf < 2; ++mf)
#pragma unroll
        for (int nf = 0; nf < NF; ++nf) {
            int oc = (wv * NF + nf) * 16 + l15;
            float bv = bias[oc];
            f32x4_t v = acc[mf][nf];
            v[0] += bv; v[1] += bv; v[2] += bv; v[3] += bv;
            acc[mf][nf] = v;
            *(f32x4_t*)&out[((size_t)(b * O + oc)) * HW + r0 + mf * 16 + lg * 4] = v;
        }

    if (DUAL) {
        __syncthreads();
        short* otile = samp;
#pragma unroll
        for (int mf = 0; mf < 2; ++mf) {
            int oc = wv * 16 + l15;
#pragma unroll
            for (int k = 0; k < 4; ++k) {
                int px = mf * 16 + lg * 4 + k;
                otile[px * 64 + oc] = f_to_bf16(acc[mf][0][k]);
            }
        }
        __syncthreads();
        int c8 = tid & 7, px = tid >> 3;
        *(bf16x8_t*)&outh[((size_t)(b * HW + r0 + px)) * 64 + c8 * 8] =
            *(bf16x8_t*)&otile[px * 64 + c8 * 8];
    }
}

// ---------------------------------------------------------------- launch
extern "C" void kernel_launch(void* const* d_in, const int* in_sizes, int n_in,
                              void* d_out, int out_size, void* d_ws, size_t ws_size,
                              hipStream_t stream)
{
    const float* x      = (const float*)d_in[0];
    const float* w_off1 = (const float*)d_in[1];
    const float* b_off1 = (const float*)d_in[2];
    const float* w_d1   = (const float*)d_in[3];
    const float* b_d1   = (const float*)d_in[4];
    const float* w_skip = (const float*)d_in[5];
    const float* b_skip = (const float*)d_in[6];
    const float* w_bl1  = (const float*)d_in[7];
    const float* w_bl2  = (const float*)d_in[8];
    const float* w_off2 = (const float*)d_in[9];
    const float* b_off2 = (const float*)d_in[10];
    const float* w_d2   = (const float*)d_in[11];
    const float* b_d2   = (const float*)d_in[12];
    const float* w_off3 = (const float*)d_in[13];
    const float* b_off3 = (const float*)d_in[14];
    const float* w_d3   = (const float*)d_in[15];
    const float* b_d3   = (const float*)d_in[16];

    const int B = 8;
    float* A     = (float*)d_ws;
    float* bufB  = A + 3686400;
    float* bufC  = bufB + 13107200;

    short* hB   = (short*)bufB;
    short* hC   = (short*)bufC;
    float* pool = bufB + 8000000;

    short* wt1    = (short*)(A + 1000000);
    short* wt2    = wt1 + 18 * 4 * 512;
    short* wtd2   = (short*)(A + 1500000);
    short* wtd3   = (short*)(A + 1550000);
    short* wtoff2 = (short*)(A + 1700000);
    short* wtoff3 = (short*)(A + 1712000);
    short* wtd1   = (short*)(A + 1750000);
    float* stats1 = A + 1800000;
    float* stats2 = stats1 + 1024;
    float* zpage  = stats1 + 2048;

    float* out0 = (float*)d_out;
    float* out1 = out0 + 13107200;
    float* out2 = out1 + 3276800;

    const float invN = 1.0f / (B * 25600);

    // 0) prep: x -> x4 bf16 NHWC4 (bufC) + pool
    prep_kernel<<<(8 * 25600 + TPB - 1) / TPB, TPB, 0, stream>>>(
        x, (unsigned short*)bufC, pool);

    repack_all_kernel<<<(299520 + TPB - 1) / TPB, TPB, 0, stream>>>(
        w_bl1, wt1, w_bl2, wt2, w_d2, wtd2, w_d3, wtd3,
        w_off2, wtoff2, w_off3, wtoff3, w_d1, wtd1, stats1);

    deform1_kernel<<<8 * 25600 / 32, TPB, 0, stream>>>(
        (const unsigned short*)bufC, w_off1, b_off1, wtd1, b_d1,
        pool, w_skip, b_skip, hB);

    conv3x3_mfma_kernel<0><<<800, TPB, 0, stream>>>(
        hB, wt1, hC, stats1, nullptr, invN, zpage);

    conv3x3_mfma_kernel<1><<<800, TPB, 0, stream>>>(
        hC, wt2, hB, stats2, stats1, invN, zpage);

    bn_apply_dual_kernel<<<8 * 400, TPB, 0, stream>>>(
        hB, stats2, out0, hC, 25600, invN);

    offconv_mfma_kernel<<<8 * 6400 / 64, TPB, 0, stream>>>(
        hC, wtoff2, b_off2, A, 160, 160, 80, 80);

    deform_mfma_kernel<64, 1><<<8 * 6400 / 32, TPB, 0, stream>>>(
        hC, A, wtd2, b_d2, out1, hB, 160, 160, 80, 80, 2);

    offconv_mfma_kernel<<<8 * 1600 / 64, TPB, 0, stream>>>(
        hB, wtoff3, b_off3, A, 80, 80, 40, 40);

    deform_mfma_kernel<256, 0><<<8 * 1600 / 32, TPB, 0, stream>>>(
        hB, A, wtd3, b_d3, out2, nullptr, 80, 80, 40, 40, 2);
}